// Round 1
// baseline (3054.330 us; speedup 1.0000x reference)
//
#include <hip/hip_runtime.h>
#include <math.h>

// ---------------------------------------------------------------------------
// DAttention forward, fp32 correctness-first implementation.
// Dims: B=4, C=512, H=W=32, G=2, gc=256, BG=8, heads=8, hc=64, mh=8, mhd=32,
//       hid=1024, N=HW=1024, ns=1024.
// ---------------------------------------------------------------------------

static constexpr int HW = 1024;

// workspace offsets (floats)
static constexpr size_t OFF_FEAT  = 0;          // [4,512,1024]
static constexpr size_t OFF_Q     = 2097152;    // [4,512,1024]
static constexpr size_t OFF_X     = 4194304;    // [8192,256] token-major residual
static constexpr size_t OFF_H     = 6291456;    // h (ln out); later o_tm (attn out)
static constexpr size_t OFF_QQ    = 8388608;    // qq; later h2
static constexpr size_t OFF_KV    = 10485760;   // [8192,512]
static constexpr size_t OFF_M     = 14680064;   // 8,388,608: mb pacc; later m_cm; later sampled/k/v/attno
static constexpr size_t OFF_MI    = 23068672;   // 8,388,608: mb pden; later mi_cm; later main pacc
static constexpr size_t OFF_OFFIN = 31457280;   // [8,256,1024] final x channel-major
static constexpr size_t OFF_OFFDW = 33554432;   // dw9 out; later main pden
static constexpr size_t OFF_POS   = 35651584;   // [8,1024,2] (x,y) sample coords

__device__ __forceinline__ float gelu_exact(float v) {
  return 0.5f * v * (1.0f + erff(v * 0.7071067811865475f));
}

// ---------------- emb conv 3x3: cat(tgt,ref) [4,1024,32,32] -> feat [4,512,32,32]
__global__ void k_emb(const float* __restrict__ tgt, const float* __restrict__ refp,
                      const float* __restrict__ w, const float* __restrict__ bias,
                      float* __restrict__ feat) {
  int bid = blockIdx.x;
  int ych = bid & 3; bid >>= 2;
  int og  = bid & 63; bid >>= 6;
  int b   = bid;
  int x = threadIdx.x & 31;
  int y = ych * 8 + (threadIdx.x >> 5);
  int o0 = og * 8;
  float acc[8];
#pragma unroll
  for (int i = 0; i < 8; ++i) acc[i] = bias[o0 + i];
  const float* wbase = w + (size_t)o0 * 9216;
  for (int half = 0; half < 2; ++half) {
    const float* src0 = (half ? refp : tgt) + (size_t)b * 512 * HW;
    const float* wh = wbase + half * 512 * 9;
    for (int ci = 0; ci < 512; ++ci) {
      const float* src = src0 + ci * HW;
      const float* wr = wh + ci * 9;
#pragma unroll
      for (int ky = 0; ky < 3; ++ky) {
        int yy = y + ky - 1;
        if ((unsigned)yy < 32u) {
          const float* row = src + yy * 32;
          float r0 = (x >= 1) ? row[x - 1] : 0.f;
          float r1 = row[x];
          float r2 = (x <= 30) ? row[x + 1] : 0.f;
#pragma unroll
          for (int oo = 0; oo < 8; ++oo) {
            const float* wo = wr + oo * 9216 + ky * 3;
            acc[oo] += r0 * wo[0] + r1 * wo[1] + r2 * wo[2];
          }
        }
      }
    }
  }
#pragma unroll
  for (int oo = 0; oo < 8; ++oo)
    feat[(size_t)(b * 512 + o0 + oo) * HW + y * 32 + x] = acc[oo];
}

// ---------------- channel-major GEMM: Y[b,o,n] = sum_c X[b,c,n] W[o,c] + bias[o]
// K=512, O=512, N=1024, BATCH=4.  grid = 4*64*4, block 256
__global__ void k_gemm_cm(const float* __restrict__ X, const float* __restrict__ Wm,
                          const float* __restrict__ bias, float* __restrict__ Y) {
  int bid = blockIdx.x;
  int nch = bid & 3; bid >>= 2;
  int og  = bid & 63; bid >>= 6;
  int b   = bid;
  int n = nch * 256 + threadIdx.x;
  int o0 = og * 8;
  float acc[8];
#pragma unroll
  for (int i = 0; i < 8; ++i) acc[i] = bias[o0 + i];
  const float* xp = X + (size_t)b * 512 * HW + n;
  for (int c = 0; c < 512; ++c) {
    float v = xp[c * HW];
#pragma unroll
    for (int oo = 0; oo < 8; ++oo) acc[oo] += v * Wm[(o0 + oo) * 512 + c];
  }
#pragma unroll
  for (int oo = 0; oo < 8; ++oo)
    Y[(size_t)(b * 512 + o0 + oo) * HW + n] = acc[oo];
}

// ---------------- ln1: feat channel-major -> x token-major, LN over 256, eps 1e-5
__global__ void k_ln1(const float* __restrict__ feat, const float* __restrict__ g_,
                      const float* __restrict__ b_, float* __restrict__ xo) {
  int t = blockIdx.x * 256 + threadIdx.x;   // 8192 tokens
  int bg = t >> 10, n = t & 1023;
  const float* src = feat + (size_t)bg * 256 * HW + n;  // (b*512+g*256)=bg*256
  float s = 0.f, s2 = 0.f;
  for (int d = 0; d < 256; ++d) { float v = src[d * HW]; s += v; s2 += v * v; }
  float mean = s * (1.f / 256.f);
  float rstd = rsqrtf(s2 * (1.f / 256.f) - mean * mean + 1e-5f);
  float* dst = xo + (size_t)t * 256;
  for (int d = 0; d < 256; ++d) {
    float v = src[d * HW];
    dst[d] = (v - mean) * rstd * g_[d] + b_[d];
  }
}

// ---------------- token-major LN (wave per token): in/out [T,256]
__global__ void k_ln_tok(const float* __restrict__ xin, const float* __restrict__ g_,
                         const float* __restrict__ b_, float* __restrict__ yo, float eps) {
  int token = (blockIdx.x * 256 + threadIdx.x) >> 6;
  int lane = threadIdx.x & 63;
  float4 v4 = *reinterpret_cast<const float4*>(xin + (size_t)token * 256 + lane * 4);
  float s  = v4.x + v4.y + v4.z + v4.w;
  float s2 = v4.x * v4.x + v4.y * v4.y + v4.z * v4.z + v4.w * v4.w;
#pragma unroll
  for (int off = 32; off; off >>= 1) { s += __shfl_xor(s, off); s2 += __shfl_xor(s2, off); }
  float mean = s * (1.f / 256.f);
  float rstd = rsqrtf(s2 * (1.f / 256.f) - mean * mean + eps);
  float4 g4 = *reinterpret_cast<const float4*>(g_ + lane * 4);
  float4 b4 = *reinterpret_cast<const float4*>(b_ + lane * 4);
  float4 o;
  o.x = (v4.x - mean) * rstd * g4.x + b4.x;
  o.y = (v4.y - mean) * rstd * g4.y + b4.y;
  o.z = (v4.z - mean) * rstd * g4.z + b4.z;
  o.w = (v4.w - mean) * rstd * g4.w + b4.w;
  *reinterpret_cast<float4*>(yo + (size_t)token * 256 + lane * 4) = o;
}

// ---------------- token-major GEMM: Y[t,o] (+=) sum_d A[t,d] W[o,d] + b[o]; K=256
__global__ void k_gemm_tm(const float* __restrict__ A, const float* __restrict__ Wm,
                          const float* __restrict__ bias, float* __restrict__ Y,
                          int O, int addres) {
  int ognum = O >> 3;
  int og = blockIdx.x % ognum;
  int tb = blockIdx.x / ognum;
  int t = tb * 256 + threadIdx.x;
  int o0 = og * 8;
  const float4* a4p = reinterpret_cast<const float4*>(A + (size_t)t * 256);
  float acc[8];
#pragma unroll
  for (int i = 0; i < 8; ++i) acc[i] = bias[o0 + i];
  for (int d4 = 0; d4 < 64; ++d4) {
    float4 a4 = a4p[d4];
#pragma unroll
    for (int oo = 0; oo < 8; ++oo) {
      const float* wr = Wm + (o0 + oo) * 256 + d4 * 4;
      acc[oo] += a4.x * wr[0] + a4.y * wr[1] + a4.z * wr[2] + a4.w * wr[3];
    }
  }
  float* y = Y + (size_t)t * O + o0;
  if (addres) {
#pragma unroll
    for (int oo = 0; oo < 8; ++oo) y[oo] += acc[oo];
  } else {
#pragma unroll
    for (int oo = 0; oo < 8; ++oo) y[oo] = acc[oo];
  }
}

// ---------------- MitBlock attention (fused, key-split S=4, partials out)
// qq [8192,256] tm, kv [8192,512] tm (first 256 = K, last 256 = V)
__global__ void k_mbattn(const float* __restrict__ qq, const float* __restrict__ kv,
                         float* __restrict__ pacc, float* __restrict__ pden) {
  int bid = blockIdx.x;               // bg(8) x hh(8) x mch(4) x sl(4) = 1024
  int sl = bid & 3; bid >>= 2;
  int mch = bid & 3; bid >>= 2;
  int hh = bid & 7; bid >>= 3;
  int bg = bid;
  int tid = threadIdx.x;
  int m = mch * 256 + tid;
  __shared__ float K_s[64][32];
  __shared__ float V_s[64][32];
  float qv[32];
  {
    const float4* qp = reinterpret_cast<const float4*>(qq + (size_t)((bg << 10) + m) * 256 + hh * 32);
#pragma unroll
    for (int i = 0; i < 8; ++i) {
      float4 v = qp[i];
      qv[i * 4] = v.x; qv[i * 4 + 1] = v.y; qv[i * 4 + 2] = v.z; qv[i * 4 + 3] = v.w;
    }
  }
  float acc[32];
#pragma unroll
  for (int e = 0; e < 32; ++e) acc[e] = 0.f;
  float den = 0.f;
  const float scale = 0.17677669529663689f;  // 32^-0.5
  for (int n0 = sl * 256; n0 < sl * 256 + 256; n0 += 64) {
    __syncthreads();
#pragma unroll
    for (int p = 0; p < 2; ++p) {
      int idx4 = p * 256 + tid;        // 0..511 (64 keys x 8 float4)
      int key = idx4 >> 3;
      int e4  = idx4 & 7;
      const float* krow = kv + (size_t)((bg << 10) + n0 + key) * 512 + hh * 32;
      reinterpret_cast<float4*>(K_s[key])[e4] = reinterpret_cast<const float4*>(krow)[e4];
      reinterpret_cast<float4*>(V_s[key])[e4] = reinterpret_cast<const float4*>(krow + 256)[e4];
    }
    __syncthreads();
    for (int kk = 0; kk < 64; ++kk) {
      float s = 0.f;
      const float4* kr = reinterpret_cast<const float4*>(K_s[kk]);
#pragma unroll
      for (int i = 0; i < 8; ++i) {
        float4 k4 = kr[i];
        s += qv[i * 4] * k4.x + qv[i * 4 + 1] * k4.y + qv[i * 4 + 2] * k4.z + qv[i * 4 + 3] * k4.w;
      }
      float p = __expf(s * scale);
      den += p;
      const float4* vr = reinterpret_cast<const float4*>(V_s[kk]);
#pragma unroll
      for (int i = 0; i < 8; ++i) {
        float4 v4 = vr[i];
        acc[i * 4] += p * v4.x; acc[i * 4 + 1] += p * v4.y;
        acc[i * 4 + 2] += p * v4.z; acc[i * 4 + 3] += p * v4.w;
      }
    }
  }
  int qidx = ((bg << 3) + hh) * 1024 + m;   // 65536
  float* pa = pacc + (size_t)(sl * 65536 + qidx) * 32;
#pragma unroll
  for (int e = 0; e < 32; ++e) pa[e] = acc[e];
  pden[sl * 65536 + qidx] = den;
}

__global__ void k_mbmerge(const float* __restrict__ pacc, const float* __restrict__ pden,
                          float* __restrict__ o_tm) {
  int t = blockIdx.x * 256 + threadIdx.x;   // 65536
  int bg = t >> 13; int hh = (t >> 10) & 7; int m = t & 1023;
  float den = 0.f;
#pragma unroll
  for (int s = 0; s < 4; ++s) den += pden[s * 65536 + t];
  float inv = 1.f / den;
  float* dst = o_tm + (size_t)((bg << 10) + m) * 256 + hh * 32;
  for (int e = 0; e < 32; ++e) {
    float a = 0.f;
#pragma unroll
    for (int s = 0; s < 4; ++s) a += pacc[(size_t)(s * 65536 + t) * 32 + e];
    dst[e] = a * inv;
  }
}

// ---------------- fc1: token-major h2 [8192,256] -> channel-major m [8,1024,1024]
__global__ void k_fc1(const float* __restrict__ A, const float* __restrict__ Wm,
                      const float* __restrict__ bias, float* __restrict__ Y) {
  int bid = blockIdx.x;           // bg(8) x og(128) x nch(4) = 4096
  int nch = bid & 3; bid >>= 2;
  int og  = bid & 127; bid >>= 7;
  int bg  = bid;
  int n = nch * 256 + threadIdx.x;
  int t = (bg << 10) + n;
  const float4* a4p = reinterpret_cast<const float4*>(A + (size_t)t * 256);
  int o0 = og * 8;
  float acc[8];
#pragma unroll
  for (int i = 0; i < 8; ++i) acc[i] = bias[o0 + i];
  for (int d4 = 0; d4 < 64; ++d4) {
    float4 a4 = a4p[d4];
#pragma unroll
    for (int oo = 0; oo < 8; ++oo) {
      const float* wr = Wm + (o0 + oo) * 256 + d4 * 4;
      acc[oo] += a4.x * wr[0] + a4.y * wr[1] + a4.z * wr[2] + a4.w * wr[3];
    }
  }
#pragma unroll
  for (int oo = 0; oo < 8; ++oo)
    Y[(size_t)((bg << 10) + o0 + oo) * HW + n] = acc[oo];
}

// ---------------- depthwise 3x3 + bias + exact GELU, channel-major [8,1024,1024]
__global__ void k_dw3(const float* __restrict__ X, const float* __restrict__ w,
                      const float* __restrict__ bias, float* __restrict__ Y) {
  int idx = blockIdx.x * 256 + threadIdx.x;   // 8*1024*1024
  int x = idx & 31, y = (idx >> 5) & 31, ch = (idx >> 10) & 1023, bg = idx >> 20;
  const float* src = X + (size_t)((bg << 10) + ch) * HW;
  const float* wr = w + ch * 9;
  float acc = bias[ch];
#pragma unroll
  for (int ky = 0; ky < 3; ++ky) {
    int yy = y + ky - 1;
    if ((unsigned)yy < 32u) {
      const float* row = src + yy * 32;
#pragma unroll
      for (int kx = 0; kx < 3; ++kx) {
        int xx = x + kx - 1;
        if ((unsigned)xx < 32u) acc += row[xx] * wr[ky * 3 + kx];
      }
    }
  }
  Y[(size_t)((bg << 10) + ch) * HW + y * 32 + x] = gelu_exact(acc);
}

// ---------------- fc2 fused: Y_cm[bg,o,n] = Xres_tm[t,o] + b[o] + sum_h Mi[bg,h,n] W[o,h]
__global__ void k_fc2(const float* __restrict__ Mi, const float* __restrict__ Wm,
                      const float* __restrict__ bias, const float* __restrict__ Xres,
                      float* __restrict__ Y) {
  int bid = blockIdx.x;            // bg(8) x og(32) x nch(4) = 1024
  int nch = bid & 3; bid >>= 2;
  int og  = bid & 31; bid >>= 5;
  int bg  = bid;
  int n = nch * 256 + threadIdx.x;
  int o0 = og * 8;
  float acc[8];
#pragma unroll
  for (int i = 0; i < 8; ++i)
    acc[i] = bias[o0 + i] + Xres[(size_t)((bg << 10) + n) * 256 + o0 + i];
  const float* mp = Mi + (size_t)(bg << 10) * HW + n;
  for (int h = 0; h < 1024; ++h) {
    float v = mp[(size_t)h * HW];
#pragma unroll
    for (int oo = 0; oo < 8; ++oo) acc[oo] += v * Wm[(o0 + oo) * 1024 + h];
  }
#pragma unroll
  for (int oo = 0; oo < 8; ++oo)
    Y[(size_t)((bg << 8) + o0 + oo) * HW + n] = acc[oo];
}

// ---------------- depthwise 9x9 pad 4 + bias, channel-major [8,256,1024]
__global__ void k_dw9(const float* __restrict__ X, const float* __restrict__ w,
                      const float* __restrict__ bias, float* __restrict__ Y) {
  int idx = blockIdx.x * 256 + threadIdx.x;   // 8*256*1024
  int x = idx & 31, y = (idx >> 5) & 31, ch = (idx >> 10) & 255, bg = idx >> 18;
  const float* src = X + (size_t)((bg << 8) + ch) * HW;
  const float* wr = w + ch * 81;
  float acc = bias[ch];
  for (int ky = 0; ky < 9; ++ky) {
    int yy = y + ky - 4;
    if ((unsigned)yy < 32u) {
      const float* row = src + yy * 32;
#pragma unroll
      for (int kx = 0; kx < 9; ++kx) {
        int xx = x + kx - 4;
        if ((unsigned)xx < 32u) acc += row[xx] * wr[ky * 9 + kx];
      }
    }
  }
  Y[(size_t)((bg << 8) + ch) * HW + y * 32 + x] = acc;
}

// ---------------- co tail: LN(ch) + GELU + [2,256] proj + tanh -> sample coords (x,y)
__global__ void k_cotail(const float* __restrict__ Xdw, const float* __restrict__ lnw,
                         const float* __restrict__ lnb, const float* __restrict__ w2,
                         float* __restrict__ pos) {
  int t = blockIdx.x * 256 + threadIdx.x;   // 8192
  int bg = t >> 10, n = t & 1023;
  const float* src = Xdw + (size_t)(bg << 8) * HW + n;
  float s = 0.f, s2 = 0.f;
  for (int c = 0; c < 256; ++c) { float v = src[c * HW]; s += v; s2 += v * v; }
  float mean = s * (1.f / 256.f);
  float rstd = rsqrtf(s2 * (1.f / 256.f) - mean * mean + 1e-5f);
  float o0 = 0.f, o1 = 0.f;
  for (int c = 0; c < 256; ++c) {
    float v = (src[c * HW] - mean) * rstd * lnw[c] + lnb[c];
    float ge = gelu_exact(v);
    o0 += ge * w2[c];
    o1 += ge * w2[256 + c];
  }
  float offy = tanhf(o0) * (2.f / 32.f);
  float offx = tanhf(o1) * (2.f / 32.f);
  int ky = n >> 5, kx = n & 31;
  float refy = ((ky + 0.5f) * (1.f / 32.f)) * 2.f - 1.f;
  float refx = ((kx + 0.5f) * (1.f / 32.f)) * 2.f - 1.f;
  pos[t * 2]     = offx + refx;   // x
  pos[t * 2 + 1] = offy + refy;   // y
}

// ---------------- bilinear grid sample: feat [8,256,32,32] at pos -> sampled [8,256,1024]
__global__ void k_gsample(const float* __restrict__ feat, const float* __restrict__ pos,
                          float* __restrict__ out) {
  int bid = blockIdx.x;            // bg(8) x nch(4)
  int nch = bid & 3; int bg = bid >> 2;
  int j = nch * 256 + threadIdx.x;
  float gx = pos[((bg << 10) + j) * 2];
  float gy = pos[((bg << 10) + j) * 2 + 1];
  float fx = (gx + 1.f) * 0.5f * 31.f;
  float fy = (gy + 1.f) * 0.5f * 31.f;
  float x0f = floorf(fx), y0f = floorf(fy);
  int x0 = (int)x0f, y0 = (int)y0f;
  float wx1 = fx - x0f, wx0 = 1.f - wx1;
  float wy1 = fy - y0f, wy0 = 1.f - wy1;
  bool vx0 = (x0 >= 0) & (x0 <= 31);
  bool vx1 = (x0 + 1 >= 0) & (x0 + 1 <= 31);
  bool vy0 = (y0 >= 0) & (y0 <= 31);
  bool vy1 = (y0 + 1 >= 0) & (y0 + 1 <= 31);
  int cx0 = min(max(x0, 0), 31), cx1 = min(max(x0 + 1, 0), 31);
  int cy0 = min(max(y0, 0), 31), cy1 = min(max(y0 + 1, 0), 31);
  float w00 = wx0 * wy0 * ((vx0 && vy0) ? 1.f : 0.f);
  float w10 = wx1 * wy0 * ((vx1 && vy0) ? 1.f : 0.f);
  float w01 = wx0 * wy1 * ((vx0 && vy1) ? 1.f : 0.f);
  float w11 = wx1 * wy1 * ((vx1 && vy1) ? 1.f : 0.f);
  int i00 = cy0 * 32 + cx0, i10 = cy0 * 32 + cx1;
  int i01 = cy1 * 32 + cx0, i11 = cy1 * 32 + cx1;
  const float* src = feat + (size_t)(bg << 8) * HW;
  float* dst = out + (size_t)(bg << 8) * HW + j;
  for (int c = 0; c < 256; ++c) {
    const float* sp = src + (size_t)c * HW;
    dst[(size_t)c * HW] = sp[i00] * w00 + sp[i10] * w10 + sp[i01] * w01 + sp[i11] * w11;
  }
}

// ---------------- main attention (fused, key-split S=4) — channel-major q/k/v
__global__ void k_mainattn(const float* __restrict__ qb, const float* __restrict__ kb,
                           const float* __restrict__ vb, float* __restrict__ pacc,
                           float* __restrict__ pden) {
  int bid = blockIdx.x;            // b(4) x hh(8) x mch(4) x sl(4) = 512
  int sl = bid & 3; bid >>= 2;
  int mch = bid & 3; bid >>= 2;
  int hh = bid & 7; bid >>= 3;
  int b = bid;
  int tid = threadIdx.x;
  int m = mch * 256 + tid;
  __shared__ float K_s[64][68];
  __shared__ float V_s[64][68];
  float qv[64];
  const float* qbase = qb + (size_t)(b * 512 + hh * 64) * HW + m;
#pragma unroll
  for (int e = 0; e < 64; ++e) qv[e] = qbase[(size_t)e * HW];
  float acc[64];
#pragma unroll
  for (int e = 0; e < 64; ++e) acc[e] = 0.f;
  float den = 0.f;
  for (int n0 = sl * 256; n0 < sl * 256 + 256; n0 += 64) {
    __syncthreads();
#pragma unroll
    for (int p = 0; p < 4; ++p) {
      int idx4 = p * 256 + tid;     // 0..1023 (64 e-rows x 16 float4 of n)
      int e  = idx4 >> 4;
      int n4 = idx4 & 15;
      float4 kvv = *reinterpret_cast<const float4*>(kb + (size_t)(b * 512 + hh * 64 + e) * HW + n0 + n4 * 4);
      K_s[n4 * 4 + 0][e] = kvv.x; K_s[n4 * 4 + 1][e] = kvv.y;
      K_s[n4 * 4 + 2][e] = kvv.z; K_s[n4 * 4 + 3][e] = kvv.w;
      float4 vvv = *reinterpret_cast<const float4*>(vb + (size_t)(b * 512 + hh * 64 + e) * HW + n0 + n4 * 4);
      V_s[n4 * 4 + 0][e] = vvv.x; V_s[n4 * 4 + 1][e] = vvv.y;
      V_s[n4 * 4 + 2][e] = vvv.z; V_s[n4 * 4 + 3][e] = vvv.w;
    }
    __syncthreads();
    for (int nn = 0; nn < 64; ++nn) {
      float s = 0.f;
      const float4* kr = reinterpret_cast<const float4*>(K_s[nn]);
#pragma unroll
      for (int i = 0; i < 16; ++i) {
        float4 k4 = kr[i];
        s += qv[i * 4] * k4.x + qv[i * 4 + 1] * k4.y + qv[i * 4 + 2] * k4.z + qv[i * 4 + 3] * k4.w;
      }
      float p = __expf(s * 0.125f);
      den += p;
      const float4* vr = reinterpret_cast<const float4*>(V_s[nn]);
#pragma unroll
      for (int i = 0; i < 16; ++i) {
        float4 v4 = vr[i];
        acc[i * 4] += p * v4.x; acc[i * 4 + 1] += p * v4.y;
        acc[i * 4 + 2] += p * v4.z; acc[i * 4 + 3] += p * v4.w;
      }
    }
  }
  int qidx = (b * 8 + hh) * 1024 + m;     // 32768
  float* pa = pacc + (size_t)(sl * 32768 + qidx) * 64;
#pragma unroll
  for (int e = 0; e < 64; ++e) pa[e] = acc[e];
  pden[sl * 32768 + qidx] = den;
}

__global__ void k_mainmerge(const float* __restrict__ pacc, const float* __restrict__ pden,
                            float* __restrict__ attno) {
  int t = blockIdx.x * 256 + threadIdx.x;   // 32768
  int b = t >> 13; int hh = (t >> 10) & 7; int m = t & 1023;
  float den = 0.f;
#pragma unroll
  for (int s = 0; s < 4; ++s) den += pden[s * 32768 + t];
  float inv = 1.f / den;
  for (int e = 0; e < 64; ++e) {
    float a = 0.f;
#pragma unroll
    for (int s = 0; s < 4; ++s) a += pacc[(size_t)(s * 32768 + t) * 64 + e];
    attno[(size_t)(b * 512 + hh * 64 + e) * HW + m] = a * inv;
  }
}

// ---------------------------------------------------------------------------
extern "C" void kernel_launch(void* const* d_in, const int* in_sizes, int n_in,
                              void* d_out, int out_size, void* d_ws, size_t ws_size,
                              hipStream_t stream) {
  const float* tgt    = (const float*)d_in[0];
  const float* refp   = (const float*)d_in[1];
  const float* emb_w  = (const float*)d_in[2];
  const float* emb_b  = (const float*)d_in[3];
  const float* q_w    = (const float*)d_in[4];
  const float* q_b    = (const float*)d_in[5];
  const float* k_w    = (const float*)d_in[6];
  const float* k_b    = (const float*)d_in[7];
  const float* v_w    = (const float*)d_in[8];
  const float* v_b    = (const float*)d_in[9];
  const float* out_w  = (const float*)d_in[10];
  const float* out_b  = (const float*)d_in[11];
  const float* ln1_w  = (const float*)d_in[12];
  const float* ln1_b  = (const float*)d_in[13];
  const float* n1_w   = (const float*)d_in[14];
  const float* n1_b   = (const float*)d_in[15];
  const float* mbq_w  = (const float*)d_in[16];
  const float* mbq_b  = (const float*)d_in[17];
  const float* mbkv_w = (const float*)d_in[18];
  const float* mbkv_b = (const float*)d_in[19];
  const float* mbp_w  = (const float*)d_in[20];
  const float* mbp_b  = (const float*)d_in[21];
  const float* n2_w   = (const float*)d_in[22];
  const float* n2_b   = (const float*)d_in[23];
  const float* fc1_w  = (const float*)d_in[24];
  const float* fc1_b  = (const float*)d_in[25];
  const float* dw3_w  = (const float*)d_in[26];
  const float* dw3_b  = (const float*)d_in[27];
  const float* fc2_w  = (const float*)d_in[28];
  const float* fc2_b  = (const float*)d_in[29];
  const float* dw9_w  = (const float*)d_in[30];
  const float* dw9_b  = (const float*)d_in[31];
  const float* coln_w = (const float*)d_in[32];
  const float* coln_b = (const float*)d_in[33];
  const float* coout_w= (const float*)d_in[34];

  float* ws = (float*)d_ws;
  float* feat   = ws + OFF_FEAT;
  float* qbuf   = ws + OFF_Q;
  float* xbuf   = ws + OFF_X;
  float* hbuf   = ws + OFF_H;      // h, later o_tm
  float* qqbuf  = ws + OFF_QQ;     // qq, later h2
  float* kvbuf  = ws + OFF_KV;
  float* mbuf   = ws + OFF_M;      // mb pacc -> m_cm -> sampled/k/v/attno
  float* mibuf  = ws + OFF_MI;     // mb pden -> mi_cm -> main pacc
  float* offin  = ws + OFF_OFFIN;
  float* offdw  = ws + OFF_OFFDW;  // later main pden
  float* posb   = ws + OFF_POS;

  float* sampled = mbuf;
  float* kbuf    = mbuf + 2097152;
  float* vbuf    = mbuf + 4194304;
  float* attno   = mbuf + 6291456;

  // 1. embedding conv
  k_emb<<<1024, 256, 0, stream>>>(tgt, refp, emb_w, emb_b, feat);
  // 2. q projection
  k_gemm_cm<<<1024, 256, 0, stream>>>(tgt, q_w, q_b, qbuf);
  // 3. ln1 -> x
  k_ln1<<<32, 256, 0, stream>>>(feat, ln1_w, ln1_b, xbuf);
  // 4. mb_n1 -> h
  k_ln_tok<<<2048, 256, 0, stream>>>(xbuf, n1_w, n1_b, hbuf, 1e-6f);
  // 5. mb q/kv projections
  k_gemm_tm<<<1024, 256, 0, stream>>>(hbuf, mbq_w, mbq_b, qqbuf, 256, 0);
  k_gemm_tm<<<2048, 256, 0, stream>>>(hbuf, mbkv_w, mbkv_b, kvbuf, 512, 0);
  // 6. mb attention (partials) + merge -> o_tm (reuse hbuf)
  k_mbattn<<<1024, 256, 0, stream>>>(qqbuf, kvbuf, mbuf, mibuf);
  k_mbmerge<<<256, 256, 0, stream>>>(mbuf, mibuf, hbuf);
  // 7. x += proj(o)
  k_gemm_tm<<<1024, 256, 0, stream>>>(hbuf, mbp_w, mbp_b, xbuf, 256, 1);
  // 8. mb_n2 -> h2 (reuse qqbuf)
  k_ln_tok<<<2048, 256, 0, stream>>>(xbuf, n2_w, n2_b, qqbuf, 1e-6f);
  // 9. fc1 -> m channel-major
  k_fc1<<<4096, 256, 0, stream>>>(qqbuf, fc1_w, fc1_b, mbuf);
  // 10. dw3 + gelu -> mi
  k_dw3<<<32768, 256, 0, stream>>>(mbuf, dw3_w, dw3_b, mibuf);
  // 11. fc2 fused residual -> offin (final x, channel-major)
  k_fc2<<<1024, 256, 0, stream>>>(mibuf, fc2_w, fc2_b, xbuf, offin);
  // 12. dw9 -> offdw
  k_dw9<<<8192, 256, 0, stream>>>(offin, dw9_w, dw9_b, offdw);
  // 13. LN + gelu + proj + tanh -> pos
  k_cotail<<<32, 256, 0, stream>>>(offdw, coln_w, coln_b, coout_w, posb);
  // 14. grid sample -> sampled
  k_gsample<<<32, 256, 0, stream>>>(feat, posb, sampled);
  // 15. k/v projections
  k_gemm_cm<<<1024, 256, 0, stream>>>(sampled, k_w, k_b, kbuf);
  k_gemm_cm<<<1024, 256, 0, stream>>>(sampled, v_w, v_b, vbuf);
  // 16. main attention (partials) + merge -> attno
  k_mainattn<<<512, 256, 0, stream>>>(qbuf, kbuf, vbuf, mibuf, offdw);
  k_mainmerge<<<128, 256, 0, stream>>>(mibuf, offdw, attno);
  // 17. out projection -> d_out
  k_gemm_cm<<<1024, 256, 0, stream>>>(attno, out_w, out_b, (float*)d_out);
}

// Round 2
// 1903.899 us; speedup vs baseline: 1.6043x; 1.6043x over previous
//
#include <hip/hip_runtime.h>
#include <math.h>

// ---------------------------------------------------------------------------
// DAttention forward. Round 1: emb conv 3x3 -> split-bf16 (hi/lo) MFMA.
// Dims: B=4, C=512, H=W=32, G=2, gc=256, BG=8, heads=8, hc=64, mh=8, mhd=32,
//       hid=1024, N=HW=1024, ns=1024.
// ---------------------------------------------------------------------------

static constexpr int HW = 1024;

// workspace offsets (floats)
static constexpr size_t OFF_FEAT  = 0;          // [4,512,1024]
static constexpr size_t OFF_Q     = 2097152;    // [4,512,1024]
static constexpr size_t OFF_X     = 4194304;    // [8192,256] token-major residual; earlier: Xt_hi/lo
static constexpr size_t OFF_H     = 6291456;    // h (ln out); later o_tm
static constexpr size_t OFF_QQ    = 8388608;    // qq; later h2
static constexpr size_t OFF_KV    = 10485760;   // [8192,512]
static constexpr size_t OFF_M     = 14680064;   // Wt_hi/lo (prep) -> mb pacc -> m_cm -> sampled/k/v/attno
static constexpr size_t OFF_MI    = 23068672;   // emb partials -> mb pden -> mi_cm -> main pacc
static constexpr size_t OFF_OFFIN = 31457280;   // [8,256,1024] final x channel-major
static constexpr size_t OFF_OFFDW = 33554432;   // dw9 out; later main pden
static constexpr size_t OFF_POS   = 35651584;   // [8,1024,2] (x,y)

typedef __attribute__((ext_vector_type(8))) short bf16x8;
typedef __attribute__((ext_vector_type(4))) float f32x4;

union V16u { int4 i4; ushort u[8]; };

__device__ __forceinline__ float gelu_exact(float v) {
  return 0.5f * v * (1.0f + erff(v * 0.7071067811865475f));
}

__device__ __forceinline__ ushort bf16_rne(float v) {
  unsigned int b = __float_as_uint(v);
  return (ushort)((b + 0x7fffu + ((b >> 16) & 1u)) >> 16);
}

// ---------------- prep: weights [512][1024][3][3] -> Wt_hi/lo [9][512][1024] bf16
__global__ void k_prepw(const float* __restrict__ w, ushort* __restrict__ Wt_hi,
                        ushort* __restrict__ Wt_lo) {
  int idx = blockIdx.x * 256 + threadIdx.x;    // 524288 = 512*1024
  int o = idx >> 10, ci = idx & 1023;
  const float* src = w + (size_t)idx * 9;
#pragma unroll
  for (int t = 0; t < 9; ++t) {
    float v = src[t];
    ushort hi = bf16_rne(v);
    float hf = __uint_as_float(((unsigned int)hi) << 16);
    ushort lo = bf16_rne(v - hf);
    size_t oo = ((size_t)(t * 512 + o)) * 1024 + ci;
    Wt_hi[oo] = hi;
    Wt_lo[oo] = lo;
  }
}

// ---------------- prep: inputs -> Xt_hi/lo [4][34][34][1024] bf16 (y/x padded, ci contig)
__global__ void k_prepx(const float* __restrict__ tgt, const float* __restrict__ refp,
                        ushort* __restrict__ Xt_hi, ushort* __restrict__ Xt_lo) {
  int idx = blockIdx.x * 256 + threadIdx.x;    // 591872 = 4*34*128*34
  int xp = idx % 34; int r = idx / 34;
  int g8 = r & 127; r >>= 7;
  int yp = r % 34; int b = r / 34;
  int y = yp - 1, x = xp - 1;
  bool valid = (unsigned)y < 32u && (unsigned)x < 32u;
  V16u hi, lo;
  const float* in = (g8 < 64) ? (tgt + ((size_t)(b * 512 + g8 * 8)) * HW)
                              : (refp + ((size_t)(b * 512 + (g8 - 64) * 8)) * HW);
#pragma unroll
  for (int j = 0; j < 8; ++j) {
    float v = valid ? in[(size_t)j * HW + y * 32 + x] : 0.f;
    ushort h = bf16_rne(v);
    float hf = __uint_as_float(((unsigned int)h) << 16);
    ushort l = bf16_rne(v - hf);
    hi.u[j] = h; lo.u[j] = l;
  }
  size_t oo = (((size_t)(b * 34 + yp)) * 34 + xp) * 1024 + g8 * 8;
  *(int4*)(Xt_hi + oo) = hi.i4;
  *(int4*)(Xt_lo + oo) = lo.i4;
}

// ---------------- emb conv via MFMA, split-bf16 3-term, 2-way K-split
// grid 512 = b(4) x yt(16) x mt(4) x ks(2); block 256 = 4 waves
__global__ __launch_bounds__(256, 2)
void k_emb_mfma(const ushort* __restrict__ Xt_hi, const ushort* __restrict__ Xt_lo,
                const ushort* __restrict__ Wt_hi, const ushort* __restrict__ Wt_lo,
                float* __restrict__ part) {
  int bid = blockIdx.x;
  int ks = bid & 1; bid >>= 1;
  int mt = bid & 3; bid >>= 2;
  int yt = bid & 15; bid >>= 4;
  int b = bid;
  int tid = threadIdx.x;
  int w = tid >> 6, l = tid & 63;
  int lr = l & 15, lu = l >> 4;
  int y0 = yt * 2;
  int obase = mt * 128 + w * 32;

  __shared__ int4 LsH[2][576];   // [buf][px*4+unit] 144 px x 32 ci bf16 hi
  __shared__ int4 LsL[2][576];   // lo

  int4 gh[3], gl[3];
  int kc0 = ks * 16;

  auto loadstage = [&](int kcg) {
#pragma unroll
    for (int i = 0; i < 3; ++i) {
      int s = tid + 256 * i;
      if (s < 576) {
        int px = s >> 2;
        int pxc = px > 135 ? 135 : px;
        int u = (s & 3) ^ (pxc & 3);
        size_t off = (((size_t)(b * 34 + y0)) * 34 + pxc) * 1024 + kcg * 32 + u * 8;
        gh[i] = *(const int4*)(Xt_hi + off);
        gl[i] = *(const int4*)(Xt_lo + off);
      }
    }
  };
  auto writestage = [&](int buf) {
#pragma unroll
    for (int i = 0; i < 3; ++i) {
      int s = tid + 256 * i;
      if (s < 576) { LsH[buf][s] = gh[i]; LsL[buf][s] = gl[i]; }
    }
  };

  f32x4 zero = {0.f, 0.f, 0.f, 0.f};
  f32x4 acc[2][4];
#pragma unroll
  for (int a = 0; a < 2; ++a)
#pragma unroll
    for (int n = 0; n < 4; ++n) acc[a][n] = zero;

  loadstage(kc0);
  writestage(0);

  for (int kc = 0; kc < 16; ++kc) {
    int buf = kc & 1;
    __syncthreads();
    if (kc < 15) loadstage(kc0 + kc + 1);
    int kcg = kc0 + kc;
    const bf16x8* BH = (const bf16x8*)&LsH[buf][0];
    const bf16x8* BL = (const bf16x8*)&LsL[buf][0];
#pragma unroll
    for (int kx = 0; kx < 3; ++kx) {
      bf16x8 bh[8], bl[8];
#pragma unroll
      for (int f = 0; f < 8; ++f) {
        int px = (f >> 1) * 34 + (f & 1) * 16 + kx + lr;
        int idx = px * 4 + (lu ^ (px & 3));
        bh[f] = BH[idx]; bl[f] = BL[idx];
      }
#pragma unroll
      for (int ky = 0; ky < 3; ++ky) {
        int tap = ky * 3 + kx;
        size_t wo = (((size_t)(tap * 512 + obase + lr)) * 1024) + kcg * 32 + lu * 8;
        bf16x8 ah0 = *(const bf16x8*)(Wt_hi + wo);
        bf16x8 al0 = *(const bf16x8*)(Wt_lo + wo);
        bf16x8 ah1 = *(const bf16x8*)(Wt_hi + wo + 16 * 1024);
        bf16x8 al1 = *(const bf16x8*)(Wt_lo + wo + 16 * 1024);
#pragma unroll
        for (int yr = 0; yr < 2; ++yr)
#pragma unroll
          for (int h = 0; h < 2; ++h) {
            int f = (yr + ky) * 2 + h;
            int nf = yr * 2 + h;
            acc[0][nf] = __builtin_amdgcn_mfma_f32_16x16x32_bf16(ah0, bh[f], acc[0][nf], 0, 0, 0);
            acc[0][nf] = __builtin_amdgcn_mfma_f32_16x16x32_bf16(ah0, bl[f], acc[0][nf], 0, 0, 0);
            acc[0][nf] = __builtin_amdgcn_mfma_f32_16x16x32_bf16(al0, bh[f], acc[0][nf], 0, 0, 0);
            acc[1][nf] = __builtin_amdgcn_mfma_f32_16x16x32_bf16(ah1, bh[f], acc[1][nf], 0, 0, 0);
            acc[1][nf] = __builtin_amdgcn_mfma_f32_16x16x32_bf16(ah1, bl[f], acc[1][nf], 0, 0, 0);
            acc[1][nf] = __builtin_amdgcn_mfma_f32_16x16x32_bf16(al1, bh[f], acc[1][nf], 0, 0, 0);
          }
      }
    }
    if (kc < 15) writestage(buf ^ 1);
  }

  // store partials: C/D layout col=lane&15, row=(lane>>4)*4+reg
  float* pb = part + (size_t)ks * 2097152;
#pragma unroll
  for (int a = 0; a < 2; ++a)
#pragma unroll
    for (int yr = 0; yr < 2; ++yr)
#pragma unroll
      for (int h = 0; h < 2; ++h) {
        f32x4 c = acc[a][yr * 2 + h];
        size_t base = ((size_t)(b * 512 + obase + a * 16 + lu * 4)) * 1024
                      + (y0 + yr) * 32 + h * 16 + lr;
#pragma unroll
        for (int r = 0; r < 4; ++r) pb[base + (size_t)r * 1024] = c[r];
      }
}

__global__ void k_embmerge(const float* __restrict__ part, const float* __restrict__ bias,
                           float* __restrict__ feat) {
  int i = blockIdx.x * 256 + threadIdx.x;   // 2097152
  int o = (i >> 10) & 511;
  feat[i] = part[i] + part[2097152 + i] + bias[o];
}

// ---------------- channel-major GEMM: Y[b,o,n] = sum_c X[b,c,n] W[o,c] + bias[o]
__global__ void k_gemm_cm(const float* __restrict__ X, const float* __restrict__ Wm,
                          const float* __restrict__ bias, float* __restrict__ Y) {
  int bid = blockIdx.x;
  int nch = bid & 3; bid >>= 2;
  int og  = bid & 63; bid >>= 6;
  int b   = bid;
  int n = nch * 256 + threadIdx.x;
  int o0 = og * 8;
  float acc[8];
#pragma unroll
  for (int i = 0; i < 8; ++i) acc[i] = bias[o0 + i];
  const float* xp = X + (size_t)b * 512 * HW + n;
  for (int c = 0; c < 512; ++c) {
    float v = xp[c * HW];
#pragma unroll
    for (int oo = 0; oo < 8; ++oo) acc[oo] += v * Wm[(o0 + oo) * 512 + c];
  }
#pragma unroll
  for (int oo = 0; oo < 8; ++oo)
    Y[(size_t)(b * 512 + o0 + oo) * HW + n] = acc[oo];
}

// ---------------- ln1: feat channel-major -> x token-major, LN over 256
__global__ void k_ln1(const float* __restrict__ feat, const float* __restrict__ g_,
                      const float* __restrict__ b_, float* __restrict__ xo) {
  int t = blockIdx.x * 256 + threadIdx.x;
  int bg = t >> 10, n = t & 1023;
  const float* src = feat + (size_t)bg * 256 * HW + n;
  float s = 0.f, s2 = 0.f;
  for (int d = 0; d < 256; ++d) { float v = src[d * HW]; s += v; s2 += v * v; }
  float mean = s * (1.f / 256.f);
  float rstd = rsqrtf(s2 * (1.f / 256.f) - mean * mean + 1e-5f);
  float* dst = xo + (size_t)t * 256;
  for (int d = 0; d < 256; ++d) {
    float v = src[d * HW];
    dst[d] = (v - mean) * rstd * g_[d] + b_[d];
  }
}

// ---------------- token-major LN (wave per token)
__global__ void k_ln_tok(const float* __restrict__ xin, const float* __restrict__ g_,
                         const float* __restrict__ b_, float* __restrict__ yo, float eps) {
  int token = (blockIdx.x * 256 + threadIdx.x) >> 6;
  int lane = threadIdx.x & 63;
  float4 v4 = *reinterpret_cast<const float4*>(xin + (size_t)token * 256 + lane * 4);
  float s  = v4.x + v4.y + v4.z + v4.w;
  float s2 = v4.x * v4.x + v4.y * v4.y + v4.z * v4.z + v4.w * v4.w;
#pragma unroll
  for (int off = 32; off; off >>= 1) { s += __shfl_xor(s, off); s2 += __shfl_xor(s2, off); }
  float mean = s * (1.f / 256.f);
  float rstd = rsqrtf(s2 * (1.f / 256.f) - mean * mean + eps);
  float4 g4 = *reinterpret_cast<const float4*>(g_ + lane * 4);
  float4 b4 = *reinterpret_cast<const float4*>(b_ + lane * 4);
  float4 o;
  o.x = (v4.x - mean) * rstd * g4.x + b4.x;
  o.y = (v4.y - mean) * rstd * g4.y + b4.y;
  o.z = (v4.z - mean) * rstd * g4.z + b4.z;
  o.w = (v4.w - mean) * rstd * g4.w + b4.w;
  *reinterpret_cast<float4*>(yo + (size_t)token * 256 + lane * 4) = o;
}

// ---------------- token-major GEMM: Y[t,o] (+=) sum_d A[t,d] W[o,d] + b[o]; K=256
__global__ void k_gemm_tm(const float* __restrict__ A, const float* __restrict__ Wm,
                          const float* __restrict__ bias, float* __restrict__ Y,
                          int O, int addres) {
  int ognum = O >> 3;
  int og = blockIdx.x % ognum;
  int tb = blockIdx.x / ognum;
  int t = tb * 256 + threadIdx.x;
  int o0 = og * 8;
  const float4* a4p = reinterpret_cast<const float4*>(A + (size_t)t * 256);
  float acc[8];
#pragma unroll
  for (int i = 0; i < 8; ++i) acc[i] = bias[o0 + i];
  for (int d4 = 0; d4 < 64; ++d4) {
    float4 a4 = a4p[d4];
#pragma unroll
    for (int oo = 0; oo < 8; ++oo) {
      const float* wr = Wm + (o0 + oo) * 256 + d4 * 4;
      acc[oo] += a4.x * wr[0] + a4.y * wr[1] + a4.z * wr[2] + a4.w * wr[3];
    }
  }
  float* y = Y + (size_t)t * O + o0;
  if (addres) {
#pragma unroll
    for (int oo = 0; oo < 8; ++oo) y[oo] += acc[oo];
  } else {
#pragma unroll
    for (int oo = 0; oo < 8; ++oo) y[oo] = acc[oo];
  }
}

// ---------------- MitBlock attention (fused, key-split S=4, partials out)
__global__ void k_mbattn(const float* __restrict__ qq, const float* __restrict__ kv,
                         float* __restrict__ pacc, float* __restrict__ pden) {
  int bid = blockIdx.x;
  int sl = bid & 3; bid >>= 2;
  int mch = bid & 3; bid >>= 2;
  int hh = bid & 7; bid >>= 3;
  int bg = bid;
  int tid = threadIdx.x;
  int m = mch * 256 + tid;
  __shared__ float K_s[64][32];
  __shared__ float V_s[64][32];
  float qv[32];
  {
    const float4* qp = reinterpret_cast<const float4*>(qq + (size_t)((bg << 10) + m) * 256 + hh * 32);
#pragma unroll
    for (int i = 0; i < 8; ++i) {
      float4 v = qp[i];
      qv[i * 4] = v.x; qv[i * 4 + 1] = v.y; qv[i * 4 + 2] = v.z; qv[i * 4 + 3] = v.w;
    }
  }
  float acc[32];
#pragma unroll
  for (int e = 0; e < 32; ++e) acc[e] = 0.f;
  float den = 0.f;
  const float scale = 0.17677669529663689f;
  for (int n0 = sl * 256; n0 < sl * 256 + 256; n0 += 64) {
    __syncthreads();
#pragma unroll
    for (int p = 0; p < 2; ++p) {
      int idx4 = p * 256 + tid;
      int key = idx4 >> 3;
      int e4  = idx4 & 7;
      const float* krow = kv + (size_t)((bg << 10) + n0 + key) * 512 + hh * 32;
      reinterpret_cast<float4*>(K_s[key])[e4] = reinterpret_cast<const float4*>(krow)[e4];
      reinterpret_cast<float4*>(V_s[key])[e4] = reinterpret_cast<const float4*>(krow + 256)[e4];
    }
    __syncthreads();
    for (int kk = 0; kk < 64; ++kk) {
      float s = 0.f;
      const float4* kr = reinterpret_cast<const float4*>(K_s[kk]);
#pragma unroll
      for (int i = 0; i < 8; ++i) {
        float4 k4 = kr[i];
        s += qv[i * 4] * k4.x + qv[i * 4 + 1] * k4.y + qv[i * 4 + 2] * k4.z + qv[i * 4 + 3] * k4.w;
      }
      float p = __expf(s * scale);
      den += p;
      const float4* vr = reinterpret_cast<const float4*>(V_s[kk]);
#pragma unroll
      for (int i = 0; i < 8; ++i) {
        float4 v4 = vr[i];
        acc[i * 4] += p * v4.x; acc[i * 4 + 1] += p * v4.y;
        acc[i * 4 + 2] += p * v4.z; acc[i * 4 + 3] += p * v4.w;
      }
    }
  }
  int qidx = ((bg << 3) + hh) * 1024 + m;
  float* pa = pacc + (size_t)(sl * 65536 + qidx) * 32;
#pragma unroll
  for (int e = 0; e < 32; ++e) pa[e] = acc[e];
  pden[sl * 65536 + qidx] = den;
}

__global__ void k_mbmerge(const float* __restrict__ pacc, const float* __restrict__ pden,
                          float* __restrict__ o_tm) {
  int t = blockIdx.x * 256 + threadIdx.x;
  int bg = t >> 13; int hh = (t >> 10) & 7; int m = t & 1023;
  float den = 0.f;
#pragma unroll
  for (int s = 0; s < 4; ++s) den += pden[s * 65536 + t];
  float inv = 1.f / den;
  float* dst = o_tm + (size_t)((bg << 10) + m) * 256 + hh * 32;
  for (int e = 0; e < 32; ++e) {
    float a = 0.f;
#pragma unroll
    for (int s = 0; s < 4; ++s) a += pacc[(size_t)(s * 65536 + t) * 32 + e];
    dst[e] = a * inv;
  }
}

// ---------------- fc1: token-major h2 [8192,256] -> channel-major m [8,1024,1024]
__global__ void k_fc1(const float* __restrict__ A, const float* __restrict__ Wm,
                      const float* __restrict__ bias, float* __restrict__ Y) {
  int bid = blockIdx.x;
  int nch = bid & 3; bid >>= 2;
  int og  = bid & 127; bid >>= 7;
  int bg  = bid;
  int n = nch * 256 + threadIdx.x;
  int t = (bg << 10) + n;
  const float4* a4p = reinterpret_cast<const float4*>(A + (size_t)t * 256);
  int o0 = og * 8;
  float acc[8];
#pragma unroll
  for (int i = 0; i < 8; ++i) acc[i] = bias[o0 + i];
  for (int d4 = 0; d4 < 64; ++d4) {
    float4 a4 = a4p[d4];
#pragma unroll
    for (int oo = 0; oo < 8; ++oo) {
      const float* wr = Wm + (o0 + oo) * 256 + d4 * 4;
      acc[oo] += a4.x * wr[0] + a4.y * wr[1] + a4.z * wr[2] + a4.w * wr[3];
    }
  }
#pragma unroll
  for (int oo = 0; oo < 8; ++oo)
    Y[(size_t)((bg << 10) + o0 + oo) * HW + n] = acc[oo];
}

// ---------------- depthwise 3x3 + bias + exact GELU
__global__ void k_dw3(const float* __restrict__ X, const float* __restrict__ w,
                      const float* __restrict__ bias, float* __restrict__ Y) {
  int idx = blockIdx.x * 256 + threadIdx.x;
  int x = idx & 31, y = (idx >> 5) & 31, ch = (idx >> 10) & 1023, bg = idx >> 20;
  const float* src = X + (size_t)((bg << 10) + ch) * HW;
  const float* wr = w + ch * 9;
  float acc = bias[ch];
#pragma unroll
  for (int ky = 0; ky < 3; ++ky) {
    int yy = y + ky - 1;
    if ((unsigned)yy < 32u) {
      const float* row = src + yy * 32;
#pragma unroll
      for (int kx = 0; kx < 3; ++kx) {
        int xx = x + kx - 1;
        if ((unsigned)xx < 32u) acc += row[xx] * wr[ky * 3 + kx];
      }
    }
  }
  Y[(size_t)((bg << 10) + ch) * HW + y * 32 + x] = gelu_exact(acc);
}

// ---------------- fc2 fused residual
__global__ void k_fc2(const float* __restrict__ Mi, const float* __restrict__ Wm,
                      const float* __restrict__ bias, const float* __restrict__ Xres,
                      float* __restrict__ Y) {
  int bid = blockIdx.x;
  int nch = bid & 3; bid >>= 2;
  int og  = bid & 31; bid >>= 5;
  int bg  = bid;
  int n = nch * 256 + threadIdx.x;
  int o0 = og * 8;
  float acc[8];
#pragma unroll
  for (int i = 0; i < 8; ++i)
    acc[i] = bias[o0 + i] + Xres[(size_t)((bg << 10) + n) * 256 + o0 + i];
  const float* mp = Mi + (size_t)(bg << 10) * HW + n;
  for (int h = 0; h < 1024; ++h) {
    float v = mp[(size_t)h * HW];
#pragma unroll
    for (int oo = 0; oo < 8; ++oo) acc[oo] += v * Wm[(o0 + oo) * 1024 + h];
  }
#pragma unroll
  for (int oo = 0; oo < 8; ++oo)
    Y[(size_t)((bg << 8) + o0 + oo) * HW + n] = acc[oo];
}

// ---------------- depthwise 9x9 pad 4 + bias
__global__ void k_dw9(const float* __restrict__ X, const float* __restrict__ w,
                      const float* __restrict__ bias, float* __restrict__ Y) {
  int idx = blockIdx.x * 256 + threadIdx.x;
  int x = idx & 31, y = (idx >> 5) & 31, ch = (idx >> 10) & 255, bg = idx >> 18;
  const float* src = X + (size_t)((bg << 8) + ch) * HW;
  const float* wr = w + ch * 81;
  float acc = bias[ch];
  for (int ky = 0; ky < 9; ++ky) {
    int yy = y + ky - 4;
    if ((unsigned)yy < 32u) {
      const float* row = src + yy * 32;
#pragma unroll
      for (int kx = 0; kx < 9; ++kx) {
        int xx = x + kx - 4;
        if ((unsigned)xx < 32u) acc += row[xx] * wr[ky * 9 + kx];
      }
    }
  }
  Y[(size_t)((bg << 8) + ch) * HW + y * 32 + x] = acc;
}

// ---------------- co tail: LN + GELU + [2,256] proj + tanh -> pos
__global__ void k_cotail(const float* __restrict__ Xdw, const float* __restrict__ lnw,
                         const float* __restrict__ lnb, const float* __restrict__ w2,
                         float* __restrict__ pos) {
  int t = blockIdx.x * 256 + threadIdx.x;
  int bg = t >> 10, n = t & 1023;
  const float* src = Xdw + (size_t)(bg << 8) * HW + n;
  float s = 0.f, s2 = 0.f;
  for (int c = 0; c < 256; ++c) { float v = src[c * HW]; s += v; s2 += v * v; }
  float mean = s * (1.f / 256.f);
  float rstd = rsqrtf(s2 * (1.f / 256.f) - mean * mean + 1e-5f);
  float o0 = 0.f, o1 = 0.f;
  for (int c = 0; c < 256; ++c) {
    float v = (src[c * HW] - mean) * rstd * lnw[c] + lnb[c];
    float ge = gelu_exact(v);
    o0 += ge * w2[c];
    o1 += ge * w2[256 + c];
  }
  float offy = tanhf(o0) * (2.f / 32.f);
  float offx = tanhf(o1) * (2.f / 32.f);
  int ky = n >> 5, kx = n & 31;
  float refy = ((ky + 0.5f) * (1.f / 32.f)) * 2.f - 1.f;
  float refx = ((kx + 0.5f) * (1.f / 32.f)) * 2.f - 1.f;
  pos[t * 2]     = offx + refx;
  pos[t * 2 + 1] = offy + refy;
}

// ---------------- bilinear grid sample
__global__ void k_gsample(const float* __restrict__ feat, const float* __restrict__ pos,
                          float* __restrict__ out) {
  int bid = blockIdx.x;
  int nch = bid & 3; int bg = bid >> 2;
  int j = nch * 256 + threadIdx.x;
  float gx = pos[((bg << 10) + j) * 2];
  float gy = pos[((bg << 10) + j) * 2 + 1];
  float fx = (gx + 1.f) * 0.5f * 31.f;
  float fy = (gy + 1.f) * 0.5f * 31.f;
  float x0f = floorf(fx), y0f = floorf(fy);
  int x0 = (int)x0f, y0 = (int)y0f;
  float wx1 = fx - x0f, wx0 = 1.f - wx1;
  float wy1 = fy - y0f, wy0 = 1.f - wy1;
  bool vx0 = (x0 >= 0) & (x0 <= 31);
  bool vx1 = (x0 + 1 >= 0) & (x0 + 1 <= 31);
  bool vy0 = (y0 >= 0) & (y0 <= 31);
  bool vy1 = (y0 + 1 >= 0) & (y0 + 1 <= 31);
  int cx0 = min(max(x0, 0), 31), cx1 = min(max(x0 + 1, 0), 31);
  int cy0 = min(max(y0, 0), 31), cy1 = min(max(y0 + 1, 0), 31);
  float w00 = wx0 * wy0 * ((vx0 && vy0) ? 1.f : 0.f);
  float w10 = wx1 * wy0 * ((vx1 && vy0) ? 1.f : 0.f);
  float w01 = wx0 * wy1 * ((vx0 && vy1) ? 1.f : 0.f);
  float w11 = wx1 * wy1 * ((vx1 && vy1) ? 1.f : 0.f);
  int i00 = cy0 * 32 + cx0, i10 = cy0 * 32 + cx1;
  int i01 = cy1 * 32 + cx0, i11 = cy1 * 32 + cx1;
  const float* src = feat + (size_t)(bg << 8) * HW;
  float* dst = out + (size_t)(bg << 8) * HW + j;
  for (int c = 0; c < 256; ++c) {
    const float* sp = src + (size_t)c * HW;
    dst[(size_t)c * HW] = sp[i00] * w00 + sp[i10] * w10 + sp[i01] * w01 + sp[i11] * w11;
  }
}

// ---------------- main attention (fused, key-split S=4)
__global__ void k_mainattn(const float* __restrict__ qb, const float* __restrict__ kb,
                           const float* __restrict__ vb, float* __restrict__ pacc,
                           float* __restrict__ pden) {
  int bid = blockIdx.x;
  int sl = bid & 3; bid >>= 2;
  int mch = bid & 3; bid >>= 2;
  int hh = bid & 7; bid >>= 3;
  int b = bid;
  int tid = threadIdx.x;
  int m = mch * 256 + tid;
  __shared__ float K_s[64][68];
  __shared__ float V_s[64][68];
  float qv[64];
  const float* qbase = qb + (size_t)(b * 512 + hh * 64) * HW + m;
#pragma unroll
  for (int e = 0; e < 64; ++e) qv[e] = qbase[(size_t)e * HW];
  float acc[64];
#pragma unroll
  for (int e = 0; e < 64; ++e) acc[e] = 0.f;
  float den = 0.f;
  for (int n0 = sl * 256; n0 < sl * 256 + 256; n0 += 64) {
    __syncthreads();
#pragma unroll
    for (int p = 0; p < 4; ++p) {
      int idx4 = p * 256 + tid;
      int e  = idx4 >> 4;
      int n4 = idx4 & 15;
      float4 kvv = *reinterpret_cast<const float4*>(kb + (size_t)(b * 512 + hh * 64 + e) * HW + n0 + n4 * 4);
      K_s[n4 * 4 + 0][e] = kvv.x; K_s[n4 * 4 + 1][e] = kvv.y;
      K_s[n4 * 4 + 2][e] = kvv.z; K_s[n4 * 4 + 3][e] = kvv.w;
      float4 vvv = *reinterpret_cast<const float4*>(vb + (size_t)(b * 512 + hh * 64 + e) * HW + n0 + n4 * 4);
      V_s[n4 * 4 + 0][e] = vvv.x; V_s[n4 * 4 + 1][e] = vvv.y;
      V_s[n4 * 4 + 2][e] = vvv.z; V_s[n4 * 4 + 3][e] = vvv.w;
    }
    __syncthreads();
    for (int nn = 0; nn < 64; ++nn) {
      float s = 0.f;
      const float4* kr = reinterpret_cast<const float4*>(K_s[nn]);
#pragma unroll
      for (int i = 0; i < 16; ++i) {
        float4 k4 = kr[i];
        s += qv[i * 4] * k4.x + qv[i * 4 + 1] * k4.y + qv[i * 4 + 2] * k4.z + qv[i * 4 + 3] * k4.w;
      }
      float p = __expf(s * 0.125f);
      den += p;
      const float4* vr = reinterpret_cast<const float4*>(V_s[nn]);
#pragma unroll
      for (int i = 0; i < 16; ++i) {
        float4 v4 = vr[i];
        acc[i * 4] += p * v4.x; acc[i * 4 + 1] += p * v4.y;
        acc[i * 4 + 2] += p * v4.z; acc[i * 4 + 3] += p * v4.w;
      }
    }
  }
  int qidx = (b * 8 + hh) * 1024 + m;
  float* pa = pacc + (size_t)(sl * 32768 + qidx) * 64;
#pragma unroll
  for (int e = 0; e < 64; ++e) pa[e] = acc[e];
  pden[sl * 32768 + qidx] = den;
}

__global__ void k_mainmerge(const float* __restrict__ pacc, const float* __restrict__ pden,
                            float* __restrict__ attno) {
  int t = blockIdx.x * 256 + threadIdx.x;
  int b = t >> 13; int hh = (t >> 10) & 7; int m = t & 1023;
  float den = 0.f;
#pragma unroll
  for (int s = 0; s < 4; ++s) den += pden[s * 32768 + t];
  float inv = 1.f / den;
  for (int e = 0; e < 64; ++e) {
    float a = 0.f;
#pragma unroll
    for (int s = 0; s < 4; ++s) a += pacc[(size_t)(s * 32768 + t) * 64 + e];
    attno[(size_t)(b * 512 + hh * 64 + e) * HW + m] = a * inv;
  }
}

// ---------------------------------------------------------------------------
extern "C" void kernel_launch(void* const* d_in, const int* in_sizes, int n_in,
                              void* d_out, int out_size, void* d_ws, size_t ws_size,
                              hipStream_t stream) {
  const float* tgt    = (const float*)d_in[0];
  const float* refp   = (const float*)d_in[1];
  const float* emb_w  = (const float*)d_in[2];
  const float* emb_b  = (const float*)d_in[3];
  const float* q_w    = (const float*)d_in[4];
  const float* q_b    = (const float*)d_in[5];
  const float* k_w    = (const float*)d_in[6];
  const float* k_b    = (const float*)d_in[7];
  const float* v_w    = (const float*)d_in[8];
  const float* v_b    = (const float*)d_in[9];
  const float* out_w  = (const float*)d_in[10];
  const float* out_b  = (const float*)d_in[11];
  const float* ln1_w  = (const float*)d_in[12];
  const float* ln1_b  = (const float*)d_in[13];
  const float* n1_w   = (const float*)d_in[14];
  const float* n1_b   = (const float*)d_in[15];
  const float* mbq_w  = (const float*)d_in[16];
  const float* mbq_b  = (const float*)d_in[17];
  const float* mbkv_w = (const float*)d_in[18];
  const float* mbkv_b = (const float*)d_in[19];
  const float* mbp_w  = (const float*)d_in[20];
  const float* mbp_b  = (const float*)d_in[21];
  const float* n2_w   = (const float*)d_in[22];
  const float* n2_b   = (const float*)d_in[23];
  const float* fc1_w  = (const float*)d_in[24];
  const float* fc1_b  = (const float*)d_in[25];
  const float* dw3_w  = (const float*)d_in[26];
  const float* dw3_b  = (const float*)d_in[27];
  const float* fc2_w  = (const float*)d_in[28];
  const float* fc2_b  = (const float*)d_in[29];
  const float* dw9_w  = (const float*)d_in[30];
  const float* dw9_b  = (const float*)d_in[31];
  const float* coln_w = (const float*)d_in[32];
  const float* coln_b = (const float*)d_in[33];
  const float* coout_w= (const float*)d_in[34];

  float* ws = (float*)d_ws;
  float* feat   = ws + OFF_FEAT;
  float* qbuf   = ws + OFF_Q;
  float* xbuf   = ws + OFF_X;
  float* hbuf   = ws + OFF_H;
  float* qqbuf  = ws + OFF_QQ;
  float* kvbuf  = ws + OFF_KV;
  float* mbuf   = ws + OFF_M;
  float* mibuf  = ws + OFF_MI;
  float* offin  = ws + OFF_OFFIN;
  float* offdw  = ws + OFF_OFFDW;
  float* posb   = ws + OFF_POS;

  float* sampled = mbuf;
  float* kbuf    = mbuf + 2097152;
  float* vbuf    = mbuf + 4194304;
  float* attno   = mbuf + 6291456;

  // emb-prep scratch (regions free at this point in the pipeline)
  ushort* Xt_hi = (ushort*)(ws + OFF_X);                 // 4*34*34*1024 bf16
  ushort* Xt_lo = (ushort*)(ws + OFF_X + 2367488);
  ushort* Wt_hi = (ushort*)(ws + OFF_M);                 // 9*512*1024 bf16
  ushort* Wt_lo = (ushort*)(ws + OFF_M + 2359296);
  float*  part  = ws + OFF_MI;                           // 2 x [4,512,1024]

  // 1. embedding conv (MFMA, split-bf16)
  k_prepw<<<2048, 256, 0, stream>>>(emb_w, Wt_hi, Wt_lo);
  k_prepx<<<2312, 256, 0, stream>>>(tgt, refp, Xt_hi, Xt_lo);
  k_emb_mfma<<<512, 256, 0, stream>>>(Xt_hi, Xt_lo, Wt_hi, Wt_lo, part);
  k_embmerge<<<8192, 256, 0, stream>>>(part, emb_b, feat);
  // 2. q projection
  k_gemm_cm<<<1024, 256, 0, stream>>>(tgt, q_w, q_b, qbuf);
  // 3. ln1 -> x
  k_ln1<<<32, 256, 0, stream>>>(feat, ln1_w, ln1_b, xbuf);
  // 4. mb_n1 -> h
  k_ln_tok<<<2048, 256, 0, stream>>>(xbuf, n1_w, n1_b, hbuf, 1e-6f);
  // 5. mb q/kv projections
  k_gemm_tm<<<1024, 256, 0, stream>>>(hbuf, mbq_w, mbq_b, qqbuf, 256, 0);
  k_gemm_tm<<<2048, 256, 0, stream>>>(hbuf, mbkv_w, mbkv_b, kvbuf, 512, 0);
  // 6. mb attention + merge
  k_mbattn<<<1024, 256, 0, stream>>>(qqbuf, kvbuf, mbuf, mibuf);
  k_mbmerge<<<256, 256, 0, stream>>>(mbuf, mibuf, hbuf);
  // 7. x += proj(o)
  k_gemm_tm<<<1024, 256, 0, stream>>>(hbuf, mbp_w, mbp_b, xbuf, 256, 1);
  // 8. mb_n2 -> h2
  k_ln_tok<<<2048, 256, 0, stream>>>(xbuf, n2_w, n2_b, qqbuf, 1e-6f);
  // 9. fc1 -> m channel-major
  k_fc1<<<4096, 256, 0, stream>>>(qqbuf, fc1_w, fc1_b, mbuf);
  // 10. dw3 + gelu
  k_dw3<<<32768, 256, 0, stream>>>(mbuf, dw3_w, dw3_b, mibuf);
  // 11. fc2 fused residual -> offin
  k_fc2<<<1024, 256, 0, stream>>>(mibuf, fc2_w, fc2_b, xbuf, offin);
  // 12. dw9
  k_dw9<<<8192, 256, 0, stream>>>(offin, dw9_w, dw9_b, offdw);
  // 13. LN + gelu + proj + tanh -> pos
  k_cotail<<<32, 256, 0, stream>>>(offdw, coln_w, coln_b, coout_w, posb);
  // 14. grid sample
  k_gsample<<<32, 256, 0, stream>>>(feat, posb, sampled);
  // 15. k/v projections
  k_gemm_cm<<<1024, 256, 0, stream>>>(sampled, k_w, k_b, kbuf);
  k_gemm_cm<<<1024, 256, 0, stream>>>(sampled, v_w, v_b, vbuf);
  // 16. main attention + merge
  k_mainattn<<<512, 256, 0, stream>>>(qbuf, kbuf, vbuf, mibuf, offdw);
  k_mainmerge<<<128, 256, 0, stream>>>(mibuf, offdw, attno);
  // 17. out projection
  k_gemm_cm<<<1024, 256, 0, stream>>>(attno, out_w, out_b, (float*)d_out);
}

// Round 3
// 1226.484 us; speedup vs baseline: 2.4903x; 1.5523x over previous
//
#include <hip/hip_runtime.h>
#include <math.h>

// ---------------------------------------------------------------------------
// DAttention forward. R3: emb conv + both attentions on split-bf16 MFMA.
// Dims: B=4, C=512, H=W=32, G=2, gc=256, BG=8, heads=8, hc=64, mh=8, mhd=32,
//       hid=1024, N=HW=1024, ns=1024.
// ---------------------------------------------------------------------------

static constexpr int HW = 1024;

// workspace offsets (floats)
static constexpr size_t OFF_FEAT  = 0;          // [4,512,1024]
static constexpr size_t OFF_Q     = 2097152;    // [4,512,1024]
static constexpr size_t OFF_X     = 4194304;    // [8192,256] token-major residual; earlier: Xt_hi/lo
static constexpr size_t OFF_H     = 6291456;    // h (ln out); later o_tm
static constexpr size_t OFF_QQ    = 8388608;    // qq; later h2
static constexpr size_t OFF_KV    = 10485760;   // [8192,512]
static constexpr size_t OFF_M     = 14680064;   // Wt prep -> mb frags -> m_cm -> sampled/k/v/attno
static constexpr size_t OFF_MI    = 23068672;   // emb partials -> mi_cm -> main attn frags
static constexpr size_t OFF_OFFIN = 31457280;   // [8,256,1024] final x channel-major
static constexpr size_t OFF_OFFDW = 33554432;   // dw9 out
static constexpr size_t OFF_POS   = 35651584;   // [8,1024,2] (x,y)

typedef __attribute__((ext_vector_type(8))) short bf16x8;
typedef __attribute__((ext_vector_type(4))) float f32x4;

union V16u { int4 i4; ushort u[8]; };

__device__ __forceinline__ float gelu_exact(float v) {
  return 0.5f * v * (1.0f + erff(v * 0.7071067811865475f));
}

__device__ __forceinline__ ushort bf16_rne(float v) {
  unsigned int b = __float_as_uint(v);
  return (ushort)((b + 0x7fffu + ((b >> 16) & 1u)) >> 16);
}

// ---------------- prep: weights [512][1024][3][3] -> Wt_hi/lo [9][512][1024] bf16
__global__ void k_prepw(const float* __restrict__ w, ushort* __restrict__ Wt_hi,
                        ushort* __restrict__ Wt_lo) {
  int idx = blockIdx.x * 256 + threadIdx.x;    // 524288 = 512*1024
  int o = idx >> 10, ci = idx & 1023;
  const float* src = w + (size_t)idx * 9;
#pragma unroll
  for (int t = 0; t < 9; ++t) {
    float v = src[t];
    ushort hi = bf16_rne(v);
    float hf = __uint_as_float(((unsigned int)hi) << 16);
    ushort lo = bf16_rne(v - hf);
    size_t oo = ((size_t)(t * 512 + o)) * 1024 + ci;
    Wt_hi[oo] = hi;
    Wt_lo[oo] = lo;
  }
}

// ---------------- prep: inputs -> Xt_hi/lo [4][34][34][1024] bf16 (padded, ci contig)
__global__ void k_prepx(const float* __restrict__ tgt, const float* __restrict__ refp,
                        ushort* __restrict__ Xt_hi, ushort* __restrict__ Xt_lo) {
  int idx = blockIdx.x * 256 + threadIdx.x;    // 591872 = 4*34*128*34
  int xp = idx % 34; int r = idx / 34;
  int g8 = r & 127; r >>= 7;
  int yp = r % 34; int b = r / 34;
  int y = yp - 1, x = xp - 1;
  bool valid = (unsigned)y < 32u && (unsigned)x < 32u;
  V16u hi, lo;
  const float* in = (g8 < 64) ? (tgt + ((size_t)(b * 512 + g8 * 8)) * HW)
                              : (refp + ((size_t)(b * 512 + (g8 - 64) * 8)) * HW);
#pragma unroll
  for (int j = 0; j < 8; ++j) {
    float v = valid ? in[(size_t)j * HW + y * 32 + x] : 0.f;
    ushort h = bf16_rne(v);
    float hf = __uint_as_float(((unsigned int)h) << 16);
    ushort l = bf16_rne(v - hf);
    hi.u[j] = h; lo.u[j] = l;
  }
  size_t oo = (((size_t)(b * 34 + yp)) * 34 + xp) * 1024 + g8 * 8;
  *(int4*)(Xt_hi + oo) = hi.i4;
  *(int4*)(Xt_lo + oo) = lo.i4;
}

// ---------------- emb conv via MFMA, split-bf16 3-term, 2-way K-split
__global__ __launch_bounds__(256, 2)
void k_emb_mfma(const ushort* __restrict__ Xt_hi, const ushort* __restrict__ Xt_lo,
                const ushort* __restrict__ Wt_hi, const ushort* __restrict__ Wt_lo,
                float* __restrict__ part) {
  int bid = blockIdx.x;
  int ks = bid & 1; bid >>= 1;
  int mt = bid & 3; bid >>= 2;
  int yt = bid & 15; bid >>= 4;
  int b = bid;
  int tid = threadIdx.x;
  int w = tid >> 6, l = tid & 63;
  int lr = l & 15, lu = l >> 4;
  int y0 = yt * 2;
  int obase = mt * 128 + w * 32;

  __shared__ int4 LsH[2][576];
  __shared__ int4 LsL[2][576];

  int4 gh[3], gl[3];
  int kc0 = ks * 16;

  auto loadstage = [&](int kcg) {
#pragma unroll
    for (int i = 0; i < 3; ++i) {
      int s = tid + 256 * i;
      if (s < 576) {
        int px = s >> 2;
        int pxc = px > 135 ? 135 : px;
        int u = (s & 3) ^ (pxc & 3);
        size_t off = (((size_t)(b * 34 + y0)) * 34 + pxc) * 1024 + kcg * 32 + u * 8;
        gh[i] = *(const int4*)(Xt_hi + off);
        gl[i] = *(const int4*)(Xt_lo + off);
      }
    }
  };
  auto writestage = [&](int buf) {
#pragma unroll
    for (int i = 0; i < 3; ++i) {
      int s = tid + 256 * i;
      if (s < 576) { LsH[buf][s] = gh[i]; LsL[buf][s] = gl[i]; }
    }
  };

  f32x4 zero = {0.f, 0.f, 0.f, 0.f};
  f32x4 acc[2][4];
#pragma unroll
  for (int a = 0; a < 2; ++a)
#pragma unroll
    for (int n = 0; n < 4; ++n) acc[a][n] = zero;

  loadstage(kc0);
  writestage(0);

  for (int kc = 0; kc < 16; ++kc) {
    int buf = kc & 1;
    __syncthreads();
    if (kc < 15) loadstage(kc0 + kc + 1);
    int kcg = kc0 + kc;
    const bf16x8* BH = (const bf16x8*)&LsH[buf][0];
    const bf16x8* BL = (const bf16x8*)&LsL[buf][0];
#pragma unroll
    for (int kx = 0; kx < 3; ++kx) {
      bf16x8 bh[8], bl[8];
#pragma unroll
      for (int f = 0; f < 8; ++f) {
        int px = (f >> 1) * 34 + (f & 1) * 16 + kx + lr;
        int idx = px * 4 + (lu ^ (px & 3));
        bh[f] = BH[idx]; bl[f] = BL[idx];
      }
#pragma unroll
      for (int ky = 0; ky < 3; ++ky) {
        int tap = ky * 3 + kx;
        size_t wo = (((size_t)(tap * 512 + obase + lr)) * 1024) + kcg * 32 + lu * 8;
        bf16x8 ah0 = *(const bf16x8*)(Wt_hi + wo);
        bf16x8 al0 = *(const bf16x8*)(Wt_lo + wo);
        bf16x8 ah1 = *(const bf16x8*)(Wt_hi + wo + 16 * 1024);
        bf16x8 al1 = *(const bf16x8*)(Wt_lo + wo + 16 * 1024);
#pragma unroll
        for (int yr = 0; yr < 2; ++yr)
#pragma unroll
          for (int h = 0; h < 2; ++h) {
            int f = (yr + ky) * 2 + h;
            int nf = yr * 2 + h;
            acc[0][nf] = __builtin_amdgcn_mfma_f32_16x16x32_bf16(ah0, bh[f], acc[0][nf], 0, 0, 0);
            acc[0][nf] = __builtin_amdgcn_mfma_f32_16x16x32_bf16(ah0, bl[f], acc[0][nf], 0, 0, 0);
            acc[0][nf] = __builtin_amdgcn_mfma_f32_16x16x32_bf16(al0, bh[f], acc[0][nf], 0, 0, 0);
            acc[1][nf] = __builtin_amdgcn_mfma_f32_16x16x32_bf16(ah1, bh[f], acc[1][nf], 0, 0, 0);
            acc[1][nf] = __builtin_amdgcn_mfma_f32_16x16x32_bf16(ah1, bl[f], acc[1][nf], 0, 0, 0);
            acc[1][nf] = __builtin_amdgcn_mfma_f32_16x16x32_bf16(al1, bh[f], acc[1][nf], 0, 0, 0);
          }
      }
    }
    if (kc < 15) writestage(buf ^ 1);
  }

  float* pb = part + (size_t)ks * 2097152;
#pragma unroll
  for (int a = 0; a < 2; ++a)
#pragma unroll
    for (int yr = 0; yr < 2; ++yr)
#pragma unroll
      for (int h = 0; h < 2; ++h) {
        f32x4 c = acc[a][yr * 2 + h];
        size_t base = ((size_t)(b * 512 + obase + a * 16 + lu * 4)) * 1024
                      + (y0 + yr) * 32 + h * 16 + lr;
#pragma unroll
        for (int r = 0; r < 4; ++r) pb[base + (size_t)r * 1024] = c[r];
      }
}

__global__ void k_embmerge(const float* __restrict__ part, const float* __restrict__ bias,
                           float* __restrict__ feat) {
  int i = blockIdx.x * 256 + threadIdx.x;
  int o = (i >> 10) & 511;
  feat[i] = part[i] + part[2097152 + i] + bias[o];
}

// ---------------- channel-major GEMM
__global__ void k_gemm_cm(const float* __restrict__ X, const float* __restrict__ Wm,
                          const float* __restrict__ bias, float* __restrict__ Y) {
  int bid = blockIdx.x;
  int nch = bid & 3; bid >>= 2;
  int og  = bid & 63; bid >>= 6;
  int b   = bid;
  int n = nch * 256 + threadIdx.x;
  int o0 = og * 8;
  float acc[8];
#pragma unroll
  for (int i = 0; i < 8; ++i) acc[i] = bias[o0 + i];
  const float* xp = X + (size_t)b * 512 * HW + n;
  for (int c = 0; c < 512; ++c) {
    float v = xp[c * HW];
#pragma unroll
    for (int oo = 0; oo < 8; ++oo) acc[oo] += v * Wm[(o0 + oo) * 512 + c];
  }
#pragma unroll
  for (int oo = 0; oo < 8; ++oo)
    Y[(size_t)(b * 512 + o0 + oo) * HW + n] = acc[oo];
}

// ---------------- ln1
__global__ void k_ln1(const float* __restrict__ feat, const float* __restrict__ g_,
                      const float* __restrict__ b_, float* __restrict__ xo) {
  int t = blockIdx.x * 256 + threadIdx.x;
  int bg = t >> 10, n = t & 1023;
  const float* src = feat + (size_t)bg * 256 * HW + n;
  float s = 0.f, s2 = 0.f;
  for (int d = 0; d < 256; ++d) { float v = src[d * HW]; s += v; s2 += v * v; }
  float mean = s * (1.f / 256.f);
  float rstd = rsqrtf(s2 * (1.f / 256.f) - mean * mean + 1e-5f);
  float* dst = xo + (size_t)t * 256;
  for (int d = 0; d < 256; ++d) {
    float v = src[d * HW];
    dst[d] = (v - mean) * rstd * g_[d] + b_[d];
  }
}

// ---------------- token-major LN
__global__ void k_ln_tok(const float* __restrict__ xin, const float* __restrict__ g_,
                         const float* __restrict__ b_, float* __restrict__ yo, float eps) {
  int token = (blockIdx.x * 256 + threadIdx.x) >> 6;
  int lane = threadIdx.x & 63;
  float4 v4 = *reinterpret_cast<const float4*>(xin + (size_t)token * 256 + lane * 4);
  float s  = v4.x + v4.y + v4.z + v4.w;
  float s2 = v4.x * v4.x + v4.y * v4.y + v4.z * v4.z + v4.w * v4.w;
#pragma unroll
  for (int off = 32; off; off >>= 1) { s += __shfl_xor(s, off); s2 += __shfl_xor(s2, off); }
  float mean = s * (1.f / 256.f);
  float rstd = rsqrtf(s2 * (1.f / 256.f) - mean * mean + eps);
  float4 g4 = *reinterpret_cast<const float4*>(g_ + lane * 4);
  float4 b4 = *reinterpret_cast<const float4*>(b_ + lane * 4);
  float4 o;
  o.x = (v4.x - mean) * rstd * g4.x + b4.x;
  o.y = (v4.y - mean) * rstd * g4.y + b4.y;
  o.z = (v4.z - mean) * rstd * g4.z + b4.z;
  o.w = (v4.w - mean) * rstd * g4.w + b4.w;
  *reinterpret_cast<float4*>(yo + (size_t)token * 256 + lane * 4) = o;
}

// ---------------- token-major GEMM
__global__ void k_gemm_tm(const float* __restrict__ A, const float* __restrict__ Wm,
                          const float* __restrict__ bias, float* __restrict__ Y,
                          int O, int addres) {
  int ognum = O >> 3;
  int og = blockIdx.x % ognum;
  int tb = blockIdx.x / ognum;
  int t = tb * 256 + threadIdx.x;
  int o0 = og * 8;
  const float4* a4p = reinterpret_cast<const float4*>(A + (size_t)t * 256);
  float acc[8];
#pragma unroll
  for (int i = 0; i < 8; ++i) acc[i] = bias[o0 + i];
  for (int d4 = 0; d4 < 64; ++d4) {
    float4 a4 = a4p[d4];
#pragma unroll
    for (int oo = 0; oo < 8; ++oo) {
      const float* wr = Wm + (o0 + oo) * 256 + d4 * 4;
      acc[oo] += a4.x * wr[0] + a4.y * wr[1] + a4.z * wr[2] + a4.w * wr[3];
    }
  }
  float* y = Y + (size_t)t * O + o0;
  if (addres) {
#pragma unroll
    for (int oo = 0; oo < 8; ++oo) y[oo] += acc[oo];
  } else {
#pragma unroll
    for (int oo = 0; oo < 8; ++oo) y[oo] = acc[oo];
  }
}

// ============ attention frag preps ============
// cm source [b, 512, 1024] (c = h*64+d) -> B/A frags: tile=(bh*64+nt)*2+dc, lane: lr=n, lu*8+j=d
__global__ void k_prep_cm_frag(const float* __restrict__ src, ushort* __restrict__ dh,
                               ushort* __restrict__ dl, float scale) {
  int gtid = blockIdx.x * 256 + threadIdx.x;   // 262144
  int l = gtid & 63, tile = gtid >> 6;
  int dc = tile & 1, nt = (tile >> 1) & 63, bh = tile >> 7;
  int lr = l & 15, lu = l >> 4;
  int b = bh >> 3, h = bh & 7;
  int n = nt * 16 + lr;
  const float* sp = src + ((size_t)(b * 512 + h * 64 + dc * 32 + lu * 8)) * 1024 + n;
  V16u hi, lo;
#pragma unroll
  for (int j = 0; j < 8; ++j) {
    float v = sp[(size_t)j * 1024] * scale;
    ushort hb = bf16_rne(v);
    float hf = __uint_as_float(((unsigned int)hb) << 16);
    hi.u[j] = hb; lo.u[j] = bf16_rne(v - hf);
  }
  *(int4*)(dh + (size_t)gtid * 8) = hi.i4;
  *(int4*)(dl + (size_t)gtid * 8) = lo.i4;
}

// cm V -> V^T A-frags: tile=(bh*4+et)*32+kc, lane: lr=e, lu*8+j=k
__global__ void k_prep_v_main(const float* __restrict__ vb, ushort* __restrict__ dh,
                              ushort* __restrict__ dl) {
  int gtid = blockIdx.x * 256 + threadIdx.x;   // 262144
  int l = gtid & 63, tile = gtid >> 6;
  int kc = tile & 31, et = (tile >> 5) & 3, bh = tile >> 7;
  int lr = l & 15, lu = l >> 4;
  int b = bh >> 3, h = bh & 7;
  int e = et * 16 + lr;
  const float* sp = vb + ((size_t)(b * 512 + h * 64 + e)) * 1024 + kc * 32 + lu * 8;
  V16u hi, lo;
#pragma unroll
  for (int j = 0; j < 8; ++j) {
    float v = sp[j];
    ushort hb = bf16_rne(v);
    float hf = __uint_as_float(((unsigned int)hb) << 16);
    hi.u[j] = hb; lo.u[j] = bf16_rne(v - hf);
  }
  *(int4*)(dh + (size_t)gtid * 8) = hi.i4;
  *(int4*)(dl + (size_t)gtid * 8) = lo.i4;
}

// tm source [8192, S] (col off hh*32) -> frags: tile=bgh*64+nt, lane: lr=n, lu*8+j=d
__global__ void k_prep_tm_frag(const float* __restrict__ src, ushort* __restrict__ dh,
                               ushort* __restrict__ dl, int S, float scale) {
  int gtid = blockIdx.x * 256 + threadIdx.x;   // 262144
  int l = gtid & 63, tile = gtid >> 6;
  int nt = tile & 63, bgh = tile >> 6;
  int lr = l & 15, lu = l >> 4;
  int bg = bgh >> 3, hh = bgh & 7;
  int n = nt * 16 + lr;
  const float* sp = src + ((size_t)(bg * 1024 + n)) * S + hh * 32 + lu * 8;
  V16u hi, lo;
#pragma unroll
  for (int j = 0; j < 8; ++j) {
    float v = sp[j] * scale;
    ushort hb = bf16_rne(v);
    float hf = __uint_as_float(((unsigned int)hb) << 16);
    hi.u[j] = hb; lo.u[j] = bf16_rne(v - hf);
  }
  *(int4*)(dh + (size_t)gtid * 8) = hi.i4;
  *(int4*)(dl + (size_t)gtid * 8) = lo.i4;
}

// mb V (kv second half, tm) -> V^T frags: tile=(bgh*2+et)*32+kc, lane: lr=e, lu*8+j=k
__global__ void k_prep_v_mb(const float* __restrict__ kv, ushort* __restrict__ dh,
                            ushort* __restrict__ dl) {
  int gtid = blockIdx.x * 256 + threadIdx.x;   // 262144
  int l = gtid & 63, tile = gtid >> 6;
  int kc = tile & 31, et = (tile >> 5) & 1, bgh = tile >> 6;
  int lr = l & 15, lu = l >> 4;
  int bg = bgh >> 3, hh = bgh & 7;
  int e = et * 16 + lr;
  V16u hi, lo;
#pragma unroll
  for (int j = 0; j < 8; ++j) {
    int k = kc * 32 + lu * 8 + j;
    float v = kv[((size_t)(bg * 1024 + k)) * 512 + 256 + hh * 32 + e];
    ushort hb = bf16_rne(v);
    float hf = __uint_as_float(((unsigned int)hb) << 16);
    hi.u[j] = hb; lo.u[j] = bf16_rne(v - hf);
  }
  *(int4*)(dh + (size_t)gtid * 8) = hi.i4;
  *(int4*)(dl + (size_t)gtid * 8) = lo.i4;
}

// ============ MitBlock attention, MFMA (d=32) ============
// grid 1024 = bgh(64) x qb(16); block 256 = 4 waves, wave = 16 q x full 1024 k
__global__ __launch_bounds__(256)
void k_mbattn_mfma(const ushort* __restrict__ Qh, const ushort* __restrict__ Ql,
                   const ushort* __restrict__ Kh, const ushort* __restrict__ Kl,
                   const ushort* __restrict__ Vh, const ushort* __restrict__ Vl,
                   float* __restrict__ o_tm) {
  int qb = blockIdx.x & 15, bgh = blockIdx.x >> 4;
  int tid = threadIdx.x, w = tid >> 6, l = tid & 63, lr = l & 15, lu = l >> 4;
  int qt = qb * 4 + w;
  bf16x8 qh = ((const bf16x8*)Qh)[(size_t)(bgh * 64 + qt) * 64 + l];
  bf16x8 ql = ((const bf16x8*)Ql)[(size_t)(bgh * 64 + qt) * 64 + l];
  __shared__ ushort Ph[4][16][72];
  __shared__ ushort Pl[4][16][72];
  f32x4 zero = {0.f, 0.f, 0.f, 0.f};
  f32x4 oacc[2] = {zero, zero};
  float den = 0.f;
  for (int kb = 0; kb < 16; ++kb) {
#pragma unroll
    for (int kt4 = 0; kt4 < 4; ++kt4) {
      int kt = kb * 4 + kt4;
      bf16x8 kh = ((const bf16x8*)Kh)[(size_t)(bgh * 64 + kt) * 64 + l];
      bf16x8 kl = ((const bf16x8*)Kl)[(size_t)(bgh * 64 + kt) * 64 + l];
      f32x4 s = zero;
      s = __builtin_amdgcn_mfma_f32_16x16x32_bf16(kh, qh, s, 0, 0, 0);
      s = __builtin_amdgcn_mfma_f32_16x16x32_bf16(kh, ql, s, 0, 0, 0);
      s = __builtin_amdgcn_mfma_f32_16x16x32_bf16(kl, qh, s, 0, 0, 0);
      uint2 uh, ul;
      {
        float p0 = __expf(s[0]), p1 = __expf(s[1]), p2 = __expf(s[2]), p3 = __expf(s[3]);
        den += (p0 + p1) + (p2 + p3);
        ushort h0 = bf16_rne(p0), h1 = bf16_rne(p1), h2 = bf16_rne(p2), h3 = bf16_rne(p3);
        float f0 = __uint_as_float((unsigned)h0 << 16), f1 = __uint_as_float((unsigned)h1 << 16);
        float f2 = __uint_as_float((unsigned)h2 << 16), f3 = __uint_as_float((unsigned)h3 << 16);
        ushort l0 = bf16_rne(p0 - f0), l1 = bf16_rne(p1 - f1);
        ushort l2 = bf16_rne(p2 - f2), l3 = bf16_rne(p3 - f3);
        uh.x = (unsigned)h0 | ((unsigned)h1 << 16); uh.y = (unsigned)h2 | ((unsigned)h3 << 16);
        ul.x = (unsigned)l0 | ((unsigned)l1 << 16); ul.y = (unsigned)l2 | ((unsigned)l3 << 16);
      }
      *(uint2*)&Ph[w][lr][kt4 * 16 + lu * 4] = uh;
      *(uint2*)&Pl[w][lr][kt4 * 16 + lu * 4] = ul;
    }
#pragma unroll
    for (int kc2 = 0; kc2 < 2; ++kc2) {
      int kc = kb * 2 + kc2;
      bf16x8 bph = *(const bf16x8*)&Ph[w][lr][kc2 * 32 + lu * 8];
      bf16x8 bpl = *(const bf16x8*)&Pl[w][lr][kc2 * 32 + lu * 8];
#pragma unroll
      for (int et = 0; et < 2; ++et) {
        bf16x8 vh = ((const bf16x8*)Vh)[(size_t)((bgh * 2 + et) * 32 + kc) * 64 + l];
        bf16x8 vl = ((const bf16x8*)Vl)[(size_t)((bgh * 2 + et) * 32 + kc) * 64 + l];
        oacc[et] = __builtin_amdgcn_mfma_f32_16x16x32_bf16(vh, bph, oacc[et], 0, 0, 0);
        oacc[et] = __builtin_amdgcn_mfma_f32_16x16x32_bf16(vh, bpl, oacc[et], 0, 0, 0);
        oacc[et] = __builtin_amdgcn_mfma_f32_16x16x32_bf16(vl, bph, oacc[et], 0, 0, 0);
      }
    }
  }
  den += __shfl_xor(den, 16);
  den += __shfl_xor(den, 32);
  float inv = 1.f / den;
  int bg = bgh >> 3, hh = bgh & 7;
  int qg = qt * 16 + lr;
#pragma unroll
  for (int et = 0; et < 2; ++et) {
    float4 o4 = { oacc[et][0] * inv, oacc[et][1] * inv, oacc[et][2] * inv, oacc[et][3] * inv };
    *(float4*)&o_tm[((size_t)(bg * 1024 + qg)) * 256 + hh * 32 + et * 16 + lu * 4] = o4;
  }
}

// ============ main attention, MFMA (d=64) ============
// grid 512 = bh(32) x qb(16); block 256 = 4 waves, wave = 16 q x full 1024 k
__global__ __launch_bounds__(256)
void k_mainattn_mfma(const ushort* __restrict__ Qh, const ushort* __restrict__ Ql,
                     const ushort* __restrict__ Kh, const ushort* __restrict__ Kl,
                     const ushort* __restrict__ Vh, const ushort* __restrict__ Vl,
                     float* __restrict__ attno) {
  int qb = blockIdx.x & 15, bh = blockIdx.x >> 4;
  int tid = threadIdx.x, w = tid >> 6, l = tid & 63, lr = l & 15, lu = l >> 4;
  int qt = qb * 4 + w;
  bf16x8 qh[2], ql[2];
#pragma unroll
  for (int dc = 0; dc < 2; ++dc) {
    qh[dc] = ((const bf16x8*)Qh)[(size_t)((bh * 64 + qt) * 2 + dc) * 64 + l];
    ql[dc] = ((const bf16x8*)Ql)[(size_t)((bh * 64 + qt) * 2 + dc) * 64 + l];
  }
  __shared__ ushort Ph[4][16][72];
  __shared__ ushort Pl[4][16][72];
  f32x4 zero = {0.f, 0.f, 0.f, 0.f};
  f32x4 oacc[4] = {zero, zero, zero, zero};
  float den = 0.f;
  for (int kb = 0; kb < 16; ++kb) {
#pragma unroll
    for (int kt4 = 0; kt4 < 4; ++kt4) {
      int kt = kb * 4 + kt4;
      f32x4 s = zero;
#pragma unroll
      for (int dc = 0; dc < 2; ++dc) {
        bf16x8 kh = ((const bf16x8*)Kh)[(size_t)((bh * 64 + kt) * 2 + dc) * 64 + l];
        bf16x8 kl = ((const bf16x8*)Kl)[(size_t)((bh * 64 + kt) * 2 + dc) * 64 + l];
        s = __builtin_amdgcn_mfma_f32_16x16x32_bf16(kh, qh[dc], s, 0, 0, 0);
        s = __builtin_amdgcn_mfma_f32_16x16x32_bf16(kh, ql[dc], s, 0, 0, 0);
        s = __builtin_amdgcn_mfma_f32_16x16x32_bf16(kl, qh[dc], s, 0, 0, 0);
      }
      uint2 uh, ul;
      {
        float p0 = __expf(s[0]), p1 = __expf(s[1]), p2 = __expf(s[2]), p3 = __expf(s[3]);
        den += (p0 + p1) + (p2 + p3);
        ushort h0 = bf16_rne(p0), h1 = bf16_rne(p1), h2 = bf16_rne(p2), h3 = bf16_rne(p3);
        float f0 = __uint_as_float((unsigned)h0 << 16), f1 = __uint_as_float((unsigned)h1 << 16);
        float f2 = __uint_as_float((unsigned)h2 << 16), f3 = __uint_as_float((unsigned)h3 << 16);
        ushort l0 = bf16_rne(p0 - f0), l1 = bf16_rne(p1 - f1);
        ushort l2 = bf16_rne(p2 - f2), l3 = bf16_rne(p3 - f3);
        uh.x = (unsigned)h0 | ((unsigned)h1 << 16); uh.y = (unsigned)h2 | ((unsigned)h3 << 16);
        ul.x = (unsigned)l0 | ((unsigned)l1 << 16); ul.y = (unsigned)l2 | ((unsigned)l3 << 16);
      }
      *(uint2*)&Ph[w][lr][kt4 * 16 + lu * 4] = uh;
      *(uint2*)&Pl[w][lr][kt4 * 16 + lu * 4] = ul;
    }
#pragma unroll
    for (int kc2 = 0; kc2 < 2; ++kc2) {
      int kc = kb * 2 + kc2;
      bf16x8 bph = *(const bf16x8*)&Ph[w][lr][kc2 * 32 + lu * 8];
      bf16x8 bpl = *(const bf16x8*)&Pl[w][lr][kc2 * 32 + lu * 8];
#pragma unroll
      for (int et = 0; et < 4; ++et) {
        bf16x8 vh = ((const bf16x8*)Vh)[(size_t)((bh * 4 + et) * 32 + kc) * 64 + l];
        bf16x8 vl = ((const bf16x8*)Vl)[(size_t)((bh * 4 + et) * 32 + kc) * 64 + l];
        oacc[et] = __builtin_amdgcn_mfma_f32_16x16x32_bf16(vh, bph, oacc[et], 0, 0, 0);
        oacc[et] = __builtin_amdgcn_mfma_f32_16x16x32_bf16(vh, bpl, oacc[et], 0, 0, 0);
        oacc[et] = __builtin_amdgcn_mfma_f32_16x16x32_bf16(vl, bph, oacc[et], 0, 0, 0);
      }
    }
  }
  den += __shfl_xor(den, 16);
  den += __shfl_xor(den, 32);
  float inv = 1.f / den;
  int b = bh >> 3, h = bh & 7;
  int qg = qt * 16 + lr;
#pragma unroll
  for (int et = 0; et < 4; ++et)
#pragma unroll
    for (int r = 0; r < 4; ++r)
      attno[((size_t)(b * 512 + h * 64 + et * 16 + lu * 4 + r)) * 1024 + qg] = oacc[et][r] * inv;
}

// ---------------- fc1
__global__ void k_fc1(const float* __restrict__ A, const float* __restrict__ Wm,
                      const float* __restrict__ bias, float* __restrict__ Y) {
  int bid = blockIdx.x;
  int nch = bid & 3; bid >>= 2;
  int og  = bid & 127; bid >>= 7;
  int bg  = bid;
  int n = nch * 256 + threadIdx.x;
  int t = (bg << 10) + n;
  const float4* a4p = reinterpret_cast<const float4*>(A + (size_t)t * 256);
  int o0 = og * 8;
  float acc[8];
#pragma unroll
  for (int i = 0; i < 8; ++i) acc[i] = bias[o0 + i];
  for (int d4 = 0; d4 < 64; ++d4) {
    float4 a4 = a4p[d4];
#pragma unroll
    for (int oo = 0; oo < 8; ++oo) {
      const float* wr = Wm + (o0 + oo) * 256 + d4 * 4;
      acc[oo] += a4.x * wr[0] + a4.y * wr[1] + a4.z * wr[2] + a4.w * wr[3];
    }
  }
#pragma unroll
  for (int oo = 0; oo < 8; ++oo)
    Y[(size_t)((bg << 10) + o0 + oo) * HW + n] = acc[oo];
}

// ---------------- depthwise 3x3 + bias + exact GELU
__global__ void k_dw3(const float* __restrict__ X, const float* __restrict__ w,
                      const float* __restrict__ bias, float* __restrict__ Y) {
  int idx = blockIdx.x * 256 + threadIdx.x;
  int x = idx & 31, y = (idx >> 5) & 31, ch = (idx >> 10) & 1023, bg = idx >> 20;
  const float* src = X + (size_t)((bg << 10) + ch) * HW;
  const float* wr = w + ch * 9;
  float acc = bias[ch];
#pragma unroll
  for (int ky = 0; ky < 3; ++ky) {
    int yy = y + ky - 1;
    if ((unsigned)yy < 32u) {
      const float* row = src + yy * 32;
#pragma unroll
      for (int kx = 0; kx < 3; ++kx) {
        int xx = x + kx - 1;
        if ((unsigned)xx < 32u) acc += row[xx] * wr[ky * 3 + kx];
      }
    }
  }
  Y[(size_t)((bg << 10) + ch) * HW + y * 32 + x] = gelu_exact(acc);
}

// ---------------- fc2 fused residual
__global__ void k_fc2(const float* __restrict__ Mi, const float* __restrict__ Wm,
                      const float* __restrict__ bias, const float* __restrict__ Xres,
                      float* __restrict__ Y) {
  int bid = blockIdx.x;
  int nch = bid & 3; bid >>= 2;
  int og  = bid & 31; bid >>= 5;
  int bg  = bid;
  int n = nch * 256 + threadIdx.x;
  int o0 = og * 8;
  float acc[8];
#pragma unroll
  for (int i = 0; i < 8; ++i)
    acc[i] = bias[o0 + i] + Xres[(size_t)((bg << 10) + n) * 256 + o0 + i];
  const float* mp = Mi + (size_t)(bg << 10) * HW + n;
  for (int h = 0; h < 1024; ++h) {
    float v = mp[(size_t)h * HW];
#pragma unroll
    for (int oo = 0; oo < 8; ++oo) acc[oo] += v * Wm[(o0 + oo) * 1024 + h];
  }
#pragma unroll
  for (int oo = 0; oo < 8; ++oo)
    Y[(size_t)((bg << 8) + o0 + oo) * HW + n] = acc[oo];
}

// ---------------- depthwise 9x9 pad 4 + bias
__global__ void k_dw9(const float* __restrict__ X, const float* __restrict__ w,
                      const float* __restrict__ bias, float* __restrict__ Y) {
  int idx = blockIdx.x * 256 + threadIdx.x;
  int x = idx & 31, y = (idx >> 5) & 31, ch = (idx >> 10) & 255, bg = idx >> 18;
  const float* src = X + (size_t)((bg << 8) + ch) * HW;
  const float* wr = w + ch * 81;
  float acc = bias[ch];
  for (int ky = 0; ky < 9; ++ky) {
    int yy = y + ky - 4;
    if ((unsigned)yy < 32u) {
      const float* row = src + yy * 32;
#pragma unroll
      for (int kx = 0; kx < 9; ++kx) {
        int xx = x + kx - 4;
        if ((unsigned)xx < 32u) acc += row[xx] * wr[ky * 9 + kx];
      }
    }
  }
  Y[(size_t)((bg << 8) + ch) * HW + y * 32 + x] = acc;
}

// ---------------- co tail
__global__ void k_cotail(const float* __restrict__ Xdw, const float* __restrict__ lnw,
                         const float* __restrict__ lnb, const float* __restrict__ w2,
                         float* __restrict__ pos) {
  int t = blockIdx.x * 256 + threadIdx.x;
  int bg = t >> 10, n = t & 1023;
  const float* src = Xdw + (size_t)(bg << 8) * HW + n;
  float s = 0.f, s2 = 0.f;
  for (int c = 0; c < 256; ++c) { float v = src[c * HW]; s += v; s2 += v * v; }
  float mean = s * (1.f / 256.f);
  float rstd = rsqrtf(s2 * (1.f / 256.f) - mean * mean + 1e-5f);
  float o0 = 0.f, o1 = 0.f;
  for (int c = 0; c < 256; ++c) {
    float v = (src[c * HW] - mean) * rstd * lnw[c] + lnb[c];
    float ge = gelu_exact(v);
    o0 += ge * w2[c];
    o1 += ge * w2[256 + c];
  }
  float offy = tanhf(o0) * (2.f / 32.f);
  float offx = tanhf(o1) * (2.f / 32.f);
  int ky = n >> 5, kx = n & 31;
  float refy = ((ky + 0.5f) * (1.f / 32.f)) * 2.f - 1.f;
  float refx = ((kx + 0.5f) * (1.f / 32.f)) * 2.f - 1.f;
  pos[t * 2]     = offx + refx;
  pos[t * 2 + 1] = offy + refy;
}

// ---------------- bilinear grid sample
__global__ void k_gsample(const float* __restrict__ feat, const float* __restrict__ pos,
                          float* __restrict__ out) {
  int bid = blockIdx.x;
  int nch = bid & 3; int bg = bid >> 2;
  int j = nch * 256 + threadIdx.x;
  float gx = pos[((bg << 10) + j) * 2];
  float gy = pos[((bg << 10) + j) * 2 + 1];
  float fx = (gx + 1.f) * 0.5f * 31.f;
  float fy = (gy + 1.f) * 0.5f * 31.f;
  float x0f = floorf(fx), y0f = floorf(fy);
  int x0 = (int)x0f, y0 = (int)y0f;
  float wx1 = fx - x0f, wx0 = 1.f - wx1;
  float wy1 = fy - y0f, wy0 = 1.f - wy1;
  bool vx0 = (x0 >= 0) & (x0 <= 31);
  bool vx1 = (x0 + 1 >= 0) & (x0 + 1 <= 31);
  bool vy0 = (y0 >= 0) & (y0 <= 31);
  bool vy1 = (y0 + 1 >= 0) & (y0 + 1 <= 31);
  int cx0 = min(max(x0, 0), 31), cx1 = min(max(x0 + 1, 0), 31);
  int cy0 = min(max(y0, 0), 31), cy1 = min(max(y0 + 1, 0), 31);
  float w00 = wx0 * wy0 * ((vx0 && vy0) ? 1.f : 0.f);
  float w10 = wx1 * wy0 * ((vx1 && vy0) ? 1.f : 0.f);
  float w01 = wx0 * wy1 * ((vx0 && vy1) ? 1.f : 0.f);
  float w11 = wx1 * wy1 * ((vx1 && vy1) ? 1.f : 0.f);
  int i00 = cy0 * 32 + cx0, i10 = cy0 * 32 + cx1;
  int i01 = cy1 * 32 + cx0, i11 = cy1 * 32 + cx1;
  const float* src = feat + (size_t)(bg << 8) * HW;
  float* dst = out + (size_t)(bg << 8) * HW + j;
  for (int c = 0; c < 256; ++c) {
    const float* sp = src + (size_t)c * HW;
    dst[(size_t)c * HW] = sp[i00] * w00 + sp[i10] * w10 + sp[i01] * w01 + sp[i11] * w11;
  }
}

// ---------------------------------------------------------------------------
extern "C" void kernel_launch(void* const* d_in, const int* in_sizes, int n_in,
                              void* d_out, int out_size, void* d_ws, size_t ws_size,
                              hipStream_t stream) {
  const float* tgt    = (const float*)d_in[0];
  const float* refp   = (const float*)d_in[1];
  const float* emb_w  = (const float*)d_in[2];
  const float* emb_b  = (const float*)d_in[3];
  const float* q_w    = (const float*)d_in[4];
  const float* q_b    = (const float*)d_in[5];
  const float* k_w    = (const float*)d_in[6];
  const float* k_b    = (const float*)d_in[7];
  const float* v_w    = (const float*)d_in[8];
  const float* v_b    = (const float*)d_in[9];
  const float* out_w  = (const float*)d_in[10];
  const float* out_b  = (const float*)d_in[11];
  const float* ln1_w  = (const float*)d_in[12];
  const float* ln1_b  = (const float*)d_in[13];
  const float* n1_w   = (const float*)d_in[14];
  const float* n1_b   = (const float*)d_in[15];
  const float* mbq_w  = (const float*)d_in[16];
  const float* mbq_b  = (const float*)d_in[17];
  const float* mbkv_w = (const float*)d_in[18];
  const float* mbkv_b = (const float*)d_in[19];
  const float* mbp_w  = (const float*)d_in[20];
  const float* mbp_b  = (const float*)d_in[21];
  const float* n2_w   = (const float*)d_in[22];
  const float* n2_b   = (const float*)d_in[23];
  const float* fc1_w  = (const float*)d_in[24];
  const float* fc1_b  = (const float*)d_in[25];
  const float* dw3_w  = (const float*)d_in[26];
  const float* dw3_b  = (const float*)d_in[27];
  const float* fc2_w  = (const float*)d_in[28];
  const float* fc2_b  = (const float*)d_in[29];
  const float* dw9_w  = (const float*)d_in[30];
  const float* dw9_b  = (const float*)d_in[31];
  const float* coln_w = (const float*)d_in[32];
  const float* coln_b = (const float*)d_in[33];
  const float* coout_w= (const float*)d_in[34];

  float* ws = (float*)d_ws;
  float* feat   = ws + OFF_FEAT;
  float* qbuf   = ws + OFF_Q;
  float* xbuf   = ws + OFF_X;
  float* hbuf   = ws + OFF_H;
  float* qqbuf  = ws + OFF_QQ;
  float* kvbuf  = ws + OFF_KV;
  float* mbuf   = ws + OFF_M;
  float* mibuf  = ws + OFF_MI;
  float* offin  = ws + OFF_OFFIN;
  float* offdw  = ws + OFF_OFFDW;
  float* posb   = ws + OFF_POS;

  float* sampled = mbuf;
  float* kbuf    = mbuf + 2097152;
  float* vbuf    = mbuf + 4194304;
  float* attno   = mbuf + 6291456;

  // emb-prep scratch
  ushort* Xt_hi = (ushort*)(ws + OFF_X);
  ushort* Xt_lo = (ushort*)(ws + OFF_X + 2367488);
  ushort* Wt_hi = (ushort*)(ws + OFF_M);
  ushort* Wt_lo = (ushort*)(ws + OFF_M + 2359296);
  float*  part  = ws + OFF_MI;

  // mb attention frag buffers (in OFF_M region, free between emb and fc1)
  ushort* mQh = (ushort*)(ws + OFF_M);
  ushort* mQl = mQh + 2097152;
  ushort* mKh = mQh + 4194304;
  ushort* mKl = mQh + 6291456;
  ushort* mVh = mQh + 8388608;
  ushort* mVl = mQh + 10485760;

  // main attention frag buffers (in OFF_MI region, free after fc2)
  ushort* aQh = (ushort*)(ws + OFF_MI);
  ushort* aQl = aQh + 2097152;
  ushort* aKh = aQh + 4194304;
  ushort* aKl = aQh + 6291456;
  ushort* aVh = aQh + 8388608;
  ushort* aVl = aQh + 10485760;

  // 1. embedding conv (MFMA, split-bf16)
  k_prepw<<<2048, 256, 0, stream>>>(emb_w, Wt_hi, Wt_lo);
  k_prepx<<<2312, 256, 0, stream>>>(tgt, refp, Xt_hi, Xt_lo);
  k_emb_mfma<<<512, 256, 0, stream>>>(Xt_hi, Xt_lo, Wt_hi, Wt_lo, part);
  k_embmerge<<<8192, 256, 0, stream>>>(part, emb_b, feat);
  // 2. q projection
  k_gemm_cm<<<1024, 256, 0, stream>>>(tgt, q_w, q_b, qbuf);
  // 3. ln1 -> x
  k_ln1<<<32, 256, 0, stream>>>(feat, ln1_w, ln1_b, xbuf);
  // 4. mb_n1 -> h
  k_ln_tok<<<2048, 256, 0, stream>>>(xbuf, n1_w, n1_b, hbuf, 1e-6f);
  // 5. mb q/kv projections
  k_gemm_tm<<<1024, 256, 0, stream>>>(hbuf, mbq_w, mbq_b, qqbuf, 256, 0);
  k_gemm_tm<<<2048, 256, 0, stream>>>(hbuf, mbkv_w, mbkv_b, kvbuf, 512, 0);
  // 6. mb attention (MFMA) -> o_tm (hbuf)
  k_prep_tm_frag<<<1024, 256, 0, stream>>>(qqbuf, mQh, mQl, 256, 0.17677669529663689f);
  k_prep_tm_frag<<<1024, 256, 0, stream>>>(kvbuf, mKh, mKl, 512, 1.f);
  k_prep_v_mb<<<1024, 256, 0, stream>>>(kvbuf, mVh, mVl);
  k_mbattn_mfma<<<1024, 256, 0, stream>>>(mQh, mQl, mKh, mKl, mVh, mVl, hbuf);
  // 7. x += proj(o)
  k_gemm_tm<<<1024, 256, 0, stream>>>(hbuf, mbp_w, mbp_b, xbuf, 256, 1);
  // 8. mb_n2 -> h2
  k_ln_tok<<<2048, 256, 0, stream>>>(xbuf, n2_w, n2_b, qqbuf, 1e-6f);
  // 9. fc1 -> m channel-major
  k_fc1<<<4096, 256, 0, stream>>>(qqbuf, fc1_w, fc1_b, mbuf);
  // 10. dw3 + gelu
  k_dw3<<<32768, 256, 0, stream>>>(mbuf, dw3_w, dw3_b, mibuf);
  // 11. fc2 fused residual -> offin
  k_fc2<<<1024, 256, 0, stream>>>(mibuf, fc2_w, fc2_b, xbuf, offin);
  // 12. dw9
  k_dw9<<<8192, 256, 0, stream>>>(offin, dw9_w, dw9_b, offdw);
  // 13. LN + gelu + proj + tanh -> pos
  k_cotail<<<32, 256, 0, stream>>>(offdw, coln_w, coln_b, coout_w, posb);
  // 14. grid sample
  k_gsample<<<32, 256, 0, stream>>>(feat, posb, sampled);
  // 15. k/v projections
  k_gemm_cm<<<1024, 256, 0, stream>>>(sampled, k_w, k_b, kbuf);
  k_gemm_cm<<<1024, 256, 0, stream>>>(sampled, v_w, v_b, vbuf);
  // 16. main attention (MFMA) -> attno
  k_prep_cm_frag<<<1024, 256, 0, stream>>>(qbuf, aQh, aQl, 0.125f);
  k_prep_cm_frag<<<1024, 256, 0, stream>>>(kbuf, aKh, aKl, 1.f);
  k_prep_v_main<<<1024, 256, 0, stream>>>(vbuf, aVh, aVl);
  k_mainattn_mfma<<<512, 256, 0, stream>>>(aQh, aQl, aKh, aKl, aVh, aVl, attno);
  // 17. out projection
  k_gemm_cm<<<1024, 256, 0, stream>>>(attno, out_w, out_b, (float*)d_out);
}

// Round 4
// 770.157 us; speedup vs baseline: 3.9659x; 1.5925x over previous
//
#include <hip/hip_runtime.h>
#include <math.h>

// ---------------------------------------------------------------------------
// DAttention forward. R4: everything matmul-shaped on split-bf16 MFMA.
// Dims: B=4, C=512, H=W=32, G=2, gc=256, BG=8, heads=8, hc=64, mh=8, mhd=32,
//       hid=1024, N=HW=1024, ns=1024.
// ---------------------------------------------------------------------------

static constexpr int HW = 1024;

typedef __attribute__((ext_vector_type(8))) short bf16x8;
typedef __attribute__((ext_vector_type(4))) float f32x4;

union V16u { int4 i4; ushort u[8]; };

__device__ __forceinline__ float gelu_exact(float v) {
  return 0.5f * v * (1.0f + erff(v * 0.7071067811865475f));
}

__device__ __forceinline__ ushort bf16_rne(float v) {
  unsigned int b = __float_as_uint(v);
  return (ushort)((b + 0x7fffu + ((b >> 16) & 1u)) >> 16);
}

__device__ __forceinline__ void split2(float v, ushort& h, ushort& l) {
  h = bf16_rne(v);
  l = bf16_rne(v - __uint_as_float(((unsigned int)h) << 16));
}

// ---------------- emb prep: weights [512][1024][3][3] -> [9][512][1024] bf16 hi/lo
__global__ void k_prepw(const float* __restrict__ w, ushort* __restrict__ Wt_hi,
                        ushort* __restrict__ Wt_lo) {
  int idx = blockIdx.x * 256 + threadIdx.x;    // 524288
  int o = idx >> 10, ci = idx & 1023;
  const float* src = w + (size_t)idx * 9;
#pragma unroll
  for (int t = 0; t < 9; ++t) {
    ushort h, l; split2(src[t], h, l);
    size_t oo = ((size_t)(t * 512 + o)) * 1024 + ci;
    Wt_hi[oo] = h; Wt_lo[oo] = l;
  }
}

// ---------------- emb prep: inputs -> [4][34][34][1024] bf16 hi/lo (padded)
__global__ void k_prepx(const float* __restrict__ tgt, const float* __restrict__ refp,
                        ushort* __restrict__ Xt_hi, ushort* __restrict__ Xt_lo) {
  int idx = blockIdx.x * 256 + threadIdx.x;    // 591872
  int xp = idx % 34; int r = idx / 34;
  int g8 = r & 127; r >>= 7;
  int yp = r % 34; int b = r / 34;
  int y = yp - 1, x = xp - 1;
  bool valid = (unsigned)y < 32u && (unsigned)x < 32u;
  V16u hi, lo;
  const float* in = (g8 < 64) ? (tgt + ((size_t)(b * 512 + g8 * 8)) * HW)
                              : (refp + ((size_t)(b * 512 + (g8 - 64) * 8)) * HW);
#pragma unroll
  for (int j = 0; j < 8; ++j) {
    float v = valid ? in[(size_t)j * HW + y * 32 + x] : 0.f;
    split2(v, hi.u[j], lo.u[j]);
  }
  size_t oo = (((size_t)(b * 34 + yp)) * 34 + xp) * 1024 + g8 * 8;
  *(int4*)(Xt_hi + oo) = hi.i4;
  *(int4*)(Xt_lo + oo) = lo.i4;
}

// ---------------- emb conv via MFMA, split-bf16 3-term, 2-way K-split
// swizzle f(px)=(px>>1)&3: 16B slot = 4*(px&1) + (lu^f(px)) -> max 2-way conflict
__global__ __launch_bounds__(256, 2)
void k_emb_mfma(const ushort* __restrict__ Xt_hi, const ushort* __restrict__ Xt_lo,
                const ushort* __restrict__ Wt_hi, const ushort* __restrict__ Wt_lo,
                float* __restrict__ part) {
  int bid = blockIdx.x;
  int ks = bid & 1; bid >>= 1;
  int mt = bid & 3; bid >>= 2;
  int yt = bid & 15; bid >>= 4;
  int b = bid;
  int tid = threadIdx.x;
  int w = tid >> 6, l = tid & 63;
  int lr = l & 15, lu = l >> 4;
  int y0 = yt * 2;
  int obase = mt * 128 + w * 32;

  __shared__ int4 LsH[2][576];
  __shared__ int4 LsL[2][576];

  int4 gh[3], gl[3];
  int kc0 = ks * 16;

  auto loadstage = [&](int kcg) {
#pragma unroll
    for (int i = 0; i < 3; ++i) {
      int s = tid + 256 * i;
      if (s < 576) {
        int px = s >> 2;
        int pxc = px > 135 ? 135 : px;
        int u = (s & 3) ^ ((pxc >> 1) & 3);
        size_t off = (((size_t)(b * 34 + y0)) * 34 + pxc) * 1024 + kcg * 32 + u * 8;
        gh[i] = *(const int4*)(Xt_hi + off);
        gl[i] = *(const int4*)(Xt_lo + off);
      }
    }
  };
  auto writestage = [&](int buf) {
#pragma unroll
    for (int i = 0; i < 3; ++i) {
      int s = tid + 256 * i;
      if (s < 576) { LsH[buf][s] = gh[i]; LsL[buf][s] = gl[i]; }
    }
  };

  f32x4 zero = {0.f, 0.f, 0.f, 0.f};
  f32x4 acc[2][4];
#pragma unroll
  for (int a = 0; a < 2; ++a)
#pragma unroll
    for (int n = 0; n < 4; ++n) acc[a][n] = zero;

  loadstage(kc0);
  writestage(0);

  for (int kc = 0; kc < 16; ++kc) {
    int buf = kc & 1;
    __syncthreads();
    if (kc < 15) loadstage(kc0 + kc + 1);
    int kcg = kc0 + kc;
    const bf16x8* BH = (const bf16x8*)&LsH[buf][0];
    const bf16x8* BL = (const bf16x8*)&LsL[buf][0];
#pragma unroll
    for (int kx = 0; kx < 3; ++kx) {
      bf16x8 bh[8], bl[8];
#pragma unroll
      for (int f = 0; f < 8; ++f) {
        int px = (f >> 1) * 34 + (f & 1) * 16 + kx + lr;
        int idx = px * 4 + (lu ^ ((px >> 1) & 3));
        bh[f] = BH[idx]; bl[f] = BL[idx];
      }
#pragma unroll
      for (int ky = 0; ky < 3; ++ky) {
        int tap = ky * 3 + kx;
        size_t wo = (((size_t)(tap * 512 + obase + lr)) * 1024) + kcg * 32 + lu * 8;
        bf16x8 ah0 = *(const bf16x8*)(Wt_hi + wo);
        bf16x8 al0 = *(const bf16x8*)(Wt_lo + wo);
        bf16x8 ah1 = *(const bf16x8*)(Wt_hi + wo + 16 * 1024);
        bf16x8 al1 = *(const bf16x8*)(Wt_lo + wo + 16 * 1024);
#pragma unroll
        for (int yr = 0; yr < 2; ++yr)
#pragma unroll
          for (int h = 0; h < 2; ++h) {
            int f = (yr + ky) * 2 + h;
            int nf = yr * 2 + h;
            acc[0][nf] = __builtin_amdgcn_mfma_f32_16x16x32_bf16(ah0, bh[f], acc[0][nf], 0, 0, 0);
            acc[0][nf] = __builtin_amdgcn_mfma_f32_16x16x32_bf16(ah0, bl[f], acc[0][nf], 0, 0, 0);
            acc[0][nf] = __builtin_amdgcn_mfma_f32_16x16x32_bf16(al0, bh[f], acc[0][nf], 0, 0, 0);
            acc[1][nf] = __builtin_amdgcn_mfma_f32_16x16x32_bf16(ah1, bh[f], acc[1][nf], 0, 0, 0);
            acc[1][nf] = __builtin_amdgcn_mfma_f32_16x16x32_bf16(ah1, bl[f], acc[1][nf], 0, 0, 0);
            acc[1][nf] = __builtin_amdgcn_mfma_f32_16x16x32_bf16(al1, bh[f], acc[1][nf], 0, 0, 0);
          }
      }
    }
    if (kc < 15) writestage(buf ^ 1);
  }

  float* pb = part + (size_t)ks * 2097152;
#pragma unroll
  for (int a = 0; a < 2; ++a)
#pragma unroll
    for (int yr = 0; yr < 2; ++yr)
#pragma unroll
      for (int h = 0; h < 2; ++h) {
        f32x4 c = acc[a][yr * 2 + h];
        size_t base = ((size_t)(b * 512 + obase + a * 16 + lu * 4)) * 1024
                      + (y0 + yr) * 32 + h * 16 + lr;
#pragma unroll
        for (int r = 0; r < 4; ++r) pb[base + (size_t)r * 1024] = c[r];
      }
}

__global__ void k_embmerge(const float* __restrict__ part, const float* __restrict__ bias,
                           float* __restrict__ feat) {
  int i = blockIdx.x * 256 + threadIdx.x;
  int o = (i >> 10) & 511;
  feat[i] = part[i] + part[2097152 + i] + bias[o];
}

// ============ generic frag preps ============
// weights [O,K] -> A-frags: fr=(ot*KC+kc), lane lr=o, lu*8+j=k
__global__ void k_prep_wfrag(const float* __restrict__ W, int K, int KC,
                             ushort* __restrict__ dh, ushort* __restrict__ dl) {
  int gtid = blockIdx.x * 256 + threadIdx.x;
  int l = gtid & 63; int fr = gtid >> 6;
  int kc = fr % KC; int ot = fr / KC;
  int lr = l & 15, lu = l >> 4;
  const float* sp = W + (size_t)(ot * 16 + lr) * K + kc * 32 + lu * 8;
  V16u hi, lo;
#pragma unroll
  for (int j = 0; j < 8; ++j) split2(sp[j], hi.u[j], lo.u[j]);
  *(int4*)(dh + (size_t)gtid * 8) = hi.i4;
  *(int4*)(dl + (size_t)gtid * 8) = lo.i4;
}

// cm activations [b][CH][1024] -> B-frags: fr=((b*64+nt)*KC+kc), lane lr=n, lu*8+j=k
__global__ void k_prep_cm2frag(const float* __restrict__ src, int CH, int KC,
                               ushort* __restrict__ dh, ushort* __restrict__ dl) {
  int gtid = blockIdx.x * 256 + threadIdx.x;
  int l = gtid & 63; int fr = gtid >> 6;
  int kc = fr % KC; int r2 = fr / KC; int nt = r2 & 63; int b = r2 >> 6;
  int lr = l & 15, lu = l >> 4;
  const float* sp = src + ((size_t)(b * CH) + kc * 32 + lu * 8) * 1024 + nt * 16 + lr;
  V16u hi, lo;
#pragma unroll
  for (int j = 0; j < 8; ++j) split2(sp[(size_t)j * 1024], hi.u[j], lo.u[j]);
  *(int4*)(dh + (size_t)gtid * 8) = hi.i4;
  *(int4*)(dl + (size_t)gtid * 8) = lo.i4;
}

// tm activations [b*1024][D] -> B-frags: fr=((b*64+nt)*KC+kc), lane lr=n(row), lu*8+j=d
__global__ void k_prep_tm2frag(const float* __restrict__ src, int D, int KC,
                               ushort* __restrict__ dh, ushort* __restrict__ dl) {
  int gtid = blockIdx.x * 256 + threadIdx.x;
  int l = gtid & 63; int fr = gtid >> 6;
  int kc = fr % KC; int r2 = fr / KC; int nt = r2 & 63; int b = r2 >> 6;
  int lr = l & 15, lu = l >> 4;
  const float* sp = src + ((size_t)(b * 1024 + nt * 16 + lr)) * D + kc * 32 + lu * 8;
  V16u hi, lo;
#pragma unroll
  for (int j = 0; j < 8; ++j) split2(sp[j], hi.u[j], lo.u[j]);
  *(int4*)(dh + (size_t)gtid * 8) = hi.i4;
  *(int4*)(dl + (size_t)gtid * 8) = lo.i4;
}

// sampled_nc [8bg][1024][256] viewed as [4b][512ch] -> B-frags (b,KC=16)
__global__ void k_prep_s2frag(const float* __restrict__ snc,
                              ushort* __restrict__ dh, ushort* __restrict__ dl) {
  int gtid = blockIdx.x * 256 + threadIdx.x;   // 262144
  int l = gtid & 63; int fr = gtid >> 6;
  int kc = fr & 15; int nt = (fr >> 4) & 63; int b = fr >> 10;
  int lr = l & 15, lu = l >> 4;
  const float* sp = snc + ((size_t)((b * 2 + (kc >> 3)) * 1024 + nt * 16 + lr)) * 256
                    + (kc & 7) * 32 + lu * 8;
  V16u hi, lo;
#pragma unroll
  for (int j = 0; j < 8; ++j) split2(sp[j], hi.u[j], lo.u[j]);
  *(int4*)(dh + (size_t)gtid * 8) = hi.i4;
  *(int4*)(dl + (size_t)gtid * 8) = lo.i4;
}

// ============ generic MFMA GEMM: Y[b][Mtot][1024] = W[Mtot,K] x B + bias ============
// grid = B * MT * 16; block 256 (4 waves); wave = 32 o x 64 n; 3-term split
__global__ __launch_bounds__(256)
void k_gemm_mfma(const ushort* __restrict__ Ah, const ushort* __restrict__ Al,
                 const ushort* __restrict__ Bh, const ushort* __restrict__ Bl,
                 const float* __restrict__ bias, float* __restrict__ Y,
                 int KC, int MT, int Mtot) {
  int bid = blockIdx.x;
  int ntb = bid & 15; bid >>= 4;
  int mt = bid % MT; int b = bid / MT;
  int tid = threadIdx.x, w = tid >> 6, l = tid & 63, lr = l & 15, lu = l >> 4;
  int ot0 = mt * 8 + w * 2;
  const bf16x8* pAh = (const bf16x8*)Ah;
  const bf16x8* pAl = (const bf16x8*)Al;
  const bf16x8* pBh = (const bf16x8*)Bh;
  const bf16x8* pBl = (const bf16x8*)Bl;
  f32x4 zero = {0.f, 0.f, 0.f, 0.f};
  f32x4 acc[2][4];
#pragma unroll
  for (int a = 0; a < 2; ++a)
#pragma unroll
    for (int n = 0; n < 4; ++n) acc[a][n] = zero;
  for (int kc = 0; kc < KC; ++kc) {
    bf16x8 a_h[2], a_l[2];
#pragma unroll
    for (int a = 0; a < 2; ++a) {
      size_t idx = ((size_t)(ot0 + a) * KC + kc) * 64 + l;
      a_h[a] = pAh[idx]; a_l[a] = pAl[idx];
    }
#pragma unroll
    for (int n = 0; n < 4; ++n) {
      size_t idx = (((size_t)(b * 64 + ntb * 4 + n)) * KC + kc) * 64 + l;
      bf16x8 b_h = pBh[idx], b_l = pBl[idx];
#pragma unroll
      for (int a = 0; a < 2; ++a) {
        acc[a][n] = __builtin_amdgcn_mfma_f32_16x16x32_bf16(a_h[a], b_h, acc[a][n], 0, 0, 0);
        acc[a][n] = __builtin_amdgcn_mfma_f32_16x16x32_bf16(a_h[a], b_l, acc[a][n], 0, 0, 0);
        acc[a][n] = __builtin_amdgcn_mfma_f32_16x16x32_bf16(a_l[a], b_h, acc[a][n], 0, 0, 0);
      }
    }
  }
#pragma unroll
  for (int a = 0; a < 2; ++a) {
    int o = (ot0 + a) * 16 + lu * 4;
#pragma unroll
    for (int n = 0; n < 4; ++n) {
      int col = (ntb * 4 + n) * 16 + lr;
#pragma unroll
      for (int r = 0; r < 4; ++r)
        Y[((size_t)(b * Mtot + o + r)) * 1024 + col] = acc[a][n][r] + bias[o + r];
    }
  }
}

// ============ transpose / transadd ============
// src [8][256][1024] -> dst [8][1024][256]
__global__ void k_transpose_nc(const float* __restrict__ src, float* __restrict__ dst) {
  __shared__ float T[64][65];
  int bid = blockIdx.x; int n0 = (bid & 15) << 6; bid >>= 4;
  int c0 = (bid & 3) << 6; int bg = bid >> 2;
  int cl = threadIdx.x & 63, rw = threadIdx.x >> 6;
#pragma unroll
  for (int i = 0; i < 16; ++i) {
    int crow = i * 4 + rw;
    T[crow][cl] = src[((size_t)(bg * 256 + c0 + crow)) * 1024 + n0 + cl];
  }
  __syncthreads();
#pragma unroll
  for (int i = 0; i < 16; ++i) {
    int nrow = i * 4 + rw;
    dst[((size_t)(bg * 1024 + n0 + nrow)) * 256 + c0 + cl] = T[cl][nrow];
  }
}

// out_cm = Yg_cm + transpose(Xtm)   (fc2 residual)
__global__ void k_transadd_cm(const float* __restrict__ Yg, const float* __restrict__ Xtm,
                              float* __restrict__ out) {
  __shared__ float T[64][65];
  int bid = blockIdx.x; int n0 = (bid & 15) << 6; bid >>= 4;
  int c0 = (bid & 3) << 6; int bg = bid >> 2;
  int cl = threadIdx.x & 63, rw = threadIdx.x >> 6;
#pragma unroll
  for (int i = 0; i < 16; ++i) {
    int nloc = i * 4 + rw;
    T[nloc][cl] = Xtm[((size_t)((bg << 10) + n0 + nloc)) * 256 + c0 + cl];
  }
  __syncthreads();
#pragma unroll
  for (int i = 0; i < 16; ++i) {
    int crow = i * 4 + rw;
    size_t oidx = ((size_t)(bg * 256 + c0 + crow)) * 1024 + n0 + cl;
    out[oidx] = Yg[oidx] + T[cl][crow];
  }
}

// Xtm += transpose(P_cm)   (mbproj residual)
__global__ void k_transadd_tm(const float* __restrict__ Pcm, float* __restrict__ Xtm) {
  __shared__ float T[64][65];
  int bid = blockIdx.x; int n0 = (bid & 15) << 6; bid >>= 4;
  int c0 = (bid & 3) << 6; int bg = bid >> 2;
  int cl = threadIdx.x & 63, rw = threadIdx.x >> 6;
#pragma unroll
  for (int i = 0; i < 16; ++i) {
    int crow = i * 4 + rw;
    T[crow][cl] = Pcm[((size_t)(bg * 256 + c0 + crow)) * 1024 + n0 + cl];
  }
  __syncthreads();
#pragma unroll
  for (int i = 0; i < 16; ++i) {
    int nrow = i * 4 + rw;
    Xtm[((size_t)((bg << 10) + n0 + nrow)) * 256 + c0 + cl] += T[cl][nrow];
  }
}

// ---------------- token-major LN (wave per token)
__global__ void k_ln_tok(const float* __restrict__ xin, const float* __restrict__ g_,
                         const float* __restrict__ b_, float* __restrict__ yo, float eps) {
  int token = (blockIdx.x * 256 + threadIdx.x) >> 6;
  int lane = threadIdx.x & 63;
  float4 v4 = *reinterpret_cast<const float4*>(xin + (size_t)token * 256 + lane * 4);
  float s  = v4.x + v4.y + v4.z + v4.w;
  float s2 = v4.x * v4.x + v4.y * v4.y + v4.z * v4.z + v4.w * v4.w;
#pragma unroll
  for (int off = 32; off; off >>= 1) { s += __shfl_xor(s, off); s2 += __shfl_xor(s2, off); }
  float mean = s * (1.f / 256.f);
  float rstd = rsqrtf(s2 * (1.f / 256.f) - mean * mean + eps);
  float4 g4 = *reinterpret_cast<const float4*>(g_ + lane * 4);
  float4 b4 = *reinterpret_cast<const float4*>(b_ + lane * 4);
  float4 o;
  o.x = (v4.x - mean) * rstd * g4.x + b4.x;
  o.y = (v4.y - mean) * rstd * g4.y + b4.y;
  o.z = (v4.z - mean) * rstd * g4.z + b4.z;
  o.w = (v4.w - mean) * rstd * g4.w + b4.w;
  *reinterpret_cast<float4*>(yo + (size_t)token * 256 + lane * 4) = o;
}

// ============ mb attention frag preps (cm sources) ============
// head-split cm [bg][CH][1024] -> frags fr=bgh*64+nt, lane lr=n, lu*8+j=d(32)
__global__ void k_prep_hsplit_cm(const float* __restrict__ src, int CH,
                                 ushort* __restrict__ dh, ushort* __restrict__ dl,
                                 float scale) {
  int gtid = blockIdx.x * 256 + threadIdx.x;   // 262144
  int l = gtid & 63; int fr = gtid >> 6;
  int nt = fr & 63; int bgh = fr >> 6;
  int bg = bgh >> 3, hh = bgh & 7;
  int lr = l & 15, lu = l >> 4;
  const float* sp = src + ((size_t)(bg * CH + hh * 32 + lu * 8)) * 1024 + nt * 16 + lr;
  V16u hi, lo;
#pragma unroll
  for (int j = 0; j < 8; ++j) split2(sp[(size_t)j * 1024] * scale, hi.u[j], lo.u[j]);
  *(int4*)(dh + (size_t)gtid * 8) = hi.i4;
  *(int4*)(dl + (size_t)gtid * 8) = lo.i4;
}

// kv_cm V half -> V^T frags: fr=(bgh*2+et)*32+kc, lane lr=e, lu*8+j=k
__global__ void k_prep_mbv_cm(const float* __restrict__ kv, ushort* __restrict__ dh,
                              ushort* __restrict__ dl) {
  int gtid = blockIdx.x * 256 + threadIdx.x;   // 262144
  int l = gtid & 63; int fr = gtid >> 6;
  int kc = fr & 31; int et = (fr >> 5) & 1; int bgh = fr >> 6;
  int bg = bgh >> 3, hh = bgh & 7;
  int lr = l & 15, lu = l >> 4;
  const float* sp = kv + ((size_t)(bg * 512 + 256 + hh * 32 + et * 16 + lr)) * 1024
                    + kc * 32 + lu * 8;
  V16u hi, lo;
#pragma unroll
  for (int j = 0; j < 8; ++j) split2(sp[j], hi.u[j], lo.u[j]);
  *(int4*)(dh + (size_t)gtid * 8) = hi.i4;
  *(int4*)(dl + (size_t)gtid * 8) = lo.i4;
}

// ============ main attention frag preps (cm, head-split d=64) ============
__global__ void k_prep_cm_frag(const float* __restrict__ src, ushort* __restrict__ dh,
                               ushort* __restrict__ dl, float scale) {
  int gtid = blockIdx.x * 256 + threadIdx.x;   // 262144
  int l = gtid & 63, tile = gtid >> 6;
  int dc = tile & 1, nt = (tile >> 1) & 63, bh = tile >> 7;
  int lr = l & 15, lu = l >> 4;
  int b = bh >> 3, h = bh & 7;
  int n = nt * 16 + lr;
  const float* sp = src + ((size_t)(b * 512 + h * 64 + dc * 32 + lu * 8)) * 1024 + n;
  V16u hi, lo;
#pragma unroll
  for (int j = 0; j < 8; ++j) split2(sp[(size_t)j * 1024] * scale, hi.u[j], lo.u[j]);
  *(int4*)(dh + (size_t)gtid * 8) = hi.i4;
  *(int4*)(dl + (size_t)gtid * 8) = lo.i4;
}

__global__ void k_prep_v_main(const float* __restrict__ vb, ushort* __restrict__ dh,
                              ushort* __restrict__ dl) {
  int gtid = blockIdx.x * 256 + threadIdx.x;   // 262144
  int l = gtid & 63, tile = gtid >> 6;
  int kc = tile & 31, et = (tile >> 5) & 3, bh = tile >> 7;
  int lr = l & 15, lu = l >> 4;
  int b = bh >> 3, h = bh & 7;
  const float* sp = vb + ((size_t)(b * 512 + h * 64 + et * 16 + lr)) * 1024 + kc * 32 + lu * 8;
  V16u hi, lo;
#pragma unroll
  for (int j = 0; j < 8; ++j) split2(sp[j], hi.u[j], lo.u[j]);
  *(int4*)(dh + (size_t)gtid * 8) = hi.i4;
  *(int4*)(dl + (size_t)gtid * 8) = lo.i4;
}

// ============ MitBlock attention (MFMA, d=32) ============
__global__ __launch_bounds__(256)
void k_mbattn_mfma(const ushort* __restrict__ Qh, const ushort* __restrict__ Ql,
                   const ushort* __restrict__ Kh, const ushort* __restrict__ Kl,
                   const ushort* __restrict__ Vh, const ushort* __restrict__ Vl,
                   float* __restrict__ o_tm) {
  int qb = blockIdx.x & 15, bgh = blockIdx.x >> 4;
  int tid = threadIdx.x, w = tid >> 6, l = tid & 63, lr = l & 15, lu = l >> 4;
  int qt = qb * 4 + w;
  bf16x8 qh = ((const bf16x8*)Qh)[(size_t)(bgh * 64 + qt) * 64 + l];
  bf16x8 ql = ((const bf16x8*)Ql)[(size_t)(bgh * 64 + qt) * 64 + l];
  __shared__ ushort Ph[4][16][72];
  __shared__ ushort Pl[4][16][72];
  f32x4 zero = {0.f, 0.f, 0.f, 0.f};
  f32x4 oacc[2] = {zero, zero};
  float den = 0.f;
  for (int kb = 0; kb < 16; ++kb) {
#pragma unroll
    for (int kt4 = 0; kt4 < 4; ++kt4) {
      int kt = kb * 4 + kt4;
      bf16x8 kh = ((const bf16x8*)Kh)[(size_t)(bgh * 64 + kt) * 64 + l];
      bf16x8 kl = ((const bf16x8*)Kl)[(size_t)(bgh * 64 + kt) * 64 + l];
      f32x4 s = zero;
      s = __builtin_amdgcn_mfma_f32_16x16x32_bf16(kh, qh, s, 0, 0, 0);
      s = __builtin_amdgcn_mfma_f32_16x16x32_bf16(kh, ql, s, 0, 0, 0);
      s = __builtin_amdgcn_mfma_f32_16x16x32_bf16(kl, qh, s, 0, 0, 0);
      uint2 uh, ul;
      {
        float p0 = __expf(s[0]), p1 = __expf(s[1]), p2 = __expf(s[2]), p3 = __expf(s[3]);
        den += (p0 + p1) + (p2 + p3);
        ushort h0, l0, h1, l1, h2, l2, h3, l3;
        split2(p0, h0, l0); split2(p1, h1, l1); split2(p2, h2, l2); split2(p3, h3, l3);
        uh.x = (unsigned)h0 | ((unsigned)h1 << 16); uh.y = (unsigned)h2 | ((unsigned)h3 << 16);
        ul.x = (unsigned)l0 | ((unsigned)l1 << 16); ul.y = (unsigned)l2 | ((unsigned)l3 << 16);
      }
      *(uint2*)&Ph[w][lr][kt4 * 16 + lu * 4] = uh;
      *(uint2*)&Pl[w][lr][kt4 * 16 + lu * 4] = ul;
    }
#pragma unroll
    for (int kc2 = 0; kc2 < 2; ++kc2) {
      int kc = kb * 2 + kc2;
      bf16x8 bph = *(const bf16x8*)&Ph[w][lr][kc2 * 32 + lu * 8];
      bf16x8 bpl = *(const bf16x8*)&Pl[w][lr][kc2 * 32 + lu * 8];
#pragma unroll
      for (int et = 0; et < 2; ++et) {
        bf16x8 vh = ((const bf16x8*)Vh)[(size_t)((bgh * 2 + et) * 32 + kc) * 64 + l];
        bf16x8 vl = ((const bf16x8*)Vl)[(size_t)((bgh * 2 + et) * 32 + kc) * 64 + l];
        oacc[et] = __builtin_amdgcn_mfma_f32_16x16x32_bf16(vh, bph, oacc[et], 0, 0, 0);
        oacc[et] = __builtin_amdgcn_mfma_f32_16x16x32_bf16(vh, bpl, oacc[et], 0, 0, 0);
        oacc[et] = __builtin_amdgcn_mfma_f32_16x16x32_bf16(vl, bph, oacc[et], 0, 0, 0);
      }
    }
  }
  den += __shfl_xor(den, 16);
  den += __shfl_xor(den, 32);
  float inv = 1.f / den;
  int bg = bgh >> 3, hh = bgh & 7;
  int qg = qt * 16 + lr;
#pragma unroll
  for (int et = 0; et < 2; ++et) {
    float4 o4 = { oacc[et][0] * inv, oacc[et][1] * inv, oacc[et][2] * inv, oacc[et][3] * inv };
    *(float4*)&o_tm[((size_t)(bg * 1024 + qg)) * 256 + hh * 32 + et * 16 + lu * 4] = o4;
  }
}

// ============ main attention (MFMA, d=64) ============
__global__ __launch_bounds__(256)
void k_mainattn_mfma(const ushort* __restrict__ Qh, const ushort* __restrict__ Ql,
                     const ushort* __restrict__ Kh, const ushort* __restrict__ Kl,
                     const ushort* __restrict__ Vh, const ushort* __restrict__ Vl,
                     float* __restrict__ attno) {
  int qb = blockIdx.x & 15, bh = blockIdx.x >> 4;
  int tid = threadIdx.x, w = tid >> 6, l = tid & 63, lr = l & 15, lu = l >> 4;
  int qt = qb * 4 + w;
  bf16x8 qh[2], ql[2];
#pragma unroll
  for (int dc = 0; dc < 2; ++dc) {
    qh[dc] = ((const bf16x8*)Qh)[(size_t)((bh * 64 + qt) * 2 + dc) * 64 + l];
    ql[dc] = ((const bf16x8*)Ql)[(size_t)((bh * 64 + qt) * 2 + dc) * 64 + l];
  }
  __shared__ ushort Ph[4][16][72];
  __shared__ ushort Pl[4][16][72];
  f32x4 zero = {0.f, 0.f, 0.f, 0.f};
  f32x4 oacc[4] = {zero, zero, zero, zero};
  float den = 0.f;
  for (int kb = 0; kb < 16; ++kb) {
#pragma unroll
    for (int kt4 = 0; kt4 < 4; ++kt4) {
      int kt = kb * 4 + kt4;
      f32x4 s = zero;
#pragma unroll
      for (int dc = 0; dc < 2; ++dc) {
        bf16x8 kh = ((const bf16x8*)Kh)[(size_t)((bh * 64 + kt) * 2 + dc) * 64 + l];
        bf16x8 kl = ((const bf16x8*)Kl)[(size_t)((bh * 64 + kt) * 2 + dc) * 64 + l];
        s = __builtin_amdgcn_mfma_f32_16x16x32_bf16(kh, qh[dc], s, 0, 0, 0);
        s = __builtin_amdgcn_mfma_f32_16x16x32_bf16(kh, ql[dc], s, 0, 0, 0);
        s = __builtin_amdgcn_mfma_f32_16x16x32_bf16(kl, qh[dc], s, 0, 0, 0);
      }
      uint2 uh, ul;
      {
        float p0 = __expf(s[0]), p1 = __expf(s[1]), p2 = __expf(s[2]), p3 = __expf(s[3]);
        den += (p0 + p1) + (p2 + p3);
        ushort h0, l0, h1, l1, h2, l2, h3, l3;
        split2(p0, h0, l0); split2(p1, h1, l1); split2(p2, h2, l2); split2(p3, h3, l3);
        uh.x = (unsigned)h0 | ((unsigned)h1 << 16); uh.y = (unsigned)h2 | ((unsigned)h3 << 16);
        ul.x = (unsigned)l0 | ((unsigned)l1 << 16); ul.y = (unsigned)l2 | ((unsigned)l3 << 16);
      }
      *(uint2*)&Ph[w][lr][kt4 * 16 + lu * 4] = uh;
      *(uint2*)&Pl[w][lr][kt4 * 16 + lu * 4] = ul;
    }
#pragma unroll
    for (int kc2 = 0; kc2 < 2; ++kc2) {
      int kc = kb * 2 + kc2;
      bf16x8 bph = *(const bf16x8*)&Ph[w][lr][kc2 * 32 + lu * 8];
      bf16x8 bpl = *(const bf16x8*)&Pl[w][lr][kc2 * 32 + lu * 8];
#pragma unroll
      for (int et = 0; et < 4; ++et) {
        bf16x8 vh = ((const bf16x8*)Vh)[(size_t)((bh * 4 + et) * 32 + kc) * 64 + l];
        bf16x8 vl = ((const bf16x8*)Vl)[(size_t)((bh * 4 + et) * 32 + kc) * 64 + l];
        oacc[et] = __builtin_amdgcn_mfma_f32_16x16x32_bf16(vh, bph, oacc[et], 0, 0, 0);
        oacc[et] = __builtin_amdgcn_mfma_f32_16x16x32_bf16(vh, bpl, oacc[et], 0, 0, 0);
        oacc[et] = __builtin_amdgcn_mfma_f32_16x16x32_bf16(vl, bph, oacc[et], 0, 0, 0);
      }
    }
  }
  den += __shfl_xor(den, 16);
  den += __shfl_xor(den, 32);
  float inv = 1.f / den;
  int b = bh >> 3, h = bh & 7;
  int qg = qt * 16 + lr;
#pragma unroll
  for (int et = 0; et < 4; ++et)
#pragma unroll
    for (int r = 0; r < 4; ++r)
      attno[((size_t)(b * 512 + h * 64 + et * 16 + lu * 4 + r)) * 1024 + qg] = oacc[et][r] * inv;
}

// ---------------- depthwise 3x3 + bias + exact GELU
__global__ void k_dw3(const float* __restrict__ X, const float* __restrict__ w,
                      const float* __restrict__ bias, float* __restrict__ Y) {
  int idx = blockIdx.x * 256 + threadIdx.x;
  int x = idx & 31, y = (idx >> 5) & 31, ch = (idx >> 10) & 1023, bg = idx >> 20;
  const float* src = X + (size_t)((bg << 10) + ch) * HW;
  const float* wr = w + ch * 9;
  float acc = bias[ch];
#pragma unroll
  for (int ky = 0; ky < 3; ++ky) {
    int yy = y + ky - 1;
    if ((unsigned)yy < 32u) {
      const float* row = src + yy * 32;
#pragma unroll
      for (int kx = 0; kx < 3; ++kx) {
        int xx = x + kx - 1;
        if ((unsigned)xx < 32u) acc += row[xx] * wr[ky * 3 + kx];
      }
    }
  }
  Y[(size_t)((bg << 10) + ch) * HW + y * 32 + x] = gelu_exact(acc);
}

// ---------------- depthwise 9x9 pad 4 + bias
__global__ void k_dw9(const float* __restrict__ X, const float* __restrict__ w,
                      const float* __restrict__ bias, float* __restrict__ Y) {
  int idx = blockIdx.x * 256 + threadIdx.x;
  int x = idx & 31, y = (idx >> 5) & 31, ch = (idx >> 10) & 255, bg = idx >> 18;
  const float* src = X + (size_t)((bg << 8) + ch) * HW;
  const float* wr = w + ch * 81;
  float acc = bias[ch];
  for (int ky = 0; ky < 9; ++ky) {
    int yy = y + ky - 4;
    if ((unsigned)yy < 32u) {
      const float* row = src + yy * 32;
#pragma unroll
      for (int kx = 0; kx < 9; ++kx) {
        int xx = x + kx - 4;
        if ((unsigned)xx < 32u) acc += row[xx] * wr[ky * 9 + kx];
      }
    }
  }
  Y[(size_t)((bg << 8) + ch) * HW + y * 32 + x] = acc;
}

// ---------------- co tail on nc layout: wave per token
__global__ void k_cotail_nc(const float* __restrict__ Xnc, const float* __restrict__ lnw,
                            const float* __restrict__ lnb, const float* __restrict__ w2,
                            float* __restrict__ pos) {
  int token = (blockIdx.x * 256 + threadIdx.x) >> 6;   // 8192
  int lane = threadIdx.x & 63;
  float4 v4 = *(const float4*)(Xnc + (size_t)token * 256 + lane * 4);
  float s = v4.x + v4.y + v4.z + v4.w;
  float s2 = v4.x * v4.x + v4.y * v4.y + v4.z * v4.z + v4.w * v4.w;
#pragma unroll
  for (int off = 32; off; off >>= 1) { s += __shfl_xor(s, off); s2 += __shfl_xor(s2, off); }
  float mean = s * (1.f / 256.f);
  float rstd = rsqrtf(s2 * (1.f / 256.f) - mean * mean + 1e-5f);
  float4 g4 = *(const float4*)(lnw + lane * 4);
  float4 b4 = *(const float4*)(lnb + lane * 4);
  float4 wa = *(const float4*)(w2 + lane * 4);
  float4 wb = *(const float4*)(w2 + 256 + lane * 4);
  float ge0 = gelu_exact((v4.x - mean) * rstd * g4.x + b4.x);
  float ge1 = gelu_exact((v4.y - mean) * rstd * g4.y + b4.y);
  float ge2 = gelu_exact((v4.z - mean) * rstd * g4.z + b4.z);
  float ge3 = gelu_exact((v4.w - mean) * rstd * g4.w + b4.w);
  float o0 = ge0 * wa.x + ge1 * wa.y + ge2 * wa.z + ge3 * wa.w;
  float o1 = ge0 * wb.x + ge1 * wb.y + ge2 * wb.z + ge3 * wb.w;
#pragma unroll
  for (int off = 32; off; off >>= 1) { o0 += __shfl_xor(o0, off); o1 += __shfl_xor(o1, off); }
  if (lane == 0) {
    float offy = tanhf(o0) * (2.f / 32.f);
    float offx = tanhf(o1) * (2.f / 32.f);
    int n = token & 1023;
    int ky = n >> 5, kx = n & 31;
    float refy = ((ky + 0.5f) * (1.f / 32.f)) * 2.f - 1.f;
    float refx = ((kx + 0.5f) * (1.f / 32.f)) * 2.f - 1.f;
    pos[token * 2] = offx + refx;
    pos[token * 2 + 1] = offy + refy;
  }
}

// ---------------- bilinear grid sample on nc layout -> sampled_nc
__global__ void k_gsample_nc(const float* __restrict__ Xnc, const float* __restrict__ pos,
                             float* __restrict__ out_nc) {
  int bid = blockIdx.x;            // bg(8) x nch(16)
  int nch = bid & 15; int bg = bid >> 4;
  int tid = threadIdx.x;           // = channel c
  __shared__ int sI[4][64];
  __shared__ float sW[4][64];
  if (tid < 64) {
    int j = nch * 64 + tid;
    float gx = pos[((bg << 10) + j) * 2];
    float gy = pos[((bg << 10) + j) * 2 + 1];
    float fx = (gx + 1.f) * 0.5f * 31.f;
    float fy = (gy + 1.f) * 0.5f * 31.f;
    float x0f = floorf(fx), y0f = floorf(fy);
    int x0 = (int)x0f, y0 = (int)y0f;
    float wx1 = fx - x0f, wx0 = 1.f - wx1;
    float wy1 = fy - y0f, wy0 = 1.f - wy1;
    bool vx0 = (x0 >= 0) & (x0 <= 31);
    bool vx1 = (x0 + 1 >= 0) & (x0 + 1 <= 31);
    bool vy0 = (y0 >= 0) & (y0 <= 31);
    bool vy1 = (y0 + 1 >= 0) & (y0 + 1 <= 31);
    int cx0 = min(max(x0, 0), 31), cx1 = min(max(x0 + 1, 0), 31);
    int cy0 = min(max(y0, 0), 31), cy1 = min(max(y0 + 1, 0), 31);
    sW[0][tid] = wx0 * wy0 * ((vx0 && vy0) ? 1.f : 0.f);
    sW[1][tid] = wx1 * wy0 * ((vx1 && vy0) ? 1.f : 0.f);
    sW[2][tid] = wx0 * wy1 * ((vx0 && vy1) ? 1.f : 0.f);
    sW[3][tid] = wx1 * wy1 * ((vx1 && vy1) ? 1.f : 0.f);
    sI[0][tid] = cy0 * 32 + cx0; sI[1][tid] = cy0 * 32 + cx1;
    sI[2][tid] = cy1 * 32 + cx0; sI[3][tid] = cy1 * 32 + cx1;
  }
  __syncthreads();
  const float* src = Xnc + (size_t)(bg << 10) * 256;
  for (int n = 0; n < 64; ++n) {
    float acc = src[(size_t)sI[0][n] * 256 + tid] * sW[0][n]
              + src[(size_t)sI[1][n] * 256 + tid] * sW[1][n]
              + src[(size_t)sI[2][n] * 256 + tid] * sW[2][n]
              + src[(size_t)sI[3][n] * 256 + tid] * sW[3][n];
    out_nc[((size_t)((bg << 10) + nch * 64 + n)) * 256 + tid] = acc;
  }
}

// ---------------------------------------------------------------------------
extern "C" void kernel_launch(void* const* d_in, const int* in_sizes, int n_in,
                              void* d_out, int out_size, void* d_ws, size_t ws_size,
                              hipStream_t stream) {
  const float* tgt    = (const float*)d_in[0];
  const float* refp   = (const float*)d_in[1];
  const float* emb_w  = (const float*)d_in[2];
  const float* emb_b  = (const float*)d_in[3];
  const float* q_w    = (const float*)d_in[4];
  const float* q_b    = (const float*)d_in[5];
  const float* k_w    = (const float*)d_in[6];
  const float* k_b    = (const float*)d_in[7];
  const float* v_w    = (const float*)d_in[8];
  const float* v_b    = (const float*)d_in[9];
  const float* out_w  = (const float*)d_in[10];
  const float* out_b  = (const float*)d_in[11];
  const float* ln1_w  = (const float*)d_in[12];
  const float* ln1_b  = (const float*)d_in[13];
  const float* n1_w   = (const float*)d_in[14];
  const float* n1_b   = (const float*)d_in[15];
  const float* mbq_w  = (const float*)d_in[16];
  const float* mbq_b  = (const float*)d_in[17];
  const float* mbkv_w = (const float*)d_in[18];
  const float* mbkv_b = (const float*)d_in[19];
  const float* mbp_w  = (const float*)d_in[20];
  const float* mbp_b  = (const float*)d_in[21];
  const float* n2_w   = (const float*)d_in[22];
  const float* n2_b   = (const float*)d_in[23];
  const float* fc1_w  = (const float*)d_in[24];
  const float* fc1_b  = (const float*)d_in[25];
  const float* dw3_w  = (const float*)d_in[26];
  const float* dw3_b  = (const float*)d_in[27];
  const float* fc2_w  = (const float*)d_in[28];
  const float* fc2_b  = (const float*)d_in[29];
  const float* dw9_w  = (const float*)d_in[30];
  const float* dw9_b  = (const float*)d_in[31];
  const float* coln_w = (const float*)d_in[32];
  const float* coln_b = (const float*)d_in[33];
  const float* coout_w= (const float*)d_in[34];

  float* ws = (float*)d_ws;
  // slabs (float offsets)
  float* slabA = ws + 0;          // feat cm -> offin -> sampled_nc
  float* qbuf  = ws + 2097152;    // q proj out (2->16)
  float* xbuf  = ws + 4194304;    // x tm
  float* slabD = ws + 6291456;    // h tm -> o_tm -> ygemm -> offdw_nc -> kbuf
  float* slabE = ws + 8388608;    // qq_cm -> h2 tm -> offdw cm -> vbuf
  float* slabF = ws + 10485760;   // kv_cm -> o/h2 frags -> mi frags -> sampled frags
  float* slabG = ws + 14680064;   // WtEmb -> h frags -> mb frags -> P_cm -> m_cm -> main frags
  float* slabH = ws + 23068672;   // part (+tgtf) -> mi_cm -> attno (+attno frags)
  float* featnc= ws + 31457280;   // feat_nc (3->14)
  float* posb  = ws + 35389440;   // [8,1024,2]

  // emb prep
  ushort* XtH = (ushort*)(ws + 4194304);
  ushort* XtL = XtH + 4734976;
  ushort* WtEH = (ushort*)slabG;
  ushort* WtEL = WtEH + 4718592;
  float* part = slabH;
  ushort* tgtfh = (ushort*)(slabH + 4194304);
  ushort* tgtfl = tgtfh + 2097152;

  // weight frags (long-lived, slab J)
  ushort* J = (ushort*)(ws + 33554432);
  ushort* wfq_h = J;                ushort* wfq_l = J + 262144;
  ushort* wfk_h = J + 524288;       ushort* wfk_l = J + 786432;
  ushort* wfv_h = J + 1048576;      ushort* wfv_l = J + 1310720;
  ushort* wfo_h = J + 1572864;      ushort* wfo_l = J + 1835008;
  ushort* wfmq_h = J + 2097152;     ushort* wfmq_l = J + 2162688;
  ushort* wfmkv_h = J + 2228224;    ushort* wfmkv_l = J + 2359296;
  ushort* wfmp_h = J + 2490368;     ushort* wfmp_l = J + 2555904;
  ushort* wff1_h = J + 2621440;     ushort* wff1_l = J + 2883584;
  ushort* wff2_h = J + 3145728;     ushort* wff2_l = J + 3407872;

  // phase pointers
  float* feat   = slabA;
  float* hbuf   = slabD;            // h tm, then o_tm
  float* qq_cm  = slabE;
  float* kv_cm  = slabF;
  ushort* hfh = (ushort*)slabG;     ushort* hfl = hfh + 2097152;
  ushort* mQh = (ushort*)slabG;     ushort* mQl = mQh + 2097152;
  ushort* mKh = mQh + 4194304;      ushort* mKl = mQh + 6291456;
  ushort* mVh = mQh + 8388608;      ushort* mVl = mQh + 10485760;
  ushort* ofh = (ushort*)slabF;     ushort* ofl = ofh + 2097152;
  float* P_cm = slabG;
  float* h2buf = slabE;
  ushort* h2fh = (ushort*)slabF;    ushort* h2fl = h2fh + 2097152;
  float* m_cm = slabG;
  float* mi_cm = slabH;
  ushort* mifh = (ushort*)slabF;    ushort* mifl = mifh + 4194304;
  float* ygemm = slabD;
  float* offin = slabA;
  float* offdw = slabE;
  float* offdwnc = slabD;
  float* samplednc = slabA;
  ushort* sfh = (ushort*)slabF;     ushort* sfl = sfh + 2097152;
  float* kbuf = slabD;
  float* vbuf = slabE;
  ushort* aQh = (ushort*)slabG;     ushort* aQl = aQh + 2097152;
  ushort* aKh = aQh + 4194304;      ushort* aKl = aQh + 6291456;
  ushort* aVh = aQh + 8388608;      ushort* aVl = aQh + 10485760;
  float* attno = slabH;
  ushort* anfh = (ushort*)(slabH + 2097152);  ushort* anfl = anfh + 2097152;

  // --- step 0: preps ---
  k_prepw<<<2048, 256, 0, stream>>>(emb_w, WtEH, WtEL);
  k_prepx<<<2312, 256, 0, stream>>>(tgt, refp, XtH, XtL);
  k_prep_wfrag<<<128, 256, 0, stream>>>(q_w, 512, 16, wfq_h, wfq_l);
  k_prep_wfrag<<<128, 256, 0, stream>>>(k_w, 512, 16, wfk_h, wfk_l);
  k_prep_wfrag<<<128, 256, 0, stream>>>(v_w, 512, 16, wfv_h, wfv_l);
  k_prep_wfrag<<<128, 256, 0, stream>>>(out_w, 512, 16, wfo_h, wfo_l);
  k_prep_wfrag<<<32, 256, 0, stream>>>(mbq_w, 256, 8, wfmq_h, wfmq_l);
  k_prep_wfrag<<<64, 256, 0, stream>>>(mbkv_w, 256, 8, wfmkv_h, wfmkv_l);
  k_prep_wfrag<<<32, 256, 0, stream>>>(mbp_w, 256, 8, wfmp_h, wfmp_l);
  k_prep_wfrag<<<128, 256, 0, stream>>>(fc1_w, 256, 8, wff1_h, wff1_l);
  k_prep_wfrag<<<128, 256, 0, stream>>>(fc2_w, 1024, 32, wff2_h, wff2_l);
  k_prep_cm2frag<<<1024, 256, 0, stream>>>(tgt, 512, 16, tgtfh, tgtfl);
  // --- step 1: emb conv ---
  k_emb_mfma<<<512, 256, 0, stream>>>(XtH, XtL, WtEH, WtEL, part);
  k_embmerge<<<8192, 256, 0, stream>>>(part, emb_b, feat);
  // --- step 2: q proj ---
  k_gemm_mfma<<<256, 256, 0, stream>>>(wfq_h, wfq_l, tgtfh, tgtfl, q_b, qbuf, 16, 4, 512);
  // --- step 3: feat_nc + ln1 -> x ---
  k_transpose_nc<<<512, 256, 0, stream>>>(feat, featnc);
  k_ln_tok<<<2048, 256, 0, stream>>>(featnc, ln1_w, ln1_b, xbuf, 1e-5f);
  // --- step 4: n1 -> h; h frags ---
  k_ln_tok<<<2048, 256, 0, stream>>>(xbuf, n1_w, n1_b, hbuf, 1e-6f);
  k_prep_tm2frag<<<1024, 256, 0, stream>>>(hbuf, 256, 8, hfh, hfl);
  // --- step 5: mbq/mbkv GEMMs -> cm ---
  k_gemm_mfma<<<256, 256, 0, stream>>>(wfmq_h, wfmq_l, hfh, hfl, mbq_b, qq_cm, 8, 2, 256);
  k_gemm_mfma<<<512, 256, 0, stream>>>(wfmkv_h, wfmkv_l, hfh, hfl, mbkv_b, kv_cm, 8, 4, 512);
  // --- step 6: mb attention ---
  k_prep_hsplit_cm<<<1024, 256, 0, stream>>>(qq_cm, 256, mQh, mQl, 0.17677669529663689f);
  k_prep_hsplit_cm<<<1024, 256, 0, stream>>>(kv_cm, 512, mKh, mKl, 1.f);
  k_prep_mbv_cm<<<1024, 256, 0, stream>>>(kv_cm, mVh, mVl);
  k_mbattn_mfma<<<1024, 256, 0, stream>>>(mQh, mQl, mKh, mKl, mVh, mVl, hbuf);
  // --- step 7: mbproj + residual ---
  k_prep_tm2frag<<<1024, 256, 0, stream>>>(hbuf, 256, 8, ofh, ofl);
  k_gemm_mfma<<<256, 256, 0, stream>>>(wfmp_h, wfmp_l, ofh, ofl, mbp_b, P_cm, 8, 2, 256);
  k_transadd_tm<<<512, 256, 0, stream>>>(P_cm, xbuf);
  // --- step 8: n2 -> h2 ---
  k_ln_tok<<<2048, 256, 0, stream>>>(xbuf, n2_w, n2_b, h2buf, 1e-6f);
  // --- step 9: fc1 ---
  k_prep_tm2frag<<<1024, 256, 0, stream>>>(h2buf, 256, 8, h2fh, h2fl);
  k_gemm_mfma<<<1024, 256, 0, stream>>>(wff1_h, wff1_l, h2fh, h2fl, fc1_b, m_cm, 8, 8, 1024);
  // --- step 10: dw3 + gelu; mi frags ---
  k_dw3<<<32768, 256, 0, stream>>>(m_cm, dw3_w, dw3_b, mi_cm);
  k_prep_cm2frag<<<4096, 256, 0, stream>>>(mi_cm, 1024, 32, mifh, mifl);
  // --- step 11: fc2 + residual transadd ---
  k_gemm_mfma<<<256, 256, 0, stream>>>(wff2_h, wff2_l, mifh, mifl, fc2_b, ygemm, 32, 2, 256);
  k_transadd_cm<<<512, 256, 0, stream>>>(ygemm, xbuf, offin);
  // --- step 12: dw9 ---
  k_dw9<<<8192, 256, 0, stream>>>(offin, dw9_w, dw9_b, offdw);
  // --- step 13: cotail ---
  k_transpose_nc<<<512, 256, 0, stream>>>(offdw, offdwnc);
  k_cotail_nc<<<2048, 256, 0, stream>>>(offdwnc, coln_w, coln_b, coout_w, posb);
  // --- step 14: grid sample ---
  k_gsample_nc<<<128, 256, 0, stream>>>(featnc, posb, samplednc);
  k_prep_s2frag<<<1024, 256, 0, stream>>>(samplednc, sfh, sfl);
  // --- step 15: k/v proj ---
  k_gemm_mfma<<<256, 256, 0, stream>>>(wfk_h, wfk_l, sfh, sfl, k_b, kbuf, 16, 4, 512);
  k_gemm_mfma<<<256, 256, 0, stream>>>(wfv_h, wfv_l, sfh, sfl, v_b, vbuf, 16, 4, 512);
  // --- step 16: main attention ---
  k_prep_cm_frag<<<1024, 256, 0, stream>>>(qbuf, aQh, aQl, 0.125f);
  k_prep_cm_frag<<<1024, 256, 0, stream>>>(kbuf, aKh, aKl, 1.f);
  k_prep_v_main<<<1024, 256, 0, stream>>>(vbuf, aVh, aVl);
  k_mainattn_mfma<<<512, 256, 0, stream>>>(aQh, aQl, aKh, aKl, aVh, aVl, attno);
  // --- step 17: out proj -> d_out ---
  k_prep_cm2frag<<<1024, 256, 0, stream>>>(attno, 512, 16, anfh, anfl);
  k_gemm_mfma<<<256, 256, 0, stream>>>(wfo_h, wfo_l, anfh, anfl, out_b, (float*)d_out, 16, 4, 512);
}

// Round 5
// 760.538 us; speedup vs baseline: 4.0160x; 1.0126x over previous
//
#include <hip/hip_runtime.h>
#include <math.h>

// ---------------------------------------------------------------------------
// DAttention forward. R5: emb occupancy (4-way K-split), frag-fused epilogues,
// nc-layout tail, fused prep dispatches.
// Dims: B=4, C=512, H=W=32, G=2, gc=256, BG=8, heads=8, hc=64, mh=8, mhd=32.
// ---------------------------------------------------------------------------

static constexpr int HW = 1024;

typedef __attribute__((ext_vector_type(8))) short bf16x8;
typedef __attribute__((ext_vector_type(4))) float f32x4;

union V16u { int4 i4; ushort u[8]; };

__device__ __forceinline__ float gelu_exact(float v) {
  return 0.5f * v * (1.0f + erff(v * 0.7071067811865475f));
}

__device__ __forceinline__ ushort bf16_rne(float v) {
  unsigned int b = __float_as_uint(v);
  return (ushort)((b + 0x7fffu + ((b >> 16) & 1u)) >> 16);
}

__device__ __forceinline__ void split2(float v, ushort& h, ushort& l) {
  h = bf16_rne(v);
  l = bf16_rne(v - __uint_as_float(((unsigned int)h) << 16));
}

// ---------------- emb prep: weights [512][1024][3][3] -> [9][512][1024] bf16 hi/lo
__global__ void k_prepw(const float* __restrict__ w, ushort* __restrict__ Wt_hi,
                        ushort* __restrict__ Wt_lo) {
  int idx = blockIdx.x * 256 + threadIdx.x;    // 524288
  int o = idx >> 10, ci = idx & 1023;
  const float* src = w + (size_t)idx * 9;
#pragma unroll
  for (int t = 0; t < 9; ++t) {
    ushort h, l; split2(src[t], h, l);
    size_t oo = ((size_t)(t * 512 + o)) * 1024 + ci;
    Wt_hi[oo] = h; Wt_lo[oo] = l;
  }
}

// ---------------- emb prep: inputs -> [4][34][34][1024] bf16 hi/lo (padded)
__global__ void k_prepx(const float* __restrict__ tgt, const float* __restrict__ refp,
                        ushort* __restrict__ Xt_hi, ushort* __restrict__ Xt_lo) {
  int idx = blockIdx.x * 256 + threadIdx.x;    // 591872
  int xp = idx % 34; int r = idx / 34;
  int g8 = r & 127; r >>= 7;
  int yp = r % 34; int b = r / 34;
  int y = yp - 1, x = xp - 1;
  bool valid = (unsigned)y < 32u && (unsigned)x < 32u;
  V16u hi, lo;
  const float* in = (g8 < 64) ? (tgt + ((size_t)(b * 512 + g8 * 8)) * HW)
                              : (refp + ((size_t)(b * 512 + (g8 - 64) * 8)) * HW);
#pragma unroll
  for (int j = 0; j < 8; ++j) {
    float v = valid ? in[(size_t)j * HW + y * 32 + x] : 0.f;
    split2(v, hi.u[j], lo.u[j]);
  }
  size_t oo = (((size_t)(b * 34 + yp)) * 34 + xp) * 1024 + g8 * 8;
  *(int4*)(Xt_hi + oo) = hi.i4;
  *(int4*)(Xt_lo + oo) = lo.i4;
}

// ---------------- emb conv via MFMA, split-bf16 3-term, 4-way K-split
__global__ __launch_bounds__(256, 4)
void k_emb_mfma(const ushort* __restrict__ Xt_hi, const ushort* __restrict__ Xt_lo,
                const ushort* __restrict__ Wt_hi, const ushort* __restrict__ Wt_lo,
                float* __restrict__ part) {
  int bid = blockIdx.x;
  int ks = bid & 3; bid >>= 2;
  int mt = bid & 3; bid >>= 2;
  int yt = bid & 15; bid >>= 4;
  int b = bid;
  int tid = threadIdx.x;
  int w = tid >> 6, l = tid & 63;
  int lr = l & 15, lu = l >> 4;
  int y0 = yt * 2;
  int obase = mt * 128 + w * 32;

  __shared__ int4 LsH[2][576];
  __shared__ int4 LsL[2][576];

  int4 gh[3], gl[3];
  int kc0 = ks * 8;

  auto loadstage = [&](int kcg) {
#pragma unroll
    for (int i = 0; i < 3; ++i) {
      int s = tid + 256 * i;
      if (s < 576) {
        int px = s >> 2;
        int pxc = px > 135 ? 135 : px;
        int u = (s & 3) ^ ((pxc >> 1) & 3);
        size_t off = (((size_t)(b * 34 + y0)) * 34 + pxc) * 1024 + kcg * 32 + u * 8;
        gh[i] = *(const int4*)(Xt_hi + off);
        gl[i] = *(const int4*)(Xt_lo + off);
      }
    }
  };
  auto writestage = [&](int buf) {
#pragma unroll
    for (int i = 0; i < 3; ++i) {
      int s = tid + 256 * i;
      if (s < 576) { LsH[buf][s] = gh[i]; LsL[buf][s] = gl[i]; }
    }
  };

  f32x4 zero = {0.f, 0.f, 0.f, 0.f};
  f32x4 acc[2][4];
#pragma unroll
  for (int a = 0; a < 2; ++a)
#pragma unroll
    for (int n = 0; n < 4; ++n) acc[a][n] = zero;

  loadstage(kc0);
  writestage(0);

  for (int kc = 0; kc < 8; ++kc) {
    int buf = kc & 1;
    __syncthreads();
    if (kc < 7) loadstage(kc0 + kc + 1);
    int kcg = kc0 + kc;
    const bf16x8* BH = (const bf16x8*)&LsH[buf][0];
    const bf16x8* BL = (const bf16x8*)&LsL[buf][0];
#pragma unroll
    for (int kx = 0; kx < 3; ++kx) {
      bf16x8 bh[8], bl[8];
#pragma unroll
      for (int f = 0; f < 8; ++f) {
        int px = (f >> 1) * 34 + (f & 1) * 16 + kx + lr;
        int idx = px * 4 + (lu ^ ((px >> 1) & 3));
        bh[f] = BH[idx]; bl[f] = BL[idx];
      }
#pragma unroll
      for (int ky = 0; ky < 3; ++ky) {
        int tap = ky * 3 + kx;
        size_t wo = (((size_t)(tap * 512 + obase + lr)) * 1024) + kcg * 32 + lu * 8;
        bf16x8 ah0 = *(const bf16x8*)(Wt_hi + wo);
        bf16x8 al0 = *(const bf16x8*)(Wt_lo + wo);
        bf16x8 ah1 = *(const bf16x8*)(Wt_hi + wo + 16 * 1024);
        bf16x8 al1 = *(const bf16x8*)(Wt_lo + wo + 16 * 1024);
#pragma unroll
        for (int yr = 0; yr < 2; ++yr)
#pragma unroll
          for (int h = 0; h < 2; ++h) {
            int f = (yr + ky) * 2 + h;
            int nf = yr * 2 + h;
            acc[0][nf] = __builtin_amdgcn_mfma_f32_16x16x32_bf16(ah0, bh[f], acc[0][nf], 0, 0, 0);
            acc[0][nf] = __builtin_amdgcn_mfma_f32_16x16x32_bf16(ah0, bl[f], acc[0][nf], 0, 0, 0);
            acc[0][nf] = __builtin_amdgcn_mfma_f32_16x16x32_bf16(al0, bh[f], acc[0][nf], 0, 0, 0);
            acc[1][nf] = __builtin_amdgcn_mfma_f32_16x16x32_bf16(ah1, bh[f], acc[1][nf], 0, 0, 0);
            acc[1][nf] = __builtin_amdgcn_mfma_f32_16x16x32_bf16(ah1, bl[f], acc[1][nf], 0, 0, 0);
            acc[1][nf] = __builtin_amdgcn_mfma_f32_16x16x32_bf16(al1, bh[f], acc[1][nf], 0, 0, 0);
          }
      }
    }
    if (kc < 7) writestage(buf ^ 1);
  }

  float* pb = part + (size_t)ks * 2097152;
#pragma unroll
  for (int a = 0; a < 2; ++a)
#pragma unroll
    for (int yr = 0; yr < 2; ++yr)
#pragma unroll
      for (int h = 0; h < 2; ++h) {
        f32x4 c = acc[a][yr * 2 + h];
        size_t base = ((size_t)(b * 512 + obase + a * 16 + lu * 4)) * 1024
                      + (y0 + yr) * 32 + h * 16 + lr;
#pragma unroll
        for (int r = 0; r < 4; ++r) pb[base + (size_t)r * 1024] = c[r];
      }
}

// ---------------- emb merge: sum 4 parts + bias, write feat_nc (transposing)
__global__ void k_embmerge_nc(const float* __restrict__ part, const float* __restrict__ bias,
                              float* __restrict__ featnc) {
  __shared__ float T[64][65];
  int bid = blockIdx.x;                 // 512 = bg(8) x c-tile(4) x n-tile(16)
  int n0 = (bid & 15) << 6; bid >>= 4;
  int c0 = (bid & 3) << 6; int bg = bid >> 2;
  int cl = threadIdx.x & 63, rw = threadIdx.x >> 6;
#pragma unroll
  for (int i = 0; i < 16; ++i) {
    int crow = i * 4 + rw;
    size_t idx = ((size_t)(bg * 256 + c0 + crow)) * 1024 + n0 + cl;
    float v = part[idx] + part[2097152 + idx] + part[4194304 + idx] + part[6291456 + idx];
    T[crow][cl] = v + bias[(bg & 1) * 256 + c0 + crow];
  }
  __syncthreads();
#pragma unroll
  for (int i = 0; i < 16; ++i) {
    int nrow = i * 4 + rw;
    featnc[((size_t)(bg * 1024 + n0 + nrow)) * 256 + c0 + cl] = T[cl][nrow];
  }
}

// ============ fused static preps: 9 weight frag sets + dw9 weight transpose ====
__device__ __forceinline__ void wfrag_body(const float* __restrict__ W, int K, int KC,
                                           ushort* __restrict__ dh, ushort* __restrict__ dl,
                                           int gtid) {
  int l = gtid & 63; int fr = gtid >> 6;
  int kc = fr % KC; int ot = fr / KC;
  int lr = l & 15, lu = l >> 4;
  const float* sp = W + (size_t)(ot * 16 + lr) * K + kc * 32 + lu * 8;
  V16u hi, lo;
#pragma unroll
  for (int j = 0; j < 8; ++j) split2(sp[j], hi.u[j], lo.u[j]);
  *(int4*)(dh + (size_t)gtid * 8) = hi.i4;
  *(int4*)(dl + (size_t)gtid * 8) = lo.i4;
}

__global__ void k_prep_wfrag9(
    const float* q_w, const float* k_w, const float* v_w, const float* o_w,
    const float* mq_w, const float* mkv_w, const float* mp_w,
    const float* f1_w, const float* f2_w, const float* dw9_w,
    ushort* qh, ushort* ql, ushort* kh, ushort* kl, ushort* vh, ushort* vl,
    ushort* oh, ushort* ol, ushort* mqh, ushort* mql, ushort* mkvh, ushort* mkvl,
    ushort* mph, ushort* mpl, ushort* f1h, ushort* f1l, ushort* f2h, ushort* f2l,
    float* wt9) {
  int bid = blockIdx.x, tid = threadIdx.x;
  if (bid < 128)      wfrag_body(q_w, 512, 16, qh, ql, bid * 256 + tid);
  else if (bid < 256) wfrag_body(k_w, 512, 16, kh, kl, (bid - 128) * 256 + tid);
  else if (bid < 384) wfrag_body(v_w, 512, 16, vh, vl, (bid - 256) * 256 + tid);
  else if (bid < 512) wfrag_body(o_w, 512, 16, oh, ol, (bid - 384) * 256 + tid);
  else if (bid < 544) wfrag_body(mq_w, 256, 8, mqh, mql, (bid - 512) * 256 + tid);
  else if (bid < 608) wfrag_body(mkv_w, 256, 8, mkvh, mkvl, (bid - 544) * 256 + tid);
  else if (bid < 640) wfrag_body(mp_w, 256, 8, mph, mpl, (bid - 608) * 256 + tid);
  else if (bid < 768) wfrag_body(f1_w, 256, 8, f1h, f1l, (bid - 640) * 256 + tid);
  else if (bid < 896) wfrag_body(f2_w, 1024, 32, f2h, f2l, (bid - 768) * 256 + tid);
  else {
    int idx = (bid - 896) * 256 + tid;  // 81*256 = 20736
    int t = idx >> 8, c = idx & 255;
    wt9[idx] = dw9_w[c * 81 + t];
  }
}

// cm activations [b][CH][1024] -> B-frags
__global__ void k_prep_cm2frag(const float* __restrict__ src, int CH, int KC,
                               ushort* __restrict__ dh, ushort* __restrict__ dl) {
  int gtid = blockIdx.x * 256 + threadIdx.x;
  int l = gtid & 63; int fr = gtid >> 6;
  int kc = fr % KC; int r2 = fr / KC; int nt = r2 & 63; int b = r2 >> 6;
  int lr = l & 15, lu = l >> 4;
  const float* sp = src + ((size_t)(b * CH) + kc * 32 + lu * 8) * 1024 + nt * 16 + lr;
  V16u hi, lo;
#pragma unroll
  for (int j = 0; j < 8; ++j) split2(sp[(size_t)j * 1024], hi.u[j], lo.u[j]);
  *(int4*)(dh + (size_t)gtid * 8) = hi.i4;
  *(int4*)(dl + (size_t)gtid * 8) = lo.i4;
}

// sampled_nc [8][1024][256] viewed as [4b][512ch] -> B-frags (KC=16)
__global__ void k_prep_s2frag(const float* __restrict__ snc,
                              ushort* __restrict__ dh, ushort* __restrict__ dl) {
  int gtid = blockIdx.x * 256 + threadIdx.x;   // 262144
  int l = gtid & 63; int fr = gtid >> 6;
  int kc = fr & 15; int nt = (fr >> 4) & 63; int b = fr >> 10;
  int lr = l & 15, lu = l >> 4;
  const float* sp = snc + ((size_t)((b * 2 + (kc >> 3)) * 1024 + nt * 16 + lr)) * 256
                    + (kc & 7) * 32 + lu * 8;
  V16u hi, lo;
#pragma unroll
  for (int j = 0; j < 8; ++j) split2(sp[j], hi.u[j], lo.u[j]);
  *(int4*)(dh + (size_t)gtid * 8) = hi.i4;
  *(int4*)(dl + (size_t)gtid * 8) = lo.i4;
}

// ============ generic MFMA GEMM: Y[b][Mtot][1024] = W[Mtot,K] x B + bias ======
__global__ __launch_bounds__(256)
void k_gemm_mfma(const ushort* __restrict__ Ah, const ushort* __restrict__ Al,
                 const ushort* __restrict__ Bh, const ushort* __restrict__ Bl,
                 const float* __restrict__ bias, float* __restrict__ Y,
                 int KC, int MT, int Mtot) {
  int bid = blockIdx.x;
  int ntb = bid & 15; bid >>= 4;
  int mt = bid % MT; int b = bid / MT;
  int tid = threadIdx.x, w = tid >> 6, l = tid & 63, lr = l & 15, lu = l >> 4;
  int ot0 = mt * 8 + w * 2;
  const bf16x8* pAh = (const bf16x8*)Ah;
  const bf16x8* pAl = (const bf16x8*)Al;
  const bf16x8* pBh = (const bf16x8*)Bh;
  const bf16x8* pBl = (const bf16x8*)Bl;
  f32x4 zero = {0.f, 0.f, 0.f, 0.f};
  f32x4 acc[2][4];
#pragma unroll
  for (int a = 0; a < 2; ++a)
#pragma unroll
    for (int n = 0; n < 4; ++n) acc[a][n] = zero;
  for (int kc = 0; kc < KC; ++kc) {
    bf16x8 a_h[2], a_l[2];
#pragma unroll
    for (int a = 0; a < 2; ++a) {
      size_t idx = ((size_t)(ot0 + a) * KC + kc) * 64 + l;
      a_h[a] = pAh[idx]; a_l[a] = pAl[idx];
    }
#pragma unroll
    for (int n = 0; n < 4; ++n) {
      size_t idx = (((size_t)(b * 64 + ntb * 4 + n)) * KC + kc) * 64 + l;
      bf16x8 b_h = pBh[idx], b_l = pBl[idx];
#pragma unroll
      for (int a = 0; a < 2; ++a) {
        acc[a][n] = __builtin_amdgcn_mfma_f32_16x16x32_bf16(a_h[a], b_h, acc[a][n], 0, 0, 0);
        acc[a][n] = __builtin_amdgcn_mfma_f32_16x16x32_bf16(a_h[a], b_l, acc[a][n], 0, 0, 0);
        acc[a][n] = __builtin_amdgcn_mfma_f32_16x16x32_bf16(a_l[a], b_h, acc[a][n], 0, 0, 0);
      }
    }
  }
#pragma unroll
  for (int a = 0; a < 2; ++a) {
    int o = (ot0 + a) * 16 + lu * 4;
#pragma unroll
    for (int n = 0; n < 4; ++n) {
      int col = (ntb * 4 + n) * 16 + lr;
#pragma unroll
      for (int r = 0; r < 4; ++r)
        Y[((size_t)(b * Mtot + o + r)) * 1024 + col] = acc[a][n][r] + bias[o + r];
    }
  }
}

// ============ transposes ============
// Xtm += transpose(P_cm)   (mbproj residual)
__global__ void k_transadd_tm(const float* __restrict__ Pcm, float* __restrict__ Xtm) {
  __shared__ float T[64][65];
  int bid = blockIdx.x; int n0 = (bid & 15) << 6; bid >>= 4;
  int c0 = (bid & 3) << 6; int bg = bid >> 2;
  int cl = threadIdx.x & 63, rw = threadIdx.x >> 6;
#pragma unroll
  for (int i = 0; i < 16; ++i) {
    int crow = i * 4 + rw;
    T[crow][cl] = Pcm[((size_t)(bg * 256 + c0 + crow)) * 1024 + n0 + cl];
  }
  __syncthreads();
#pragma unroll
  for (int i = 0; i < 16; ++i) {
    int nrow = i * 4 + rw;
    Xtm[((size_t)((bg << 10) + n0 + nrow)) * 256 + c0 + cl] += T[cl][nrow];
  }
}

// offin_nc = transpose(ygemm_cm) + xbuf_tm   (fc2 residual)
__global__ void k_transadd_nc(const float* __restrict__ Yg, const float* __restrict__ Xtm,
                              float* __restrict__ out_nc) {
  __shared__ float T[64][65];
  int bid = blockIdx.x; int n0 = (bid & 15) << 6; bid >>= 4;
  int c0 = (bid & 3) << 6; int bg = bid >> 2;
  int cl = threadIdx.x & 63, rw = threadIdx.x >> 6;
#pragma unroll
  for (int i = 0; i < 16; ++i) {
    int crow = i * 4 + rw;
    T[crow][cl] = Yg[((size_t)(bg * 256 + c0 + crow)) * 1024 + n0 + cl];
  }
  __syncthreads();
#pragma unroll
  for (int i = 0; i < 16; ++i) {
    int nrow = i * 4 + rw;
    size_t a = ((size_t)((bg << 10) + n0 + nrow)) * 256 + c0 + cl;
    out_nc[a] = T[cl][nrow] + Xtm[a];
  }
}

// ---------------- token-major LN -> tm out (ln1 residual stream)
__global__ void k_ln_tok(const float* __restrict__ xin, const float* __restrict__ g_,
                         const float* __restrict__ b_, float* __restrict__ yo, float eps) {
  int token = (blockIdx.x * 256 + threadIdx.x) >> 6;
  int lane = threadIdx.x & 63;
  float4 v4 = *reinterpret_cast<const float4*>(xin + (size_t)token * 256 + lane * 4);
  float s  = v4.x + v4.y + v4.z + v4.w;
  float s2 = v4.x * v4.x + v4.y * v4.y + v4.z * v4.z + v4.w * v4.w;
#pragma unroll
  for (int off = 32; off; off >>= 1) { s += __shfl_xor(s, off); s2 += __shfl_xor(s2, off); }
  float mean = s * (1.f / 256.f);
  float rstd = rsqrtf(s2 * (1.f / 256.f) - mean * mean + eps);
  float4 g4 = *reinterpret_cast<const float4*>(g_ + lane * 4);
  float4 b4 = *reinterpret_cast<const float4*>(b_ + lane * 4);
  float4 o;
  o.x = (v4.x - mean) * rstd * g4.x + b4.x;
  o.y = (v4.y - mean) * rstd * g4.y + b4.y;
  o.z = (v4.z - mean) * rstd * g4.z + b4.z;
  o.w = (v4.w - mean) * rstd * g4.w + b4.w;
  *reinterpret_cast<float4*>(yo + (size_t)token * 256 + lane * 4) = o;
}

// ---------------- token-major LN -> B-frags directly (KC=8)
__global__ void k_ln_frag(const float* __restrict__ xin, const float* __restrict__ g_,
                          const float* __restrict__ b_, ushort* __restrict__ dh,
                          ushort* __restrict__ dl, float eps) {
  int token = (blockIdx.x * 256 + threadIdx.x) >> 6;
  int lane = threadIdx.x & 63;
  float4 v4 = *reinterpret_cast<const float4*>(xin + (size_t)token * 256 + lane * 4);
  float s  = v4.x + v4.y + v4.z + v4.w;
  float s2 = v4.x * v4.x + v4.y * v4.y + v4.z * v4.z + v4.w * v4.w;
#pragma unroll
  for (int off = 32; off; off >>= 1) { s += __shfl_xor(s, off); s2 += __shfl_xor(s2, off); }
  float mean = s * (1.f / 256.f);
  float rstd = rsqrtf(s2 * (1.f / 256.f) - mean * mean + eps);
  float4 g4 = *reinterpret_cast<const float4*>(g_ + lane * 4);
  float4 b4 = *reinterpret_cast<const float4*>(b_ + lane * 4);
  float vals[4];
  vals[0] = (v4.x - mean) * rstd * g4.x + b4.x;
  vals[1] = (v4.y - mean) * rstd * g4.y + b4.y;
  vals[2] = (v4.z - mean) * rstd * g4.z + b4.z;
  vals[3] = (v4.w - mean) * rstd * g4.w + b4.w;
  ushort4 h4, l4;
  split2(vals[0], h4.x, l4.x); split2(vals[1], h4.y, l4.y);
  split2(vals[2], h4.z, l4.z); split2(vals[3], h4.w, l4.w);
  int bg = token >> 10, nt = (token >> 4) & 63, lr = token & 15;
  int kc = lane >> 3, lu_f = (lane >> 1) & 3, j0 = (lane & 1) * 4;
  size_t base = ((((size_t)(bg * 64 + nt)) * 8 + kc) * 64 + lu_f * 16 + lr) * 8 + j0;
  *(ushort4*)(dh + base) = h4;
  *(ushort4*)(dl + base) = l4;
}

// ============ fused mb-attn input preps (Q / K / V^T frags) ============
__global__ void k_prep_mb3(const float* __restrict__ qq_cm, const float* __restrict__ kv_cm,
                           ushort* __restrict__ mQh, ushort* __restrict__ mQl,
                           ushort* __restrict__ mKh, ushort* __restrict__ mKl,
                           ushort* __restrict__ mVh, ushort* __restrict__ mVl) {
  int bid = blockIdx.x, tid = threadIdx.x;
  int sect = bid >> 10, lb = bid & 1023;
  int gtid = lb * 256 + tid;                 // 262144
  int l = gtid & 63; int fr = gtid >> 6;
  int lr = l & 15, lu = l >> 4;
  V16u hi, lo;
  if (sect < 2) {                            // Q (scale) / K (hsplit, frag lr=n)
    int nt = fr & 63; int bgh = fr >> 6;
    int bg = bgh >> 3, hh = bgh & 7;
    const float* src = sect == 0 ? qq_cm : kv_cm;
    int CH = sect == 0 ? 256 : 512;
    float scale = sect == 0 ? 0.17677669529663689f : 1.f;
    const float* sp = src + ((size_t)(bg * CH + hh * 32 + lu * 8)) * 1024 + nt * 16 + lr;
#pragma unroll
    for (int j = 0; j < 8; ++j) split2(sp[(size_t)j * 1024] * scale, hi.u[j], lo.u[j]);
    ushort* dh = sect == 0 ? mQh : mKh;
    ushort* dl = sect == 0 ? mQl : mKl;
    *(int4*)(dh + (size_t)gtid * 8) = hi.i4;
    *(int4*)(dl + (size_t)gtid * 8) = lo.i4;
  } else {                                   // V^T frags: lr=e, lu*8+j=k
    int kc = fr & 31; int et = (fr >> 5) & 1; int bgh = fr >> 6;
    int bg = bgh >> 3, hh = bgh & 7;
    const float* sp = kv_cm + ((size_t)(bg * 512 + 256 + hh * 32 + et * 16 + lr)) * 1024
                      + kc * 32 + lu * 8;
#pragma unroll
    for (int j = 0; j < 8; ++j) split2(sp[j], hi.u[j], lo.u[j]);
    *(int4*)(mVh + (size_t)gtid * 8) = hi.i4;
    *(int4*)(mVl + (size_t)gtid * 8) = lo.i4;
  }
}

// ============ fused main-attn input preps ============
__global__ void k_prep_main3(const float* __restrict__ qb, const float* __restrict__ kb,
                             const float* __restrict__ vb,
                             ushort* __restrict__ aQh, ushort* __restrict__ aQl,
                             ushort* __restrict__ aKh, ushort* __restrict__ aKl,
                             ushort* __restrict__ aVh, ushort* __restrict__ aVl) {
  int bid = blockIdx.x, tid = threadIdx.x;
  int sect = bid >> 10, lb = bid & 1023;
  int gtid = lb * 256 + tid;                 // 262144
  int l = gtid & 63, tile = gtid >> 6;
  int lr = l & 15, lu = l >> 4;
  V16u hi, lo;
  if (sect < 2) {                            // Q / K (frag lr=n, d along lu)
    int dc = tile & 1, nt = (tile >> 1) & 63, bh = tile >> 7;
    int b = bh >> 3, h = bh & 7;
    const float* src = sect == 0 ? qb : kb;
    float scale = sect == 0 ? 0.125f : 1.f;
    const float* sp = src + ((size_t)(b * 512 + h * 64 + dc * 32 + lu * 8)) * 1024
                      + nt * 16 + lr;
#pragma unroll
    for (int j = 0; j < 8; ++j) split2(sp[(size_t)j * 1024] * scale, hi.u[j], lo.u[j]);
    ushort* dh = sect == 0 ? aQh : aKh;
    ushort* dl = sect == 0 ? aQl : aKl;
    *(int4*)(dh + (size_t)gtid * 8) = hi.i4;
    *(int4*)(dl + (size_t)gtid * 8) = lo.i4;
  } else {                                   // V^T frags
    int kc = tile & 31, et = (tile >> 5) & 3, bh = tile >> 7;
    int b = bh >> 3, h = bh & 7;
    const float* sp = vb + ((size_t)(b * 512 + h * 64 + et * 16 + lr)) * 1024 + kc * 32 + lu * 8;
#pragma unroll
    for (int j = 0; j < 8; ++j) split2(sp[j], hi.u[j], lo.u[j]);
    *(int4*)(aVh + (size_t)gtid * 8) = hi.i4;
    *(int4*)(aVl + (size_t)gtid * 8) = lo.i4;
  }
}

// ============ MitBlock attention (MFMA, d=32), epilogue -> B-frags ============
__global__ __launch_bounds__(256)
void k_mbattn_mfma(const ushort* __restrict__ Qh, const ushort* __restrict__ Ql,
                   const ushort* __restrict__ Kh, const ushort* __restrict__ Kl,
                   const ushort* __restrict__ Vh, const ushort* __restrict__ Vl,
                   ushort* __restrict__ ofh, ushort* __restrict__ ofl) {
  int qb = blockIdx.x & 15, bgh = blockIdx.x >> 4;
  int tid = threadIdx.x, w = tid >> 6, l = tid & 63, lr = l & 15, lu = l >> 4;
  int qt = qb * 4 + w;
  bf16x8 qh = ((const bf16x8*)Qh)[(size_t)(bgh * 64 + qt) * 64 + l];
  bf16x8 ql = ((const bf16x8*)Ql)[(size_t)(bgh * 64 + qt) * 64 + l];
  __shared__ ushort Ph[4][16][72];
  __shared__ ushort Pl[4][16][72];
  f32x4 zero = {0.f, 0.f, 0.f, 0.f};
  f32x4 oacc[2] = {zero, zero};
  float den = 0.f;
  for (int kb = 0; kb < 16; ++kb) {
#pragma unroll
    for (int kt4 = 0; kt4 < 4; ++kt4) {
      int kt = kb * 4 + kt4;
      bf16x8 kh = ((const bf16x8*)Kh)[(size_t)(bgh * 64 + kt) * 64 + l];
      bf16x8 kl = ((const bf16x8*)Kl)[(size_t)(bgh * 64 + kt) * 64 + l];
      f32x4 s = zero;
      s = __builtin_amdgcn_mfma_f32_16x16x32_bf16(kh, qh, s, 0, 0, 0);
      s = __builtin_amdgcn_mfma_f32_16x16x32_bf16(kh, ql, s, 0, 0, 0);
      s = __builtin_amdgcn_mfma_f32_16x16x32_bf16(kl, qh, s, 0, 0, 0);
      uint2 uh, ul;
      {
        float p0 = __expf(s[0]), p1 = __expf(s[1]), p2 = __expf(s[2]), p3 = __expf(s[3]);
        den += (p0 + p1) + (p2 + p3);
        ushort h0, l0, h1, l1, h2, l2, h3, l3;
        split2(p0, h0, l0); split2(p1, h1, l1); split2(p2, h2, l2); split2(p3, h3, l3);
        uh.x = (unsigned)h0 | ((unsigned)h1 << 16); uh.y = (unsigned)h2 | ((unsigned)h3 << 16);
        ul.x = (unsigned)l0 | ((unsigned)l1 << 16); ul.y = (unsigned)l2 | ((unsigned)l3 << 16);
      }
      *(uint2*)&Ph[w][lr][kt4 * 16 + lu * 4] = uh;
      *(uint2*)&Pl[w][lr][kt4 * 16 + lu * 4] = ul;
    }
#pragma unroll
    for (int kc2 = 0; kc2 < 2; ++kc2) {
      int kc = kb * 2 + kc2;
      bf16x8 bph = *(const bf16x8*)&Ph[w][lr][kc2 * 32 + lu * 8];
      bf16x8 bpl = *(const bf16x8*)&Pl[w][lr][kc2 * 32 + lu * 8];
#pragma unroll
      for (int et = 0; et < 2; ++et) {
        bf16x8 vh = ((const bf16x8*)Vh)[(size_t)((bgh * 2 + et) * 32 + kc) * 64 + l];
        bf16x8 vl = ((const bf16x8*)Vl)[(size_t)((bgh * 2 + et) * 32 + kc) * 64 + l];
        oacc[et] = __builtin_amdgcn_mfma_f32_16x16x32_bf16(vh, bph, oacc[et], 0, 0, 0);
        oacc[et] = __builtin_amdgcn_mfma_f32_16x16x32_bf16(vh, bpl, oacc[et], 0, 0, 0);
        oacc[et] = __builtin_amdgcn_mfma_f32_16x16x32_bf16(vl, bph, oacc[et], 0, 0, 0);
      }
    }
  }
  den += __shfl_xor(den, 16);
  den += __shfl_xor(den, 32);
  float inv = 1.f / den;
  int bg = bgh >> 3, hh = bgh & 7;
  // frag write: ch = hh*32 + et*16 + lu*4 + r  ->  kc=hh, lu_f=et*2+(lu>>1), j0=(lu&1)*4
#pragma unroll
  for (int et = 0; et < 2; ++et) {
    ushort4 h4, l4;
    split2(oacc[et][0] * inv, h4.x, l4.x); split2(oacc[et][1] * inv, h4.y, l4.y);
    split2(oacc[et][2] * inv, h4.z, l4.z); split2(oacc[et][3] * inv, h4.w, l4.w);
    int lu_f = et * 2 + (lu >> 1), j0 = (lu & 1) * 4;
    size_t base = ((((size_t)(bg * 64 + qt)) * 8 + hh) * 64 + lu_f * 16 + lr) * 8 + j0;
    *(ushort4*)(ofh + base) = h4;
    *(ushort4*)(ofl + base) = l4;
  }
}

// ============ main attention (MFMA, d=64), epilogue -> B-frags (KC=16) ========
__global__ __launch_bounds__(256)
void k_mainattn_mfma(const ushort* __restrict__ Qh, const ushort* __restrict__ Ql,
                     const ushort* __restrict__ Kh, const ushort* __restrict__ Kl,
                     const ushort* __restrict__ Vh, const ushort* __restrict__ Vl,
                     ushort* __restrict__ anfh, ushort* __restrict__ anfl) {
  int qb = blockIdx.x & 15, bh = blockIdx.x >> 4;
  int tid = threadIdx.x, w = tid >> 6, l = tid & 63, lr = l & 15, lu = l >> 4;
  int qt = qb * 4 + w;
  bf16x8 qh[2], ql[2];
#pragma unroll
  for (int dc = 0; dc < 2; ++dc) {
    qh[dc] = ((const bf16x8*)Qh)[(size_t)((bh * 64 + qt) * 2 + dc) * 64 + l];
    ql[dc] = ((const bf16x8*)Ql)[(size_t)((bh * 64 + qt) * 2 + dc) * 64 + l];
  }
  __shared__ ushort Ph[4][16][72];
  __shared__ ushort Pl[4][16][72];
  f32x4 zero = {0.f, 0.f, 0.f, 0.f};
  f32x4 oacc[4] = {zero, zero, zero, zero};
  float den = 0.f;
  for (int kb = 0; kb < 16; ++kb) {
#pragma unroll
    for (int kt4 = 0; kt4 < 4; ++kt4) {
      int kt = kb * 4 + kt4;
      f32x4 s = zero;
#pragma unroll
      for (int dc = 0; dc < 2; ++dc) {
        bf16x8 kh = ((const bf16x8*)Kh)[(size_t)((bh * 64 + kt) * 2 + dc) * 64 + l];
        bf16x8 kl = ((const bf16x8*)Kl)[(size_t)((bh * 64 + kt) * 2 + dc) * 64 + l];
        s = __builtin_amdgcn_mfma_f32_16x16x32_bf16(kh, qh[dc], s, 0, 0, 0);
        s = __builtin_amdgcn_mfma_f32_16x16x32_bf16(kh, ql[dc], s, 0, 0, 0);
        s = __builtin_amdgcn_mfma_f32_16x16x32_bf16(kl, qh[dc], s, 0, 0, 0);
      }
      uint2 uh, ul;
      {
        float p0 = __expf(s[0]), p1 = __expf(s[1]), p2 = __expf(s[2]), p3 = __expf(s[3]);
        den += (p0 + p1) + (p2 + p3);
        ushort h0, l0, h1, l1, h2, l2, h3, l3;
        split2(p0, h0, l0); split2(p1, h1, l1); split2(p2, h2, l2); split2(p3, h3, l3);
        uh.x = (unsigned)h0 | ((unsigned)h1 << 16); uh.y = (unsigned)h2 | ((unsigned)h3 << 16);
        ul.x = (unsigned)l0 | ((unsigned)l1 << 16); ul.y = (unsigned)l2 | ((unsigned)l3 << 16);
      }
      *(uint2*)&Ph[w][lr][kt4 * 16 + lu * 4] = uh;
      *(uint2*)&Pl[w][lr][kt4 * 16 + lu * 4] = ul;
    }
#pragma unroll
    for (int kc2 = 0; kc2 < 2; ++kc2) {
      int kc = kb * 2 + kc2;
      bf16x8 bph = *(const bf16x8*)&Ph[w][lr][kc2 * 32 + lu * 8];
      bf16x8 bpl = *(const bf16x8*)&Pl[w][lr][kc2 * 32 + lu * 8];
#pragma unroll
      for (int et = 0; et < 4; ++et) {
        bf16x8 vh = ((const bf16x8*)Vh)[(size_t)((bh * 4 + et) * 32 + kc) * 64 + l];
        bf16x8 vl = ((const bf16x8*)Vl)[(size_t)((bh * 4 + et) * 32 + kc) * 64 + l];
        oacc[et] = __builtin_amdgcn_mfma_f32_16x16x32_bf16(vh, bph, oacc[et], 0, 0, 0);
        oacc[et] = __builtin_amdgcn_mfma_f32_16x16x32_bf16(vh, bpl, oacc[et], 0, 0, 0);
        oacc[et] = __builtin_amdgcn_mfma_f32_16x16x32_bf16(vl, bph, oacc[et], 0, 0, 0);
      }
    }
  }
  den += __shfl_xor(den, 16);
  den += __shfl_xor(den, 32);
  float inv = 1.f / den;
  int b = bh >> 3, h = bh & 7;
  // frag write: ch = h*64 + et*16 + lu*4 + r -> kc=h*2+(et>>1), lu_f=(et&1)*2+(lu>>1)
#pragma unroll
  for (int et = 0; et < 4; ++et) {
    ushort4 h4, l4;
    split2(oacc[et][0] * inv, h4.x, l4.x); split2(oacc[et][1] * inv, h4.y, l4.y);
    split2(oacc[et][2] * inv, h4.z, l4.z); split2(oacc[et][3] * inv, h4.w, l4.w);
    int kc = h * 2 + (et >> 1);
    int lu_f = (et & 1) * 2 + (lu >> 1), j0 = (lu & 1) * 4;
    size_t base = ((((size_t)(b * 64 + qt)) * 16 + kc) * 64 + lu_f * 16 + lr) * 8 + j0;
    *(ushort4*)(anfh + base) = h4;
    *(ushort4*)(anfl + base) = l4;
  }
}

// ---------------- depthwise 3x3 + bias + exact GELU (cm)
__global__ void k_dw3(const float* __restrict__ X, const float* __restrict__ w,
                      const float* __restrict__ bias, float* __restrict__ Y) {
  int idx = blockIdx.x * 256 + threadIdx.x;
  int x = idx & 31, y = (idx >> 5) & 31, ch = (idx >> 10) & 1023, bg = idx >> 20;
  const float* src = X + (size_t)((bg << 10) + ch) * HW;
  const float* wr = w + ch * 9;
  float acc = bias[ch];
#pragma unroll
  for (int ky = 0; ky < 3; ++ky) {
    int yy = y + ky - 1;
    if ((unsigned)yy < 32u) {
      const float* row = src + yy * 32;
#pragma unroll
      for (int kx = 0; kx < 3; ++kx) {
        int xx = x + kx - 1;
        if ((unsigned)xx < 32u) acc += row[xx] * wr[ky * 3 + kx];
      }
    }
  }
  Y[(size_t)((bg << 10) + ch) * HW + y * 32 + x] = gelu_exact(acc);
}

// ---------------- depthwise 9x9 pad 4 on nc layout, wt9 = transposed weights
__global__ void k_dw9_nc(const float* __restrict__ Xnc, const float* __restrict__ wt9,
                         const float* __restrict__ bias, float* __restrict__ Ync) {
  int bid = blockIdx.x;               // 1024 = bg(8) x ptile(128), 8 px per block
  int pt = bid & 127; int bg = bid >> 7;
  int tid = threadIdx.x;              // = channel
  int y = pt >> 2, x0 = (pt & 3) * 8;
  float acc[8];
  float bs = bias[tid];
#pragma unroll
  for (int p = 0; p < 8; ++p) acc[p] = bs;
  const float* src = Xnc + (size_t)(bg << 10) * 256;
  for (int ky = 0; ky < 9; ++ky) {
    int yy = y + ky - 4;
    if ((unsigned)yy >= 32u) continue;
#pragma unroll
    for (int kx = 0; kx < 9; ++kx) {
      float wv = wt9[(ky * 9 + kx) * 256 + tid];
#pragma unroll
      for (int p = 0; p < 8; ++p) {
        int xx = x0 + p + kx - 4;
        if ((unsigned)xx < 32u)
          acc[p] += src[(size_t)(yy * 32 + xx) * 256 + tid] * wv;
      }
    }
  }
#pragma unroll
  for (int p = 0; p < 8; ++p)
    Ync[((size_t)((bg << 10) + y * 32 + x0 + p)) * 256 + tid] = acc[p];
}

// ---------------- co tail on nc layout: wave per token
__global__ void k_cotail_nc(const float* __restrict__ Xnc, const float* __restrict__ lnw,
                            const float* __restrict__ lnb, const float* __restrict__ w2,
                            float* __restrict__ pos) {
  int token = (blockIdx.x * 256 + threadIdx.x) >> 6;   // 8192
  int lane = threadIdx.x & 63;
  float4 v4 = *(const float4*)(Xnc + (size_t)token * 256 + lane * 4);
  float s = v4.x + v4.y + v4.z + v4.w;
  float s2 = v4.x * v4.x + v4.y * v4.y + v4.z * v4.z + v4.w * v4.w;
#pragma unroll
  for (int off = 32; off; off >>= 1) { s += __shfl_xor(s, off); s2 += __shfl_xor(s2, off); }
  float mean = s * (1.f / 256.f);
  float rstd = rsqrtf(s2 * (1.f / 256.f) - mean * mean + 1e-5f);
  float4 g4 = *(const float4*)(lnw + lane * 4);
  float4 b4 = *(const float4*)(lnb + lane * 4);
  float4 wa = *(const float4*)(w2 + lane * 4);
  float4 wb = *(const float4*)(w2 + 256 + lane * 4);
  float ge0 = gelu_exact((v4.x - mean) * rstd * g4.x + b4.x);
  float ge1 = gelu_exact((v4.y - mean) * rstd * g4.y + b4.y);
  float ge2 = gelu_exact((v4.z - mean) * rstd * g4.z + b4.z);
  float ge3 = gelu_exact((v4.w - mean) * rstd * g4.w + b4.w);
  float o0 = ge0 * wa.x + ge1 * wa.y + ge2 * wa.z + ge3 * wa.w;
  float o1 = ge0 * wb.x + ge1 * wb.y + ge2 * wb.z + ge3 * wb.w;
#pragma unroll
  for (int off = 32; off; off >>= 1) { o0 += __shfl_xor(o0, off); o1 += __shfl_xor(o1, off); }
  if (lane == 0) {
    float offy = tanhf(o0) * (2.f / 32.f);
    float offx = tanhf(o1) * (2.f / 32.f);
    int n = token & 1023;
    int ky = n >> 5, kx = n & 31;
    float refy = ((ky + 0.5f) * (1.f / 32.f)) * 2.f - 1.f;
    float refx = ((kx + 0.5f) * (1.f / 32.f)) * 2.f - 1.f;
    pos[token * 2] = offx + refx;
    pos[token * 2 + 1] = offy + refy;
  }
}

// ---------------- bilinear grid sample on nc layout -> sampled_nc
__global__ void k_gsample_nc(const float* __restrict__ Xnc, const float* __restrict__ pos,
                             float* __restrict__ out_nc) {
  int bid = blockIdx.x;            // bg(8) x nch(16)
  int nch = bid & 15; int bg = bid >> 4;
  int tid = threadIdx.x;           // = channel c
  __shared__ int sI[4][64];
  __shared__ float sW[4][64];
  if (tid < 64) {
    int j = nch * 64 + tid;
    float gx = pos[((bg << 10) + j) * 2];
    float gy = pos[((bg << 10) + j) * 2 + 1];
    float fx = (gx + 1.f) * 0.5f * 31.f;
    float fy = (gy + 1.f) * 0.5f * 31.f;
    float x0f = floorf(fx), y0f = floorf(fy);
    int x0 = (int)x0f, y0 = (int)y0f;
    float wx1 = fx - x0f, wx0 = 1.f - wx1;
    float wy1 = fy - y0f, wy0 = 1.f - wy1;
    bool vx0 = (x0 >= 0) & (x0 <= 31);
    bool vx1 = (x0 + 1 >= 0) & (x0 + 1 <= 31);
    bool vy0 = (y0 >= 0) & (y0 <= 31);
    bool vy1 = (y0 + 1 >= 0) & (y0 + 1 <= 31);
    int cx0 = min(max(x0, 0), 31), cx1 = min(max(x0 + 1, 0), 31);
    int cy0 = min(max(y0, 0), 31), cy1 = min(max(y0 + 1, 0), 31);
    sW[0][tid] = wx0 * wy0 * ((vx0 && vy0) ? 1.f : 0.f);
    sW[1][tid] = wx1 * wy0 * ((vx1 && vy0) ? 1.f : 0.f);
    sW[2][tid] = wx0 * wy1 * ((vx0 && vy1) ? 1.f : 0.f);
    sW[3][tid] = wx1 * wy1 * ((vx1 && vy1) ? 1.f : 0.f);
    sI[0][tid] = cy0 * 32 + cx0; sI[1][tid] = cy0 * 32 + cx1;
    sI[2][tid] = cy1 * 32 + cx0; sI[3][tid] = cy1 * 32 + cx1;
  }
  __syncthreads();
  const float* src = Xnc + (size_t)(bg << 10) * 256;
  for (int n = 0; n < 64; ++n) {
    float acc = src[(size_t)sI[0][n] * 256 + tid] * sW[0][n]
              + src[(size_t)sI[1][n] * 256 + tid] * sW[1][n]
              + src[(size_t)sI[2][n] * 256 + tid] * sW[2][n]
              + src[(size_t)sI[3][n] * 256 + tid] * sW[3][n];
    out_nc[((size_t)((bg << 10) + nch * 64 + n)) * 256 + tid] = acc;
  }
}

// ---------------------------------------------------------------------------
extern "C" void kernel_launch(void* const* d_in, const int* in_sizes, int n_in,
                              void* d_out, int out_size, void* d_ws, size_t ws_size,
                              hipStream_t stream) {
  const float* tgt    = (const float*)d_in[0];
  const float* refp   = (const float*)d_in[1];
  const float* emb_w  = (const float*)d_in[2];
  const float* emb_b  = (const float*)d_in[3];
  const float* q_w    = (const float*)d_in[4];
  const float* q_b    = (const float*)d_in[5];
  const float* k_w    = (const float*)d_in[6];
  const float* k_b    = (const float*)d_in[7];
  const float* v_w    = (const float*)d_in[8];
  const float* v_b    = (const float*)d_in[9];
  const float* out_w  = (const float*)d_in[10];
  const float* out_b  = (const float*)d_in[11];
  const float* ln1_w  = (const float*)d_in[12];
  const float* ln1_b  = (const float*)d_in[13];
  const float* n1_w   = (const float*)d_in[14];
  const float* n1_b   = (const float*)d_in[15];
  const float* mbq_w  = (const float*)d_in[16];
  const float* mbq_b  = (const float*)d_in[17];
  const float* mbkv_w = (const float*)d_in[18];
  const float* mbkv_b = (const float*)d_in[19];
  const float* mbp_w  = (const float*)d_in[20];
  const float* mbp_b  = (const float*)d_in[21];
  const float* n2_w   = (const float*)d_in[22];
  const float* n2_b   = (const float*)d_in[23];
  const float* fc1_w  = (const float*)d_in[24];
  const float* fc1_b  = (const float*)d_in[25];
  const float* dw3_w  = (const float*)d_in[26];
  const float* dw3_b  = (const float*)d_in[27];
  const float* fc2_w  = (const float*)d_in[28];
  const float* fc2_b  = (const float*)d_in[29];
  const float* dw9_w  = (const float*)d_in[30];
  const float* dw9_b  = (const float*)d_in[31];
  const float* coln_w = (const float*)d_in[32];
  const float* coln_b = (const float*)d_in[33];
  const float* coout_w= (const float*)d_in[34];

  float* ws = (float*)d_ws;
  // slabs (float offsets)
  float* slabA = ws + 0;          // offin_nc -> sampled_nc
  float* qbuf  = ws + 2097152;    // q proj out (persists to step 16)
  float* xbuf  = ws + 4194304;    // x tm residual (overlaps XtH until ln1)
  float* slabD = ws + 6291456;    // P_cm -> ygemm -> kbuf
  float* slabE = ws + 8388608;    // qq_cm -> offdw_nc -> vbuf
  float* slabF = ws + 10485760;   // tgtf -> kv_cm -> ofrags -> h2frags -> mifrags -> sfrags
  float* slabG = ws + 14680064;   // WtEmb -> hfrags -> mbfrags -> m_cm -> mainfrags
  float* slabH = ws + 23068672;   // part(4) -> mi_cm -> attn-out frags
  float* featnc= ws + 31457280;   // feat_nc (persists to step 14)
  float* posb  = ws + 35389440;   // [8,1024,2]
  float* wt9   = ws + 35405824;   // [81][256] transposed dw9 weights

  // emb prep
  ushort* XtH = (ushort*)(ws + 4194304);
  ushort* XtL = XtH + 4734976;
  ushort* WtEH = (ushort*)slabG;
  ushort* WtEL = WtEH + 4718592;
  float* part = slabH;                         // 4 x 2097152
  ushort* tgtfh = (ushort*)slabF;              // tgt B-frags
  ushort* tgtfl = tgtfh + 2097152;

  // weight frags (long-lived, slab J)
  ushort* J = (ushort*)(ws + 33554432);
  ushort* wfq_h = J;                ushort* wfq_l = J + 262144;
  ushort* wfk_h = J + 524288;       ushort* wfk_l = J + 786432;
  ushort* wfv_h = J + 1048576;      ushort* wfv_l = J + 1310720;
  ushort* wfo_h = J + 1572864;      ushort* wfo_l = J + 1835008;
  ushort* wfmq_h = J + 2097152;     ushort* wfmq_l = J + 2162688;
  ushort* wfmkv_h = J + 2228224;    ushort* wfmkv_l = J + 2359296;
  ushort* wfmp_h = J + 2490368;     ushort* wfmp_l = J + 2555904;
  ushort* wff1_h = J + 2621440;     ushort* wff1_l = J + 2883584;
  ushort* wff2_h = J + 3145728;     ushort* wff2_l = J + 3407872;

  // phase pointers
  ushort* hfh = (ushort*)slabG;     ushort* hfl = hfh + 2097152;  // n1 frags
  float* qq_cm  = slabE;
  float* kv_cm  = slabF;
  ushort* mQh = (ushort*)slabG;     ushort* mQl = mQh + 2097152;
  ushort* mKh = mQh + 4194304;      ushort* mKl = mQh + 6291456;
  ushort* mVh = mQh + 8388608;      ushort* mVl = mQh + 10485760;
  ushort* ofh = (ushort*)slabF;     ushort* ofl = ofh + 2097152;  // mb-attn out frags
  float* P_cm = slabD;
  ushort* h2fh = (ushort*)slabF;    ushort* h2fl = h2fh + 2097152;
  float* m_cm = slabG;
  float* mi_cm = slabH;
  ushort* mifh = (ushort*)slabF;    ushort* mifl = mifh + 4194304;
  float* ygemm = slabD;
  float* offin = slabA;
  float* offdwnc = slabE;
  float* samplednc = slabA;
  ushort* sfh = (ushort*)slabF;     ushort* sfl = sfh + 2097152;
  float* kbuf = slabD;
  float* vbuf = slabE;
  ushort* aQh = (ushort*)slabG;     ushort* aQl = aQh + 2097152;
  ushort* aKh = aQh + 4194304;      ushort* aKl = aQh + 6291456;
  ushort* aVh = aQh + 8388608;      ushort* aVl = aQh + 10485760;
  ushort* anfh = (ushort*)slabH;    ushort* anfl = anfh + 2097152;

  // --- step 0: preps ---
  k_prepw<<<2048, 256, 0, stream>>>(emb_w, WtEH, WtEL);
  k_prepx<<<2312, 256, 0, stream>>>(tgt, refp, XtH, XtL);
  k_prep_wfrag9<<<977, 256, 0, stream>>>(q_w, k_w, v_w, out_w, mbq_w, mbkv_w, mbp_w,
                                         fc1_w, fc2_w, dw9_w,
                                         wfq_h, wfq_l, wfk_h, wfk_l, wfv_h, wfv_l,
                                         wfo_h, wfo_l, wfmq_h, wfmq_l, wfmkv_h, wfmkv_l,
                                         wfmp_h, wfmp_l, wff1_h, wff1_l, wff2_h, wff2_l,
                                         wt9);
  k_prep_cm2frag<<<1024, 256, 0, stream>>>(tgt, 512, 16, tgtfh, tgtfl);
  // --- step 1: emb conv (4-way K-split) ---
  k_emb_mfma<<<1024, 256, 0, stream>>>(XtH, XtL, WtEH, WtEL, part);
  k_embmerge_nc<<<512, 256, 0, stream>>>(part, emb_b, featnc);
  // --- step 2: q proj ---
  k_gemm_mfma<<<256, 256, 0, stream>>>(wfq_h, wfq_l, tgtfh, tgtfl, q_b, qbuf, 16, 4, 512);
  // --- step 3: ln1 -> x (tm residual) ---
  k_ln_tok<<<2048, 256, 0, stream>>>(featnc, ln1_w, ln1_b, xbuf, 1e-5f);
  // --- step 4: n1 -> h frags directly ---
  k_ln_frag<<<2048, 256, 0, stream>>>(xbuf, n1_w, n1_b, hfh, hfl, 1e-6f);
  // --- step 5: mbq/mbkv GEMMs -> cm ---
  k_gemm_mfma<<<256, 256, 0, stream>>>(wfmq_h, wfmq_l, hfh, hfl, mbq_b, qq_cm, 8, 2, 256);
  k_gemm_mfma<<<512, 256, 0, stream>>>(wfmkv_h, wfmkv_l, hfh, hfl, mbkv_b, kv_cm, 8, 4, 512);
  // --- step 6: mb attention (fused prep; epilogue writes o frags) ---
  k_prep_mb3<<<3072, 256, 0, stream>>>(qq_cm, kv_cm, mQh, mQl, mKh, mKl, mVh, mVl);
  k_mbattn_mfma<<<1024, 256, 0, stream>>>(mQh, mQl, mKh, mKl, mVh, mVl, ofh, ofl);
  // --- step 7: mbproj + residual ---
  k_gemm_mfma<<<256, 256, 0, stream>>>(wfmp_h, wfmp_l, ofh, ofl, mbp_b, P_cm, 8, 2, 256);
  k_transadd_tm<<<512, 256, 0, stream>>>(P_cm, xbuf);
  // --- step 8: n2 -> h2 frags directly ---
  k_ln_frag<<<2048, 256, 0, stream>>>(xbuf, n2_w, n2_b, h2fh, h2fl, 1e-6f);
  // --- step 9: fc1 ---
  k_gemm_mfma<<<1024, 256, 0, stream>>>(wff1_h, wff1_l, h2fh, h2fl, fc1_b, m_cm, 8, 8, 1024);
  // --- step 10: dw3 + gelu; mi frags ---
  k_dw3<<<32768, 256, 0, stream>>>(m_cm, dw3_w, dw3_b, mi_cm);
  k_prep_cm2frag<<<4096, 256, 0, stream>>>(mi_cm, 1024, 32, mifh, mifl);
  // --- step 11: fc2 + residual -> offin nc ---
  k_gemm_mfma<<<256, 256, 0, stream>>>(wff2_h, wff2_l, mifh, mifl, fc2_b, ygemm, 32, 2, 256);
  k_transadd_nc<<<512, 256, 0, stream>>>(ygemm, xbuf, offin);
  // --- step 12: dw9 on nc ---
  k_dw9_nc<<<1024, 256, 0, stream>>>(offin, wt9, dw9_b, offdwnc);
  // --- step 13: cotail ---
  k_cotail_nc<<<2048, 256, 0, stream>>>(offdwnc, coln_w, coln_b, coout_w, posb);
  // --- step 14: grid sample + frags ---
  k_gsample_nc<<<128, 256, 0, stream>>>(featnc, posb, samplednc);
  k_prep_s2frag<<<1024, 256, 0, stream>>>(samplednc, sfh, sfl);
  // --- step 15: k/v proj ---
  k_gemm_mfma<<<256, 256, 0, stream>>>(wfk_h, wfk_l, sfh, sfl, k_b, kbuf, 16, 4, 512);
  k_gemm_mfma<<<256, 256, 0, stream>>>(wfv_h, wfv_l, sfh, sfl, v_b, vbuf, 16, 4, 512);
  // --- step 16: main attention (fused prep; epilogue writes out-frags) ---
  k_prep_main3<<<3072, 256, 0, stream>>>(qbuf, kbuf, vbuf, aQh, aQl, aKh, aKl, aVh, aVl);
  k_mainattn_mfma<<<512, 256, 0, stream>>>(aQh, aQl, aKh, aKl, aVh, aVl, anfh, anfl);
  // --- step 17: out proj -> d_out ---
  k_gemm_mfma<<<256, 256, 0, stream>>>(wfo_h, wfo_l, anfh, anfl, out_b, (float*)d_out, 16, 4, 512);
}

// Round 6
// 716.709 us; speedup vs baseline: 4.2616x; 1.0612x over previous
//
#include <hip/hip_runtime.h>
#include <math.h>

// ---------------------------------------------------------------------------
// DAttention forward. R6: XCD-swizzled emb grid (weight L2 residency) +
// finer GEMM wave tiling (2x wave parallelism).
// Dims: B=4, C=512, H=W=32, G=2, gc=256, BG=8, heads=8, hc=64, mh=8, mhd=32.
// ---------------------------------------------------------------------------

static constexpr int HW = 1024;

typedef __attribute__((ext_vector_type(8))) short bf16x8;
typedef __attribute__((ext_vector_type(4))) float f32x4;

union V16u { int4 i4; ushort u[8]; };

__device__ __forceinline__ float gelu_exact(float v) {
  return 0.5f * v * (1.0f + erff(v * 0.7071067811865475f));
}

__device__ __forceinline__ ushort bf16_rne(float v) {
  unsigned int b = __float_as_uint(v);
  return (ushort)((b + 0x7fffu + ((b >> 16) & 1u)) >> 16);
}

__device__ __forceinline__ void split2(float v, ushort& h, ushort& l) {
  h = bf16_rne(v);
  l = bf16_rne(v - __uint_as_float(((unsigned int)h) << 16));
}

// ---------------- emb prep: weights [512][1024][3][3] -> [9][512][1024] bf16 hi/lo
__global__ void k_prepw(const float* __restrict__ w, ushort* __restrict__ Wt_hi,
                        ushort* __restrict__ Wt_lo) {
  int idx = blockIdx.x * 256 + threadIdx.x;    // 524288
  int o = idx >> 10, ci = idx & 1023;
  const float* src = w + (size_t)idx * 9;
#pragma unroll
  for (int t = 0; t < 9; ++t) {
    ushort h, l; split2(src[t], h, l);
    size_t oo = ((size_t)(t * 512 + o)) * 1024 + ci;
    Wt_hi[oo] = h; Wt_lo[oo] = l;
  }
}

// ---------------- emb prep: inputs -> [4][34][34][1024] bf16 hi/lo (padded)
__global__ void k_prepx(const float* __restrict__ tgt, const float* __restrict__ refp,
                        ushort* __restrict__ Xt_hi, ushort* __restrict__ Xt_lo) {
  int idx = blockIdx.x * 256 + threadIdx.x;    // 591872
  int xp = idx % 34; int r = idx / 34;
  int g8 = r & 127; r >>= 7;
  int yp = r % 34; int b = r / 34;
  int y = yp - 1, x = xp - 1;
  bool valid = (unsigned)y < 32u && (unsigned)x < 32u;
  V16u hi, lo;
  const float* in = (g8 < 64) ? (tgt + ((size_t)(b * 512 + g8 * 8)) * HW)
                              : (refp + ((size_t)(b * 512 + (g8 - 64) * 8)) * HW);
#pragma unroll
  for (int j = 0; j < 8; ++j) {
    float v = valid ? in[(size_t)j * HW + y * 32 + x] : 0.f;
    split2(v, hi.u[j], lo.u[j]);
  }
  size_t oo = (((size_t)(b * 34 + yp)) * 34 + xp) * 1024 + g8 * 8;
  *(int4*)(Xt_hi + oo) = hi.i4;
  *(int4*)(Xt_lo + oo) = lo.i4;
}

// ---------------- emb conv via MFMA, split-bf16 3-term, 4-way K-split
// XCD swizzle: logical w = ((ks*4+mt)*4+b)*16+yt; each XCD (bid&7) owns 128
// consecutive logical blocks = 2 (ks,mt) weight combos = 2.4 MB, L2-resident.
__global__ __launch_bounds__(256, 4)
void k_emb_mfma(const ushort* __restrict__ Xt_hi, const ushort* __restrict__ Xt_lo,
                const ushort* __restrict__ Wt_hi, const ushort* __restrict__ Wt_lo,
                float* __restrict__ part) {
  int wg = (blockIdx.x & 7) * 128 + (blockIdx.x >> 3);
  int yt = wg & 15; wg >>= 4;
  int b  = wg & 3;  wg >>= 2;
  int mt = wg & 3;  wg >>= 2;
  int ks = wg;
  int tid = threadIdx.x;
  int w = tid >> 6, l = tid & 63;
  int lr = l & 15, lu = l >> 4;
  int y0 = yt * 2;
  int obase = mt * 128 + w * 32;

  __shared__ int4 LsH[2][576];
  __shared__ int4 LsL[2][576];

  int4 gh[3], gl[3];
  int kc0 = ks * 8;

  auto loadstage = [&](int kcg) {
#pragma unroll
    for (int i = 0; i < 3; ++i) {
      int s = tid + 256 * i;
      if (s < 576) {
        int px = s >> 2;
        int pxc = px > 135 ? 135 : px;
        int u = (s & 3) ^ ((pxc >> 1) & 3);
        size_t off = (((size_t)(b * 34 + y0)) * 34 + pxc) * 1024 + kcg * 32 + u * 8;
        gh[i] = *(const int4*)(Xt_hi + off);
        gl[i] = *(const int4*)(Xt_lo + off);
      }
    }
  };
  auto writestage = [&](int buf) {
#pragma unroll
    for (int i = 0; i < 3; ++i) {
      int s = tid + 256 * i;
      if (s < 576) { LsH[buf][s] = gh[i]; LsL[buf][s] = gl[i]; }
    }
  };

  f32x4 zero = {0.f, 0.f, 0.f, 0.f};
  f32x4 acc[2][4];
#pragma unroll
  for (int a = 0; a < 2; ++a)
#pragma unroll
    for (int n = 0; n < 4; ++n) acc[a][n] = zero;

  loadstage(kc0);
  writestage(0);

  for (int kc = 0; kc < 8; ++kc) {
    int buf = kc & 1;
    __syncthreads();
    if (kc < 7) loadstage(kc0 + kc + 1);
    int kcg = kc0 + kc;
    const bf16x8* BH = (const bf16x8*)&LsH[buf][0];
    const bf16x8* BL = (const bf16x8*)&LsL[buf][0];
#pragma unroll
    for (int kx = 0; kx < 3; ++kx) {
      bf16x8 bh[8], bl[8];
#pragma unroll
      for (int f = 0; f < 8; ++f) {
        int px = (f >> 1) * 34 + (f & 1) * 16 + kx + lr;
        int idx = px * 4 + (lu ^ ((px >> 1) & 3));
        bh[f] = BH[idx]; bl[f] = BL[idx];
      }
#pragma unroll
      for (int ky = 0; ky < 3; ++ky) {
        int tap = ky * 3 + kx;
        size_t wo = (((size_t)(tap * 512 + obase + lr)) * 1024) + kcg * 32 + lu * 8;
        bf16x8 ah0 = *(const bf16x8*)(Wt_hi + wo);
        bf16x8 al0 = *(const bf16x8*)(Wt_lo + wo);
        bf16x8 ah1 = *(const bf16x8*)(Wt_hi + wo + 16 * 1024);
        bf16x8 al1 = *(const bf16x8*)(Wt_lo + wo + 16 * 1024);
#pragma unroll
        for (int yr = 0; yr < 2; ++yr)
#pragma unroll
          for (int h = 0; h < 2; ++h) {
            int f = (yr + ky) * 2 + h;
            int nf = yr * 2 + h;
            acc[0][nf] = __builtin_amdgcn_mfma_f32_16x16x32_bf16(ah0, bh[f], acc[0][nf], 0, 0, 0);
            acc[0][nf] = __builtin_amdgcn_mfma_f32_16x16x32_bf16(ah0, bl[f], acc[0][nf], 0, 0, 0);
            acc[0][nf] = __builtin_amdgcn_mfma_f32_16x16x32_bf16(al0, bh[f], acc[0][nf], 0, 0, 0);
            acc[1][nf] = __builtin_amdgcn_mfma_f32_16x16x32_bf16(ah1, bh[f], acc[1][nf], 0, 0, 0);
            acc[1][nf] = __builtin_amdgcn_mfma_f32_16x16x32_bf16(ah1, bl[f], acc[1][nf], 0, 0, 0);
            acc[1][nf] = __builtin_amdgcn_mfma_f32_16x16x32_bf16(al1, bh[f], acc[1][nf], 0, 0, 0);
          }
      }
    }
    if (kc < 7) writestage(buf ^ 1);
  }

  float* pb = part + (size_t)ks * 2097152;
#pragma unroll
  for (int a = 0; a < 2; ++a)
#pragma unroll
    for (int yr = 0; yr < 2; ++yr)
#pragma unroll
      for (int h = 0; h < 2; ++h) {
        f32x4 c = acc[a][yr * 2 + h];
        size_t base = ((size_t)(b * 512 + obase + a * 16 + lu * 4)) * 1024
                      + (y0 + yr) * 32 + h * 16 + lr;
#pragma unroll
        for (int r = 0; r < 4; ++r) pb[base + (size_t)r * 1024] = c[r];
      }
}

// ---------------- emb merge: sum 4 parts + bias, write feat_nc (transposing)
__global__ void k_embmerge_nc(const float* __restrict__ part, const float* __restrict__ bias,
                              float* __restrict__ featnc) {
  __shared__ float T[64][65];
  int bid = blockIdx.x;                 // 512 = bg(8) x c-tile(4) x n-tile(16)
  int n0 = (bid & 15) << 6; bid >>= 4;
  int c0 = (bid & 3) << 6; int bg = bid >> 2;
  int cl = threadIdx.x & 63, rw = threadIdx.x >> 6;
#pragma unroll
  for (int i = 0; i < 16; ++i) {
    int crow = i * 4 + rw;
    size_t idx = ((size_t)(bg * 256 + c0 + crow)) * 1024 + n0 + cl;
    float v = part[idx] + part[2097152 + idx] + part[4194304 + idx] + part[6291456 + idx];
    T[crow][cl] = v + bias[(bg & 1) * 256 + c0 + crow];
  }
  __syncthreads();
#pragma unroll
  for (int i = 0; i < 16; ++i) {
    int nrow = i * 4 + rw;
    featnc[((size_t)(bg * 1024 + n0 + nrow)) * 256 + c0 + cl] = T[cl][nrow];
  }
}

// ============ fused static preps: 9 weight frag sets + dw9 weight transpose ====
__device__ __forceinline__ void wfrag_body(const float* __restrict__ W, int K, int KC,
                                           ushort* __restrict__ dh, ushort* __restrict__ dl,
                                           int gtid) {
  int l = gtid & 63; int fr = gtid >> 6;
  int kc = fr % KC; int ot = fr / KC;
  int lr = l & 15, lu = l >> 4;
  const float* sp = W + (size_t)(ot * 16 + lr) * K + kc * 32 + lu * 8;
  V16u hi, lo;
#pragma unroll
  for (int j = 0; j < 8; ++j) split2(sp[j], hi.u[j], lo.u[j]);
  *(int4*)(dh + (size_t)gtid * 8) = hi.i4;
  *(int4*)(dl + (size_t)gtid * 8) = lo.i4;
}

__global__ void k_prep_wfrag9(
    const float* q_w, const float* k_w, const float* v_w, const float* o_w,
    const float* mq_w, const float* mkv_w, const float* mp_w,
    const float* f1_w, const float* f2_w, const float* dw9_w,
    ushort* qh, ushort* ql, ushort* kh, ushort* kl, ushort* vh, ushort* vl,
    ushort* oh, ushort* ol, ushort* mqh, ushort* mql, ushort* mkvh, ushort* mkvl,
    ushort* mph, ushort* mpl, ushort* f1h, ushort* f1l, ushort* f2h, ushort* f2l,
    float* wt9) {
  int bid = blockIdx.x, tid = threadIdx.x;
  if (bid < 128)      wfrag_body(q_w, 512, 16, qh, ql, bid * 256 + tid);
  else if (bid < 256) wfrag_body(k_w, 512, 16, kh, kl, (bid - 128) * 256 + tid);
  else if (bid < 384) wfrag_body(v_w, 512, 16, vh, vl, (bid - 256) * 256 + tid);
  else if (bid < 512) wfrag_body(o_w, 512, 16, oh, ol, (bid - 384) * 256 + tid);
  else if (bid < 544) wfrag_body(mq_w, 256, 8, mqh, mql, (bid - 512) * 256 + tid);
  else if (bid < 608) wfrag_body(mkv_w, 256, 8, mkvh, mkvl, (bid - 544) * 256 + tid);
  else if (bid < 640) wfrag_body(mp_w, 256, 8, mph, mpl, (bid - 608) * 256 + tid);
  else if (bid < 768) wfrag_body(f1_w, 256, 8, f1h, f1l, (bid - 640) * 256 + tid);
  else if (bid < 896) wfrag_body(f2_w, 1024, 32, f2h, f2l, (bid - 768) * 256 + tid);
  else {
    int idx = (bid - 896) * 256 + tid;  // 81*256 = 20736
    int t = idx >> 8, c = idx & 255;
    wt9[idx] = dw9_w[c * 81 + t];
  }
}

// cm activations [b][CH][1024] -> B-frags
__global__ void k_prep_cm2frag(const float* __restrict__ src, int CH, int KC,
                               ushort* __restrict__ dh, ushort* __restrict__ dl) {
  int gtid = blockIdx.x * 256 + threadIdx.x;
  int l = gtid & 63; int fr = gtid >> 6;
  int kc = fr % KC; int r2 = fr / KC; int nt = r2 & 63; int b = r2 >> 6;
  int lr = l & 15, lu = l >> 4;
  const float* sp = src + ((size_t)(b * CH) + kc * 32 + lu * 8) * 1024 + nt * 16 + lr;
  V16u hi, lo;
#pragma unroll
  for (int j = 0; j < 8; ++j) split2(sp[(size_t)j * 1024], hi.u[j], lo.u[j]);
  *(int4*)(dh + (size_t)gtid * 8) = hi.i4;
  *(int4*)(dl + (size_t)gtid * 8) = lo.i4;
}

// sampled_nc [8][1024][256] viewed as [4b][512ch] -> B-frags (KC=16)
__global__ void k_prep_s2frag(const float* __restrict__ snc,
                              ushort* __restrict__ dh, ushort* __restrict__ dl) {
  int gtid = blockIdx.x * 256 + threadIdx.x;   // 262144
  int l = gtid & 63; int fr = gtid >> 6;
  int kc = fr & 15; int nt = (fr >> 4) & 63; int b = fr >> 10;
  int lr = l & 15, lu = l >> 4;
  const float* sp = snc + ((size_t)((b * 2 + (kc >> 3)) * 1024 + nt * 16 + lr)) * 256
                    + (kc & 7) * 32 + lu * 8;
  V16u hi, lo;
#pragma unroll
  for (int j = 0; j < 8; ++j) split2(sp[j], hi.u[j], lo.u[j]);
  *(int4*)(dh + (size_t)gtid * 8) = hi.i4;
  *(int4*)(dl + (size_t)gtid * 8) = lo.i4;
}

// ============ generic MFMA GEMM: Y[b][Mtot][1024] = W[Mtot,K] x B + bias ======
// block = 4 waves arranged 2x2: block tile 64o x 64n, wave = 32o x 32n.
// grid = B * MT * 16, MT = Mtot/64.
__global__ __launch_bounds__(256)
void k_gemm_mfma(const ushort* __restrict__ Ah, const ushort* __restrict__ Al,
                 const ushort* __restrict__ Bh, const ushort* __restrict__ Bl,
                 const float* __restrict__ bias, float* __restrict__ Y,
                 int KC, int MT, int Mtot) {
  int bid = blockIdx.x;
  int ntb = bid & 15; bid >>= 4;
  int mt = bid % MT; int b = bid / MT;
  int tid = threadIdx.x, w = tid >> 6, l = tid & 63, lr = l & 15, lu = l >> 4;
  int wo = w >> 1, wn = w & 1;
  int ot0 = mt * 4 + wo * 2;          // 2 o-tiles = 32 o
  int nf0 = ntb * 4 + wn * 2;         // 2 n-frags = 32 n
  const bf16x8* pAh = (const bf16x8*)Ah;
  const bf16x8* pAl = (const bf16x8*)Al;
  const bf16x8* pBh = (const bf16x8*)Bh;
  const bf16x8* pBl = (const bf16x8*)Bl;
  f32x4 zero = {0.f, 0.f, 0.f, 0.f};
  f32x4 acc[2][2];
#pragma unroll
  for (int a = 0; a < 2; ++a)
#pragma unroll
    for (int n = 0; n < 2; ++n) acc[a][n] = zero;
  for (int kc = 0; kc < KC; ++kc) {
    bf16x8 a_h[2], a_l[2];
#pragma unroll
    for (int a = 0; a < 2; ++a) {
      size_t idx = ((size_t)(ot0 + a) * KC + kc) * 64 + l;
      a_h[a] = pAh[idx]; a_l[a] = pAl[idx];
    }
#pragma unroll
    for (int n = 0; n < 2; ++n) {
      size_t idx = (((size_t)(b * 64 + nf0 + n)) * KC + kc) * 64 + l;
      bf16x8 b_h = pBh[idx], b_l = pBl[idx];
#pragma unroll
      for (int a = 0; a < 2; ++a) {
        acc[a][n] = __builtin_amdgcn_mfma_f32_16x16x32_bf16(a_h[a], b_h, acc[a][n], 0, 0, 0);
        acc[a][n] = __builtin_amdgcn_mfma_f32_16x16x32_bf16(a_h[a], b_l, acc[a][n], 0, 0, 0);
        acc[a][n] = __builtin_amdgcn_mfma_f32_16x16x32_bf16(a_l[a], b_h, acc[a][n], 0, 0, 0);
      }
    }
  }
#pragma unroll
  for (int a = 0; a < 2; ++a) {
    int o = (ot0 + a) * 16 + lu * 4;
#pragma unroll
    for (int n = 0; n < 2; ++n) {
      int col = (nf0 + n) * 16 + lr;
#pragma unroll
      for (int r = 0; r < 4; ++r)
        Y[((size_t)(b * Mtot + o + r)) * 1024 + col] = acc[a][n][r] + bias[o + r];
    }
  }
}

// ============ transposes ============
// Xtm += transpose(P_cm)   (mbproj residual)
__global__ void k_transadd_tm(const float* __restrict__ Pcm, float* __restrict__ Xtm) {
  __shared__ float T[64][65];
  int bid = blockIdx.x; int n0 = (bid & 15) << 6; bid >>= 4;
  int c0 = (bid & 3) << 6; int bg = bid >> 2;
  int cl = threadIdx.x & 63, rw = threadIdx.x >> 6;
#pragma unroll
  for (int i = 0; i < 16; ++i) {
    int crow = i * 4 + rw;
    T[crow][cl] = Pcm[((size_t)(bg * 256 + c0 + crow)) * 1024 + n0 + cl];
  }
  __syncthreads();
#pragma unroll
  for (int i = 0; i < 16; ++i) {
    int nrow = i * 4 + rw;
    Xtm[((size_t)((bg << 10) + n0 + nrow)) * 256 + c0 + cl] += T[cl][nrow];
  }
}

// offin_nc = transpose(ygemm_cm) + xbuf_tm   (fc2 residual)
__global__ void k_transadd_nc(const float* __restrict__ Yg, const float* __restrict__ Xtm,
                              float* __restrict__ out_nc) {
  __shared__ float T[64][65];
  int bid = blockIdx.x; int n0 = (bid & 15) << 6; bid >>= 4;
  int c0 = (bid & 3) << 6; int bg = bid >> 2;
  int cl = threadIdx.x & 63, rw = threadIdx.x >> 6;
#pragma unroll
  for (int i = 0; i < 16; ++i) {
    int crow = i * 4 + rw;
    T[crow][cl] = Yg[((size_t)(bg * 256 + c0 + crow)) * 1024 + n0 + cl];
  }
  __syncthreads();
#pragma unroll
  for (int i = 0; i < 16; ++i) {
    int nrow = i * 4 + rw;
    size_t a = ((size_t)((bg << 10) + n0 + nrow)) * 256 + c0 + cl;
    out_nc[a] = T[cl][nrow] + Xtm[a];
  }
}

// ---------------- token-major LN -> tm out (ln1 residual stream)
__global__ void k_ln_tok(const float* __restrict__ xin, const float* __restrict__ g_,
                         const float* __restrict__ b_, float* __restrict__ yo, float eps) {
  int token = (blockIdx.x * 256 + threadIdx.x) >> 6;
  int lane = threadIdx.x & 63;
  float4 v4 = *reinterpret_cast<const float4*>(xin + (size_t)token * 256 + lane * 4);
  float s  = v4.x + v4.y + v4.z + v4.w;
  float s2 = v4.x * v4.x + v4.y * v4.y + v4.z * v4.z + v4.w * v4.w;
#pragma unroll
  for (int off = 32; off; off >>= 1) { s += __shfl_xor(s, off); s2 += __shfl_xor(s2, off); }
  float mean = s * (1.f / 256.f);
  float rstd = rsqrtf(s2 * (1.f / 256.f) - mean * mean + eps);
  float4 g4 = *reinterpret_cast<const float4*>(g_ + lane * 4);
  float4 b4 = *reinterpret_cast<const float4*>(b_ + lane * 4);
  float4 o;
  o.x = (v4.x - mean) * rstd * g4.x + b4.x;
  o.y = (v4.y - mean) * rstd * g4.y + b4.y;
  o.z = (v4.z - mean) * rstd * g4.z + b4.z;
  o.w = (v4.w - mean) * rstd * g4.w + b4.w;
  *reinterpret_cast<float4*>(yo + (size_t)token * 256 + lane * 4) = o;
}

// ---------------- token-major LN -> B-frags directly (KC=8)
__global__ void k_ln_frag(const float* __restrict__ xin, const float* __restrict__ g_,
                          const float* __restrict__ b_, ushort* __restrict__ dh,
                          ushort* __restrict__ dl, float eps) {
  int token = (blockIdx.x * 256 + threadIdx.x) >> 6;
  int lane = threadIdx.x & 63;
  float4 v4 = *reinterpret_cast<const float4*>(xin + (size_t)token * 256 + lane * 4);
  float s  = v4.x + v4.y + v4.z + v4.w;
  float s2 = v4.x * v4.x + v4.y * v4.y + v4.z * v4.z + v4.w * v4.w;
#pragma unroll
  for (int off = 32; off; off >>= 1) { s += __shfl_xor(s, off); s2 += __shfl_xor(s2, off); }
  float mean = s * (1.f / 256.f);
  float rstd = rsqrtf(s2 * (1.f / 256.f) - mean * mean + eps);
  float4 g4 = *reinterpret_cast<const float4*>(g_ + lane * 4);
  float4 b4 = *reinterpret_cast<const float4*>(b_ + lane * 4);
  float vals[4];
  vals[0] = (v4.x - mean) * rstd * g4.x + b4.x;
  vals[1] = (v4.y - mean) * rstd * g4.y + b4.y;
  vals[2] = (v4.z - mean) * rstd * g4.z + b4.z;
  vals[3] = (v4.w - mean) * rstd * g4.w + b4.w;
  ushort4 h4, l4;
  split2(vals[0], h4.x, l4.x); split2(vals[1], h4.y, l4.y);
  split2(vals[2], h4.z, l4.z); split2(vals[3], h4.w, l4.w);
  int bg = token >> 10, nt = (token >> 4) & 63, lr = token & 15;
  int kc = lane >> 3, lu_f = (lane >> 1) & 3, j0 = (lane & 1) * 4;
  size_t base = ((((size_t)(bg * 64 + nt)) * 8 + kc) * 64 + lu_f * 16 + lr) * 8 + j0;
  *(ushort4*)(dh + base) = h4;
  *(ushort4*)(dl + base) = l4;
}

// ============ fused mb-attn input preps (Q / K / V^T frags) ============
__global__ void k_prep_mb3(const float* __restrict__ qq_cm, const float* __restrict__ kv_cm,
                           ushort* __restrict__ mQh, ushort* __restrict__ mQl,
                           ushort* __restrict__ mKh, ushort* __restrict__ mKl,
                           ushort* __restrict__ mVh, ushort* __restrict__ mVl) {
  int bid = blockIdx.x, tid = threadIdx.x;
  int sect = bid >> 10, lb = bid & 1023;
  int gtid = lb * 256 + tid;                 // 262144
  int l = gtid & 63; int fr = gtid >> 6;
  int lr = l & 15, lu = l >> 4;
  V16u hi, lo;
  if (sect < 2) {                            // Q (scale) / K (hsplit, frag lr=n)
    int nt = fr & 63; int bgh = fr >> 6;
    int bg = bgh >> 3, hh = bgh & 7;
    const float* src = sect == 0 ? qq_cm : kv_cm;
    int CH = sect == 0 ? 256 : 512;
    float scale = sect == 0 ? 0.17677669529663689f : 1.f;
    const float* sp = src + ((size_t)(bg * CH + hh * 32 + lu * 8)) * 1024 + nt * 16 + lr;
#pragma unroll
    for (int j = 0; j < 8; ++j) split2(sp[(size_t)j * 1024] * scale, hi.u[j], lo.u[j]);
    ushort* dh = sect == 0 ? mQh : mKh;
    ushort* dl = sect == 0 ? mQl : mKl;
    *(int4*)(dh + (size_t)gtid * 8) = hi.i4;
    *(int4*)(dl + (size_t)gtid * 8) = lo.i4;
  } else {                                   // V^T frags: lr=e, lu*8+j=k
    int kc = fr & 31; int et = (fr >> 5) & 1; int bgh = fr >> 6;
    int bg = bgh >> 3, hh = bgh & 7;
    const float* sp = kv_cm + ((size_t)(bg * 512 + 256 + hh * 32 + et * 16 + lr)) * 1024
                      + kc * 32 + lu * 8;
#pragma unroll
    for (int j = 0; j < 8; ++j) split2(sp[j], hi.u[j], lo.u[j]);
    *(int4*)(mVh + (size_t)gtid * 8) = hi.i4;
    *(int4*)(mVl + (size_t)gtid * 8) = lo.i4;
  }
}

// ============ fused main-attn input preps ============
__global__ void k_prep_main3(const float* __restrict__ qb, const float* __restrict__ kb,
                             const float* __restrict__ vb,
                             ushort* __restrict__ aQh, ushort* __restrict__ aQl,
                             ushort* __restrict__ aKh, ushort* __restrict__ aKl,
                             ushort* __restrict__ aVh, ushort* __restrict__ aVl) {
  int bid = blockIdx.x, tid = threadIdx.x;
  int sect = bid >> 10, lb = bid & 1023;
  int gtid = lb * 256 + tid;                 // 262144
  int l = gtid & 63, tile = gtid >> 6;
  int lr = l & 15, lu = l >> 4;
  V16u hi, lo;
  if (sect < 2) {                            // Q / K (frag lr=n, d along lu)
    int dc = tile & 1, nt = (tile >> 1) & 63, bh = tile >> 7;
    int b = bh >> 3, h = bh & 7;
    const float* src = sect == 0 ? qb : kb;
    float scale = sect == 0 ? 0.125f : 1.f;
    const float* sp = src + ((size_t)(b * 512 + h * 64 + dc * 32 + lu * 8)) * 1024
                      + nt * 16 + lr;
#pragma unroll
    for (int j = 0; j < 8; ++j) split2(sp[(size_t)j * 1024] * scale, hi.u[j], lo.u[j]);
    ushort* dh = sect == 0 ? aQh : aKh;
    ushort* dl = sect == 0 ? aQl : aKl;
    *(int4*)(dh + (size_t)gtid * 8) = hi.i4;
    *(int4*)(dl + (size_t)gtid * 8) = lo.i4;
  } else {                                   // V^T frags
    int kc = tile & 31, et = (tile >> 5) & 3, bh = tile >> 7;
    int b = bh >> 3, h = bh & 7;
    const float* sp = vb + ((size_t)(b * 512 + h * 64 + et * 16 + lr)) * 1024 + kc * 32 + lu * 8;
#pragma unroll
    for (int j = 0; j < 8; ++j) split2(sp[j], hi.u[j], lo.u[j]);
    *(int4*)(aVh + (size_t)gtid * 8) = hi.i4;
    *(int4*)(aVl + (size_t)gtid * 8) = lo.i4;
  }
}

// ============ MitBlock attention (MFMA, d=32), epilogue -> B-frags ============
__global__ __launch_bounds__(256)
void k_mbattn_mfma(const ushort* __restrict__ Qh, const ushort* __restrict__ Ql,
                   const ushort* __restrict__ Kh, const ushort* __restrict__ Kl,
                   const ushort* __restrict__ Vh, const ushort* __restrict__ Vl,
                   ushort* __restrict__ ofh, ushort* __restrict__ ofl) {
  int qb = blockIdx.x & 15, bgh = blockIdx.x >> 4;
  int tid = threadIdx.x, w = tid >> 6, l = tid & 63, lr = l & 15, lu = l >> 4;
  int qt = qb * 4 + w;
  bf16x8 qh = ((const bf16x8*)Qh)[(size_t)(bgh * 64 + qt) * 64 + l];
  bf16x8 ql = ((const bf16x8*)Ql)[(size_t)(bgh * 64 + qt) * 64 + l];
  __shared__ ushort Ph[4][16][72];
  __shared__ ushort Pl[4][16][72];
  f32x4 zero = {0.f, 0.f, 0.f, 0.f};
  f32x4 oacc[2] = {zero, zero};
  float den = 0.f;
  for (int kb = 0; kb < 16; ++kb) {
#pragma unroll
    for (int kt4 = 0; kt4 < 4; ++kt4) {
      int kt = kb * 4 + kt4;
      bf16x8 kh = ((const bf16x8*)Kh)[(size_t)(bgh * 64 + kt) * 64 + l];
      bf16x8 kl = ((const bf16x8*)Kl)[(size_t)(bgh * 64 + kt) * 64 + l];
      f32x4 s = zero;
      s = __builtin_amdgcn_mfma_f32_16x16x32_bf16(kh, qh, s, 0, 0, 0);
      s = __builtin_amdgcn_mfma_f32_16x16x32_bf16(kh, ql, s, 0, 0, 0);
      s = __builtin_amdgcn_mfma_f32_16x16x32_bf16(kl, qh, s, 0, 0, 0);
      uint2 uh, ul;
      {
        float p0 = __expf(s[0]), p1 = __expf(s[1]), p2 = __expf(s[2]), p3 = __expf(s[3]);
        den += (p0 + p1) + (p2 + p3);
        ushort h0, l0, h1, l1, h2, l2, h3, l3;
        split2(p0, h0, l0); split2(p1, h1, l1); split2(p2, h2, l2); split2(p3, h3, l3);
        uh.x = (unsigned)h0 | ((unsigned)h1 << 16); uh.y = (unsigned)h2 | ((unsigned)h3 << 16);
        ul.x = (unsigned)l0 | ((unsigned)l1 << 16); ul.y = (unsigned)l2 | ((unsigned)l3 << 16);
      }
      *(uint2*)&Ph[w][lr][kt4 * 16 + lu * 4] = uh;
      *(uint2*)&Pl[w][lr][kt4 * 16 + lu * 4] = ul;
    }
#pragma unroll
    for (int kc2 = 0; kc2 < 2; ++kc2) {
      int kc = kb * 2 + kc2;
      bf16x8 bph = *(const bf16x8*)&Ph[w][lr][kc2 * 32 + lu * 8];
      bf16x8 bpl = *(const bf16x8*)&Pl[w][lr][kc2 * 32 + lu * 8];
#pragma unroll
      for (int et = 0; et < 2; ++et) {
        bf16x8 vh = ((const bf16x8*)Vh)[(size_t)((bgh * 2 + et) * 32 + kc) * 64 + l];
        bf16x8 vl = ((const bf16x8*)Vl)[(size_t)((bgh * 2 + et) * 32 + kc) * 64 + l];
        oacc[et] = __builtin_amdgcn_mfma_f32_16x16x32_bf16(vh, bph, oacc[et], 0, 0, 0);
        oacc[et] = __builtin_amdgcn_mfma_f32_16x16x32_bf16(vh, bpl, oacc[et], 0, 0, 0);
        oacc[et] = __builtin_amdgcn_mfma_f32_16x16x32_bf16(vl, bph, oacc[et], 0, 0, 0);
      }
    }
  }
  den += __shfl_xor(den, 16);
  den += __shfl_xor(den, 32);
  float inv = 1.f / den;
  int bg = bgh >> 3, hh = bgh & 7;
#pragma unroll
  for (int et = 0; et < 2; ++et) {
    ushort4 h4, l4;
    split2(oacc[et][0] * inv, h4.x, l4.x); split2(oacc[et][1] * inv, h4.y, l4.y);
    split2(oacc[et][2] * inv, h4.z, l4.z); split2(oacc[et][3] * inv, h4.w, l4.w);
    int lu_f = et * 2 + (lu >> 1), j0 = (lu & 1) * 4;
    size_t base = ((((size_t)(bg * 64 + qt)) * 8 + hh) * 64 + lu_f * 16 + lr) * 8 + j0;
    *(ushort4*)(ofh + base) = h4;
    *(ushort4*)(ofl + base) = l4;
  }
}

// ============ main attention (MFMA, d=64), epilogue -> B-frags (KC=16) ========
__global__ __launch_bounds__(256)
void k_mainattn_mfma(const ushort* __restrict__ Qh, const ushort* __restrict__ Ql,
                     const ushort* __restrict__ Kh, const ushort* __restrict__ Kl,
                     const ushort* __restrict__ Vh, const ushort* __restrict__ Vl,
                     ushort* __restrict__ anfh, ushort* __restrict__ anfl) {
  int qb = blockIdx.x & 15, bh = blockIdx.x >> 4;
  int tid = threadIdx.x, w = tid >> 6, l = tid & 63, lr = l & 15, lu = l >> 4;
  int qt = qb * 4 + w;
  bf16x8 qh[2], ql[2];
#pragma unroll
  for (int dc = 0; dc < 2; ++dc) {
    qh[dc] = ((const bf16x8*)Qh)[(size_t)((bh * 64 + qt) * 2 + dc) * 64 + l];
    ql[dc] = ((const bf16x8*)Ql)[(size_t)((bh * 64 + qt) * 2 + dc) * 64 + l];
  }
  __shared__ ushort Ph[4][16][72];
  __shared__ ushort Pl[4][16][72];
  f32x4 zero = {0.f, 0.f, 0.f, 0.f};
  f32x4 oacc[4] = {zero, zero, zero, zero};
  float den = 0.f;
  for (int kb = 0; kb < 16; ++kb) {
#pragma unroll
    for (int kt4 = 0; kt4 < 4; ++kt4) {
      int kt = kb * 4 + kt4;
      f32x4 s = zero;
#pragma unroll
      for (int dc = 0; dc < 2; ++dc) {
        bf16x8 kh = ((const bf16x8*)Kh)[(size_t)((bh * 64 + kt) * 2 + dc) * 64 + l];
        bf16x8 kl = ((const bf16x8*)Kl)[(size_t)((bh * 64 + kt) * 2 + dc) * 64 + l];
        s = __builtin_amdgcn_mfma_f32_16x16x32_bf16(kh, qh[dc], s, 0, 0, 0);
        s = __builtin_amdgcn_mfma_f32_16x16x32_bf16(kh, ql[dc], s, 0, 0, 0);
        s = __builtin_amdgcn_mfma_f32_16x16x32_bf16(kl, qh[dc], s, 0, 0, 0);
      }
      uint2 uh, ul;
      {
        float p0 = __expf(s[0]), p1 = __expf(s[1]), p2 = __expf(s[2]), p3 = __expf(s[3]);
        den += (p0 + p1) + (p2 + p3);
        ushort h0, l0, h1, l1, h2, l2, h3, l3;
        split2(p0, h0, l0); split2(p1, h1, l1); split2(p2, h2, l2); split2(p3, h3, l3);
        uh.x = (unsigned)h0 | ((unsigned)h1 << 16); uh.y = (unsigned)h2 | ((unsigned)h3 << 16);
        ul.x = (unsigned)l0 | ((unsigned)l1 << 16); ul.y = (unsigned)l2 | ((unsigned)l3 << 16);
      }
      *(uint2*)&Ph[w][lr][kt4 * 16 + lu * 4] = uh;
      *(uint2*)&Pl[w][lr][kt4 * 16 + lu * 4] = ul;
    }
#pragma unroll
    for (int kc2 = 0; kc2 < 2; ++kc2) {
      int kc = kb * 2 + kc2;
      bf16x8 bph = *(const bf16x8*)&Ph[w][lr][kc2 * 32 + lu * 8];
      bf16x8 bpl = *(const bf16x8*)&Pl[w][lr][kc2 * 32 + lu * 8];
#pragma unroll
      for (int et = 0; et < 4; ++et) {
        bf16x8 vh = ((const bf16x8*)Vh)[(size_t)((bh * 4 + et) * 32 + kc) * 64 + l];
        bf16x8 vl = ((const bf16x8*)Vl)[(size_t)((bh * 4 + et) * 32 + kc) * 64 + l];
        oacc[et] = __builtin_amdgcn_mfma_f32_16x16x32_bf16(vh, bph, oacc[et], 0, 0, 0);
        oacc[et] = __builtin_amdgcn_mfma_f32_16x16x32_bf16(vh, bpl, oacc[et], 0, 0, 0);
        oacc[et] = __builtin_amdgcn_mfma_f32_16x16x32_bf16(vl, bph, oacc[et], 0, 0, 0);
      }
    }
  }
  den += __shfl_xor(den, 16);
  den += __shfl_xor(den, 32);
  float inv = 1.f / den;
  int b = bh >> 3, h = bh & 7;
#pragma unroll
  for (int et = 0; et < 4; ++et) {
    ushort4 h4, l4;
    split2(oacc[et][0] * inv, h4.x, l4.x); split2(oacc[et][1] * inv, h4.y, l4.y);
    split2(oacc[et][2] * inv, h4.z, l4.z); split2(oacc[et][3] * inv, h4.w, l4.w);
    int kc = h * 2 + (et >> 1);
    int lu_f = (et & 1) * 2 + (lu >> 1), j0 = (lu & 1) * 4;
    size_t base = ((((size_t)(b * 64 + qt)) * 16 + kc) * 64 + lu_f * 16 + lr) * 8 + j0;
    *(ushort4*)(anfh + base) = h4;
    *(ushort4*)(anfl + base) = l4;
  }
}

// ---------------- depthwise 3x3 + bias + exact GELU (cm)
__global__ void k_dw3(const float* __restrict__ X, const float* __restrict__ w,
                      const float* __restrict__ bias, float* __restrict__ Y) {
  int idx = blockIdx.x * 256 + threadIdx.x;
  int x = idx & 31, y = (idx >> 5) & 31, ch = (idx >> 10) & 1023, bg = idx >> 20;
  const float* src = X + (size_t)((bg << 10) + ch) * HW;
  const float* wr = w + ch * 9;
  float acc = bias[ch];
#pragma unroll
  for (int ky = 0; ky < 3; ++ky) {
    int yy = y + ky - 1;
    if ((unsigned)yy < 32u) {
      const float* row = src + yy * 32;
#pragma unroll
      for (int kx = 0; kx < 3; ++kx) {
        int xx = x + kx - 1;
        if ((unsigned)xx < 32u) acc += row[xx] * wr[ky * 3 + kx];
      }
    }
  }
  Y[(size_t)((bg << 10) + ch) * HW + y * 32 + x] = gelu_exact(acc);
}

// ---------------- depthwise 9x9 pad 4 on nc layout, wt9 = transposed weights
__global__ void k_dw9_nc(const float* __restrict__ Xnc, const float* __restrict__ wt9,
                         const float* __restrict__ bias, float* __restrict__ Ync) {
  int bid = blockIdx.x;               // 1024 = bg(8) x ptile(128), 8 px per block
  int pt = bid & 127; int bg = bid >> 7;
  int tid = threadIdx.x;              // = channel
  int y = pt >> 2, x0 = (pt & 3) * 8;
  float acc[8];
  float bs = bias[tid];
#pragma unroll
  for (int p = 0; p < 8; ++p) acc[p] = bs;
  const float* src = Xnc + (size_t)(bg << 10) * 256;
  for (int ky = 0; ky < 9; ++ky) {
    int yy = y + ky - 4;
    if ((unsigned)yy >= 32u) continue;
#pragma unroll
    for (int kx = 0; kx < 9; ++kx) {
      float wv = wt9[(ky * 9 + kx) * 256 + tid];
#pragma unroll
      for (int p = 0; p < 8; ++p) {
        int xx = x0 + p + kx - 4;
        if ((unsigned)xx < 32u)
          acc[p] += src[(size_t)(yy * 32 + xx) * 256 + tid] * wv;
      }
    }
  }
#pragma unroll
  for (int p = 0; p < 8; ++p)
    Ync[((size_t)((bg << 10) + y * 32 + x0 + p)) * 256 + tid] = acc[p];
}

// ---------------- co tail on nc layout: wave per token
__global__ void k_cotail_nc(const float* __restrict__ Xnc, const float* __restrict__ lnw,
                            const float* __restrict__ lnb, const float* __restrict__ w2,
                            float* __restrict__ pos) {
  int token = (blockIdx.x * 256 + threadIdx.x) >> 6;   // 8192
  int lane = threadIdx.x & 63;
  float4 v4 = *(const float4*)(Xnc + (size_t)token * 256 + lane * 4);
  float s = v4.x + v4.y + v4.z + v4.w;
  float s2 = v4.x * v4.x + v4.y * v4.y + v4.z * v4.z + v4.w * v4.w;
#pragma unroll
  for (int off = 32; off; off >>= 1) { s += __shfl_xor(s, off); s2 += __shfl_xor(s2, off); }
  float mean = s * (1.f / 256.f);
  float rstd = rsqrtf(s2 * (1.f / 256.f) - mean * mean + 1e-5f);
  float4 g4 = *(const float4*)(lnw + lane * 4);
  float4 b4 = *(const float4*)(lnb + lane * 4);
  float4 wa = *(const float4*)(w2 + lane * 4);
  float4 wb = *(const float4*)(w2 + 256 + lane * 4);
  float ge0 = gelu_exact((v4.x - mean) * rstd * g4.x + b4.x);
  float ge1 = gelu_exact((v4.y - mean) * rstd * g4.y + b4.y);
  float ge2 = gelu_exact((v4.z - mean) * rstd * g4.z + b4.z);
  float ge3 = gelu_exact((v4.w - mean) * rstd * g4.w + b4.w);
  float o0 = ge0 * wa.x + ge1 * wa.y + ge2 * wa.z + ge3 * wa.w;
  float o1 = ge0 * wb.x + ge1 * wb.y + ge2 * wb.z + ge3 * wb.w;
#pragma unroll
  for (int off = 32; off; off >>= 1) { o0 += __shfl_xor(o0, off); o1 += __shfl_xor(o1, off); }
  if (lane == 0) {
    float offy = tanhf(o0) * (2.f / 32.f);
    float offx = tanhf(o1) * (2.f / 32.f);
    int n = token & 1023;
    int ky = n >> 5, kx = n & 31;
    float refy = ((ky + 0.5f) * (1.f / 32.f)) * 2.f - 1.f;
    float refx = ((kx + 0.5f) * (1.f / 32.f)) * 2.f - 1.f;
    pos[token * 2] = offx + refx;
    pos[token * 2 + 1] = offy + refy;
  }
}

// ---------------- bilinear grid sample on nc layout -> sampled_nc
__global__ void k_gsample_nc(const float* __restrict__ Xnc, const float* __restrict__ pos,
                             float* __restrict__ out_nc) {
  int bid = blockIdx.x;            // bg(8) x nch(16)
  int nch = bid & 15; int bg = bid >> 4;
  int tid = threadIdx.x;           // = channel c
  __shared__ int sI[4][64];
  __shared__ float sW[4][64];
  if (tid < 64) {
    int j = nch * 64 + tid;
    float gx = pos[((bg << 10) + j) * 2];
    float gy = pos[((bg << 10) + j) * 2 + 1];
    float fx = (gx + 1.f) * 0.5f * 31.f;
    float fy = (gy + 1.f) * 0.5f * 31.f;
    float x0f = floorf(fx), y0f = floorf(fy);
    int x0 = (int)x0f, y0 = (int)y0f;
    float wx1 = fx - x0f, wx0 = 1.f - wx1;
    float wy1 = fy - y0f, wy0 = 1.f - wy1;
    bool vx0 = (x0 >= 0) & (x0 <= 31);
    bool vx1 = (x0 + 1 >= 0) & (x0 + 1 <= 31);
    bool vy0 = (y0 >= 0) & (y0 <= 31);
    bool vy1 = (y0 + 1 >= 0) & (y0 + 1 <= 31);
    int cx0 = min(max(x0, 0), 31), cx1 = min(max(x0 + 1, 0), 31);
    int cy0 = min(max(y0, 0), 31), cy1 = min(max(y0 + 1, 0), 31);
    sW[0][tid] = wx0 * wy0 * ((vx0 && vy0) ? 1.f : 0.f);
    sW[1][tid] = wx1 * wy0 * ((vx1 && vy0) ? 1.f : 0.f);
    sW[2][tid] = wx0 * wy1 * ((vx0 && vy1) ? 1.f : 0.f);
    sW[3][tid] = wx1 * wy1 * ((vx1 && vy1) ? 1.f : 0.f);
    sI[0][tid] = cy0 * 32 + cx0; sI[1][tid] = cy0 * 32 + cx1;
    sI[2][tid] = cy1 * 32 + cx0; sI[3][tid] = cy1 * 32 + cx1;
  }
  __syncthreads();
  const float* src = Xnc + (size_t)(bg << 10) * 256;
  for (int n = 0; n < 64; ++n) {
    float acc = src[(size_t)sI[0][n] * 256 + tid] * sW[0][n]
              + src[(size_t)sI[1][n] * 256 + tid] * sW[1][n]
              + src[(size_t)sI[2][n] * 256 + tid] * sW[2][n]
              + src[(size_t)sI[3][n] * 256 + tid] * sW[3][n];
    out_nc[((size_t)((bg << 10) + nch * 64 + n)) * 256 + tid] = acc;
  }
}

// ---------------------------------------------------------------------------
extern "C" void kernel_launch(void* const* d_in, const int* in_sizes, int n_in,
                              void* d_out, int out_size, void* d_ws, size_t ws_size,
                              hipStream_t stream) {
  const float* tgt    = (const float*)d_in[0];
  const float* refp   = (const float*)d_in[1];
  const float* emb_w  = (const float*)d_in[2];
  const float* emb_b  = (const float*)d_in[3];
  const float* q_w    = (const float*)d_in[4];
  const float* q_b    = (const float*)d_in[5];
  const float* k_w    = (const float*)d_in[6];
  const float* k_b    = (const float*)d_in[7];
  const float* v_w    = (const float*)d_in[8];
  const float* v_b    = (const float*)d_in[9];
  const float* out_w  = (const float*)d_in[10];
  const float* out_b  = (const float*)d_in[11];
  const float* ln1_w  = (const float*)d_in[12];
  const float* ln1_b  = (const float*)d_in[13];
  const float* n1_w   = (const float*)d_in[14];
  const float* n1_b   = (const float*)d_in[15];
  const float* mbq_w  = (const float*)d_in[16];
  const float* mbq_b  = (const float*)d_in[17];
  const float* mbkv_w = (const float*)d_in[18];
  const float* mbkv_b = (const float*)d_in[19];
  const float* mbp_w  = (const float*)d_in[20];
  const float* mbp_b  = (const float*)d_in[21];
  const float* n2_w   = (const float*)d_in[22];
  const float* n2_b   = (const float*)d_in[23];
  const float* fc1_w  = (const float*)d_in[24];
  const float* fc1_b  = (const float*)d_in[25];
  const float* dw3_w  = (const float*)d_in[26];
  const float* dw3_b  = (const float*)d_in[27];
  const float* fc2_w  = (const float*)d_in[28];
  const float* fc2_b  = (const float*)d_in[29];
  const float* dw9_w  = (const float*)d_in[30];
  const float* dw9_b  = (const float*)d_in[31];
  const float* coln_w = (const float*)d_in[32];
  const float* coln_b = (const float*)d_in[33];
  const float* coout_w= (const float*)d_in[34];

  float* ws = (float*)d_ws;
  // slabs (float offsets)
  float* slabA = ws + 0;          // offin_nc -> sampled_nc
  float* qbuf  = ws + 2097152;    // q proj out (persists to step 16)
  float* xbuf  = ws + 4194304;    // x tm residual (overlaps XtH until ln1)
  float* slabD = ws + 6291456;    // P_cm -> ygemm -> kbuf
  float* slabE = ws + 8388608;    // qq_cm -> offdw_nc -> vbuf
  float* slabF = ws + 10485760;   // tgtf -> kv_cm -> ofrags -> h2frags -> mifrags -> sfrags
  float* slabG = ws + 14680064;   // WtEmb -> hfrags -> mbfrags -> m_cm -> mainfrags
  float* slabH = ws + 23068672;   // part(4) -> mi_cm -> attn-out frags
  float* featnc= ws + 31457280;   // feat_nc (persists to step 14)
  float* posb  = ws + 35389440;   // [8,1024,2]
  float* wt9   = ws + 35405824;   // [81][256] transposed dw9 weights

  // emb prep
  ushort* XtH = (ushort*)(ws + 4194304);
  ushort* XtL = XtH + 4734976;
  ushort* WtEH = (ushort*)slabG;
  ushort* WtEL = WtEH + 4718592;
  float* part = slabH;                         // 4 x 2097152
  ushort* tgtfh = (ushort*)slabF;              // tgt B-frags
  ushort* tgtfl = tgtfh + 2097152;

  // weight frags (long-lived, slab J)
  ushort* J = (ushort*)(ws + 33554432);
  ushort* wfq_h = J;                ushort* wfq_l = J + 262144;
  ushort* wfk_h = J + 524288;       ushort* wfk_l = J + 786432;
  ushort* wfv_h = J + 1048576;      ushort* wfv_l = J + 1310720;
  ushort* wfo_h = J + 1572864;      ushort* wfo_l = J + 1835008;
  ushort* wfmq_h = J + 2097152;     ushort* wfmq_l = J + 2162688;
  ushort* wfmkv_h = J + 2228224;    ushort* wfmkv_l = J + 2359296;
  ushort* wfmp_h = J + 2490368;     ushort* wfmp_l = J + 2555904;
  ushort* wff1_h = J + 2621440;     ushort* wff1_l = J + 2883584;
  ushort* wff2_h = J + 3145728;     ushort* wff2_l = J + 3407872;

  // phase pointers
  ushort* hfh = (ushort*)slabG;     ushort* hfl = hfh + 2097152;  // n1 frags
  float* qq_cm  = slabE;
  float* kv_cm  = slabF;
  ushort* mQh = (ushort*)slabG;     ushort* mQl = mQh + 2097152;
  ushort* mKh = mQh + 4194304;      ushort* mKl = mQh + 6291456;
  ushort* mVh = mQh + 8388608;      ushort* mVl = mQh + 10485760;
  ushort* ofh = (ushort*)slabF;     ushort* ofl = ofh + 2097152;  // mb-attn out frags
  float* P_cm = slabD;
  ushort* h2fh = (ushort*)slabF;    ushort* h2fl = h2fh + 2097152;
  float* m_cm = slabG;
  float* mi_cm = slabH;
  ushort* mifh = (ushort*)slabF;    ushort* mifl = mifh + 4194304;
  float* ygemm = slabD;
  float* offin = slabA;
  float* offdwnc = slabE;
  float* samplednc = slabA;
  ushort* sfh = (ushort*)slabF;     ushort* sfl = sfh + 2097152;
  float* kbuf = slabD;
  float* vbuf = slabE;
  ushort* aQh = (ushort*)slabG;     ushort* aQl = aQh + 2097152;
  ushort* aKh = aQh + 4194304;      ushort* aKl = aQh + 6291456;
  ushort* aVh = aQh + 8388608;      ushort* aVl = aQh + 10485760;
  ushort* anfh = (ushort*)slabH;    ushort* anfl = anfh + 2097152;

  // --- step 0: preps ---
  k_prepw<<<2048, 256, 0, stream>>>(emb_w, WtEH, WtEL);
  k_prepx<<<2312, 256, 0, stream>>>(tgt, refp, XtH, XtL);
  k_prep_wfrag9<<<977, 256, 0, stream>>>(q_w, k_w, v_w, out_w, mbq_w, mbkv_w, mbp_w,
                                         fc1_w, fc2_w, dw9_w,
                                         wfq_h, wfq_l, wfk_h, wfk_l, wfv_h, wfv_l,
                                         wfo_h, wfo_l, wfmq_h, wfmq_l, wfmkv_h, wfmkv_l,
                                         wfmp_h, wfmp_l, wff1_h, wff1_l, wff2_h, wff2_l,
                                         wt9);
  k_prep_cm2frag<<<1024, 256, 0, stream>>>(tgt, 512, 16, tgtfh, tgtfl);
  // --- step 1: emb conv (4-way K-split, XCD swizzle) ---
  k_emb_mfma<<<1024, 256, 0, stream>>>(XtH, XtL, WtEH, WtEL, part);
  k_embmerge_nc<<<512, 256, 0, stream>>>(part, emb_b, featnc);
  // --- step 2: q proj ---
  k_gemm_mfma<<<512, 256, 0, stream>>>(wfq_h, wfq_l, tgtfh, tgtfl, q_b, qbuf, 16, 8, 512);
  // --- step 3: ln1 -> x (tm residual) ---
  k_ln_tok<<<2048, 256, 0, stream>>>(featnc, ln1_w, ln1_b, xbuf, 1e-5f);
  // --- step 4: n1 -> h frags directly ---
  k_ln_frag<<<2048, 256, 0, stream>>>(xbuf, n1_w, n1_b, hfh, hfl, 1e-6f);
  // --- step 5: mbq/mbkv GEMMs -> cm ---
  k_gemm_mfma<<<512, 256, 0, stream>>>(wfmq_h, wfmq_l, hfh, hfl, mbq_b, qq_cm, 8, 4, 256);
  k_gemm_mfma<<<1024, 256, 0, stream>>>(wfmkv_h, wfmkv_l, hfh, hfl, mbkv_b, kv_cm, 8, 8, 512);
  // --- step 6: mb attention (fused prep; epilogue writes o frags) ---
  k_prep_mb3<<<3072, 256, 0, stream>>>(qq_cm, kv_cm, mQh, mQl, mKh, mKl, mVh, mVl);
  k_mbattn_mfma<<<1024, 256, 0, stream>>>(mQh, mQl, mKh, mKl, mVh, mVl, ofh, ofl);
  // --- step 7: mbproj + residual ---
  k_gemm_mfma<<<512, 256, 0, stream>>>(wfmp_h, wfmp_l, ofh, ofl, mbp_b, P_cm, 8, 4, 256);
  k_transadd_tm<<<512, 256, 0, stream>>>(P_cm, xbuf);
  // --- step 8: n2 -> h2 frags directly ---
  k_ln_frag<<<2048, 256, 0, stream>>>(xbuf, n2_w, n2_b, h2fh, h2fl, 1e-6f);
  // --- step 9: fc1 ---
  k_gemm_mfma<<<2048, 256, 0, stream>>>(wff1_h, wff1_l, h2fh, h2fl, fc1_b, m_cm, 8, 16, 1024);
  // --- step 10: dw3 + gelu; mi frags ---
  k_dw3<<<32768, 256, 0, stream>>>(m_cm, dw3_w, dw3_b, mi_cm);
  k_prep_cm2frag<<<4096, 256, 0, stream>>>(mi_cm, 1024, 32, mifh, mifl);
  // --- step 11: fc2 + residual -> offin nc ---
  k_gemm_mfma<<<512, 256, 0, stream>>>(wff2_h, wff2_l, mifh, mifl, fc2_b, ygemm, 32, 4, 256);
  k_transadd_nc<<<512, 256, 0, stream>>>(ygemm, xbuf, offin);
  // --- step 12: dw9 on nc ---
  k_dw9_nc<<<1024, 256, 0, stream>>>(offin, wt9, dw9_b, offdwnc);
  // --- step 13: cotail ---
  k_cotail_nc<<<2048, 256, 0, stream>>>(offdwnc, coln_w, coln_b, coout_w, posb);
  // --- step 14: grid sample + frags ---
  k_gsample_nc<<<128, 256, 0, stream>>>(featnc, posb, samplednc);
  k_prep_s2frag<<<1024, 256, 0, stream>>>(samplednc, sfh, sfl);
  // --- step 15: k/v proj ---
  k_gemm_mfma<<<512, 256, 0, stream>>>(wfk_h, wfk_l, sfh, sfl, k_b, kbuf, 16, 8, 512);
  k_gemm_mfma<<<512, 256, 0, stream>>>(wfv_h, wfv_l, sfh, sfl, v_b, vbuf, 16, 8, 512);
  // --- step 16: main attention (fused prep; epilogue writes out-frags) ---
  k_prep_main3<<<3072, 256, 0, stream>>>(qbuf, kbuf, vbuf, aQh, aQl, aKh, aKl, aVh, aVl);
  k_mainattn_mfma<<<512, 256, 0, stream>>>(aQh, aQl, aKh, aKl, aVh, aVl, anfh, anfl);
  // --- step 17: out proj -> d_out ---
  k_gemm_mfma<<<512, 256, 0, stream>>>(wfo_h, wfo_l, anfh, anfl, out_b, (float*)d_out, 16, 8, 512);
}

// Round 8
// 619.204 us; speedup vs baseline: 4.9327x; 1.1575x over previous
//
#include <hip/hip_runtime.h>
#include <math.h>

// ---------------------------------------------------------------------------
// DAttention forward. R8: fix mif frag aliasing (race across replays).
// mifh/mifl moved to slabG (8M floats, exact fit); no other changes vs R7.
// Dims: B=4, C=512, H=W=32, G=2, gc=256, BG=8, heads=8, hc=64, mh=8, mhd=32.
// ---------------------------------------------------------------------------

static constexpr int HW = 1024;

typedef __attribute__((ext_vector_type(8))) short bf16x8;
typedef __attribute__((ext_vector_type(4))) float f32x4;

union V16u { int4 i4; ushort u[8]; };

__device__ __forceinline__ float gelu_exact(float v) {
  return 0.5f * v * (1.0f + erff(v * 0.7071067811865475f));
}

__device__ __forceinline__ ushort bf16_rne(float v) {
  unsigned int b = __float_as_uint(v);
  return (ushort)((b + 0x7fffu + ((b >> 16) & 1u)) >> 16);
}

__device__ __forceinline__ void split2(float v, ushort& h, ushort& l) {
  h = bf16_rne(v);
  l = bf16_rne(v - __uint_as_float(((unsigned int)h) << 16));
}

// ---------------- emb prep: weights [512][1024][3][3] -> [9][512][1024] bf16 hi/lo
__global__ void k_prepw(const float* __restrict__ w, ushort* __restrict__ Wt_hi,
                        ushort* __restrict__ Wt_lo) {
  int idx = blockIdx.x * 256 + threadIdx.x;    // 524288
  int o = idx >> 10, ci = idx & 1023;
  const float* src = w + (size_t)idx * 9;
#pragma unroll
  for (int t = 0; t < 9; ++t) {
    ushort h, l; split2(src[t], h, l);
    size_t oo = ((size_t)(t * 512 + o)) * 1024 + ci;
    Wt_hi[oo] = h; Wt_lo[oo] = l;
  }
}

// ---------------- emb prep: inputs -> [4][34][34][1024] bf16 hi/lo (padded)
__global__ void k_prepx(const float* __restrict__ tgt, const float* __restrict__ refp,
                        ushort* __restrict__ Xt_hi, ushort* __restrict__ Xt_lo) {
  int idx = blockIdx.x * 256 + threadIdx.x;    // 591872
  int xp = idx % 34; int r = idx / 34;
  int g8 = r & 127; r >>= 7;
  int yp = r % 34; int b = r / 34;
  int y = yp - 1, x = xp - 1;
  bool valid = (unsigned)y < 32u && (unsigned)x < 32u;
  V16u hi, lo;
  const float* in = (g8 < 64) ? (tgt + ((size_t)(b * 512 + g8 * 8)) * HW)
                              : (refp + ((size_t)(b * 512 + (g8 - 64) * 8)) * HW);
#pragma unroll
  for (int j = 0; j < 8; ++j) {
    float v = valid ? in[(size_t)j * HW + y * 32 + x] : 0.f;
    split2(v, hi.u[j], lo.u[j]);
  }
  size_t oo = (((size_t)(b * 34 + yp)) * 34 + xp) * 1024 + g8 * 8;
  *(int4*)(Xt_hi + oo) = hi.i4;
  *(int4*)(Xt_lo + oo) = lo.i4;
}

// ---------------- emb conv via MFMA, split-bf16, 4-way K-split, 4 rows/wave
__global__ __launch_bounds__(256, 2)
void k_emb_mfma(const ushort* __restrict__ Xt_hi, const ushort* __restrict__ Xt_lo,
                const ushort* __restrict__ Wt_hi, const ushort* __restrict__ Wt_lo,
                float* __restrict__ part) {
  int wgid = (blockIdx.x & 7) * 64 + (blockIdx.x >> 3);
  int yt = wgid & 7;  wgid >>= 3;
  int b  = wgid & 3;  wgid >>= 2;
  int mt = wgid & 3;  wgid >>= 2;
  int ks = wgid;                       // [0,4)
  int tid = threadIdx.x;
  int w = tid >> 6, l = tid & 63;
  int lr = l & 15, lu = l >> 4;
  int y0 = yt * 4;
  int obase = mt * 128 + w * 32;

  // halo: padded rows y0..y0+5, 6*34 = 204 px, 816 int4 entries per buffer
  __shared__ int4 LsH[2][816];
  __shared__ int4 LsL[2][816];

  int4 gh[4], gl[4];
  int kc0 = ks * 8;

  auto loadstage = [&](int kcg) {
#pragma unroll
    for (int i = 0; i < 4; ++i) {
      int s = tid + 256 * i;
      if (s < 816) {
        int px = s >> 2;               // [0,204) all valid
        int u = (s & 3) ^ ((px >> 1) & 3);
        size_t off = ((size_t)(b * 34 + y0) * 34 + px) * 1024 + kcg * 32 + u * 8;
        gh[i] = *(const int4*)(Xt_hi + off);
        gl[i] = *(const int4*)(Xt_lo + off);
      }
    }
  };
  auto writestage = [&](int buf) {
#pragma unroll
    for (int i = 0; i < 4; ++i) {
      int s = tid + 256 * i;
      if (s < 816) { LsH[buf][s] = gh[i]; LsL[buf][s] = gl[i]; }
    }
  };

  f32x4 zero = {0.f, 0.f, 0.f, 0.f};
  f32x4 acc[2][8];
#pragma unroll
  for (int a = 0; a < 2; ++a)
#pragma unroll
    for (int n = 0; n < 8; ++n) acc[a][n] = zero;

  loadstage(kc0);
  writestage(0);

  for (int kc = 0; kc < 8; ++kc) {
    int buf = kc & 1;
    __syncthreads();
    if (kc < 7) loadstage(kc0 + kc + 1);
    int kcg = kc0 + kc;
    const bf16x8* BH = (const bf16x8*)&LsH[buf][0];
    const bf16x8* BL = (const bf16x8*)&LsL[buf][0];
#pragma unroll
    for (int kx = 0; kx < 3; ++kx) {
      bf16x8 bh[12], bl[12];
#pragma unroll
      for (int f = 0; f < 12; ++f) {
        int px = (f >> 1) * 34 + (f & 1) * 16 + kx + lr;
        int idx = px * 4 + (lu ^ ((px >> 1) & 3));
        bh[f] = BH[idx]; bl[f] = BL[idx];
      }
#pragma unroll
      for (int ky = 0; ky < 3; ++ky) {
        int tap = ky * 3 + kx;
        size_t wo = (((size_t)(tap * 512 + obase + lr)) * 1024) + kcg * 32 + lu * 8;
        bf16x8 ah0 = *(const bf16x8*)(Wt_hi + wo);
        bf16x8 al0 = *(const bf16x8*)(Wt_lo + wo);
        bf16x8 ah1 = *(const bf16x8*)(Wt_hi + wo + 16 * 1024);
        bf16x8 al1 = *(const bf16x8*)(Wt_lo + wo + 16 * 1024);
#pragma unroll
        for (int yr = 0; yr < 4; ++yr)
#pragma unroll
          for (int h = 0; h < 2; ++h) {
            int f = (yr + ky) * 2 + h;
            int nf = yr * 2 + h;
            acc[0][nf] = __builtin_amdgcn_mfma_f32_16x16x32_bf16(ah0, bh[f], acc[0][nf], 0, 0, 0);
            acc[0][nf] = __builtin_amdgcn_mfma_f32_16x16x32_bf16(ah0, bl[f], acc[0][nf], 0, 0, 0);
            acc[0][nf] = __builtin_amdgcn_mfma_f32_16x16x32_bf16(al0, bh[f], acc[0][nf], 0, 0, 0);
            acc[1][nf] = __builtin_amdgcn_mfma_f32_16x16x32_bf16(ah1, bh[f], acc[1][nf], 0, 0, 0);
            acc[1][nf] = __builtin_amdgcn_mfma_f32_16x16x32_bf16(ah1, bl[f], acc[1][nf], 0, 0, 0);
            acc[1][nf] = __builtin_amdgcn_mfma_f32_16x16x32_bf16(al1, bh[f], acc[1][nf], 0, 0, 0);
          }
      }
    }
    if (kc < 7) writestage(buf ^ 1);
  }

  float* pb = part + (size_t)ks * 2097152;
#pragma unroll
  for (int a = 0; a < 2; ++a)
#pragma unroll
    for (int yr = 0; yr < 4; ++yr)
#pragma unroll
      for (int h = 0; h < 2; ++h) {
        f32x4 c = acc[a][yr * 2 + h];
        size_t base = ((size_t)(b * 512 + obase + a * 16 + lu * 4)) * 1024
                      + (y0 + yr) * 32 + h * 16 + lr;
#pragma unroll
        for (int r = 0; r < 4; ++r) pb[base + (size_t)r * 1024] = c[r];
      }
}

// ---------------- emb merge: sum 4 parts + bias, write feat_nc (transposing)
__global__ void k_embmerge_nc(const float* __restrict__ part, const float* __restrict__ bias,
                              float* __restrict__ featnc) {
  __shared__ float T[64][65];
  int bid = blockIdx.x;                 // 512 = bg(8) x c-tile(4) x n-tile(16)
  int n0 = (bid & 15) << 6; bid >>= 4;
  int c0 = (bid & 3) << 6; int bg = bid >> 2;
  int cl = threadIdx.x & 63, rw = threadIdx.x >> 6;
#pragma unroll
  for (int i = 0; i < 16; ++i) {
    int crow = i * 4 + rw;
    size_t idx = ((size_t)(bg * 256 + c0 + crow)) * 1024 + n0 + cl;
    float v = part[idx] + part[2097152 + idx] + part[4194304 + idx] + part[6291456 + idx];
    T[crow][cl] = v + bias[(bg & 1) * 256 + c0 + crow];
  }
  __syncthreads();
#pragma unroll
  for (int i = 0; i < 16; ++i) {
    int nrow = i * 4 + rw;
    featnc[((size_t)(bg * 1024 + n0 + nrow)) * 256 + c0 + cl] = T[cl][nrow];
  }
}

// ============ fused static preps: 9 weight frag sets + dw9 weight transpose ====
__device__ __forceinline__ void wfrag_body(const float* __restrict__ W, int K, int KC,
                                           ushort* __restrict__ dh, ushort* __restrict__ dl,
                                           int gtid) {
  int l = gtid & 63; int fr = gtid >> 6;
  int kc = fr % KC; int ot = fr / KC;
  int lr = l & 15, lu = l >> 4;
  const float* sp = W + (size_t)(ot * 16 + lr) * K + kc * 32 + lu * 8;
  V16u hi, lo;
#pragma unroll
  for (int j = 0; j < 8; ++j) split2(sp[j], hi.u[j], lo.u[j]);
  *(int4*)(dh + (size_t)gtid * 8) = hi.i4;
  *(int4*)(dl + (size_t)gtid * 8) = lo.i4;
}

__global__ void k_prep_wfrag9(
    const float* q_w, const float* k_w, const float* v_w, const float* o_w,
    const float* mq_w, const float* mkv_w, const float* mp_w,
    const float* f1_w, const float* f2_w, const float* dw9_w,
    ushort* qh, ushort* ql, ushort* kh, ushort* kl, ushort* vh, ushort* vl,
    ushort* oh, ushort* ol, ushort* mqh, ushort* mql, ushort* mkvh, ushort* mkvl,
    ushort* mph, ushort* mpl, ushort* f1h, ushort* f1l, ushort* f2h, ushort* f2l,
    float* wt9) {
  int bid = blockIdx.x, tid = threadIdx.x;
  if (bid < 128)      wfrag_body(q_w, 512, 16, qh, ql, bid * 256 + tid);
  else if (bid < 256) wfrag_body(k_w, 512, 16, kh, kl, (bid - 128) * 256 + tid);
  else if (bid < 384) wfrag_body(v_w, 512, 16, vh, vl, (bid - 256) * 256 + tid);
  else if (bid < 512) wfrag_body(o_w, 512, 16, oh, ol, (bid - 384) * 256 + tid);
  else if (bid < 544) wfrag_body(mq_w, 256, 8, mqh, mql, (bid - 512) * 256 + tid);
  else if (bid < 608) wfrag_body(mkv_w, 256, 8, mkvh, mkvl, (bid - 544) * 256 + tid);
  else if (bid < 640) wfrag_body(mp_w, 256, 8, mph, mpl, (bid - 608) * 256 + tid);
  else if (bid < 768) wfrag_body(f1_w, 256, 8, f1h, f1l, (bid - 640) * 256 + tid);
  else if (bid < 896) wfrag_body(f2_w, 1024, 32, f2h, f2l, (bid - 768) * 256 + tid);
  else {
    int idx = (bid - 896) * 256 + tid;  // 81*256 = 20736
    int t = idx >> 8, c = idx & 255;
    wt9[idx] = dw9_w[c * 81 + t];
  }
}

// cm activations [b][CH][1024] -> B-frags
__global__ void k_prep_cm2frag(const float* __restrict__ src, int CH, int KC,
                               ushort* __restrict__ dh, ushort* __restrict__ dl) {
  int gtid = blockIdx.x * 256 + threadIdx.x;
  int l = gtid & 63; int fr = gtid >> 6;
  int kc = fr % KC; int r2 = fr / KC; int nt = r2 & 63; int b = r2 >> 6;
  int lr = l & 15, lu = l >> 4;
  const float* sp = src + ((size_t)(b * CH) + kc * 32 + lu * 8) * 1024 + nt * 16 + lr;
  V16u hi, lo;
#pragma unroll
  for (int j = 0; j < 8; ++j) split2(sp[(size_t)j * 1024], hi.u[j], lo.u[j]);
  *(int4*)(dh + (size_t)gtid * 8) = hi.i4;
  *(int4*)(dl + (size_t)gtid * 8) = lo.i4;
}

// sampled_nc [8][1024][256] viewed as [4b][512ch] -> B-frags (KC=16)
__global__ void k_prep_s2frag(const float* __restrict__ snc,
                              ushort* __restrict__ dh, ushort* __restrict__ dl) {
  int gtid = blockIdx.x * 256 + threadIdx.x;   // 262144
  int l = gtid & 63; int fr = gtid >> 6;
  int kc = fr & 15; int nt = (fr >> 4) & 63; int b = fr >> 10;
  int lr = l & 15, lu = l >> 4;
  const float* sp = snc + ((size_t)((b * 2 + (kc >> 3)) * 1024 + nt * 16 + lr)) * 256
                    + (kc & 7) * 32 + lu * 8;
  V16u hi, lo;
#pragma unroll
  for (int j = 0; j < 8; ++j) split2(sp[j], hi.u[j], lo.u[j]);
  *(int4*)(dh + (size_t)gtid * 8) = hi.i4;
  *(int4*)(dl + (size_t)gtid * 8) = lo.i4;
}

// ============ generic MFMA GEMM: Y[b][Mtot][1024] = W[Mtot,K] x B + bias ======
__global__ __launch_bounds__(256)
void k_gemm_mfma(const ushort* __restrict__ Ah, const ushort* __restrict__ Al,
                 const ushort* __restrict__ Bh, const ushort* __restrict__ Bl,
                 const float* __restrict__ bias, float* __restrict__ Y,
                 int KC, int MT, int Mtot) {
  int bid = blockIdx.x;
  int ntb = bid & 15; bid >>= 4;
  int mt = bid % MT; int b = bid / MT;
  int tid = threadIdx.x, w = tid >> 6, l = tid & 63, lr = l & 15, lu = l >> 4;
  int wo = w >> 1, wn = w & 1;
  int ot0 = mt * 4 + wo * 2;
  int nf0 = ntb * 4 + wn * 2;
  const bf16x8* pAh = (const bf16x8*)Ah;
  const bf16x8* pAl = (const bf16x8*)Al;
  const bf16x8* pBh = (const bf16x8*)Bh;
  const bf16x8* pBl = (const bf16x8*)Bl;
  f32x4 zero = {0.f, 0.f, 0.f, 0.f};
  f32x4 acc[2][2];
#pragma unroll
  for (int a = 0; a < 2; ++a)
#pragma unroll
    for (int n = 0; n < 2; ++n) acc[a][n] = zero;
  for (int kc = 0; kc < KC; ++kc) {
    bf16x8 a_h[2], a_l[2];
#pragma unroll
    for (int a = 0; a < 2; ++a) {
      size_t idx = ((size_t)(ot0 + a) * KC + kc) * 64 + l;
      a_h[a] = pAh[idx]; a_l[a] = pAl[idx];
    }
#pragma unroll
    for (int n = 0; n < 2; ++n) {
      size_t idx = (((size_t)(b * 64 + nf0 + n)) * KC + kc) * 64 + l;
      bf16x8 b_h = pBh[idx], b_l = pBl[idx];
#pragma unroll
      for (int a = 0; a < 2; ++a) {
        acc[a][n] = __builtin_amdgcn_mfma_f32_16x16x32_bf16(a_h[a], b_h, acc[a][n], 0, 0, 0);
        acc[a][n] = __builtin_amdgcn_mfma_f32_16x16x32_bf16(a_h[a], b_l, acc[a][n], 0, 0, 0);
        acc[a][n] = __builtin_amdgcn_mfma_f32_16x16x32_bf16(a_l[a], b_h, acc[a][n], 0, 0, 0);
      }
    }
  }
#pragma unroll
  for (int a = 0; a < 2; ++a) {
    int o = (ot0 + a) * 16 + lu * 4;
#pragma unroll
    for (int n = 0; n < 2; ++n) {
      int col = (nf0 + n) * 16 + lr;
#pragma unroll
      for (int r = 0; r < 4; ++r)
        Y[((size_t)(b * Mtot + o + r)) * 1024 + col] = acc[a][n][r] + bias[o + r];
    }
  }
}

// ============ transposes ============
__global__ void k_transadd_tm(const float* __restrict__ Pcm, float* __restrict__ Xtm) {
  __shared__ float T[64][65];
  int bid = blockIdx.x; int n0 = (bid & 15) << 6; bid >>= 4;
  int c0 = (bid & 3) << 6; int bg = bid >> 2;
  int cl = threadIdx.x & 63, rw = threadIdx.x >> 6;
#pragma unroll
  for (int i = 0; i < 16; ++i) {
    int crow = i * 4 + rw;
    T[crow][cl] = Pcm[((size_t)(bg * 256 + c0 + crow)) * 1024 + n0 + cl];
  }
  __syncthreads();
#pragma unroll
  for (int i = 0; i < 16; ++i) {
    int nrow = i * 4 + rw;
    Xtm[((size_t)((bg << 10) + n0 + nrow)) * 256 + c0 + cl] += T[cl][nrow];
  }
}

__global__ void k_transadd_nc(const float* __restrict__ Yg, const float* __restrict__ Xtm,
                              float* __restrict__ out_nc) {
  __shared__ float T[64][65];
  int bid = blockIdx.x; int n0 = (bid & 15) << 6; bid >>= 4;
  int c0 = (bid & 3) << 6; int bg = bid >> 2;
  int cl = threadIdx.x & 63, rw = threadIdx.x >> 6;
#pragma unroll
  for (int i = 0; i < 16; ++i) {
    int crow = i * 4 + rw;
    T[crow][cl] = Yg[((size_t)(bg * 256 + c0 + crow)) * 1024 + n0 + cl];
  }
  __syncthreads();
#pragma unroll
  for (int i = 0; i < 16; ++i) {
    int nrow = i * 4 + rw;
    size_t a = ((size_t)((bg << 10) + n0 + nrow)) * 256 + c0 + cl;
    out_nc[a] = T[cl][nrow] + Xtm[a];
  }
}

// ---------------- token-major LN -> tm out
__global__ void k_ln_tok(const float* __restrict__ xin, const float* __restrict__ g_,
                         const float* __restrict__ b_, float* __restrict__ yo, float eps) {
  int token = (blockIdx.x * 256 + threadIdx.x) >> 6;
  int lane = threadIdx.x & 63;
  float4 v4 = *reinterpret_cast<const float4*>(xin + (size_t)token * 256 + lane * 4);
  float s  = v4.x + v4.y + v4.z + v4.w;
  float s2 = v4.x * v4.x + v4.y * v4.y + v4.z * v4.z + v4.w * v4.w;
#pragma unroll
  for (int off = 32; off; off >>= 1) { s += __shfl_xor(s, off); s2 += __shfl_xor(s2, off); }
  float mean = s * (1.f / 256.f);
  float rstd = rsqrtf(s2 * (1.f / 256.f) - mean * mean + eps);
  float4 g4 = *reinterpret_cast<const float4*>(g_ + lane * 4);
  float4 b4 = *reinterpret_cast<const float4*>(b_ + lane * 4);
  float4 o;
  o.x = (v4.x - mean) * rstd * g4.x + b4.x;
  o.y = (v4.y - mean) * rstd * g4.y + b4.y;
  o.z = (v4.z - mean) * rstd * g4.z + b4.z;
  o.w = (v4.w - mean) * rstd * g4.w + b4.w;
  *reinterpret_cast<float4*>(yo + (size_t)token * 256 + lane * 4) = o;
}

// ---------------- token-major LN -> B-frags directly (KC=8)
__global__ void k_ln_frag(const float* __restrict__ xin, const float* __restrict__ g_,
                          const float* __restrict__ b_, ushort* __restrict__ dh,
                          ushort* __restrict__ dl, float eps) {
  int token = (blockIdx.x * 256 + threadIdx.x) >> 6;
  int lane = threadIdx.x & 63;
  float4 v4 = *reinterpret_cast<const float4*>(xin + (size_t)token * 256 + lane * 4);
  float s  = v4.x + v4.y + v4.z + v4.w;
  float s2 = v4.x * v4.x + v4.y * v4.y + v4.z * v4.z + v4.w * v4.w;
#pragma unroll
  for (int off = 32; off; off >>= 1) { s += __shfl_xor(s, off); s2 += __shfl_xor(s2, off); }
  float mean = s * (1.f / 256.f);
  float rstd = rsqrtf(s2 * (1.f / 256.f) - mean * mean + eps);
  float4 g4 = *reinterpret_cast<const float4*>(g_ + lane * 4);
  float4 b4 = *reinterpret_cast<const float4*>(b_ + lane * 4);
  float vals[4];
  vals[0] = (v4.x - mean) * rstd * g4.x + b4.x;
  vals[1] = (v4.y - mean) * rstd * g4.y + b4.y;
  vals[2] = (v4.z - mean) * rstd * g4.z + b4.z;
  vals[3] = (v4.w - mean) * rstd * g4.w + b4.w;
  ushort4 h4, l4;
  split2(vals[0], h4.x, l4.x); split2(vals[1], h4.y, l4.y);
  split2(vals[2], h4.z, l4.z); split2(vals[3], h4.w, l4.w);
  int bg = token >> 10, nt = (token >> 4) & 63, lr = token & 15;
  int kc = lane >> 3, lu_f = (lane >> 1) & 3, j0 = (lane & 1) * 4;
  size_t base = ((((size_t)(bg * 64 + nt)) * 8 + kc) * 64 + lu_f * 16 + lr) * 8 + j0;
  *(ushort4*)(dh + base) = h4;
  *(ushort4*)(dl + base) = l4;
}

// ============ fused mb-attn input preps (Q / K / V^T frags) ============
__global__ void k_prep_mb3(const float* __restrict__ qq_cm, const float* __restrict__ kv_cm,
                           ushort* __restrict__ mQh, ushort* __restrict__ mQl,
                           ushort* __restrict__ mKh, ushort* __restrict__ mKl,
                           ushort* __restrict__ mVh, ushort* __restrict__ mVl) {
  int bid = blockIdx.x, tid = threadIdx.x;
  int sect = bid >> 10, lb = bid & 1023;
  int gtid = lb * 256 + tid;                 // 262144
  int l = gtid & 63; int fr = gtid >> 6;
  int lr = l & 15, lu = l >> 4;
  V16u hi, lo;
  if (sect < 2) {
    int nt = fr & 63; int bgh = fr >> 6;
    int bg = bgh >> 3, hh = bgh & 7;
    const float* src = sect == 0 ? qq_cm : kv_cm;
    int CH = sect == 0 ? 256 : 512;
    float scale = sect == 0 ? 0.17677669529663689f : 1.f;
    const float* sp = src + ((size_t)(bg * CH + hh * 32 + lu * 8)) * 1024 + nt * 16 + lr;
#pragma unroll
    for (int j = 0; j < 8; ++j) split2(sp[(size_t)j * 1024] * scale, hi.u[j], lo.u[j]);
    ushort* dh = sect == 0 ? mQh : mKh;
    ushort* dl = sect == 0 ? mQl : mKl;
    *(int4*)(dh + (size_t)gtid * 8) = hi.i4;
    *(int4*)(dl + (size_t)gtid * 8) = lo.i4;
  } else {
    int kc = fr & 31; int et = (fr >> 5) & 1; int bgh = fr >> 6;
    int bg = bgh >> 3, hh = bgh & 7;
    const float* sp = kv_cm + ((size_t)(bg * 512 + 256 + hh * 32 + et * 16 + lr)) * 1024
                      + kc * 32 + lu * 8;
#pragma unroll
    for (int j = 0; j < 8; ++j) split2(sp[j], hi.u[j], lo.u[j]);
    *(int4*)(mVh + (size_t)gtid * 8) = hi.i4;
    *(int4*)(mVl + (size_t)gtid * 8) = lo.i4;
  }
}

// ============ fused main-attn input preps ============
__global__ void k_prep_main3(const float* __restrict__ qb, const float* __restrict__ kb,
                             const float* __restrict__ vb,
                             ushort* __restrict__ aQh, ushort* __restrict__ aQl,
                             ushort* __restrict__ aKh, ushort* __restrict__ aKl,
                             ushort* __restrict__ aVh, ushort* __restrict__ aVl) {
  int bid = blockIdx.x, tid = threadIdx.x;
  int sect = bid >> 10, lb = bid & 1023;
  int gtid = lb * 256 + tid;                 // 262144
  int l = gtid & 63, tile = gtid >> 6;
  int lr = l & 15, lu = l >> 4;
  V16u hi, lo;
  if (sect < 2) {
    int dc = tile & 1, nt = (tile >> 1) & 63, bh = tile >> 7;
    int b = bh >> 3, h = bh & 7;
    const float* src = sect == 0 ? qb : kb;
    float scale = sect == 0 ? 0.125f : 1.f;
    const float* sp = src + ((size_t)(b * 512 + h * 64 + dc * 32 + lu * 8)) * 1024
                      + nt * 16 + lr;
#pragma unroll
    for (int j = 0; j < 8; ++j) split2(sp[(size_t)j * 1024] * scale, hi.u[j], lo.u[j]);
    ushort* dh = sect == 0 ? aQh : aKh;
    ushort* dl = sect == 0 ? aQl : aKl;
    *(int4*)(dh + (size_t)gtid * 8) = hi.i4;
    *(int4*)(dl + (size_t)gtid * 8) = lo.i4;
  } else {
    int kc = tile & 31, et = (tile >> 5) & 3, bh = tile >> 7;
    int b = bh >> 3, h = bh & 7;
    const float* sp = vb + ((size_t)(b * 512 + h * 64 + et * 16 + lr)) * 1024 + kc * 32 + lu * 8;
#pragma unroll
    for (int j = 0; j < 8; ++j) split2(sp[j], hi.u[j], lo.u[j]);
    *(int4*)(aVh + (size_t)gtid * 8) = hi.i4;
    *(int4*)(aVl + (size_t)gtid * 8) = lo.i4;
  }
}

// ============ MitBlock attention (MFMA, d=32), epilogue -> B-frags ============
__global__ __launch_bounds__(256)
void k_mbattn_mfma(const ushort* __restrict__ Qh, const ushort* __restrict__ Ql,
                   const ushort* __restrict__ Kh, const ushort* __restrict__ Kl,
                   const ushort* __restrict__ Vh, const ushort* __restrict__ Vl,
                   ushort* __restrict__ ofh, ushort* __restrict__ ofl) {
  int qb = blockIdx.x & 15, bgh = blockIdx.x >> 4;
  int tid = threadIdx.x, w = tid >> 6, l = tid & 63, lr = l & 15, lu = l >> 4;
  int qt = qb * 4 + w;
  bf16x8 qh = ((const bf16x8*)Qh)[(size_t)(bgh * 64 + qt) * 64 + l];
  bf16x8 ql = ((const bf16x8*)Ql)[(size_t)(bgh * 64 + qt) * 64 + l];
  __shared__ ushort Ph[4][16][72];
  __shared__ ushort Pl[4][16][72];
  f32x4 zero = {0.f, 0.f, 0.f, 0.f};
  f32x4 oacc[2] = {zero, zero};
  float den = 0.f;
  for (int kb = 0; kb < 16; ++kb) {
#pragma unroll
    for (int kt4 = 0; kt4 < 4; ++kt4) {
      int kt = kb * 4 + kt4;
      bf16x8 kh = ((const bf16x8*)Kh)[(size_t)(bgh * 64 + kt) * 64 + l];
      bf16x8 kl = ((const bf16x8*)Kl)[(size_t)(bgh * 64 + kt) * 64 + l];
      f32x4 s = zero;
      s = __builtin_amdgcn_mfma_f32_16x16x32_bf16(kh, qh, s, 0, 0, 0);
      s = __builtin_amdgcn_mfma_f32_16x16x32_bf16(kh, ql, s, 0, 0, 0);
      s = __builtin_amdgcn_mfma_f32_16x16x32_bf16(kl, qh, s, 0, 0, 0);
      uint2 uh, ul;
      {
        float p0 = __expf(s[0]), p1 = __expf(s[1]), p2 = __expf(s[2]), p3 = __expf(s[3]);
        den += (p0 + p1) + (p2 + p3);
        ushort h0, l0, h1, l1, h2, l2, h3, l3;
        split2(p0, h0, l0); split2(p1, h1, l1); split2(p2, h2, l2); split2(p3, h3, l3);
        uh.x = (unsigned)h0 | ((unsigned)h1 << 16); uh.y = (unsigned)h2 | ((unsigned)h3 << 16);
        ul.x = (unsigned)l0 | ((unsigned)l1 << 16); ul.y = (unsigned)l2 | ((unsigned)l3 << 16);
      }
      *(uint2*)&Ph[w][lr][kt4 * 16 + lu * 4] = uh;
      *(uint2*)&Pl[w][lr][kt4 * 16 + lu * 4] = ul;
    }
#pragma unroll
    for (int kc2 = 0; kc2 < 2; ++kc2) {
      int kc = kb * 2 + kc2;
      bf16x8 bph = *(const bf16x8*)&Ph[w][lr][kc2 * 32 + lu * 8];
      bf16x8 bpl = *(const bf16x8*)&Pl[w][lr][kc2 * 32 + lu * 8];
#pragma unroll
      for (int et = 0; et < 2; ++et) {
        bf16x8 vh = ((const bf16x8*)Vh)[(size_t)((bgh * 2 + et) * 32 + kc) * 64 + l];
        bf16x8 vl = ((const bf16x8*)Vl)[(size_t)((bgh * 2 + et) * 32 + kc) * 64 + l];
        oacc[et] = __builtin_amdgcn_mfma_f32_16x16x32_bf16(vh, bph, oacc[et], 0, 0, 0);
        oacc[et] = __builtin_amdgcn_mfma_f32_16x16x32_bf16(vh, bpl, oacc[et], 0, 0, 0);
        oacc[et] = __builtin_amdgcn_mfma_f32_16x16x32_bf16(vl, bph, oacc[et], 0, 0, 0);
      }
    }
  }
  den += __shfl_xor(den, 16);
  den += __shfl_xor(den, 32);
  float inv = 1.f / den;
  int bg = bgh >> 3, hh = bgh & 7;
#pragma unroll
  for (int et = 0; et < 2; ++et) {
    ushort4 h4, l4;
    split2(oacc[et][0] * inv, h4.x, l4.x); split2(oacc[et][1] * inv, h4.y, l4.y);
    split2(oacc[et][2] * inv, h4.z, l4.z); split2(oacc[et][3] * inv, h4.w, l4.w);
    int lu_f = et * 2 + (lu >> 1), j0 = (lu & 1) * 4;
    size_t base = ((((size_t)(bg * 64 + qt)) * 8 + hh) * 64 + lu_f * 16 + lr) * 8 + j0;
    *(ushort4*)(ofh + base) = h4;
    *(ushort4*)(ofl + base) = l4;
  }
}

// ============ main attention (MFMA, d=64), epilogue -> B-frags (KC=16) ========
__global__ __launch_bounds__(256)
void k_mainattn_mfma(const ushort* __restrict__ Qh, const ushort* __restrict__ Ql,
                     const ushort* __restrict__ Kh, const ushort* __restrict__ Kl,
                     const ushort* __restrict__ Vh, const ushort* __restrict__ Vl,
                     ushort* __restrict__ anfh, ushort* __restrict__ anfl) {
  int qb = blockIdx.x & 15, bh = blockIdx.x >> 4;
  int tid = threadIdx.x, w = tid >> 6, l = tid & 63, lr = l & 15, lu = l >> 4;
  int qt = qb * 4 + w;
  bf16x8 qh[2], ql[2];
#pragma unroll
  for (int dc = 0; dc < 2; ++dc) {
    qh[dc] = ((const bf16x8*)Qh)[(size_t)((bh * 64 + qt) * 2 + dc) * 64 + l];
    ql[dc] = ((const bf16x8*)Ql)[(size_t)((bh * 64 + qt) * 2 + dc) * 64 + l];
  }
  __shared__ ushort Ph[4][16][72];
  __shared__ ushort Pl[4][16][72];
  f32x4 zero = {0.f, 0.f, 0.f, 0.f};
  f32x4 oacc[4] = {zero, zero, zero, zero};
  float den = 0.f;
  for (int kb = 0; kb < 16; ++kb) {
#pragma unroll
    for (int kt4 = 0; kt4 < 4; ++kt4) {
      int kt = kb * 4 + kt4;
      f32x4 s = zero;
#pragma unroll
      for (int dc = 0; dc < 2; ++dc) {
        bf16x8 kh = ((const bf16x8*)Kh)[(size_t)((bh * 64 + kt) * 2 + dc) * 64 + l];
        bf16x8 kl = ((const bf16x8*)Kl)[(size_t)((bh * 64 + kt) * 2 + dc) * 64 + l];
        s = __builtin_amdgcn_mfma_f32_16x16x32_bf16(kh, qh[dc], s, 0, 0, 0);
        s = __builtin_amdgcn_mfma_f32_16x16x32_bf16(kh, ql[dc], s, 0, 0, 0);
        s = __builtin_amdgcn_mfma_f32_16x16x32_bf16(kl, qh[dc], s, 0, 0, 0);
      }
      uint2 uh, ul;
      {
        float p0 = __expf(s[0]), p1 = __expf(s[1]), p2 = __expf(s[2]), p3 = __expf(s[3]);
        den += (p0 + p1) + (p2 + p3);
        ushort h0, l0, h1, l1, h2, l2, h3, l3;
        split2(p0, h0, l0); split2(p1, h1, l1); split2(p2, h2, l2); split2(p3, h3, l3);
        uh.x = (unsigned)h0 | ((unsigned)h1 << 16); uh.y = (unsigned)h2 | ((unsigned)h3 << 16);
        ul.x = (unsigned)l0 | ((unsigned)l1 << 16); ul.y = (unsigned)l2 | ((unsigned)l3 << 16);
      }
      *(uint2*)&Ph[w][lr][kt4 * 16 + lu * 4] = uh;
      *(uint2*)&Pl[w][lr][kt4 * 16 + lu * 4] = ul;
    }
#pragma unroll
    for (int kc2 = 0; kc2 < 2; ++kc2) {
      int kc = kb * 2 + kc2;
      bf16x8 bph = *(const bf16x8*)&Ph[w][lr][kc2 * 32 + lu * 8];
      bf16x8 bpl = *(const bf16x8*)&Pl[w][lr][kc2 * 32 + lu * 8];
#pragma unroll
      for (int et = 0; et < 4; ++et) {
        bf16x8 vh = ((const bf16x8*)Vh)[(size_t)((bh * 4 + et) * 32 + kc) * 64 + l];
        bf16x8 vl = ((const bf16x8*)Vl)[(size_t)((bh * 4 + et) * 32 + kc) * 64 + l];
        oacc[et] = __builtin_amdgcn_mfma_f32_16x16x32_bf16(vh, bph, oacc[et], 0, 0, 0);
        oacc[et] = __builtin_amdgcn_mfma_f32_16x16x32_bf16(vh, bpl, oacc[et], 0, 0, 0);
        oacc[et] = __builtin_amdgcn_mfma_f32_16x16x32_bf16(vl, bph, oacc[et], 0, 0, 0);
      }
    }
  }
  den += __shfl_xor(den, 16);
  den += __shfl_xor(den, 32);
  float inv = 1.f / den;
  int b = bh >> 3, h = bh & 7;
#pragma unroll
  for (int et = 0; et < 4; ++et) {
    ushort4 h4, l4;
    split2(oacc[et][0] * inv, h4.x, l4.x); split2(oacc[et][1] * inv, h4.y, l4.y);
    split2(oacc[et][2] * inv, h4.z, l4.z); split2(oacc[et][3] * inv, h4.w, l4.w);
    int kc = h * 2 + (et >> 1);
    int lu_f = (et & 1) * 2 + (lu >> 1), j0 = (lu & 1) * 4;
    size_t base = ((((size_t)(b * 64 + qt)) * 16 + kc) * 64 + lu_f * 16 + lr) * 8 + j0;
    *(ushort4*)(anfh + base) = h4;
    *(ushort4*)(anfl + base) = l4;
  }
}

// ---------------- depthwise 3x3 + bias + exact GELU (cm)
__global__ void k_dw3(const float* __restrict__ X, const float* __restrict__ w,
                      const float* __restrict__ bias, float* __restrict__ Y) {
  int idx = blockIdx.x * 256 + threadIdx.x;
  int x = idx & 31, y = (idx >> 5) & 31, ch = (idx >> 10) & 1023, bg = idx >> 20;
  const float* src = X + (size_t)((bg << 10) + ch) * HW;
  const float* wr = w + ch * 9;
  float acc = bias[ch];
#pragma unroll
  for (int ky = 0; ky < 3; ++ky) {
    int yy = y + ky - 1;
    if ((unsigned)yy < 32u) {
      const float* row = src + yy * 32;
#pragma unroll
      for (int kx = 0; kx < 3; ++kx) {
        int xx = x + kx - 1;
        if ((unsigned)xx < 32u) acc += row[xx] * wr[ky * 3 + kx];
      }
    }
  }
  Y[(size_t)((bg << 10) + ch) * HW + y * 32 + x] = gelu_exact(acc);
}

// ---------------- depthwise 9x9 pad 4 on nc layout, wt9 = transposed weights
__global__ void k_dw9_nc(const float* __restrict__ Xnc, const float* __restrict__ wt9,
                         const float* __restrict__ bias, float* __restrict__ Ync) {
  int bid = blockIdx.x;               // 1024 = bg(8) x ptile(128), 8 px per block
  int pt = bid & 127; int bg = bid >> 7;
  int tid = threadIdx.x;              // = channel
  int y = pt >> 2, x0 = (pt & 3) * 8;
  float acc[8];
  float bs = bias[tid];
#pragma unroll
  for (int p = 0; p < 8; ++p) acc[p] = bs;
  const float* src = Xnc + (size_t)(bg << 10) * 256;
  for (int ky = 0; ky < 9; ++ky) {
    int yy = y + ky - 4;
    if ((unsigned)yy >= 32u) continue;
#pragma unroll
    for (int kx = 0; kx < 9; ++kx) {
      float wv = wt9[(ky * 9 + kx) * 256 + tid];
#pragma unroll
      for (int p = 0; p < 8; ++p) {
        int xx = x0 + p + kx - 4;
        if ((unsigned)xx < 32u)
          acc[p] += src[(size_t)(yy * 32 + xx) * 256 + tid] * wv;
      }
    }
  }
#pragma unroll
  for (int p = 0; p < 8; ++p)
    Ync[((size_t)((bg << 10) + y * 32 + x0 + p)) * 256 + tid] = acc[p];
}

// ---------------- co tail on nc layout: wave per token
__global__ void k_cotail_nc(const float* __restrict__ Xnc, const float* __restrict__ lnw,
                            const float* __restrict__ lnb, const float* __restrict__ w2,
                            float* __restrict__ pos) {
  int token = (blockIdx.x * 256 + threadIdx.x) >> 6;   // 8192
  int lane = threadIdx.x & 63;
  float4 v4 = *(const float4*)(Xnc + (size_t)token * 256 + lane * 4);
  float s = v4.x + v4.y + v4.z + v4.w;
  float s2 = v4.x * v4.x + v4.y * v4.y + v4.z * v4.z + v4.w * v4.w;
#pragma unroll
  for (int off = 32; off; off >>= 1) { s += __shfl_xor(s, off); s2 += __shfl_xor(s2, off); }
  float mean = s * (1.f / 256.f);
  float rstd = rsqrtf(s2 * (1.f / 256.f) - mean * mean + 1e-5f);
  float4 g4 = *(const float4*)(lnw + lane * 4);
  float4 b4 = *(const float4*)(lnb + lane * 4);
  float4 wa = *(const float4*)(w2 + lane * 4);
  float4 wb = *(const float4*)(w2 + 256 + lane * 4);
  float ge0 = gelu_exact((v4.x - mean) * rstd * g4.x + b4.x);
  float ge1 = gelu_exact((v4.y - mean) * rstd * g4.y + b4.y);
  float ge2 = gelu_exact((v4.z - mean) * rstd * g4.z + b4.z);
  float ge3 = gelu_exact((v4.w - mean) * rstd * g4.w + b4.w);
  float o0 = ge0 * wa.x + ge1 * wa.y + ge2 * wa.z + ge3 * wa.w;
  float o1 = ge0 * wb.x + ge1 * wb.y + ge2 * wb.z + ge3 * wb.w;
#pragma unroll
  for (int off = 32; off; off >>= 1) { o0 += __shfl_xor(o0, off); o1 += __shfl_xor(o1, off); }
  if (lane == 0) {
    float offy = tanhf(o0) * (2.f / 32.f);
    float offx = tanhf(o1) * (2.f / 32.f);
    int n = token & 1023;
    int ky = n >> 5, kx = n & 31;
    float refy = ((ky + 0.5f) * (1.f / 32.f)) * 2.f - 1.f;
    float refx = ((kx + 0.5f) * (1.f / 32.f)) * 2.f - 1.f;
    pos[token * 2] = offx + refx;
    pos[token * 2 + 1] = offy + refy;
  }
}

// ---------------- bilinear grid sample on nc layout -> sampled_nc
__global__ void k_gsample_nc(const float* __restrict__ Xnc, const float* __restrict__ pos,
                             float* __restrict__ out_nc) {
  int bid = blockIdx.x;            // bg(8) x nch(16)
  int nch = bid & 15; int bg = bid >> 4;
  int tid = threadIdx.x;           // = channel c
  __shared__ int sI[4][64];
  __shared__ float sW[4][64];
  if (tid < 64) {
    int j = nch * 64 + tid;
    float gx = pos[((bg << 10) + j) * 2];
    float gy = pos[((bg << 10) + j) * 2 + 1];
    float fx = (gx + 1.f) * 0.5f * 31.f;
    float fy = (gy + 1.f) * 0.5f * 31.f;
    float x0f = floorf(fx), y0f = floorf(fy);
    int x0 = (int)x0f, y0 = (int)y0f;
    float wx1 = fx - x0f, wx0 = 1.f - wx1;
    float wy1 = fy - y0f, wy0 = 1.f - wy1;
    bool vx0 = (x0 >= 0) & (x0 <= 31);
    bool vx1 = (x0 + 1 >= 0) & (x0 + 1 <= 31);
    bool vy0 = (y0 >= 0) & (y0 <= 31);
    bool vy1 = (y0 + 1 >= 0) & (y0 + 1 <= 31);
    int cx0 = min(max(x0, 0), 31), cx1 = min(max(x0 + 1, 0), 31);
    int cy0 = min(max(y0, 0), 31), cy1 = min(max(y0 + 1, 0), 31);
    sW[0][tid] = wx0 * wy0 * ((vx0 && vy0) ? 1.f : 0.f);
    sW[1][tid] = wx1 * wy0 * ((vx1 && vy0) ? 1.f : 0.f);
    sW[2][tid] = wx0 * wy1 * ((vx0 && vy1) ? 1.f : 0.f);
    sW[3][tid] = wx1 * wy1 * ((vx1 && vy1) ? 1.f : 0.f);
    sI[0][tid] = cy0 * 32 + cx0; sI[1][tid] = cy0 * 32 + cx1;
    sI[2][tid] = cy1 * 32 + cx0; sI[3][tid] = cy1 * 32 + cx1;
  }
  __syncthreads();
  const float* src = Xnc + (size_t)(bg << 10) * 256;
  for (int n = 0; n < 64; ++n) {
    float acc = src[(size_t)sI[0][n] * 256 + tid] * sW[0][n]
              + src[(size_t)sI[1][n] * 256 + tid] * sW[1][n]
              + src[(size_t)sI[2][n] * 256 + tid] * sW[2][n]
              + src[(size_t)sI[3][n] * 256 + tid] * sW[3][n];
    out_nc[((size_t)((bg << 10) + nch * 64 + n)) * 256 + tid] = acc;
  }
}

// ---------------------------------------------------------------------------
extern "C" void kernel_launch(void* const* d_in, const int* in_sizes, int n_in,
                              void* d_out, int out_size, void* d_ws, size_t ws_size,
                              hipStream_t stream) {
  const float* tgt    = (const float*)d_in[0];
  const float* refp   = (const float*)d_in[1];
  const float* emb_w  = (const float*)d_in[2];
  const float* emb_b  = (const float*)d_in[3];
  const float* q_w    = (const float*)d_in[4];
  const float* q_b    = (const float*)d_in[5];
  const float* k_w    = (const float*)d_in[6];
  const float* k_b    = (const float*)d_in[7];
  const float* v_w    = (const float*)d_in[8];
  const float* v_b    = (const float*)d_in[9];
  const float* out_w  = (const float*)d_in[10];
  const float* out_b  = (const float*)d_in[11];
  const float* ln1_w  = (const float*)d_in[12];
  const float* ln1_b  = (const float*)d_in[13];
  const float* n1_w   = (const float*)d_in[14];
  const float* n1_b   = (const float*)d_in[15];
  const float* mbq_w  = (const float*)d_in[16];
  const float* mbq_b  = (const float*)d_in[17];
  const float* mbkv_w = (const float*)d_in[18];
  const float* mbkv_b = (const float*)d_in[19];
  const float* mbp_w  = (const float*)d_in[20];
  const float* mbp_b  = (const float*)d_in[21];
  const float* n2_w   = (const float*)d_in[22];
  const float* n2_b   = (const float*)d_in[23];
  const float* fc1_w  = (const float*)d_in[24];
  const float* fc1_b  = (const float*)d_in[25];
  const float* dw3_w  = (const float*)d_in[26];
  const float* dw3_b  = (const float*)d_in[27];
  const float* fc2_w  = (const float*)d_in[28];
  const float* fc2_b  = (const float*)d_in[29];
  const float* dw9_w  = (const float*)d_in[30];
  const float* dw9_b  = (const float*)d_in[31];
  const float* coln_w = (const float*)d_in[32];
  const float* coln_b = (const float*)d_in[33];
  const float* coout_w= (const float*)d_in[34];

  float* ws = (float*)d_ws;
  float* slabA = ws + 0;
  float* qbuf  = ws + 2097152;
  float* xbuf  = ws + 4194304;
  float* slabD = ws + 6291456;
  float* slabE = ws + 8388608;
  float* slabF = ws + 10485760;
  float* slabG = ws + 14680064;
  float* slabH = ws + 23068672;
  float* featnc= ws + 31457280;
  float* posb  = ws + 35389440;
  float* wt9   = ws + 35405824;

  ushort* XtH = (ushort*)(ws + 4194304);
  ushort* XtL = XtH + 4734976;
  ushort* WtEH = (ushort*)slabG;
  ushort* WtEL = WtEH + 4718592;
  float* part = slabH;
  ushort* tgtfh = (ushort*)slabF;
  ushort* tgtfl = tgtfh + 2097152;

  ushort* J = (ushort*)(ws + 33554432);
  ushort* wfq_h = J;                ushort* wfq_l = J + 262144;
  ushort* wfk_h = J + 524288;       ushort* wfk_l = J + 786432;
  ushort* wfv_h = J + 1048576;      ushort* wfv_l = J + 1310720;
  ushort* wfo_h = J + 1572864;      ushort* wfo_l = J + 1835008;
  ushort* wfmq_h = J + 2097152;     ushort* wfmq_l = J + 2162688;
  ushort* wfmkv_h = J + 2228224;    ushort* wfmkv_l = J + 2359296;
  ushort* wfmp_h = J + 2490368;     ushort* wfmp_l = J + 2555904;
  ushort* wff1_h = J + 2621440;     ushort* wff1_l = J + 2883584;
  ushort* wff2_h = J + 3145728;     ushort* wff2_l = J + 3407872;

  ushort* hfh = (ushort*)slabG;     ushort* hfl = hfh + 2097152;
  float* qq_cm  = slabE;
  float* kv_cm  = slabF;
  ushort* mQh = (ushort*)slabG;     ushort* mQl = mQh + 2097152;
  ushort* mKh = mQh + 4194304;      ushort* mKl = mQh + 6291456;
  ushort* mVh = mQh + 8388608;      ushort* mVl = mQh + 10485760;
  ushort* ofh = (ushort*)slabF;     ushort* ofl = ofh + 2097152;
  float* P_cm = slabD;
  ushort* h2fh = (ushort*)slabF;    ushort* h2fl = h2fh + 2097152;
  float* m_cm = slabG;
  float* mi_cm = slabH;
  // FIX (R8): mi frags need 8,388,608 ushorts EACH. Place both in slabG
  // (8,388,608 floats = 16,777,216 ushorts, exact fit). m_cm (slabG) is dead
  // after k_dw3 consumes it one kernel earlier. Previously mifl = mifh +
  // 4194304 aliased mifh's upper half -> block-scheduling race across replays.
  ushort* mifh = (ushort*)slabG;    ushort* mifl = mifh + 8388608;
  float* ygemm = slabD;
  float* offin = slabA;
  float* offdwnc = slabE;
  float* samplednc = slabA;
  ushort* sfh = (ushort*)slabF;     ushort* sfl = sfh + 2097152;
  float* kbuf = slabD;
  float* vbuf = slabE;
  ushort* aQh = (ushort*)slabG;     ushort* aQl = aQh + 2097152;
  ushort* aKh = aQh + 4194304;      ushort* aKl = aQh + 6291456;
  ushort* aVh = aQh + 8388608;      ushort* aVl = aQh + 10485760;
  ushort* anfh = (ushort*)slabH;    ushort* anfl = anfh + 2097152;

  // --- step 0: preps ---
  k_prepw<<<2048, 256, 0, stream>>>(emb_w, WtEH, WtEL);
  k_prepx<<<2312, 256, 0, stream>>>(tgt, refp, XtH, XtL);
  k_prep_wfrag9<<<977, 256, 0, stream>>>(q_w, k_w, v_w, out_w, mbq_w, mbkv_w, mbp_w,
                                         fc1_w, fc2_w, dw9_w,
                                         wfq_h, wfq_l, wfk_h, wfk_l, wfv_h, wfv_l,
                                         wfo_h, wfo_l, wfmq_h, wfmq_l, wfmkv_h, wfmkv_l,
                                         wfmp_h, wfmp_l, wff1_h, wff1_l, wff2_h, wff2_l,
                                         wt9);
  k_prep_cm2frag<<<1024, 256, 0, stream>>>(tgt, 512, 16, tgtfh, tgtfl);
  // --- step 1: emb conv (4 rows/wave, 4-way K-split) ---
  k_emb_mfma<<<512, 256, 0, stream>>>(XtH, XtL, WtEH, WtEL, part);
  k_embmerge_nc<<<512, 256, 0, stream>>>(part, emb_b, featnc);
  // --- step 2: q proj ---
  k_gemm_mfma<<<512, 256, 0, stream>>>(wfq_h, wfq_l, tgtfh, tgtfl, q_b, qbuf, 16, 8, 512);
  // --- step 3: ln1 -> x (tm residual) ---
  k_ln_tok<<<2048, 256, 0, stream>>>(featnc, ln1_w, ln1_b, xbuf, 1e-5f);
  // --- step 4: n1 -> h frags directly ---
  k_ln_frag<<<2048, 256, 0, stream>>>(xbuf, n1_w, n1_b, hfh, hfl, 1e-6f);
  // --- step 5: mbq/mbkv GEMMs -> cm ---
  k_gemm_mfma<<<512, 256, 0, stream>>>(wfmq_h, wfmq_l, hfh, hfl, mbq_b, qq_cm, 8, 4, 256);
  k_gemm_mfma<<<1024, 256, 0, stream>>>(wfmkv_h, wfmkv_l, hfh, hfl, mbkv_b, kv_cm, 8, 8, 512);
  // --- step 6: mb attention ---
  k_prep_mb3<<<3072, 256, 0, stream>>>(qq_cm, kv_cm, mQh, mQl, mKh, mKl, mVh, mVl);
  k_mbattn_mfma<<<1024, 256, 0, stream>>>(mQh, mQl, mKh, mKl, mVh, mVl, ofh, ofl);
  // --- step 7: mbproj + residual ---
  k_gemm_mfma<<<512, 256, 0, stream>>>(wfmp_h, wfmp_l, ofh, ofl, mbp_b, P_cm, 8, 4, 256);
  k_transadd_tm<<<512, 256, 0, stream>>>(P_cm, xbuf);
  // --- step 8: n2 -> h2 frags directly ---
  k_ln_frag<<<2048, 256, 0, stream>>>(xbuf, n2_w, n2_b, h2fh, h2fl, 1e-6f);
  // --- step 9: fc1 ---
  k_gemm_mfma<<<2048, 256, 0, stream>>>(wff1_h, wff1_l, h2fh, h2fl, fc1_b, m_cm, 8, 16, 1024);
  // --- step 10: dw3 + gelu; mi frags (now in slabG, m_cm dead) ---
  k_dw3<<<32768, 256, 0, stream>>>(m_cm, dw3_w, dw3_b, mi_cm);
  k_prep_cm2frag<<<4096, 256, 0, stream>>>(mi_cm, 1024, 32, mifh, mifl);
  // --- step 11: fc2 + residual -> offin nc ---
  k_gemm_mfma<<<512, 256, 0, stream>>>(wff2_h, wff2_l, mifh, mifl, fc2_b, ygemm, 32, 4, 256);
  k_transadd_nc<<<512, 256, 0, stream>>>(ygemm, xbuf, offin);
  // --- step 12: dw9 on nc ---
  k_dw9_nc<<<1024, 256, 0, stream>>>(offin, wt9, dw9_b, offdwnc);
  // --- step 13: cotail ---
  k_cotail_nc<<<2048, 256, 0, stream>>>(offdwnc, coln_w, coln_b, coout_w, posb);
  // --- step 14: grid sample + frags ---
  k_gsample_nc<<<128, 256, 0, stream>>>(featnc, posb, samplednc);
  k_prep_s2frag<<<1024, 256, 0, stream>>>(samplednc, sfh, sfl);
  // --- step 15: k/v proj ---
  k_gemm_mfma<<<512, 256, 0, stream>>>(wfk_h, wfk_l, sfh, sfl, k_b, kbuf, 16, 8, 512);
  k_gemm_mfma<<<512, 256, 0, stream>>>(wfv_h, wfv_l, sfh, sfl, v_b, vbuf, 16, 8, 512);
  // --- step 16: main attention ---
  k_prep_main3<<<3072, 256, 0, stream>>>(qbuf, kbuf, vbuf, aQh, aQl, aKh, aKl, aVh, aVl);
  k_mainattn_mfma<<<512, 256, 0, stream>>>(aQh, aQl, aKh, aKl, aVh, aVl, anfh, anfl);
  // --- step 17: out proj -> d_out ---
  k_gemm_mfma<<<512, 256, 0, stream>>>(wfo_h, wfo_l, anfh, anfl, out_b, (float*)d_out, 16, 8, 512);
}

// Round 10
// 591.534 us; speedup vs baseline: 5.1634x; 1.0468x over previous
//
#include <hip/hip_runtime.h>
#include <math.h>

// ---------------------------------------------------------------------------
// DAttention forward. R10: R9 (mega-prep, fused ln1+n1, combined GEMMs) with
// the combined-weight frag offsets FIXED: v frags at +262144 ushorts (not
// +2097152), mkv frags at +65536 (not +524288). Those wrong offsets clobbered
// fc1's weight frags and left the v-frag region poisoned.
// Dims: B=4, C=512, H=W=32, G=2, gc=256, BG=8, heads=8, hc=64, mh=8, mhd=32.
// ---------------------------------------------------------------------------

static constexpr int HW = 1024;

typedef __attribute__((ext_vector_type(8))) short bf16x8;
typedef __attribute__((ext_vector_type(4))) float f32x4;

union V16u { int4 i4; ushort u[8]; };

__device__ __forceinline__ float gelu_exact(float v) {
  return 0.5f * v * (1.0f + erff(v * 0.7071067811865475f));
}

__device__ __forceinline__ ushort bf16_rne(float v) {
  unsigned int b = __float_as_uint(v);
  return (ushort)((b + 0x7fffu + ((b >> 16) & 1u)) >> 16);
}

__device__ __forceinline__ void split2(float v, ushort& h, ushort& l) {
  h = bf16_rne(v);
  l = bf16_rne(v - __uint_as_float(((unsigned int)h) << 16));
}

// ---------------- weight frag body (shared)
__device__ __forceinline__ void wfrag_body(const float* __restrict__ W, int K, int KC,
                                           ushort* __restrict__ dh, ushort* __restrict__ dl,
                                           int gtid) {
  int l = gtid & 63; int fr = gtid >> 6;
  int kc = fr % KC; int ot = fr / KC;
  int lr = l & 15, lu = l >> 4;
  const float* sp = W + (size_t)(ot * 16 + lr) * K + kc * 32 + lu * 8;
  V16u hi, lo;
#pragma unroll
  for (int j = 0; j < 8; ++j) split2(sp[j], hi.u[j], lo.u[j]);
  *(int4*)(dh + (size_t)gtid * 8) = hi.i4;
  *(int4*)(dl + (size_t)gtid * 8) = lo.i4;
}

// ---------------- MEGA-PREP: emb w/x prep + all weight frags + wt9 + biases.
__global__ void k_prep_all(
    const float* __restrict__ emb_w, const float* __restrict__ tgt,
    const float* __restrict__ refp,
    const float* q_w, const float* k_w, const float* v_w, const float* o_w,
    const float* mq_w, const float* mkv_w, const float* mp_w,
    const float* f1_w, const float* f2_w, const float* dw9_w,
    const float* mq_b, const float* mkv_b, const float* k_b, const float* v_b,
    ushort* __restrict__ WtEH, ushort* __restrict__ WtEL,
    ushort* __restrict__ XtH, ushort* __restrict__ XtL,
    ushort* qh, ushort* ql, ushort* kvh, ushort* kvl,
    ushort* oh, ushort* ol, ushort* mqkvh, ushort* mqkvl,
    ushort* mph, ushort* mpl, ushort* f1h, ushort* f1l, ushort* f2h, ushort* f2l,
    float* wt9, float* biasmb, float* biaskv) {
  int bid = blockIdx.x, tid = threadIdx.x;
  if (bid < 2048) {                      // emb weights -> [9][512][1024] hi/lo
    int idx = bid * 256 + tid;
    int o = idx >> 10, ci = idx & 1023;
    const float* src = emb_w + (size_t)idx * 9;
#pragma unroll
    for (int t = 0; t < 9; ++t) {
      ushort h, l; split2(src[t], h, l);
      size_t oo = ((size_t)(t * 512 + o)) * 1024 + ci;
      WtEH[oo] = h; WtEL[oo] = l;
    }
  } else if (bid < 4360) {               // inputs -> [4][34][34][1024] hi/lo
    int idx = (bid - 2048) * 256 + tid;
    int xp = idx % 34; int r = idx / 34;
    int g8 = r & 127; r >>= 7;
    int yp = r % 34; int b = r / 34;
    int y = yp - 1, x = xp - 1;
    bool valid = (unsigned)y < 32u && (unsigned)x < 32u;
    V16u hi, lo;
    const float* in = (g8 < 64) ? (tgt + ((size_t)(b * 512 + g8 * 8)) * HW)
                                : (refp + ((size_t)(b * 512 + (g8 - 64) * 8)) * HW);
#pragma unroll
    for (int j = 0; j < 8; ++j) {
      float v = valid ? in[(size_t)j * HW + y * 32 + x] : 0.f;
      split2(v, hi.u[j], lo.u[j]);
    }
    size_t oo = (((size_t)(b * 34 + yp)) * 34 + xp) * 1024 + g8 * 8;
    *(int4*)(XtH + oo) = hi.i4;
    *(int4*)(XtL + oo) = lo.i4;
  }
  else if (bid < 4488) wfrag_body(q_w, 512, 16, qh, ql, (bid - 4360) * 256 + tid);
  else if (bid < 4616) wfrag_body(k_w, 512, 16, kvh, kvl, (bid - 4488) * 256 + tid);
  // FIX: v frags (combined ot 32..63) start at ushort offset 262144, the size
  // of one 512x512 frag set (O/16 * KC * 64 * 8 = 262144).
  else if (bid < 4744) wfrag_body(v_w, 512, 16, kvh + 262144, kvl + 262144,
                                  (bid - 4616) * 256 + tid);
  else if (bid < 4872) wfrag_body(o_w, 512, 16, oh, ol, (bid - 4744) * 256 + tid);
  else if (bid < 4904) wfrag_body(mq_w, 256, 8, mqkvh, mqkvl, (bid - 4872) * 256 + tid);
  // FIX: mkv frags (combined ot 16..47) start at ushort offset 65536
  // (= 256x256 frag set size).
  else if (bid < 4968) wfrag_body(mkv_w, 256, 8, mqkvh + 65536, mqkvl + 65536,
                                  (bid - 4904) * 256 + tid);
  else if (bid < 5000) wfrag_body(mp_w, 256, 8, mph, mpl, (bid - 4968) * 256 + tid);
  else if (bid < 5128) wfrag_body(f1_w, 256, 8, f1h, f1l, (bid - 5000) * 256 + tid);
  else if (bid < 5256) wfrag_body(f2_w, 1024, 32, f2h, f2l, (bid - 5128) * 256 + tid);
  else if (bid < 5337) {                 // dw9 weight transpose [81][256]
    int idx = (bid - 5256) * 256 + tid;
    int t = idx >> 8, c = idx & 255;
    wt9[idx] = dw9_w[c * 81 + t];
  } else {                               // biases: 7 blocks x 256 = 1792
    int idx = (bid - 5337) * 256 + tid;
    if (idx < 768) biasmb[idx] = idx < 256 ? mq_b[idx] : mkv_b[idx - 256];
    else if (idx < 1792) {
      int j = idx - 768;
      biaskv[j] = j < 512 ? k_b[j] : v_b[j - 512];
    }
  }
}

// cm activations [b][CH][1024] -> B-frags
__global__ void k_prep_cm2frag(const float* __restrict__ src, int CH, int KC,
                               ushort* __restrict__ dh, ushort* __restrict__ dl) {
  int gtid = blockIdx.x * 256 + threadIdx.x;
  int l = gtid & 63; int fr = gtid >> 6;
  int kc = fr % KC; int r2 = fr / KC; int nt = r2 & 63; int b = r2 >> 6;
  int lr = l & 15, lu = l >> 4;
  const float* sp = src + ((size_t)(b * CH) + kc * 32 + lu * 8) * 1024 + nt * 16 + lr;
  V16u hi, lo;
#pragma unroll
  for (int j = 0; j < 8; ++j) split2(sp[(size_t)j * 1024], hi.u[j], lo.u[j]);
  *(int4*)(dh + (size_t)gtid * 8) = hi.i4;
  *(int4*)(dl + (size_t)gtid * 8) = lo.i4;
}

// ---------------- emb conv via MFMA, split-bf16, 4-way K-split, 4 rows/wave
__global__ __launch_bounds__(256, 2)
void k_emb_mfma(const ushort* __restrict__ Xt_hi, const ushort* __restrict__ Xt_lo,
                const ushort* __restrict__ Wt_hi, const ushort* __restrict__ Wt_lo,
                float* __restrict__ part) {
  int wgid = (blockIdx.x & 7) * 64 + (blockIdx.x >> 3);
  int yt = wgid & 7;  wgid >>= 3;
  int b  = wgid & 3;  wgid >>= 2;
  int mt = wgid & 3;  wgid >>= 2;
  int ks = wgid;
  int tid = threadIdx.x;
  int w = tid >> 6, l = tid & 63;
  int lr = l & 15, lu = l >> 4;
  int y0 = yt * 4;
  int obase = mt * 128 + w * 32;

  __shared__ int4 LsH[2][816];
  __shared__ int4 LsL[2][816];

  int4 gh[4], gl[4];
  int kc0 = ks * 8;

  auto loadstage = [&](int kcg) {
#pragma unroll
    for (int i = 0; i < 4; ++i) {
      int s = tid + 256 * i;
      if (s < 816) {
        int px = s >> 2;
        int u = (s & 3) ^ ((px >> 1) & 3);
        size_t off = ((size_t)(b * 34 + y0) * 34 + px) * 1024 + kcg * 32 + u * 8;
        gh[i] = *(const int4*)(Xt_hi + off);
        gl[i] = *(const int4*)(Xt_lo + off);
      }
    }
  };
  auto writestage = [&](int buf) {
#pragma unroll
    for (int i = 0; i < 4; ++i) {
      int s = tid + 256 * i;
      if (s < 816) { LsH[buf][s] = gh[i]; LsL[buf][s] = gl[i]; }
    }
  };

  f32x4 zero = {0.f, 0.f, 0.f, 0.f};
  f32x4 acc[2][8];
#pragma unroll
  for (int a = 0; a < 2; ++a)
#pragma unroll
    for (int n = 0; n < 8; ++n) acc[a][n] = zero;

  loadstage(kc0);
  writestage(0);

  for (int kc = 0; kc < 8; ++kc) {
    int buf = kc & 1;
    __syncthreads();
    if (kc < 7) loadstage(kc0 + kc + 1);
    int kcg = kc0 + kc;
    const bf16x8* BH = (const bf16x8*)&LsH[buf][0];
    const bf16x8* BL = (const bf16x8*)&LsL[buf][0];
#pragma unroll
    for (int kx = 0; kx < 3; ++kx) {
      bf16x8 bh[12], bl[12];
#pragma unroll
      for (int f = 0; f < 12; ++f) {
        int px = (f >> 1) * 34 + (f & 1) * 16 + kx + lr;
        int idx = px * 4 + (lu ^ ((px >> 1) & 3));
        bh[f] = BH[idx]; bl[f] = BL[idx];
      }
#pragma unroll
      for (int ky = 0; ky < 3; ++ky) {
        int tap = ky * 3 + kx;
        size_t wo = (((size_t)(tap * 512 + obase + lr)) * 1024) + kcg * 32 + lu * 8;
        bf16x8 ah0 = *(const bf16x8*)(Wt_hi + wo);
        bf16x8 al0 = *(const bf16x8*)(Wt_lo + wo);
        bf16x8 ah1 = *(const bf16x8*)(Wt_hi + wo + 16 * 1024);
        bf16x8 al1 = *(const bf16x8*)(Wt_lo + wo + 16 * 1024);
#pragma unroll
        for (int yr = 0; yr < 4; ++yr)
#pragma unroll
          for (int h = 0; h < 2; ++h) {
            int f = (yr + ky) * 2 + h;
            int nf = yr * 2 + h;
            acc[0][nf] = __builtin_amdgcn_mfma_f32_16x16x32_bf16(ah0, bh[f], acc[0][nf], 0, 0, 0);
            acc[0][nf] = __builtin_amdgcn_mfma_f32_16x16x32_bf16(ah0, bl[f], acc[0][nf], 0, 0, 0);
            acc[0][nf] = __builtin_amdgcn_mfma_f32_16x16x32_bf16(al0, bh[f], acc[0][nf], 0, 0, 0);
            acc[1][nf] = __builtin_amdgcn_mfma_f32_16x16x32_bf16(ah1, bh[f], acc[1][nf], 0, 0, 0);
            acc[1][nf] = __builtin_amdgcn_mfma_f32_16x16x32_bf16(ah1, bl[f], acc[1][nf], 0, 0, 0);
            acc[1][nf] = __builtin_amdgcn_mfma_f32_16x16x32_bf16(al1, bh[f], acc[1][nf], 0, 0, 0);
          }
      }
    }
    if (kc < 7) writestage(buf ^ 1);
  }

  float* pb = part + (size_t)ks * 2097152;
#pragma unroll
  for (int a = 0; a < 2; ++a)
#pragma unroll
    for (int yr = 0; yr < 4; ++yr)
#pragma unroll
      for (int h = 0; h < 2; ++h) {
        f32x4 c = acc[a][yr * 2 + h];
        size_t base = ((size_t)(b * 512 + obase + a * 16 + lu * 4)) * 1024
                      + (y0 + yr) * 32 + h * 16 + lr;
#pragma unroll
        for (int r = 0; r < 4; ++r) pb[base + (size_t)r * 1024] = c[r];
      }
}

// ---------------- emb merge: sum 4 parts + bias, write feat_nc (transposing)
__global__ void k_embmerge_nc(const float* __restrict__ part, const float* __restrict__ bias,
                              float* __restrict__ featnc) {
  __shared__ float T[64][65];
  int bid = blockIdx.x;
  int n0 = (bid & 15) << 6; bid >>= 4;
  int c0 = (bid & 3) << 6; int bg = bid >> 2;
  int cl = threadIdx.x & 63, rw = threadIdx.x >> 6;
#pragma unroll
  for (int i = 0; i < 16; ++i) {
    int crow = i * 4 + rw;
    size_t idx = ((size_t)(bg * 256 + c0 + crow)) * 1024 + n0 + cl;
    float v = part[idx] + part[2097152 + idx] + part[4194304 + idx] + part[6291456 + idx];
    T[crow][cl] = v + bias[(bg & 1) * 256 + c0 + crow];
  }
  __syncthreads();
#pragma unroll
  for (int i = 0; i < 16; ++i) {
    int nrow = i * 4 + rw;
    featnc[((size_t)(bg * 1024 + n0 + nrow)) * 256 + c0 + cl] = T[cl][nrow];
  }
}

// sampled_nc [8][1024][256] viewed as [4b][512ch] -> B-frags (KC=16)
__global__ void k_prep_s2frag(const float* __restrict__ snc,
                              ushort* __restrict__ dh, ushort* __restrict__ dl) {
  int gtid = blockIdx.x * 256 + threadIdx.x;
  int l = gtid & 63; int fr = gtid >> 6;
  int kc = fr & 15; int nt = (fr >> 4) & 63; int b = fr >> 10;
  int lr = l & 15, lu = l >> 4;
  const float* sp = snc + ((size_t)((b * 2 + (kc >> 3)) * 1024 + nt * 16 + lr)) * 256
                    + (kc & 7) * 32 + lu * 8;
  V16u hi, lo;
#pragma unroll
  for (int j = 0; j < 8; ++j) split2(sp[j], hi.u[j], lo.u[j]);
  *(int4*)(dh + (size_t)gtid * 8) = hi.i4;
  *(int4*)(dl + (size_t)gtid * 8) = lo.i4;
}

// ============ generic MFMA GEMM: Y[b][Mtot][1024] = W[Mtot,K] x B + bias ======
__global__ __launch_bounds__(256)
void k_gemm_mfma(const ushort* __restrict__ Ah, const ushort* __restrict__ Al,
                 const ushort* __restrict__ Bh, const ushort* __restrict__ Bl,
                 const float* __restrict__ bias, float* __restrict__ Y,
                 int KC, int MT, int Mtot) {
  int bid = blockIdx.x;
  int ntb = bid & 15; bid >>= 4;
  int mt = bid % MT; int b = bid / MT;
  int tid = threadIdx.x, w = tid >> 6, l = tid & 63, lr = l & 15, lu = l >> 4;
  int wo = w >> 1, wn = w & 1;
  int ot0 = mt * 4 + wo * 2;
  int nf0 = ntb * 4 + wn * 2;
  const bf16x8* pAh = (const bf16x8*)Ah;
  const bf16x8* pAl = (const bf16x8*)Al;
  const bf16x8* pBh = (const bf16x8*)Bh;
  const bf16x8* pBl = (const bf16x8*)Bl;
  f32x4 zero = {0.f, 0.f, 0.f, 0.f};
  f32x4 acc[2][2];
#pragma unroll
  for (int a = 0; a < 2; ++a)
#pragma unroll
    for (int n = 0; n < 2; ++n) acc[a][n] = zero;
  for (int kc = 0; kc < KC; ++kc) {
    bf16x8 a_h[2], a_l[2];
#pragma unroll
    for (int a = 0; a < 2; ++a) {
      size_t idx = ((size_t)(ot0 + a) * KC + kc) * 64 + l;
      a_h[a] = pAh[idx]; a_l[a] = pAl[idx];
    }
#pragma unroll
    for (int n = 0; n < 2; ++n) {
      size_t idx = (((size_t)(b * 64 + nf0 + n)) * KC + kc) * 64 + l;
      bf16x8 b_h = pBh[idx], b_l = pBl[idx];
#pragma unroll
      for (int a = 0; a < 2; ++a) {
        acc[a][n] = __builtin_amdgcn_mfma_f32_16x16x32_bf16(a_h[a], b_h, acc[a][n], 0, 0, 0);
        acc[a][n] = __builtin_amdgcn_mfma_f32_16x16x32_bf16(a_h[a], b_l, acc[a][n], 0, 0, 0);
        acc[a][n] = __builtin_amdgcn_mfma_f32_16x16x32_bf16(a_l[a], b_h, acc[a][n], 0, 0, 0);
      }
    }
  }
#pragma unroll
  for (int a = 0; a < 2; ++a) {
    int o = (ot0 + a) * 16 + lu * 4;
#pragma unroll
    for (int n = 0; n < 2; ++n) {
      int col = (nf0 + n) * 16 + lr;
#pragma unroll
      for (int r = 0; r < 4; ++r)
        Y[((size_t)(b * Mtot + o + r)) * 1024 + col] = acc[a][n][r] + bias[o + r];
    }
  }
}

// ============ transposes ============
__global__ void k_transadd_tm(const float* __restrict__ Pcm, float* __restrict__ Xtm) {
  __shared__ float T[64][65];
  int bid = blockIdx.x; int n0 = (bid & 15) << 6; bid >>= 4;
  int c0 = (bid & 3) << 6; int bg = bid >> 2;
  int cl = threadIdx.x & 63, rw = threadIdx.x >> 6;
#pragma unroll
  for (int i = 0; i < 16; ++i) {
    int crow = i * 4 + rw;
    T[crow][cl] = Pcm[((size_t)(bg * 256 + c0 + crow)) * 1024 + n0 + cl];
  }
  __syncthreads();
#pragma unroll
  for (int i = 0; i < 16; ++i) {
    int nrow = i * 4 + rw;
    Xtm[((size_t)((bg << 10) + n0 + nrow)) * 256 + c0 + cl] += T[cl][nrow];
  }
}

__global__ void k_transadd_nc(const float* __restrict__ Yg, const float* __restrict__ Xtm,
                              float* __restrict__ out_nc) {
  __shared__ float T[64][65];
  int bid = blockIdx.x; int n0 = (bid & 15) << 6; bid >>= 4;
  int c0 = (bid & 3) << 6; int bg = bid >> 2;
  int cl = threadIdx.x & 63, rw = threadIdx.x >> 6;
#pragma unroll
  for (int i = 0; i < 16; ++i) {
    int crow = i * 4 + rw;
    T[crow][cl] = Yg[((size_t)(bg * 256 + c0 + crow)) * 1024 + n0 + cl];
  }
  __syncthreads();
#pragma unroll
  for (int i = 0; i < 16; ++i) {
    int nrow = i * 4 + rw;
    size_t a = ((size_t)((bg << 10) + n0 + nrow)) * 256 + c0 + cl;
    out_nc[a] = T[cl][nrow] + Xtm[a];
  }
}

// ---------------- FUSED ln1 (->xbuf) + n1 (->B-frags), wave per token
__global__ void k_ln1n1(const float* __restrict__ featnc,
                        const float* __restrict__ g1, const float* __restrict__ b1,
                        const float* __restrict__ gn, const float* __restrict__ bn,
                        float* __restrict__ xbuf,
                        ushort* __restrict__ dh, ushort* __restrict__ dl) {
  int token = (blockIdx.x * 256 + threadIdx.x) >> 6;
  int lane = threadIdx.x & 63;
  float4 v4 = *reinterpret_cast<const float4*>(featnc + (size_t)token * 256 + lane * 4);
  float s  = v4.x + v4.y + v4.z + v4.w;
  float s2 = v4.x * v4.x + v4.y * v4.y + v4.z * v4.z + v4.w * v4.w;
#pragma unroll
  for (int off = 32; off; off >>= 1) { s += __shfl_xor(s, off); s2 += __shfl_xor(s2, off); }
  float mean = s * (1.f / 256.f);
  float rstd = rsqrtf(s2 * (1.f / 256.f) - mean * mean + 1e-5f);
  float4 g4 = *reinterpret_cast<const float4*>(g1 + lane * 4);
  float4 b4 = *reinterpret_cast<const float4*>(b1 + lane * 4);
  float4 x;
  x.x = (v4.x - mean) * rstd * g4.x + b4.x;
  x.y = (v4.y - mean) * rstd * g4.y + b4.y;
  x.z = (v4.z - mean) * rstd * g4.z + b4.z;
  x.w = (v4.w - mean) * rstd * g4.w + b4.w;
  *reinterpret_cast<float4*>(xbuf + (size_t)token * 256 + lane * 4) = x;
  float t  = x.x + x.y + x.z + x.w;
  float t2 = x.x * x.x + x.y * x.y + x.z * x.z + x.w * x.w;
#pragma unroll
  for (int off = 32; off; off >>= 1) { t += __shfl_xor(t, off); t2 += __shfl_xor(t2, off); }
  float mean2 = t * (1.f / 256.f);
  float rstd2 = rsqrtf(t2 * (1.f / 256.f) - mean2 * mean2 + 1e-6f);
  float4 gg = *reinterpret_cast<const float4*>(gn + lane * 4);
  float4 bb = *reinterpret_cast<const float4*>(bn + lane * 4);
  ushort4 h4, l4;
  split2((x.x - mean2) * rstd2 * gg.x + bb.x, h4.x, l4.x);
  split2((x.y - mean2) * rstd2 * gg.y + bb.y, h4.y, l4.y);
  split2((x.z - mean2) * rstd2 * gg.z + bb.z, h4.z, l4.z);
  split2((x.w - mean2) * rstd2 * gg.w + bb.w, h4.w, l4.w);
  int bg = token >> 10, nt = (token >> 4) & 63, lr = token & 15;
  int kc = lane >> 3, lu_f = (lane >> 1) & 3, j0 = (lane & 1) * 4;
  size_t base = ((((size_t)(bg * 64 + nt)) * 8 + kc) * 64 + lu_f * 16 + lr) * 8 + j0;
  *(ushort4*)(dh + base) = h4;
  *(ushort4*)(dl + base) = l4;
}

// ---------------- token-major LN -> B-frags (KC=8), standalone (n2)
__global__ void k_ln_frag(const float* __restrict__ xin, const float* __restrict__ g_,
                          const float* __restrict__ b_, ushort* __restrict__ dh,
                          ushort* __restrict__ dl, float eps) {
  int token = (blockIdx.x * 256 + threadIdx.x) >> 6;
  int lane = threadIdx.x & 63;
  float4 v4 = *reinterpret_cast<const float4*>(xin + (size_t)token * 256 + lane * 4);
  float s  = v4.x + v4.y + v4.z + v4.w;
  float s2 = v4.x * v4.x + v4.y * v4.y + v4.z * v4.z + v4.w * v4.w;
#pragma unroll
  for (int off = 32; off; off >>= 1) { s += __shfl_xor(s, off); s2 += __shfl_xor(s2, off); }
  float mean = s * (1.f / 256.f);
  float rstd = rsqrtf(s2 * (1.f / 256.f) - mean * mean + eps);
  float4 g4 = *reinterpret_cast<const float4*>(g_ + lane * 4);
  float4 b4 = *reinterpret_cast<const float4*>(b_ + lane * 4);
  ushort4 h4, l4;
  split2((v4.x - mean) * rstd * g4.x + b4.x, h4.x, l4.x);
  split2((v4.y - mean) * rstd * g4.y + b4.y, h4.y, l4.y);
  split2((v4.z - mean) * rstd * g4.z + b4.z, h4.z, l4.z);
  split2((v4.w - mean) * rstd * g4.w + b4.w, h4.w, l4.w);
  int bg = token >> 10, nt = (token >> 4) & 63, lr = token & 15;
  int kc = lane >> 3, lu_f = (lane >> 1) & 3, j0 = (lane & 1) * 4;
  size_t base = ((((size_t)(bg * 64 + nt)) * 8 + kc) * 64 + lu_f * 16 + lr) * 8 + j0;
  *(ushort4*)(dh + base) = h4;
  *(ushort4*)(dl + base) = l4;
}

// ============ fused mb-attn input preps, reading combined qkv_cm [8][768][1024]
__global__ void k_prep_mb3(const float* __restrict__ qkv,
                           ushort* __restrict__ mQh, ushort* __restrict__ mQl,
                           ushort* __restrict__ mKh, ushort* __restrict__ mKl,
                           ushort* __restrict__ mVh, ushort* __restrict__ mVl) {
  int bid = blockIdx.x, tid = threadIdx.x;
  int sect = bid >> 10, lb = bid & 1023;
  int gtid = lb * 256 + tid;
  int l = gtid & 63; int fr = gtid >> 6;
  int lr = l & 15, lu = l >> 4;
  V16u hi, lo;
  if (sect < 2) {
    int nt = fr & 63; int bgh = fr >> 6;
    int bg = bgh >> 3, hh = bgh & 7;
    int rowbase = sect == 0 ? 0 : 256;
    float scale = sect == 0 ? 0.17677669529663689f : 1.f;
    const float* sp = qkv + ((size_t)(bg * 768 + rowbase + hh * 32 + lu * 8)) * 1024
                      + nt * 16 + lr;
#pragma unroll
    for (int j = 0; j < 8; ++j) split2(sp[(size_t)j * 1024] * scale, hi.u[j], lo.u[j]);
    ushort* dh = sect == 0 ? mQh : mKh;
    ushort* dl = sect == 0 ? mQl : mKl;
    *(int4*)(dh + (size_t)gtid * 8) = hi.i4;
    *(int4*)(dl + (size_t)gtid * 8) = lo.i4;
  } else {
    int kc = fr & 31; int et = (fr >> 5) & 1; int bgh = fr >> 6;
    int bg = bgh >> 3, hh = bgh & 7;
    const float* sp = qkv + ((size_t)(bg * 768 + 512 + hh * 32 + et * 16 + lr)) * 1024
                      + kc * 32 + lu * 8;
#pragma unroll
    for (int j = 0; j < 8; ++j) split2(sp[j], hi.u[j], lo.u[j]);
    *(int4*)(mVh + (size_t)gtid * 8) = hi.i4;
    *(int4*)(mVl + (size_t)gtid * 8) = lo.i4;
  }
}

// ============ fused main-attn input preps, reading qbuf + combined kv2 [4][1024][1024]
__global__ void k_prep_main3(const float* __restrict__ qb, const float* __restrict__ kv2,
                             ushort* __restrict__ aQh, ushort* __restrict__ aQl,
                             ushort* __restrict__ aKh, ushort* __restrict__ aKl,
                             ushort* __restrict__ aVh, ushort* __restrict__ aVl) {
  int bid = blockIdx.x, tid = threadIdx.x;
  int sect = bid >> 10, lb = bid & 1023;
  int gtid = lb * 256 + tid;
  int l = gtid & 63, tile = gtid >> 6;
  int lr = l & 15, lu = l >> 4;
  V16u hi, lo;
  if (sect < 2) {
    int dc = tile & 1, nt = (tile >> 1) & 63, bh = tile >> 7;
    int b = bh >> 3, h = bh & 7;
    const float* sp;
    float scale;
    if (sect == 0) {
      scale = 0.125f;
      sp = qb + ((size_t)(b * 512 + h * 64 + dc * 32 + lu * 8)) * 1024 + nt * 16 + lr;
    } else {
      scale = 1.f;
      sp = kv2 + ((size_t)(b * 1024 + h * 64 + dc * 32 + lu * 8)) * 1024 + nt * 16 + lr;
    }
#pragma unroll
    for (int j = 0; j < 8; ++j) split2(sp[(size_t)j * 1024] * scale, hi.u[j], lo.u[j]);
    ushort* dh = sect == 0 ? aQh : aKh;
    ushort* dl = sect == 0 ? aQl : aKl;
    *(int4*)(dh + (size_t)gtid * 8) = hi.i4;
    *(int4*)(dl + (size_t)gtid * 8) = lo.i4;
  } else {
    int kc = tile & 31, et = (tile >> 5) & 3, bh = tile >> 7;
    int b = bh >> 3, h = bh & 7;
    const float* sp = kv2 + ((size_t)(b * 1024 + 512 + h * 64 + et * 16 + lr)) * 1024
                      + kc * 32 + lu * 8;
#pragma unroll
    for (int j = 0; j < 8; ++j) split2(sp[j], hi.u[j], lo.u[j]);
    *(int4*)(aVh + (size_t)gtid * 8) = hi.i4;
    *(int4*)(aVl + (size_t)gtid * 8) = lo.i4;
  }
}

// ============ MitBlock attention (MFMA, d=32), epilogue -> B-frags ============
__global__ __launch_bounds__(256)
void k_mbattn_mfma(const ushort* __restrict__ Qh, const ushort* __restrict__ Ql,
                   const ushort* __restrict__ Kh, const ushort* __restrict__ Kl,
                   const ushort* __restrict__ Vh, const ushort* __restrict__ Vl,
                   ushort* __restrict__ ofh, ushort* __restrict__ ofl) {
  int qb = blockIdx.x & 15, bgh = blockIdx.x >> 4;
  int tid = threadIdx.x, w = tid >> 6, l = tid & 63, lr = l & 15, lu = l >> 4;
  int qt = qb * 4 + w;
  bf16x8 qh = ((const bf16x8*)Qh)[(size_t)(bgh * 64 + qt) * 64 + l];
  bf16x8 ql = ((const bf16x8*)Ql)[(size_t)(bgh * 64 + qt) * 64 + l];
  __shared__ ushort Ph[4][16][72];
  __shared__ ushort Pl[4][16][72];
  f32x4 zero = {0.f, 0.f, 0.f, 0.f};
  f32x4 oacc[2] = {zero, zero};
  float den = 0.f;
  for (int kb = 0; kb < 16; ++kb) {
#pragma unroll
    for (int kt4 = 0; kt4 < 4; ++kt4) {
      int kt = kb * 4 + kt4;
      bf16x8 kh = ((const bf16x8*)Kh)[(size_t)(bgh * 64 + kt) * 64 + l];
      bf16x8 kl = ((const bf16x8*)Kl)[(size_t)(bgh * 64 + kt) * 64 + l];
      f32x4 s = zero;
      s = __builtin_amdgcn_mfma_f32_16x16x32_bf16(kh, qh, s, 0, 0, 0);
      s = __builtin_amdgcn_mfma_f32_16x16x32_bf16(kh, ql, s, 0, 0, 0);
      s = __builtin_amdgcn_mfma_f32_16x16x32_bf16(kl, qh, s, 0, 0, 0);
      uint2 uh, ul;
      {
        float p0 = __expf(s[0]), p1 = __expf(s[1]), p2 = __expf(s[2]), p3 = __expf(s[3]);
        den += (p0 + p1) + (p2 + p3);
        ushort h0, l0, h1, l1, h2, l2, h3, l3;
        split2(p0, h0, l0); split2(p1, h1, l1); split2(p2, h2, l2); split2(p3, h3, l3);
        uh.x = (unsigned)h0 | ((unsigned)h1 << 16); uh.y = (unsigned)h2 | ((unsigned)h3 << 16);
        ul.x = (unsigned)l0 | ((unsigned)l1 << 16); ul.y = (unsigned)l2 | ((unsigned)l3 << 16);
      }
      *(uint2*)&Ph[w][lr][kt4 * 16 + lu * 4] = uh;
      *(uint2*)&Pl[w][lr][kt4 * 16 + lu * 4] = ul;
    }
#pragma unroll
    for (int kc2 = 0; kc2 < 2; ++kc2) {
      int kc = kb * 2 + kc2;
      bf16x8 bph = *(const bf16x8*)&Ph[w][lr][kc2 * 32 + lu * 8];
      bf16x8 bpl = *(const bf16x8*)&Pl[w][lr][kc2 * 32 + lu * 8];
#pragma unroll
      for (int et = 0; et < 2; ++et) {
        bf16x8 vh = ((const bf16x8*)Vh)[(size_t)((bgh * 2 + et) * 32 + kc) * 64 + l];
        bf16x8 vl = ((const bf16x8*)Vl)[(size_t)((bgh * 2 + et) * 32 + kc) * 64 + l];
        oacc[et] = __builtin_amdgcn_mfma_f32_16x16x32_bf16(vh, bph, oacc[et], 0, 0, 0);
        oacc[et] = __builtin_amdgcn_mfma_f32_16x16x32_bf16(vh, bpl, oacc[et], 0, 0, 0);
        oacc[et] = __builtin_amdgcn_mfma_f32_16x16x32_bf16(vl, bph, oacc[et], 0, 0, 0);
      }
    }
  }
  den += __shfl_xor(den, 16);
  den += __shfl_xor(den, 32);
  float inv = 1.f / den;
  int bg = bgh >> 3, hh = bgh & 7;
#pragma unroll
  for (int et = 0; et < 2; ++et) {
    ushort4 h4, l4;
    split2(oacc[et][0] * inv, h4.x, l4.x); split2(oacc[et][1] * inv, h4.y, l4.y);
    split2(oacc[et][2] * inv, h4.z, l4.z); split2(oacc[et][3] * inv, h4.w, l4.w);
    int lu_f = et * 2 + (lu >> 1), j0 = (lu & 1) * 4;
    size_t base = ((((size_t)(bg * 64 + qt)) * 8 + hh) * 64 + lu_f * 16 + lr) * 8 + j0;
    *(ushort4*)(ofh + base) = h4;
    *(ushort4*)(ofl + base) = l4;
  }
}

// ============ main attention (MFMA, d=64), epilogue -> B-frags (KC=16) ========
__global__ __launch_bounds__(256)
void k_mainattn_mfma(const ushort* __restrict__ Qh, const ushort* __restrict__ Ql,
                     const ushort* __restrict__ Kh, const ushort* __restrict__ Kl,
                     const ushort* __restrict__ Vh, const ushort* __restrict__ Vl,
                     ushort* __restrict__ anfh, ushort* __restrict__ anfl) {
  int qb = blockIdx.x & 15, bh = blockIdx.x >> 4;
  int tid = threadIdx.x, w = tid >> 6, l = tid & 63, lr = l & 15, lu = l >> 4;
  int qt = qb * 4 + w;
  bf16x8 qh[2], ql[2];
#pragma unroll
  for (int dc = 0; dc < 2; ++dc) {
    qh[dc] = ((const bf16x8*)Qh)[(size_t)((bh * 64 + qt) * 2 + dc) * 64 + l];
    ql[dc] = ((const bf16x8*)Ql)[(size_t)((bh * 64 + qt) * 2 + dc) * 64 + l];
  }
  __shared__ ushort Ph[4][16][72];
  __shared__ ushort Pl[4][16][72];
  f32x4 zero = {0.f, 0.f, 0.f, 0.f};
  f32x4 oacc[4] = {zero, zero, zero, zero};
  float den = 0.f;
  for (int kb = 0; kb < 16; ++kb) {
#pragma unroll
    for (int kt4 = 0; kt4 < 4; ++kt4) {
      int kt = kb * 4 + kt4;
      f32x4 s = zero;
#pragma unroll
      for (int dc = 0; dc < 2; ++dc) {
        bf16x8 kh = ((const bf16x8*)Kh)[(size_t)((bh * 64 + kt) * 2 + dc) * 64 + l];
        bf16x8 kl = ((const bf16x8*)Kl)[(size_t)((bh * 64 + kt) * 2 + dc) * 64 + l];
        s = __builtin_amdgcn_mfma_f32_16x16x32_bf16(kh, qh[dc], s, 0, 0, 0);
        s = __builtin_amdgcn_mfma_f32_16x16x32_bf16(kh, ql[dc], s, 0, 0, 0);
        s = __builtin_amdgcn_mfma_f32_16x16x32_bf16(kl, qh[dc], s, 0, 0, 0);
      }
      uint2 uh, ul;
      {
        float p0 = __expf(s[0]), p1 = __expf(s[1]), p2 = __expf(s[2]), p3 = __expf(s[3]);
        den += (p0 + p1) + (p2 + p3);
        ushort h0, l0, h1, l1, h2, l2, h3, l3;
        split2(p0, h0, l0); split2(p1, h1, l1); split2(p2, h2, l2); split2(p3, h3, l3);
        uh.x = (unsigned)h0 | ((unsigned)h1 << 16); uh.y = (unsigned)h2 | ((unsigned)h3 << 16);
        ul.x = (unsigned)l0 | ((unsigned)l1 << 16); ul.y = (unsigned)l2 | ((unsigned)l3 << 16);
      }
      *(uint2*)&Ph[w][lr][kt4 * 16 + lu * 4] = uh;
      *(uint2*)&Pl[w][lr][kt4 * 16 + lu * 4] = ul;
    }
#pragma unroll
    for (int kc2 = 0; kc2 < 2; ++kc2) {
      int kc = kb * 2 + kc2;
      bf16x8 bph = *(const bf16x8*)&Ph[w][lr][kc2 * 32 + lu * 8];
      bf16x8 bpl = *(const bf16x8*)&Pl[w][lr][kc2 * 32 + lu * 8];
#pragma unroll
      for (int et = 0; et < 4; ++et) {
        bf16x8 vh = ((const bf16x8*)Vh)[(size_t)((bh * 4 + et) * 32 + kc) * 64 + l];
        bf16x8 vl = ((const bf16x8*)Vl)[(size_t)((bh * 4 + et) * 32 + kc) * 64 + l];
        oacc[et] = __builtin_amdgcn_mfma_f32_16x16x32_bf16(vh, bph, oacc[et], 0, 0, 0);
        oacc[et] = __builtin_amdgcn_mfma_f32_16x16x32_bf16(vh, bpl, oacc[et], 0, 0, 0);
        oacc[et] = __builtin_amdgcn_mfma_f32_16x16x32_bf16(vl, bph, oacc[et], 0, 0, 0);
      }
    }
  }
  den += __shfl_xor(den, 16);
  den += __shfl_xor(den, 32);
  float inv = 1.f / den;
  int b = bh >> 3, h = bh & 7;
#pragma unroll
  for (int et = 0; et < 4; ++et) {
    ushort4 h4, l4;
    split2(oacc[et][0] * inv, h4.x, l4.x); split2(oacc[et][1] * inv, h4.y, l4.y);
    split2(oacc[et][2] * inv, h4.z, l4.z); split2(oacc[et][3] * inv, h4.w, l4.w);
    int kc = h * 2 + (et >> 1);
    int lu_f = (et & 1) * 2 + (lu >> 1), j0 = (lu & 1) * 4;
    size_t base = ((((size_t)(b * 64 + qt)) * 16 + kc) * 64 + lu_f * 16 + lr) * 8 + j0;
    *(ushort4*)(anfh + base) = h4;
    *(ushort4*)(anfl + base) = l4;
  }
}

// ---------------- depthwise 3x3 + bias + exact GELU (cm)
__global__ void k_dw3(const float* __restrict__ X, const float* __restrict__ w,
                      const float* __restrict__ bias, float* __restrict__ Y) {
  int idx = blockIdx.x * 256 + threadIdx.x;
  int x = idx & 31, y = (idx >> 5) & 31, ch = (idx >> 10) & 1023, bg = idx >> 20;
  const float* src = X + (size_t)((bg << 10) + ch) * HW;
  const float* wr = w + ch * 9;
  float acc = bias[ch];
#pragma unroll
  for (int ky = 0; ky < 3; ++ky) {
    int yy = y + ky - 1;
    if ((unsigned)yy < 32u) {
      const float* row = src + yy * 32;
#pragma unroll
      for (int kx = 0; kx < 3; ++kx) {
        int xx = x + kx - 1;
        if ((unsigned)xx < 32u) acc += row[xx] * wr[ky * 3 + kx];
      }
    }
  }
  Y[(size_t)((bg << 10) + ch) * HW + y * 32 + x] = gelu_exact(acc);
}

// ---------------- depthwise 9x9 pad 4 on nc layout
__global__ void k_dw9_nc(const float* __restrict__ Xnc, const float* __restrict__ wt9,
                         const float* __restrict__ bias, float* __restrict__ Ync) {
  int bid = blockIdx.x;
  int pt = bid & 127; int bg = bid >> 7;
  int tid = threadIdx.x;
  int y = pt >> 2, x0 = (pt & 3) * 8;
  float acc[8];
  float bs = bias[tid];
#pragma unroll
  for (int p = 0; p < 8; ++p) acc[p] = bs;
  const float* src = Xnc + (size_t)(bg << 10) * 256;
  for (int ky = 0; ky < 9; ++ky) {
    int yy = y + ky - 4;
    if ((unsigned)yy >= 32u) continue;
#pragma unroll
    for (int kx = 0; kx < 9; ++kx) {
      float wv = wt9[(ky * 9 + kx) * 256 + tid];
#pragma unroll
      for (int p = 0; p < 8; ++p) {
        int xx = x0 + p + kx - 4;
        if ((unsigned)xx < 32u)
          acc[p] += src[(size_t)(yy * 32 + xx) * 256 + tid] * wv;
      }
    }
  }
#pragma unroll
  for (int p = 0; p < 8; ++p)
    Ync[((size_t)((bg << 10) + y * 32 + x0 + p)) * 256 + tid] = acc[p];
}

// ---------------- co tail on nc layout: wave per token
__global__ void k_cotail_nc(const float* __restrict__ Xnc, const float* __restrict__ lnw,
                            const float* __restrict__ lnb, const float* __restrict__ w2,
                            float* __restrict__ pos) {
  int token = (blockIdx.x * 256 + threadIdx.x) >> 6;
  int lane = threadIdx.x & 63;
  float4 v4 = *(const float4*)(Xnc + (size_t)token * 256 + lane * 4);
  float s = v4.x + v4.y + v4.z + v4.w;
  float s2 = v4.x * v4.x + v4.y * v4.y + v4.z * v4.z + v4.w * v4.w;
#pragma unroll
  for (int off = 32; off; off >>= 1) { s += __shfl_xor(s, off); s2 += __shfl_xor(s2, off); }
  float mean = s * (1.f / 256.f);
  float rstd = rsqrtf(s2 * (1.f / 256.f) - mean * mean + 1e-5f);
  float4 g4 = *(const float4*)(lnw + lane * 4);
  float4 b4 = *(const float4*)(lnb + lane * 4);
  float4 wa = *(const float4*)(w2 + lane * 4);
  float4 wb = *(const float4*)(w2 + 256 + lane * 4);
  float ge0 = gelu_exact((v4.x - mean) * rstd * g4.x + b4.x);
  float ge1 = gelu_exact((v4.y - mean) * rstd * g4.y + b4.y);
  float ge2 = gelu_exact((v4.z - mean) * rstd * g4.z + b4.z);
  float ge3 = gelu_exact((v4.w - mean) * rstd * g4.w + b4.w);
  float o0 = ge0 * wa.x + ge1 * wa.y + ge2 * wa.z + ge3 * wa.w;
  float o1 = ge0 * wb.x + ge1 * wb.y + ge2 * wb.z + ge3 * wb.w;
#pragma unroll
  for (int off = 32; off; off >>= 1) { o0 += __shfl_xor(o0, off); o1 += __shfl_xor(o1, off); }
  if (lane == 0) {
    float offy = tanhf(o0) * (2.f / 32.f);
    float offx = tanhf(o1) * (2.f / 32.f);
    int n = token & 1023;
    int ky = n >> 5, kx = n & 31;
    float refy = ((ky + 0.5f) * (1.f / 32.f)) * 2.f - 1.f;
    float refx = ((kx + 0.5f) * (1.f / 32.f)) * 2.f - 1.f;
    pos[token * 2] = offx + refx;
    pos[token * 2 + 1] = offy + refy;
  }
}

// ---------------- bilinear grid sample on nc layout -> sampled_nc
__global__ void k_gsample_nc(const float* __restrict__ Xnc, const float* __restrict__ pos,
                             float* __restrict__ out_nc) {
  int bid = blockIdx.x;
  int nch = bid & 15; int bg = bid >> 4;
  int tid = threadIdx.x;
  __shared__ int sI[4][64];
  __shared__ float sW[4][64];
  if (tid < 64) {
    int j = nch * 64 + tid;
    float gx = pos[((bg << 10) + j) * 2];
    float gy = pos[((bg << 10) + j) * 2 + 1];
    float fx = (gx + 1.f) * 0.5f * 31.f;
    float fy = (gy + 1.f) * 0.5f * 31.f;
    float x0f = floorf(fx), y0f = floorf(fy);
    int x0 = (int)x0f, y0 = (int)y0f;
    float wx1 = fx - x0f, wx0 = 1.f - wx1;
    float wy1 = fy - y0f, wy0 = 1.f - wy1;
    bool vx0 = (x0 >= 0) & (x0 <= 31);
    bool vx1 = (x0 + 1 >= 0) & (x0 + 1 <= 31);
    bool vy0 = (y0 >= 0) & (y0 <= 31);
    bool vy1 = (y0 + 1 >= 0) & (y0 + 1 <= 31);
    int cx0 = min(max(x0, 0), 31), cx1 = min(max(x0 + 1, 0), 31);
    int cy0 = min(max(y0, 0), 31), cy1 = min(max(y0 + 1, 0), 31);
    sW[0][tid] = wx0 * wy0 * ((vx0 && vy0) ? 1.f : 0.f);
    sW[1][tid] = wx1 * wy0 * ((vx1 && vy0) ? 1.f : 0.f);
    sW[2][tid] = wx0 * wy1 * ((vx0 && vy1) ? 1.f : 0.f);
    sW[3][tid] = wx1 * wy1 * ((vx1 && vy1) ? 1.f : 0.f);
    sI[0][tid] = cy0 * 32 + cx0; sI[1][tid] = cy0 * 32 + cx1;
    sI[2][tid] = cy1 * 32 + cx0; sI[3][tid] = cy1 * 32 + cx1;
  }
  __syncthreads();
  const float* src = Xnc + (size_t)(bg << 10) * 256;
  for (int n = 0; n < 64; ++n) {
    float acc = src[(size_t)sI[0][n] * 256 + tid] * sW[0][n]
              + src[(size_t)sI[1][n] * 256 + tid] * sW[1][n]
              + src[(size_t)sI[2][n] * 256 + tid] * sW[2][n]
              + src[(size_t)sI[3][n] * 256 + tid] * sW[3][n];
    out_nc[((size_t)((bg << 10) + nch * 64 + n)) * 256 + tid] = acc;
  }
}

// ---------------------------------------------------------------------------
extern "C" void kernel_launch(void* const* d_in, const int* in_sizes, int n_in,
                              void* d_out, int out_size, void* d_ws, size_t ws_size,
                              hipStream_t stream) {
  const float* tgt    = (const float*)d_in[0];
  const float* refp   = (const float*)d_in[1];
  const float* emb_w  = (const float*)d_in[2];
  const float* emb_b  = (const float*)d_in[3];
  const float* q_w    = (const float*)d_in[4];
  const float* q_b    = (const float*)d_in[5];
  const float* k_w    = (const float*)d_in[6];
  const float* k_b    = (const float*)d_in[7];
  const float* v_w    = (const float*)d_in[8];
  const float* v_b    = (const float*)d_in[9];
  const float* out_w  = (const float*)d_in[10];
  const float* out_b  = (const float*)d_in[11];
  const float* ln1_w  = (const float*)d_in[12];
  const float* ln1_b  = (const float*)d_in[13];
  const float* n1_w   = (const float*)d_in[14];
  const float* n1_b   = (const float*)d_in[15];
  const float* mbq_w  = (const float*)d_in[16];
  const float* mbq_b  = (const float*)d_in[17];
  const float* mbkv_w = (const float*)d_in[18];
  const float* mbkv_b = (const float*)d_in[19];
  const float* mbp_w  = (const float*)d_in[20];
  const float* mbp_b  = (const float*)d_in[21];
  const float* n2_w   = (const float*)d_in[22];
  const float* n2_b   = (const float*)d_in[23];
  const float* fc1_w  = (const float*)d_in[24];
  const float* fc1_b  = (const float*)d_in[25];
  const float* dw3_w  = (const float*)d_in[26];
  const float* dw3_b  = (const float*)d_in[27];
  const float* fc2_w  = (const float*)d_in[28];
  const float* fc2_b  = (const float*)d_in[29];
  const float* dw9_w  = (const float*)d_in[30];
  const float* dw9_b  = (const float*)d_in[31];
  const float* coln_w = (const float*)d_in[32];
  const float* coln_b = (const float*)d_in[33];
  const float* coout_w= (const float*)d_in[34];

  float* ws = (float*)d_ws;
  float* slabA = ws + 0;
  float* qbuf  = ws + 2097152;
  float* xbuf  = ws + 4194304;
  float* slabD = ws + 6291456;
  float* slabE = ws + 8388608;
  float* slabF = ws + 10485760;
  float* slabG = ws + 14680064;
  float* slabH = ws + 23068672;
  float* featnc= ws + 31457280;
  float* posb  = ws + 35389440;
  float* wt9   = ws + 35405824;     // 20736 floats
  float* biasmb= ws + 35426560;     // 768
  float* biaskv= ws + 35427328;     // 1024 (ends 35428352)

  ushort* XtH = (ushort*)(ws + 4194304);
  ushort* XtL = XtH + 4734976;
  ushort* WtEH = (ushort*)slabG;
  ushort* WtEL = WtEH + 4718592;
  float* part = slabH;
  ushort* tgtfh = (ushort*)slabF;
  ushort* tgtfl = tgtfh + 2097152;

  // weight frags (slab J, ws+33554432, ushort; total 3670016 ushorts)
  ushort* J = (ushort*)(ws + 33554432);
  ushort* wfq_h   = J;                ushort* wfq_l   = J + 262144;
  ushort* wfkv_h  = J + 524288;       ushort* wfkv_l  = J + 1048576;   // 524288 each
  ushort* wfo_h   = J + 1572864;      ushort* wfo_l   = J + 1835008;
  ushort* wfmqkv_h= J + 2097152;      ushort* wfmqkv_l= J + 2293760;   // 196608 each
  ushort* wfmp_h  = J + 2490368;      ushort* wfmp_l  = J + 2555904;
  ushort* wff1_h  = J + 2621440;      ushort* wff1_l  = J + 2883584;
  ushort* wff2_h  = J + 3145728;      ushort* wff2_l  = J + 3407872;

  // phase pointers
  ushort* hfh = (ushort*)slabG;     ushort* hfl = hfh + 2097152;   // n1 frags
  float* qkv_cm = slabE;            // [8][768][1024] = slabE+slabF exactly
  ushort* mQh = (ushort*)slabG;     ushort* mQl = mQh + 2097152;
  ushort* mKh = mQh + 4194304;      ushort* mKl = mQh + 6291456;
  ushort* mVh = mQh + 8388608;      ushort* mVl = mQh + 10485760;
  ushort* ofh = (ushort*)slabF;     ushort* ofl = ofh + 2097152;   // mb out frags
  float* P_cm = slabD;
  ushort* h2fh = (ushort*)slabF;    ushort* h2fl = h2fh + 2097152;
  float* m_cm = slabG;
  float* mi_cm = slabH;
  ushort* mifh = (ushort*)slabG;    ushort* mifl = mifh + 8388608; // slabG exact fit
  float* ygemm = slabD;
  float* offin = slabA;
  float* offdwnc = slabE;
  float* samplednc = slabA;
  ushort* sfh = (ushort*)slabF;     ushort* sfl = sfh + 2097152;
  float* kv2 = slabD;               // [4][1024][1024] = slabD+slabE exactly
  ushort* aQh = (ushort*)slabG;     ushort* aQl = aQh + 2097152;
  ushort* aKh = aQh + 4194304;      ushort* aKl = aQh + 6291456;
  ushort* aVh = aQh + 8388608;      ushort* aVl = aQh + 10485760;
  ushort* anfh = (ushort*)slabH;    ushort* anfl = anfh + 2097152;

  // --- step 0: mega-prep + tgt frags ---
  k_prep_all<<<5344, 256, 0, stream>>>(
      emb_w, tgt, refp, q_w, k_w, v_w, out_w, mbq_w, mbkv_w, mbp_w, fc1_w, fc2_w,
      dw9_w, mbq_b, mbkv_b, k_b, v_b,
      WtEH, WtEL, XtH, XtL,
      wfq_h, wfq_l, wfkv_h, wfkv_l, wfo_h, wfo_l, wfmqkv_h, wfmqkv_l,
      wfmp_h, wfmp_l, wff1_h, wff1_l, wff2_h, wff2_l,
      wt9, biasmb, biaskv);
  k_prep_cm2frag<<<1024, 256, 0, stream>>>(tgt, 512, 16, tgtfh, tgtfl);
  // --- step 1: emb conv + merge ---
  k_emb_mfma<<<512, 256, 0, stream>>>(XtH, XtL, WtEH, WtEL, part);
  k_embmerge_nc<<<512, 256, 0, stream>>>(part, emb_b, featnc);
  // --- step 2: q proj ---
  k_gemm_mfma<<<512, 256, 0, stream>>>(wfq_h, wfq_l, tgtfh, tgtfl, q_b, qbuf, 16, 8, 512);
  // --- step 3+4: fused ln1 -> xbuf + n1 -> frags ---
  k_ln1n1<<<2048, 256, 0, stream>>>(featnc, ln1_w, ln1_b, n1_w, n1_b, xbuf, hfh, hfl);
  // --- step 5: combined mbq+mbkv GEMM (O=768) -> qkv_cm ---
  k_gemm_mfma<<<1536, 256, 0, stream>>>(wfmqkv_h, wfmqkv_l, hfh, hfl, biasmb, qkv_cm, 8, 12, 768);
  // --- step 6: mb attention ---
  k_prep_mb3<<<3072, 256, 0, stream>>>(qkv_cm, mQh, mQl, mKh, mKl, mVh, mVl);
  k_mbattn_mfma<<<1024, 256, 0, stream>>>(mQh, mQl, mKh, mKl, mVh, mVl, ofh, ofl);
  // --- step 7: mbproj + residual ---
  k_gemm_mfma<<<512, 256, 0, stream>>>(wfmp_h, wfmp_l, ofh, ofl, mbp_b, P_cm, 8, 4, 256);
  k_transadd_tm<<<512, 256, 0, stream>>>(P_cm, xbuf);
  // --- step 8: n2 -> h2 frags ---
  k_ln_frag<<<2048, 256, 0, stream>>>(xbuf, n2_w, n2_b, h2fh, h2fl, 1e-6f);
  // --- step 9: fc1 ---
  k_gemm_mfma<<<2048, 256, 0, stream>>>(wff1_h, wff1_l, h2fh, h2fl, fc1_b, m_cm, 8, 16, 1024);
  // --- step 10: dw3 + gelu; mi frags ---
  k_dw3<<<32768, 256, 0, stream>>>(m_cm, dw3_w, dw3_b, mi_cm);
  k_prep_cm2frag<<<4096, 256, 0, stream>>>(mi_cm, 1024, 32, mifh, mifl);
  // --- step 11: fc2 + residual -> offin nc ---
  k_gemm_mfma<<<512, 256, 0, stream>>>(wff2_h, wff2_l, mifh, mifl, fc2_b, ygemm, 32, 4, 256);
  k_transadd_nc<<<512, 256, 0, stream>>>(ygemm, xbuf, offin);
  // --- step 12: dw9 ---
  k_dw9_nc<<<1024, 256, 0, stream>>>(offin, wt9, dw9_b, offdwnc);
  // --- step 13: cotail ---
  k_cotail_nc<<<2048, 256, 0, stream>>>(offdwnc, coln_w, coln_b, coout_w, posb);
  // --- step 14: grid sample + frags ---
  k_gsample_nc<<<128, 256, 0, stream>>>(featnc, posb, samplednc);
  k_prep_s2frag<<<1024, 256, 0, stream>>>(samplednc, sfh, sfl);
  // --- step 15: combined k+v proj (O=1024) -> kv2 ---
  k_gemm_mfma<<<1024, 256, 0, stream>>>(wfkv_h, wfkv_l, sfh, sfl, biaskv, kv2, 16, 16, 1024);
  // --- step 16: main attention ---
  k_prep_main3<<<3072, 256, 0, stream>>>(qbuf, kv2, aQh, aQl, aKh, aKl, aVh, aVl);
  k_mainattn_mfma<<<512, 256, 0, stream>>>(aQh, aQl, aKh, aKl, aVh, aVl, anfh, anfl);
  // --- step 17: out proj -> d_out ---
  k_gemm_mfma<<<512, 256, 0, stream>>>(wfo_h, wfo_l, anfh, anfl, out_b, (float*)d_out, 16, 8, 512);
}

// Round 11
// 575.701 us; speedup vs baseline: 5.3054x; 1.0275x over previous
//
#include <hip/hip_runtime.h>
#include <math.h>

// ---------------------------------------------------------------------------
// DAttention forward. R11: attention-frag GEMM epilogues — mqkv / qproj / kv
// GEMMs write MFMA frags directly (Q-scales folded into weights+bias at prep);
// k_prep_mb3 and k_prep_main3 deleted.
// Dims: B=4, C=512, H=W=32, G=2, gc=256, BG=8, heads=8, hc=64, mh=8, mhd=32.
// ---------------------------------------------------------------------------

static constexpr int HW = 1024;

typedef __attribute__((ext_vector_type(8))) short bf16x8;
typedef __attribute__((ext_vector_type(4))) float f32x4;

union V16u { int4 i4; ushort u[8]; };

__device__ __forceinline__ float gelu_exact(float v) {
  return 0.5f * v * (1.0f + erff(v * 0.7071067811865475f));
}

__device__ __forceinline__ ushort bf16_rne(float v) {
  unsigned int b = __float_as_uint(v);
  return (ushort)((b + 0x7fffu + ((b >> 16) & 1u)) >> 16);
}

__device__ __forceinline__ void split2(float v, ushort& h, ushort& l) {
  h = bf16_rne(v);
  l = bf16_rne(v - __uint_as_float(((unsigned int)h) << 16));
}

// ---------------- weight frag body (shared); scale folded into weights
__device__ __forceinline__ void wfrag_body(const float* __restrict__ W, int K, int KC,
                                           ushort* __restrict__ dh, ushort* __restrict__ dl,
                                           int gtid, float scale) {
  int l = gtid & 63; int fr = gtid >> 6;
  int kc = fr % KC; int ot = fr / KC;
  int lr = l & 15, lu = l >> 4;
  const float* sp = W + (size_t)(ot * 16 + lr) * K + kc * 32 + lu * 8;
  V16u hi, lo;
#pragma unroll
  for (int j = 0; j < 8; ++j) split2(sp[j] * scale, hi.u[j], lo.u[j]);
  *(int4*)(dh + (size_t)gtid * 8) = hi.i4;
  *(int4*)(dl + (size_t)gtid * 8) = lo.i4;
}

// ---------------- MEGA-PREP: emb w/x prep + all weight frags + wt9 + biases.
__global__ void k_prep_all(
    const float* __restrict__ emb_w, const float* __restrict__ tgt,
    const float* __restrict__ refp,
    const float* q_w, const float* k_w, const float* v_w, const float* o_w,
    const float* mq_w, const float* mkv_w, const float* mp_w,
    const float* f1_w, const float* f2_w, const float* dw9_w,
    const float* q_b, const float* mq_b, const float* mkv_b,
    const float* k_b, const float* v_b,
    ushort* __restrict__ WtEH, ushort* __restrict__ WtEL,
    ushort* __restrict__ XtH, ushort* __restrict__ XtL,
    ushort* qh, ushort* ql, ushort* kvh, ushort* kvl,
    ushort* oh, ushort* ol, ushort* mqkvh, ushort* mqkvl,
    ushort* mph, ushort* mpl, ushort* f1h, ushort* f1l, ushort* f2h, ushort* f2l,
    float* wt9, float* biasmb, float* biaskv, float* biasq) {
  int bid = blockIdx.x, tid = threadIdx.x;
  if (bid < 2048) {                      // emb weights -> [9][512][1024] hi/lo
    int idx = bid * 256 + tid;
    int o = idx >> 10, ci = idx & 1023;
    const float* src = emb_w + (size_t)idx * 9;
#pragma unroll
    for (int t = 0; t < 9; ++t) {
      ushort h, l; split2(src[t], h, l);
      size_t oo = ((size_t)(t * 512 + o)) * 1024 + ci;
      WtEH[oo] = h; WtEL[oo] = l;
    }
  } else if (bid < 4360) {               // inputs -> [4][34][34][1024] hi/lo
    int idx = (bid - 2048) * 256 + tid;
    int xp = idx % 34; int r = idx / 34;
    int g8 = r & 127; r >>= 7;
    int yp = r % 34; int b = r / 34;
    int y = yp - 1, x = xp - 1;
    bool valid = (unsigned)y < 32u && (unsigned)x < 32u;
    V16u hi, lo;
    const float* in = (g8 < 64) ? (tgt + ((size_t)(b * 512 + g8 * 8)) * HW)
                                : (refp + ((size_t)(b * 512 + (g8 - 64) * 8)) * HW);
#pragma unroll
    for (int j = 0; j < 8; ++j) {
      float v = valid ? in[(size_t)j * HW + y * 32 + x] : 0.f;
      split2(v, hi.u[j], lo.u[j]);
    }
    size_t oo = (((size_t)(b * 34 + yp)) * 34 + xp) * 1024 + g8 * 8;
    *(int4*)(XtH + oo) = hi.i4;
    *(int4*)(XtL + oo) = lo.i4;
  }
  // q weights pre-scaled by 0.125 (main-attn softmax scale)
  else if (bid < 4488) wfrag_body(q_w, 512, 16, qh, ql, (bid - 4360) * 256 + tid, 0.125f);
  else if (bid < 4616) wfrag_body(k_w, 512, 16, kvh, kvl, (bid - 4488) * 256 + tid, 1.f);
  // v frags at +262144 (one 512x512 frag set)
  else if (bid < 4744) wfrag_body(v_w, 512, 16, kvh + 262144, kvl + 262144,
                                  (bid - 4616) * 256 + tid, 1.f);
  else if (bid < 4872) wfrag_body(o_w, 512, 16, oh, ol, (bid - 4744) * 256 + tid, 1.f);
  // mq pre-scaled by 32^-0.5
  else if (bid < 4904) wfrag_body(mq_w, 256, 8, mqkvh, mqkvl, (bid - 4872) * 256 + tid,
                                  0.17677669529663689f);
  // mkv frags at +65536 (one 256x256 frag set)
  else if (bid < 4968) wfrag_body(mkv_w, 256, 8, mqkvh + 65536, mqkvl + 65536,
                                  (bid - 4904) * 256 + tid, 1.f);
  else if (bid < 5000) wfrag_body(mp_w, 256, 8, mph, mpl, (bid - 4968) * 256 + tid, 1.f);
  else if (bid < 5128) wfrag_body(f1_w, 256, 8, f1h, f1l, (bid - 5000) * 256 + tid, 1.f);
  else if (bid < 5256) wfrag_body(f2_w, 1024, 32, f2h, f2l, (bid - 5128) * 256 + tid, 1.f);
  else if (bid < 5337) {                 // dw9 weight transpose [81][256]
    int idx = (bid - 5256) * 256 + tid;
    int t = idx >> 8, c = idx & 255;
    wt9[idx] = dw9_w[c * 81 + t];
  } else {                               // biases: 9 blocks x 256 = 2304
    int idx = (bid - 5337) * 256 + tid;
    if (idx < 768)
      biasmb[idx] = idx < 256 ? mq_b[idx] * 0.17677669529663689f : mkv_b[idx - 256];
    else if (idx < 1792) {
      int j = idx - 768;
      biaskv[j] = j < 512 ? k_b[j] : v_b[j - 512];
    } else if (idx < 2304) {
      biasq[idx - 1792] = q_b[idx - 1792] * 0.125f;
    }
  }
}

// cm activations [b][CH][1024] -> B-frags
__global__ void k_prep_cm2frag(const float* __restrict__ src, int CH, int KC,
                               ushort* __restrict__ dh, ushort* __restrict__ dl) {
  int gtid = blockIdx.x * 256 + threadIdx.x;
  int l = gtid & 63; int fr = gtid >> 6;
  int kc = fr % KC; int r2 = fr / KC; int nt = r2 & 63; int b = r2 >> 6;
  int lr = l & 15, lu = l >> 4;
  const float* sp = src + ((size_t)(b * CH) + kc * 32 + lu * 8) * 1024 + nt * 16 + lr;
  V16u hi, lo;
#pragma unroll
  for (int j = 0; j < 8; ++j) split2(sp[(size_t)j * 1024], hi.u[j], lo.u[j]);
  *(int4*)(dh + (size_t)gtid * 8) = hi.i4;
  *(int4*)(dl + (size_t)gtid * 8) = lo.i4;
}

// ---------------- emb conv via MFMA, split-bf16, 4-way K-split, 4 rows/wave
__global__ __launch_bounds__(256, 2)
void k_emb_mfma(const ushort* __restrict__ Xt_hi, const ushort* __restrict__ Xt_lo,
                const ushort* __restrict__ Wt_hi, const ushort* __restrict__ Wt_lo,
                float* __restrict__ part) {
  int wgid = (blockIdx.x & 7) * 64 + (blockIdx.x >> 3);
  int yt = wgid & 7;  wgid >>= 3;
  int b  = wgid & 3;  wgid >>= 2;
  int mt = wgid & 3;  wgid >>= 2;
  int ks = wgid;
  int tid = threadIdx.x;
  int w = tid >> 6, l = tid & 63;
  int lr = l & 15, lu = l >> 4;
  int y0 = yt * 4;
  int obase = mt * 128 + w * 32;

  __shared__ int4 LsH[2][816];
  __shared__ int4 LsL[2][816];

  int4 gh[4], gl[4];
  int kc0 = ks * 8;

  auto loadstage = [&](int kcg) {
#pragma unroll
    for (int i = 0; i < 4; ++i) {
      int s = tid + 256 * i;
      if (s < 816) {
        int px = s >> 2;
        int u = (s & 3) ^ ((px >> 1) & 3);
        size_t off = ((size_t)(b * 34 + y0) * 34 + px) * 1024 + kcg * 32 + u * 8;
        gh[i] = *(const int4*)(Xt_hi + off);
        gl[i] = *(const int4*)(Xt_lo + off);
      }
    }
  };
  auto writestage = [&](int buf) {
#pragma unroll
    for (int i = 0; i < 4; ++i) {
      int s = tid + 256 * i;
      if (s < 816) { LsH[buf][s] = gh[i]; LsL[buf][s] = gl[i]; }
    }
  };

  f32x4 zero = {0.f, 0.f, 0.f, 0.f};
  f32x4 acc[2][8];
#pragma unroll
  for (int a = 0; a < 2; ++a)
#pragma unroll
    for (int n = 0; n < 8; ++n) acc[a][n] = zero;

  loadstage(kc0);
  writestage(0);

  for (int kc = 0; kc < 8; ++kc) {
    int buf = kc & 1;
    __syncthreads();
    if (kc < 7) loadstage(kc0 + kc + 1);
    int kcg = kc0 + kc;
    const bf16x8* BH = (const bf16x8*)&LsH[buf][0];
    const bf16x8* BL = (const bf16x8*)&LsL[buf][0];
#pragma unroll
    for (int kx = 0; kx < 3; ++kx) {
      bf16x8 bh[12], bl[12];
#pragma unroll
      for (int f = 0; f < 12; ++f) {
        int px = (f >> 1) * 34 + (f & 1) * 16 + kx + lr;
        int idx = px * 4 + (lu ^ ((px >> 1) & 3));
        bh[f] = BH[idx]; bl[f] = BL[idx];
      }
#pragma unroll
      for (int ky = 0; ky < 3; ++ky) {
        int tap = ky * 3 + kx;
        size_t wo = (((size_t)(tap * 512 + obase + lr)) * 1024) + kcg * 32 + lu * 8;
        bf16x8 ah0 = *(const bf16x8*)(Wt_hi + wo);
        bf16x8 al0 = *(const bf16x8*)(Wt_lo + wo);
        bf16x8 ah1 = *(const bf16x8*)(Wt_hi + wo + 16 * 1024);
        bf16x8 al1 = *(const bf16x8*)(Wt_lo + wo + 16 * 1024);
#pragma unroll
        for (int yr = 0; yr < 4; ++yr)
#pragma unroll
          for (int h = 0; h < 2; ++h) {
            int f = (yr + ky) * 2 + h;
            int nf = yr * 2 + h;
            acc[0][nf] = __builtin_amdgcn_mfma_f32_16x16x32_bf16(ah0, bh[f], acc[0][nf], 0, 0, 0);
            acc[0][nf] = __builtin_amdgcn_mfma_f32_16x16x32_bf16(ah0, bl[f], acc[0][nf], 0, 0, 0);
            acc[0][nf] = __builtin_amdgcn_mfma_f32_16x16x32_bf16(al0, bh[f], acc[0][nf], 0, 0, 0);
            acc[1][nf] = __builtin_amdgcn_mfma_f32_16x16x32_bf16(ah1, bh[f], acc[1][nf], 0, 0, 0);
            acc[1][nf] = __builtin_amdgcn_mfma_f32_16x16x32_bf16(ah1, bl[f], acc[1][nf], 0, 0, 0);
            acc[1][nf] = __builtin_amdgcn_mfma_f32_16x16x32_bf16(al1, bh[f], acc[1][nf], 0, 0, 0);
          }
      }
    }
    if (kc < 7) writestage(buf ^ 1);
  }

  float* pb = part + (size_t)ks * 2097152;
#pragma unroll
  for (int a = 0; a < 2; ++a)
#pragma unroll
    for (int yr = 0; yr < 4; ++yr)
#pragma unroll
      for (int h = 0; h < 2; ++h) {
        f32x4 c = acc[a][yr * 2 + h];
        size_t base = ((size_t)(b * 512 + obase + a * 16 + lu * 4)) * 1024
                      + (y0 + yr) * 32 + h * 16 + lr;
#pragma unroll
        for (int r = 0; r < 4; ++r) pb[base + (size_t)r * 1024] = c[r];
      }
}

// ---------------- emb merge: sum 4 parts + bias, write feat_nc (transposing)
__global__ void k_embmerge_nc(const float* __restrict__ part, const float* __restrict__ bias,
                              float* __restrict__ featnc) {
  __shared__ float T[64][65];
  int bid = blockIdx.x;
  int n0 = (bid & 15) << 6; bid >>= 4;
  int c0 = (bid & 3) << 6; int bg = bid >> 2;
  int cl = threadIdx.x & 63, rw = threadIdx.x >> 6;
#pragma unroll
  for (int i = 0; i < 16; ++i) {
    int crow = i * 4 + rw;
    size_t idx = ((size_t)(bg * 256 + c0 + crow)) * 1024 + n0 + cl;
    float v = part[idx] + part[2097152 + idx] + part[4194304 + idx] + part[6291456 + idx];
    T[crow][cl] = v + bias[(bg & 1) * 256 + c0 + crow];
  }
  __syncthreads();
#pragma unroll
  for (int i = 0; i < 16; ++i) {
    int nrow = i * 4 + rw;
    featnc[((size_t)(bg * 1024 + n0 + nrow)) * 256 + c0 + cl] = T[cl][nrow];
  }
}

// sampled_nc [8][1024][256] viewed as [4b][512ch] -> B-frags (KC=16)
__global__ void k_prep_s2frag(const float* __restrict__ snc,
                              ushort* __restrict__ dh, ushort* __restrict__ dl) {
  int gtid = blockIdx.x * 256 + threadIdx.x;
  int l = gtid & 63; int fr = gtid >> 6;
  int kc = fr & 15; int nt = (fr >> 4) & 63; int b = fr >> 10;
  int lr = l & 15, lu = l >> 4;
  const float* sp = snc + ((size_t)((b * 2 + (kc >> 3)) * 1024 + nt * 16 + lr)) * 256
                    + (kc & 7) * 32 + lu * 8;
  V16u hi, lo;
#pragma unroll
  for (int j = 0; j < 8; ++j) split2(sp[j], hi.u[j], lo.u[j]);
  *(int4*)(dh + (size_t)gtid * 8) = hi.i4;
  *(int4*)(dl + (size_t)gtid * 8) = lo.i4;
}

// ============ generic MFMA GEMM (cm fp32 output) ============
__global__ __launch_bounds__(256)
void k_gemm_mfma(const ushort* __restrict__ Ah, const ushort* __restrict__ Al,
                 const ushort* __restrict__ Bh, const ushort* __restrict__ Bl,
                 const float* __restrict__ bias, float* __restrict__ Y,
                 int KC, int MT, int Mtot) {
  int bid = blockIdx.x;
  int ntb = bid & 15; bid >>= 4;
  int mt = bid % MT; int b = bid / MT;
  int tid = threadIdx.x, w = tid >> 6, l = tid & 63, lr = l & 15, lu = l >> 4;
  int wo = w >> 1, wn = w & 1;
  int ot0 = mt * 4 + wo * 2;
  int nf0 = ntb * 4 + wn * 2;
  const bf16x8* pAh = (const bf16x8*)Ah;
  const bf16x8* pAl = (const bf16x8*)Al;
  const bf16x8* pBh = (const bf16x8*)Bh;
  const bf16x8* pBl = (const bf16x8*)Bl;
  f32x4 zero = {0.f, 0.f, 0.f, 0.f};
  f32x4 acc[2][2];
#pragma unroll
  for (int a = 0; a < 2; ++a)
#pragma unroll
    for (int n = 0; n < 2; ++n) acc[a][n] = zero;
  for (int kc = 0; kc < KC; ++kc) {
    bf16x8 a_h[2], a_l[2];
#pragma unroll
    for (int a = 0; a < 2; ++a) {
      size_t idx = ((size_t)(ot0 + a) * KC + kc) * 64 + l;
      a_h[a] = pAh[idx]; a_l[a] = pAl[idx];
    }
#pragma unroll
    for (int n = 0; n < 2; ++n) {
      size_t idx = (((size_t)(b * 64 + nf0 + n)) * KC + kc) * 64 + l;
      bf16x8 b_h = pBh[idx], b_l = pBl[idx];
#pragma unroll
      for (int a = 0; a < 2; ++a) {
        acc[a][n] = __builtin_amdgcn_mfma_f32_16x16x32_bf16(a_h[a], b_h, acc[a][n], 0, 0, 0);
        acc[a][n] = __builtin_amdgcn_mfma_f32_16x16x32_bf16(a_h[a], b_l, acc[a][n], 0, 0, 0);
        acc[a][n] = __builtin_amdgcn_mfma_f32_16x16x32_bf16(a_l[a], b_h, acc[a][n], 0, 0, 0);
      }
    }
  }
#pragma unroll
  for (int a = 0; a < 2; ++a) {
    int o = (ot0 + a) * 16 + lu * 4;
#pragma unroll
    for (int n = 0; n < 2; ++n) {
      int col = (nf0 + n) * 16 + lr;
#pragma unroll
      for (int r = 0; r < 4; ++r)
        Y[((size_t)(b * Mtot + o + r)) * 1024 + col] = acc[a][n][r] + bias[o + r];
    }
  }
}

// ============ GEMM with mb-attention frag epilogue (d=32 heads) ============
// Mtot=768: o<256 -> Q frags, <512 -> K frags, else V^T frags. grid = 8*12*16.
__global__ __launch_bounds__(256)
void k_gemm_frag_mb(const ushort* __restrict__ Ah, const ushort* __restrict__ Al,
                    const ushort* __restrict__ Bh, const ushort* __restrict__ Bl,
                    const float* __restrict__ bias,
                    ushort* __restrict__ mQh, ushort* __restrict__ mQl,
                    ushort* __restrict__ mKh, ushort* __restrict__ mKl,
                    ushort* __restrict__ mVh, ushort* __restrict__ mVl) {
  int bid = blockIdx.x;
  int ntb = bid & 15; bid >>= 4;
  int mt = bid % 12; int b = bid / 12;
  int tid = threadIdx.x, w = tid >> 6, l = tid & 63, lr = l & 15, lu = l >> 4;
  int wo = w >> 1, wn = w & 1;
  int ot0 = mt * 4 + wo * 2;
  int nf0 = ntb * 4 + wn * 2;
  const bf16x8* pAh = (const bf16x8*)Ah;
  const bf16x8* pAl = (const bf16x8*)Al;
  const bf16x8* pBh = (const bf16x8*)Bh;
  const bf16x8* pBl = (const bf16x8*)Bl;
  f32x4 zero = {0.f, 0.f, 0.f, 0.f};
  f32x4 acc[2][2];
#pragma unroll
  for (int a = 0; a < 2; ++a)
#pragma unroll
    for (int n = 0; n < 2; ++n) acc[a][n] = zero;
  for (int kc = 0; kc < 8; ++kc) {
    bf16x8 a_h[2], a_l[2];
#pragma unroll
    for (int a = 0; a < 2; ++a) {
      size_t idx = ((size_t)(ot0 + a) * 8 + kc) * 64 + l;
      a_h[a] = pAh[idx]; a_l[a] = pAl[idx];
    }
#pragma unroll
    for (int n = 0; n < 2; ++n) {
      size_t idx = (((size_t)(b * 64 + nf0 + n)) * 8 + kc) * 64 + l;
      bf16x8 b_h = pBh[idx], b_l = pBl[idx];
#pragma unroll
      for (int a = 0; a < 2; ++a) {
        acc[a][n] = __builtin_amdgcn_mfma_f32_16x16x32_bf16(a_h[a], b_h, acc[a][n], 0, 0, 0);
        acc[a][n] = __builtin_amdgcn_mfma_f32_16x16x32_bf16(a_h[a], b_l, acc[a][n], 0, 0, 0);
        acc[a][n] = __builtin_amdgcn_mfma_f32_16x16x32_bf16(a_l[a], b_h, acc[a][n], 0, 0, 0);
      }
    }
  }
#pragma unroll
  for (int a = 0; a < 2; ++a) {
    int o0 = (ot0 + a) * 16 + lu * 4;   // 4 consecutive channels
#pragma unroll
    for (int n = 0; n < 2; ++n) {
      int col = (nf0 + n) * 16 + lr;    // token
      ushort4 h4, l4;
      split2(acc[a][n][0] + bias[o0 + 0], h4.x, l4.x);
      split2(acc[a][n][1] + bias[o0 + 1], h4.y, l4.y);
      split2(acc[a][n][2] + bias[o0 + 2], h4.z, l4.z);
      split2(acc[a][n][3] + bias[o0 + 3], h4.w, l4.w);
      if (o0 < 512) {                   // Q or K: lane lr=token, lu*8+j=d
        int oo = o0 & 255;
        int hh = oo >> 5, d = oo & 31;
        ushort* dh = o0 < 256 ? mQh : mKh;
        ushort* dl = o0 < 256 ? mQl : mKl;
        size_t base = ((((size_t)(b * 8 + hh) * 64 + (col >> 4)) * 64)
                       + ((d >> 3) << 4) + (col & 15)) * 8 + (d & 7);
        *(ushort4*)(dh + base) = h4;
        *(ushort4*)(dl + base) = l4;
      } else {                          // V^T: lane lr=channel, lu*8+j=token
        int oo = o0 - 512;
        int hh = oo >> 5, d = oo & 31;
        int et = d >> 4;
        size_t eb = ((((size_t)((b * 8 + hh) * 2 + et)) * 32 + (col >> 5)) * 64
                     + ((col >> 3) & 3) * 16 + (d & 15)) * 8 + (col & 7);
        mVh[eb] = h4.x; mVh[eb + 8] = h4.y; mVh[eb + 16] = h4.z; mVh[eb + 24] = h4.w;
        mVl[eb] = l4.x; mVl[eb + 8] = l4.y; mVl[eb + 16] = l4.z; mVl[eb + 24] = l4.w;
      }
    }
  }
}

// ============ GEMM with main-attention frag epilogue (d=64 heads) ============
// o < vbase -> QK-style frags (fh/fl); o >= vbase -> V^T frags (vfh/vfl).
__global__ __launch_bounds__(256)
void k_gemm_frag_main(const ushort* __restrict__ Ah, const ushort* __restrict__ Al,
                      const ushort* __restrict__ Bh, const ushort* __restrict__ Bl,
                      const float* __restrict__ bias,
                      ushort* __restrict__ fh, ushort* __restrict__ fl,
                      ushort* __restrict__ vfh, ushort* __restrict__ vfl,
                      int vbase, int KC, int MT) {
  int bid = blockIdx.x;
  int ntb = bid & 15; bid >>= 4;
  int mt = bid % MT; int b = bid / MT;
  int tid = threadIdx.x, w = tid >> 6, l = tid & 63, lr = l & 15, lu = l >> 4;
  int wo = w >> 1, wn = w & 1;
  int ot0 = mt * 4 + wo * 2;
  int nf0 = ntb * 4 + wn * 2;
  const bf16x8* pAh = (const bf16x8*)Ah;
  const bf16x8* pAl = (const bf16x8*)Al;
  const bf16x8* pBh = (const bf16x8*)Bh;
  const bf16x8* pBl = (const bf16x8*)Bl;
  f32x4 zero = {0.f, 0.f, 0.f, 0.f};
  f32x4 acc[2][2];
#pragma unroll
  for (int a = 0; a < 2; ++a)
#pragma unroll
    for (int n = 0; n < 2; ++n) acc[a][n] = zero;
  for (int kc = 0; kc < KC; ++kc) {
    bf16x8 a_h[2], a_l[2];
#pragma unroll
    for (int a = 0; a < 2; ++a) {
      size_t idx = ((size_t)(ot0 + a) * KC + kc) * 64 + l;
      a_h[a] = pAh[idx]; a_l[a] = pAl[idx];
    }
#pragma unroll
    for (int n = 0; n < 2; ++n) {
      size_t idx = (((size_t)(b * 64 + nf0 + n)) * KC + kc) * 64 + l;
      bf16x8 b_h = pBh[idx], b_l = pBl[idx];
#pragma unroll
      for (int a = 0; a < 2; ++a) {
        acc[a][n] = __builtin_amdgcn_mfma_f32_16x16x32_bf16(a_h[a], b_h, acc[a][n], 0, 0, 0);
        acc[a][n] = __builtin_amdgcn_mfma_f32_16x16x32_bf16(a_h[a], b_l, acc[a][n], 0, 0, 0);
        acc[a][n] = __builtin_amdgcn_mfma_f32_16x16x32_bf16(a_l[a], b_h, acc[a][n], 0, 0, 0);
      }
    }
  }
#pragma unroll
  for (int a = 0; a < 2; ++a) {
    int o0 = (ot0 + a) * 16 + lu * 4;
#pragma unroll
    for (int n = 0; n < 2; ++n) {
      int col = (nf0 + n) * 16 + lr;
      ushort4 h4, l4;
      split2(acc[a][n][0] + bias[o0 + 0], h4.x, l4.x);
      split2(acc[a][n][1] + bias[o0 + 1], h4.y, l4.y);
      split2(acc[a][n][2] + bias[o0 + 2], h4.z, l4.z);
      split2(acc[a][n][3] + bias[o0 + 3], h4.w, l4.w);
      if (o0 < vbase) {                 // QK frag: [((b*8+h)*64+nt)*2+dc]
        int h = o0 >> 6, d = o0 & 63;
        int dc = d >> 5;
        size_t base = (((((size_t)(b * 8 + h) * 64 + (col >> 4)) * 2 + dc) * 64)
                       + (((d & 31) >> 3) << 4) + (col & 15)) * 8 + (d & 7);
        *(ushort4*)(fh + base) = h4;
        *(ushort4*)(fl + base) = l4;
      } else {                          // V^T frag: [((b*8+h)*4+et)*32+kc]
        int oo = o0 - vbase;
        int h = oo >> 6, d = oo & 63;
        int et = d >> 4;
        size_t eb = ((((size_t)((b * 8 + h) * 4 + et)) * 32 + (col >> 5)) * 64
                     + ((col >> 3) & 3) * 16 + (d & 15)) * 8 + (col & 7);
        vfh[eb] = h4.x; vfh[eb + 8] = h4.y; vfh[eb + 16] = h4.z; vfh[eb + 24] = h4.w;
        vfl[eb] = l4.x; vfl[eb + 8] = l4.y; vfl[eb + 16] = l4.z; vfl[eb + 24] = l4.w;
      }
    }
  }
}

// ============ transposes ============
__global__ void k_transadd_tm(const float* __restrict__ Pcm, float* __restrict__ Xtm) {
  __shared__ float T[64][65];
  int bid = blockIdx.x; int n0 = (bid & 15) << 6; bid >>= 4;
  int c0 = (bid & 3) << 6; int bg = bid >> 2;
  int cl = threadIdx.x & 63, rw = threadIdx.x >> 6;
#pragma unroll
  for (int i = 0; i < 16; ++i) {
    int crow = i * 4 + rw;
    T[crow][cl] = Pcm[((size_t)(bg * 256 + c0 + crow)) * 1024 + n0 + cl];
  }
  __syncthreads();
#pragma unroll
  for (int i = 0; i < 16; ++i) {
    int nrow = i * 4 + rw;
    Xtm[((size_t)((bg << 10) + n0 + nrow)) * 256 + c0 + cl] += T[cl][nrow];
  }
}

__global__ void k_transadd_nc(const float* __restrict__ Yg, const float* __restrict__ Xtm,
                              float* __restrict__ out_nc) {
  __shared__ float T[64][65];
  int bid = blockIdx.x; int n0 = (bid & 15) << 6; bid >>= 4;
  int c0 = (bid & 3) << 6; int bg = bid >> 2;
  int cl = threadIdx.x & 63, rw = threadIdx.x >> 6;
#pragma unroll
  for (int i = 0; i < 16; ++i) {
    int crow = i * 4 + rw;
    T[crow][cl] = Yg[((size_t)(bg * 256 + c0 + crow)) * 1024 + n0 + cl];
  }
  __syncthreads();
#pragma unroll
  for (int i = 0; i < 16; ++i) {
    int nrow = i * 4 + rw;
    size_t a = ((size_t)((bg << 10) + n0 + nrow)) * 256 + c0 + cl;
    out_nc[a] = T[cl][nrow] + Xtm[a];
  }
}

// ---------------- FUSED ln1 (->xbuf) + n1 (->B-frags), wave per token
__global__ void k_ln1n1(const float* __restrict__ featnc,
                        const float* __restrict__ g1, const float* __restrict__ b1,
                        const float* __restrict__ gn, const float* __restrict__ bn,
                        float* __restrict__ xbuf,
                        ushort* __restrict__ dh, ushort* __restrict__ dl) {
  int token = (blockIdx.x * 256 + threadIdx.x) >> 6;
  int lane = threadIdx.x & 63;
  float4 v4 = *reinterpret_cast<const float4*>(featnc + (size_t)token * 256 + lane * 4);
  float s  = v4.x + v4.y + v4.z + v4.w;
  float s2 = v4.x * v4.x + v4.y * v4.y + v4.z * v4.z + v4.w * v4.w;
#pragma unroll
  for (int off = 32; off; off >>= 1) { s += __shfl_xor(s, off); s2 += __shfl_xor(s2, off); }
  float mean = s * (1.f / 256.f);
  float rstd = rsqrtf(s2 * (1.f / 256.f) - mean * mean + 1e-5f);
  float4 g4 = *reinterpret_cast<const float4*>(g1 + lane * 4);
  float4 b4 = *reinterpret_cast<const float4*>(b1 + lane * 4);
  float4 x;
  x.x = (v4.x - mean) * rstd * g4.x + b4.x;
  x.y = (v4.y - mean) * rstd * g4.y + b4.y;
  x.z = (v4.z - mean) * rstd * g4.z + b4.z;
  x.w = (v4.w - mean) * rstd * g4.w + b4.w;
  *reinterpret_cast<float4*>(xbuf + (size_t)token * 256 + lane * 4) = x;
  float t  = x.x + x.y + x.z + x.w;
  float t2 = x.x * x.x + x.y * x.y + x.z * x.z + x.w * x.w;
#pragma unroll
  for (int off = 32; off; off >>= 1) { t += __shfl_xor(t, off); t2 += __shfl_xor(t2, off); }
  float mean2 = t * (1.f / 256.f);
  float rstd2 = rsqrtf(t2 * (1.f / 256.f) - mean2 * mean2 + 1e-6f);
  float4 gg = *reinterpret_cast<const float4*>(gn + lane * 4);
  float4 bb = *reinterpret_cast<const float4*>(bn + lane * 4);
  ushort4 h4, l4;
  split2((x.x - mean2) * rstd2 * gg.x + bb.x, h4.x, l4.x);
  split2((x.y - mean2) * rstd2 * gg.y + bb.y, h4.y, l4.y);
  split2((x.z - mean2) * rstd2 * gg.z + bb.z, h4.z, l4.z);
  split2((x.w - mean2) * rstd2 * gg.w + bb.w, h4.w, l4.w);
  int bg = token >> 10, nt = (token >> 4) & 63, lr = token & 15;
  int kc = lane >> 3, lu_f = (lane >> 1) & 3, j0 = (lane & 1) * 4;
  size_t base = ((((size_t)(bg * 64 + nt)) * 8 + kc) * 64 + lu_f * 16 + lr) * 8 + j0;
  *(ushort4*)(dh + base) = h4;
  *(ushort4*)(dl + base) = l4;
}

// ---------------- token-major LN -> B-frags (KC=8), standalone (n2)
__global__ void k_ln_frag(const float* __restrict__ xin, const float* __restrict__ g_,
                          const float* __restrict__ b_, ushort* __restrict__ dh,
                          ushort* __restrict__ dl, float eps) {
  int token = (blockIdx.x * 256 + threadIdx.x) >> 6;
  int lane = threadIdx.x & 63;
  float4 v4 = *reinterpret_cast<const float4*>(xin + (size_t)token * 256 + lane * 4);
  float s  = v4.x + v4.y + v4.z + v4.w;
  float s2 = v4.x * v4.x + v4.y * v4.y + v4.z * v4.z + v4.w * v4.w;
#pragma unroll
  for (int off = 32; off; off >>= 1) { s += __shfl_xor(s, off); s2 += __shfl_xor(s2, off); }
  float mean = s * (1.f / 256.f);
  float rstd = rsqrtf(s2 * (1.f / 256.f) - mean * mean + eps);
  float4 g4 = *reinterpret_cast<const float4*>(g_ + lane * 4);
  float4 b4 = *reinterpret_cast<const float4*>(b_ + lane * 4);
  ushort4 h4, l4;
  split2((v4.x - mean) * rstd * g4.x + b4.x, h4.x, l4.x);
  split2((v4.y - mean) * rstd * g4.y + b4.y, h4.y, l4.y);
  split2((v4.z - mean) * rstd * g4.z + b4.z, h4.z, l4.z);
  split2((v4.w - mean) * rstd * g4.w + b4.w, h4.w, l4.w);
  int bg = token >> 10, nt = (token >> 4) & 63, lr = token & 15;
  int kc = lane >> 3, lu_f = (lane >> 1) & 3, j0 = (lane & 1) * 4;
  size_t base = ((((size_t)(bg * 64 + nt)) * 8 + kc) * 64 + lu_f * 16 + lr) * 8 + j0;
  *(ushort4*)(dh + base) = h4;
  *(ushort4*)(dl + base) = l4;
}

// ============ MitBlock attention (MFMA, d=32), epilogue -> B-frags ============
__global__ __launch_bounds__(256)
void k_mbattn_mfma(const ushort* __restrict__ Qh, const ushort* __restrict__ Ql,
                   const ushort* __restrict__ Kh, const ushort* __restrict__ Kl,
                   const ushort* __restrict__ Vh, const ushort* __restrict__ Vl,
                   ushort* __restrict__ ofh, ushort* __restrict__ ofl) {
  int qb = blockIdx.x & 15, bgh = blockIdx.x >> 4;
  int tid = threadIdx.x, w = tid >> 6, l = tid & 63, lr = l & 15, lu = l >> 4;
  int qt = qb * 4 + w;
  bf16x8 qh = ((const bf16x8*)Qh)[(size_t)(bgh * 64 + qt) * 64 + l];
  bf16x8 ql = ((const bf16x8*)Ql)[(size_t)(bgh * 64 + qt) * 64 + l];
  __shared__ ushort Ph[4][16][72];
  __shared__ ushort Pl[4][16][72];
  f32x4 zero = {0.f, 0.f, 0.f, 0.f};
  f32x4 oacc[2] = {zero, zero};
  float den = 0.f;
  for (int kb = 0; kb < 16; ++kb) {
#pragma unroll
    for (int kt4 = 0; kt4 < 4; ++kt4) {
      int kt = kb * 4 + kt4;
      bf16x8 kh = ((const bf16x8*)Kh)[(size_t)(bgh * 64 + kt) * 64 + l];
      bf16x8 kl = ((const bf16x8*)Kl)[(size_t)(bgh * 64 + kt) * 64 + l];
      f32x4 s = zero;
      s = __builtin_amdgcn_mfma_f32_16x16x32_bf16(kh, qh, s, 0, 0, 0);
      s = __builtin_amdgcn_mfma_f32_16x16x32_bf16(kh, ql, s, 0, 0, 0);
      s = __builtin_amdgcn_mfma_f32_16x16x32_bf16(kl, qh, s, 0, 0, 0);
      uint2 uh, ul;
      {
        float p0 = __expf(s[0]), p1 = __expf(s[1]), p2 = __expf(s[2]), p3 = __expf(s[3]);
        den += (p0 + p1) + (p2 + p3);
        ushort h0, l0, h1, l1, h2, l2, h3, l3;
        split2(p0, h0, l0); split2(p1, h1, l1); split2(p2, h2, l2); split2(p3, h3, l3);
        uh.x = (unsigned)h0 | ((unsigned)h1 << 16); uh.y = (unsigned)h2 | ((unsigned)h3 << 16);
        ul.x = (unsigned)l0 | ((unsigned)l1 << 16); ul.y = (unsigned)l2 | ((unsigned)l3 << 16);
      }
      *(uint2*)&Ph[w][lr][kt4 * 16 + lu * 4] = uh;
      *(uint2*)&Pl[w][lr][kt4 * 16 + lu * 4] = ul;
    }
#pragma unroll
    for (int kc2 = 0; kc2 < 2; ++kc2) {
      int kc = kb * 2 + kc2;
      bf16x8 bph = *(const bf16x8*)&Ph[w][lr][kc2 * 32 + lu * 8];
      bf16x8 bpl = *(const bf16x8*)&Pl[w][lr][kc2 * 32 + lu * 8];
#pragma unroll
      for (int et = 0; et < 2; ++et) {
        bf16x8 vh = ((const bf16x8*)Vh)[(size_t)((bgh * 2 + et) * 32 + kc) * 64 + l];
        bf16x8 vl = ((const bf16x8*)Vl)[(size_t)((bgh * 2 + et) * 32 + kc) * 64 + l];
        oacc[et] = __builtin_amdgcn_mfma_f32_16x16x32_bf16(vh, bph, oacc[et], 0, 0, 0);
        oacc[et] = __builtin_amdgcn_mfma_f32_16x16x32_bf16(vh, bpl, oacc[et], 0, 0, 0);
        oacc[et] = __builtin_amdgcn_mfma_f32_16x16x32_bf16(vl, bph, oacc[et], 0, 0, 0);
      }
    }
  }
  den += __shfl_xor(den, 16);
  den += __shfl_xor(den, 32);
  float inv = 1.f / den;
  int bg = bgh >> 3, hh = bgh & 7;
#pragma unroll
  for (int et = 0; et < 2; ++et) {
    ushort4 h4, l4;
    split2(oacc[et][0] * inv, h4.x, l4.x); split2(oacc[et][1] * inv, h4.y, l4.y);
    split2(oacc[et][2] * inv, h4.z, l4.z); split2(oacc[et][3] * inv, h4.w, l4.w);
    int lu_f = et * 2 + (lu >> 1), j0 = (lu & 1) * 4;
    size_t base = ((((size_t)(bg * 64 + qt)) * 8 + hh) * 64 + lu_f * 16 + lr) * 8 + j0;
    *(ushort4*)(ofh + base) = h4;
    *(ushort4*)(ofl + base) = l4;
  }
}

// ============ main attention (MFMA, d=64), epilogue -> B-frags (KC=16) ========
__global__ __launch_bounds__(256)
void k_mainattn_mfma(const ushort* __restrict__ Qh, const ushort* __restrict__ Ql,
                     const ushort* __restrict__ Kh, const ushort* __restrict__ Kl,
                     const ushort* __restrict__ Vh, const ushort* __restrict__ Vl,
                     ushort* __restrict__ anfh, ushort* __restrict__ anfl) {
  int qb = blockIdx.x & 15, bh = blockIdx.x >> 4;
  int tid = threadIdx.x, w = tid >> 6, l = tid & 63, lr = l & 15, lu = l >> 4;
  int qt = qb * 4 + w;
  bf16x8 qh[2], ql[2];
#pragma unroll
  for (int dc = 0; dc < 2; ++dc) {
    qh[dc] = ((const bf16x8*)Qh)[(size_t)((bh * 64 + qt) * 2 + dc) * 64 + l];
    ql[dc] = ((const bf16x8*)Ql)[(size_t)((bh * 64 + qt) * 2 + dc) * 64 + l];
  }
  __shared__ ushort Ph[4][16][72];
  __shared__ ushort Pl[4][16][72];
  f32x4 zero = {0.f, 0.f, 0.f, 0.f};
  f32x4 oacc[4] = {zero, zero, zero, zero};
  float den = 0.f;
  for (int kb = 0; kb < 16; ++kb) {
#pragma unroll
    for (int kt4 = 0; kt4 < 4; ++kt4) {
      int kt = kb * 4 + kt4;
      f32x4 s = zero;
#pragma unroll
      for (int dc = 0; dc < 2; ++dc) {
        bf16x8 kh = ((const bf16x8*)Kh)[(size_t)((bh * 64 + kt) * 2 + dc) * 64 + l];
        bf16x8 kl = ((const bf16x8*)Kl)[(size_t)((bh * 64 + kt) * 2 + dc) * 64 + l];
        s = __builtin_amdgcn_mfma_f32_16x16x32_bf16(kh, qh[dc], s, 0, 0, 0);
        s = __builtin_amdgcn_mfma_f32_16x16x32_bf16(kh, ql[dc], s, 0, 0, 0);
        s = __builtin_amdgcn_mfma_f32_16x16x32_bf16(kl, qh[dc], s, 0, 0, 0);
      }
      uint2 uh, ul;
      {
        float p0 = __expf(s[0]), p1 = __expf(s[1]), p2 = __expf(s[2]), p3 = __expf(s[3]);
        den += (p0 + p1) + (p2 + p3);
        ushort h0, l0, h1, l1, h2, l2, h3, l3;
        split2(p0, h0, l0); split2(p1, h1, l1); split2(p2, h2, l2); split2(p3, h3, l3);
        uh.x = (unsigned)h0 | ((unsigned)h1 << 16); uh.y = (unsigned)h2 | ((unsigned)h3 << 16);
        ul.x = (unsigned)l0 | ((unsigned)l1 << 16); ul.y = (unsigned)l2 | ((unsigned)l3 << 16);
      }
      *(uint2*)&Ph[w][lr][kt4 * 16 + lu * 4] = uh;
      *(uint2*)&Pl[w][lr][kt4 * 16 + lu * 4] = ul;
    }
#pragma unroll
    for (int kc2 = 0; kc2 < 2; ++kc2) {
      int kc = kb * 2 + kc2;
      bf16x8 bph = *(const bf16x8*)&Ph[w][lr][kc2 * 32 + lu * 8];
      bf16x8 bpl = *(const bf16x8*)&Pl[w][lr][kc2 * 32 + lu * 8];
#pragma unroll
      for (int et = 0; et < 4; ++et) {
        bf16x8 vh = ((const bf16x8*)Vh)[(size_t)((bh * 4 + et) * 32 + kc) * 64 + l];
        bf16x8 vl = ((const bf16x8*)Vl)[(size_t)((bh * 4 + et) * 32 + kc) * 64 + l];
        oacc[et] = __builtin_amdgcn_mfma_f32_16x16x32_bf16(vh, bph, oacc[et], 0, 0, 0);
        oacc[et] = __builtin_amdgcn_mfma_f32_16x16x32_bf16(vh, bpl, oacc[et], 0, 0, 0);
        oacc[et] = __builtin_amdgcn_mfma_f32_16x16x32_bf16(vl, bph, oacc[et], 0, 0, 0);
      }
    }
  }
  den += __shfl_xor(den, 16);
  den += __shfl_xor(den, 32);
  float inv = 1.f / den;
  int b = bh >> 3, h = bh & 7;
#pragma unroll
  for (int et = 0; et < 4; ++et) {
    ushort4 h4, l4;
    split2(oacc[et][0] * inv, h4.x, l4.x); split2(oacc[et][1] * inv, h4.y, l4.y);
    split2(oacc[et][2] * inv, h4.z, l4.z); split2(oacc[et][3] * inv, h4.w, l4.w);
    int kc = h * 2 + (et >> 1);
    int lu_f = (et & 1) * 2 + (lu >> 1), j0 = (lu & 1) * 4;
    size_t base = ((((size_t)(b * 64 + qt)) * 16 + kc) * 64 + lu_f * 16 + lr) * 8 + j0;
    *(ushort4*)(anfh + base) = h4;
    *(ushort4*)(anfl + base) = l4;
  }
}

// ---------------- depthwise 3x3 + bias + exact GELU (cm)
__global__ void k_dw3(const float* __restrict__ X, const float* __restrict__ w,
                      const float* __restrict__ bias, float* __restrict__ Y) {
  int idx = blockIdx.x * 256 + threadIdx.x;
  int x = idx & 31, y = (idx >> 5) & 31, ch = (idx >> 10) & 1023, bg = idx >> 20;
  const float* src = X + (size_t)((bg << 10) + ch) * HW;
  const float* wr = w + ch * 9;
  float acc = bias[ch];
#pragma unroll
  for (int ky = 0; ky < 3; ++ky) {
    int yy = y + ky - 1;
    if ((unsigned)yy < 32u) {
      const float* row = src + yy * 32;
#pragma unroll
      for (int kx = 0; kx < 3; ++kx) {
        int xx = x + kx - 1;
        if ((unsigned)xx < 32u) acc += row[xx] * wr[ky * 3 + kx];
      }
    }
  }
  Y[(size_t)((bg << 10) + ch) * HW + y * 32 + x] = gelu_exact(acc);
}

// ---------------- depthwise 9x9 pad 4 on nc layout
__global__ void k_dw9_nc(const float* __restrict__ Xnc, const float* __restrict__ wt9,
                         const float* __restrict__ bias, float* __restrict__ Ync) {
  int bid = blockIdx.x;
  int pt = bid & 127; int bg = bid >> 7;
  int tid = threadIdx.x;
  int y = pt >> 2, x0 = (pt & 3) * 8;
  float acc[8];
  float bs = bias[tid];
#pragma unroll
  for (int p = 0; p < 8; ++p) acc[p] = bs;
  const float* src = Xnc + (size_t)(bg << 10) * 256;
  for (int ky = 0; ky < 9; ++ky) {
    int yy = y + ky - 4;
    if ((unsigned)yy >= 32u) continue;
#pragma unroll
    for (int kx = 0; kx < 9; ++kx) {
      float wv = wt9[(ky * 9 + kx) * 256 + tid];
#pragma unroll
      for (int p = 0; p < 8; ++p) {
        int xx = x0 + p + kx - 4;
        if ((unsigned)xx < 32u)
          acc[p] += src[(size_t)(yy * 32 + xx) * 256 + tid] * wv;
      }
    }
  }
#pragma unroll
  for (int p = 0; p < 8; ++p)
    Ync[((size_t)((bg << 10) + y * 32 + x0 + p)) * 256 + tid] = acc[p];
}

// ---------------- co tail on nc layout: wave per token
__global__ void k_cotail_nc(const float* __restrict__ Xnc, const float* __restrict__ lnw,
                            const float* __restrict__ lnb, const float* __restrict__ w2,
                            float* __restrict__ pos) {
  int token = (blockIdx.x * 256 + threadIdx.x) >> 6;
  int lane = threadIdx.x & 63;
  float4 v4 = *(const float4*)(Xnc + (size_t)token * 256 + lane * 4);
  float s = v4.x + v4.y + v4.z + v4.w;
  float s2 = v4.x * v4.x + v4.y * v4.y + v4.z * v4.z + v4.w * v4.w;
#pragma unroll
  for (int off = 32; off; off >>= 1) { s += __shfl_xor(s, off); s2 += __shfl_xor(s2, off); }
  float mean = s * (1.f / 256.f);
  float rstd = rsqrtf(s2 * (1.f / 256.f) - mean * mean + 1e-5f);
  float4 g4 = *(const float4*)(lnw + lane * 4);
  float4 b4 = *(const float4*)(lnb + lane * 4);
  float4 wa = *(const float4*)(w2 + lane * 4);
  float4 wb = *(const float4*)(w2 + 256 + lane * 4);
  float ge0 = gelu_exact((v4.x - mean) * rstd * g4.x + b4.x);
  float ge1 = gelu_exact((v4.y - mean) * rstd * g4.y + b4.y);
  float ge2 = gelu_exact((v4.z - mean) * rstd * g4.z + b4.z);
  float ge3 = gelu_exact((v4.w - mean) * rstd * g4.w + b4.w);
  float o0 = ge0 * wa.x + ge1 * wa.y + ge2 * wa.z + ge3 * wa.w;
  float o1 = ge0 * wb.x + ge1 * wb.y + ge2 * wb.z + ge3 * wb.w;
#pragma unroll
  for (int off = 32; off; off >>= 1) { o0 += __shfl_xor(o0, off); o1 += __shfl_xor(o1, off); }
  if (lane == 0) {
    float offy = tanhf(o0) * (2.f / 32.f);
    float offx = tanhf(o1) * (2.f / 32.f);
    int n = token & 1023;
    int ky = n >> 5, kx = n & 31;
    float refy = ((ky + 0.5f) * (1.f / 32.f)) * 2.f - 1.f;
    float refx = ((kx + 0.5f) * (1.f / 32.f)) * 2.f - 1.f;
    pos[token * 2] = offx + refx;
    pos[token * 2 + 1] = offy + refy;
  }
}

// ---------------- bilinear grid sample on nc layout -> sampled_nc
__global__ void k_gsample_nc(const float* __restrict__ Xnc, const float* __restrict__ pos,
                             float* __restrict__ out_nc) {
  int bid = blockIdx.x;
  int nch = bid & 15; int bg = bid >> 4;
  int tid = threadIdx.x;
  __shared__ int sI[4][64];
  __shared__ float sW[4][64];
  if (tid < 64) {
    int j = nch * 64 + tid;
    float gx = pos[((bg << 10) + j) * 2];
    float gy = pos[((bg << 10) + j) * 2 + 1];
    float fx = (gx + 1.f) * 0.5f * 31.f;
    float fy = (gy + 1.f) * 0.5f * 31.f;
    float x0f = floorf(fx), y0f = floorf(fy);
    int x0 = (int)x0f, y0 = (int)y0f;
    float wx1 = fx - x0f, wx0 = 1.f - wx1;
    float wy1 = fy - y0f, wy0 = 1.f - wy1;
    bool vx0 = (x0 >= 0) & (x0 <= 31);
    bool vx1 = (x0 + 1 >= 0) & (x0 + 1 <= 31);
    bool vy0 = (y0 >= 0) & (y0 <= 31);
    bool vy1 = (y0 + 1 >= 0) & (y0 + 1 <= 31);
    int cx0 = min(max(x0, 0), 31), cx1 = min(max(x0 + 1, 0), 31);
    int cy0 = min(max(y0, 0), 31), cy1 = min(max(y0 + 1, 0), 31);
    sW[0][tid] = wx0 * wy0 * ((vx0 && vy0) ? 1.f : 0.f);
    sW[1][tid] = wx1 * wy0 * ((vx1 && vy0) ? 1.f : 0.f);
    sW[2][tid] = wx0 * wy1 * ((vx0 && vy1) ? 1.f : 0.f);
    sW[3][tid] = wx1 * wy1 * ((vx1 && vy1) ? 1.f : 0.f);
    sI[0][tid] = cy0 * 32 + cx0; sI[1][tid] = cy0 * 32 + cx1;
    sI[2][tid] = cy1 * 32 + cx0; sI[3][tid] = cy1 * 32 + cx1;
  }
  __syncthreads();
  const float* src = Xnc + (size_t)(bg << 10) * 256;
  for (int n = 0; n < 64; ++n) {
    float acc = src[(size_t)sI[0][n] * 256 + tid] * sW[0][n]
              + src[(size_t)sI[1][n] * 256 + tid] * sW[1][n]
              + src[(size_t)sI[2][n] * 256 + tid] * sW[2][n]
              + src[(size_t)sI[3][n] * 256 + tid] * sW[3][n];
    out_nc[((size_t)((bg << 10) + nch * 64 + n)) * 256 + tid] = acc;
  }
}

// ---------------------------------------------------------------------------
extern "C" void kernel_launch(void* const* d_in, const int* in_sizes, int n_in,
                              void* d_out, int out_size, void* d_ws, size_t ws_size,
                              hipStream_t stream) {
  const float* tgt    = (const float*)d_in[0];
  const float* refp   = (const float*)d_in[1];
  const float* emb_w  = (const float*)d_in[2];
  const float* emb_b  = (const float*)d_in[3];
  const float* q_w    = (const float*)d_in[4];
  const float* q_b    = (const float*)d_in[5];
  const float* k_w    = (const float*)d_in[6];
  const float* k_b    = (const float*)d_in[7];
  const float* v_w    = (const float*)d_in[8];
  const float* v_b    = (const float*)d_in[9];
  const float* out_w  = (const float*)d_in[10];
  const float* out_b  = (const float*)d_in[11];
  const float* ln1_w  = (const float*)d_in[12];
  const float* ln1_b  = (const float*)d_in[13];
  const float* n1_w   = (const float*)d_in[14];
  const float* n1_b   = (const float*)d_in[15];
  const float* mbq_w  = (const float*)d_in[16];
  const float* mbq_b  = (const float*)d_in[17];
  const float* mbkv_w = (const float*)d_in[18];
  const float* mbkv_b = (const float*)d_in[19];
  const float* mbp_w  = (const float*)d_in[20];
  const float* mbp_b  = (const float*)d_in[21];
  const float* n2_w   = (const float*)d_in[22];
  const float* n2_b   = (const float*)d_in[23];
  const float* fc1_w  = (const float*)d_in[24];
  const float* fc1_b  = (const float*)d_in[25];
  const float* dw3_w  = (const float*)d_in[26];
  const float* dw3_b  = (const float*)d_in[27];
  const float* fc2_w  = (const float*)d_in[28];
  const float* fc2_b  = (const float*)d_in[29];
  const float* dw9_w  = (const float*)d_in[30];
  const float* dw9_b  = (const float*)d_in[31];
  const float* coln_w = (const float*)d_in[32];
  const float* coln_b = (const float*)d_in[33];
  const float* coout_w= (const float*)d_in[34];

  float* ws = (float*)d_ws;
  float* slabA = ws + 0;
  float* qfrag = ws + 2097152;      // main Q frags (hi+lo), persists to step 16
  float* xbuf  = ws + 4194304;
  float* slabD = ws + 6291456;
  float* slabE = ws + 8388608;
  float* slabF = ws + 10485760;
  float* slabG = ws + 14680064;
  float* slabH = ws + 23068672;
  float* featnc= ws + 31457280;
  float* posb  = ws + 35389440;
  float* wt9   = ws + 35405824;     // 20736 floats
  float* biasmb= ws + 35426560;     // 768 (mq part pre-scaled)
  float* biaskv= ws + 35427328;     // 1024
  float* biasq = ws + 35428352;     // 512 (pre-scaled)

  ushort* XtH = (ushort*)(ws + 4194304);
  ushort* XtL = XtH + 4734976;
  ushort* WtEH = (ushort*)slabG;
  ushort* WtEL = WtEH + 4718592;
  float* part = slabH;
  ushort* tgtfh = (ushort*)slabF;
  ushort* tgtfl = tgtfh + 2097152;

  // weight frags (slab J)
  ushort* J = (ushort*)(ws + 33554432);
  ushort* wfq_h   = J;                ushort* wfq_l   = J + 262144;
  ushort* wfkv_h  = J + 524288;       ushort* wfkv_l  = J + 1048576;
  ushort* wfo_h   = J + 1572864;      ushort* wfo_l   = J + 1835008;
  ushort* wfmqkv_h= J + 2097152;      ushort* wfmqkv_l= J + 2293760;
  ushort* wfmp_h  = J + 2490368;      ushort* wfmp_l  = J + 2555904;
  ushort* wff1_h  = J + 2621440;      ushort* wff1_l  = J + 2883584;
  ushort* wff2_h  = J + 3145728;      ushort* wff2_l  = J + 3407872;

  // phase pointers
  ushort* hfh = (ushort*)slabH;     ushort* hfl = hfh + 2097152;   // n1 frags (part dead)
  ushort* mQh = (ushort*)slabG;     ushort* mQl = mQh + 2097152;
  ushort* mKh = mQh + 4194304;      ushort* mKl = mQh + 6291456;
  ushort* mVh = mQh + 8388608;      ushort* mVl = mQh + 10485760;
  ushort* ofh = (ushort*)slabF;     ushort* ofl = ofh + 2097152;   // mb out frags
  float* P_cm = slabD;
  ushort* h2fh = (ushort*)slabF;    ushort* h2fl = h2fh + 2097152;
  float* m_cm = slabG;
  float* mi_cm = slabH;
  ushort* mifh = (ushort*)slabG;    ushort* mifl = mifh + 8388608;
  float* ygemm = slabD;
  float* offin = slabA;
  float* offdwnc = slabE;
  float* samplednc = slabA;
  ushort* sfh = (ushort*)slabF;     ushort* sfl = sfh + 2097152;
  ushort* aQh = (ushort*)qfrag;     ushort* aQl = aQh + 2097152;   // main Q frags
  ushort* aKh = (ushort*)slabG;     ushort* aKl = aKh + 2097152;   // main K/V frags
  ushort* aVh = aKh + 4194304;      ushort* aVl = aKh + 6291456;
  ushort* anfh = (ushort*)slabH;    ushort* anfl = anfh + 2097152;

  // --- step 0: mega-prep + tgt frags ---
  k_prep_all<<<5346, 256, 0, stream>>>(
      emb_w, tgt, refp, q_w, k_w, v_w, out_w, mbq_w, mbkv_w, mbp_w, fc1_w, fc2_w,
      dw9_w, q_b, mbq_b, mbkv_b, k_b, v_b,
      WtEH, WtEL, XtH, XtL,
      wfq_h, wfq_l, wfkv_h, wfkv_l, wfo_h, wfo_l, wfmqkv_h, wfmqkv_l,
      wfmp_h, wfmp_l, wff1_h, wff1_l, wff2_h, wff2_l,
      wt9, biasmb, biaskv, biasq);
  k_prep_cm2frag<<<1024, 256, 0, stream>>>(tgt, 512, 16, tgtfh, tgtfl);
  // --- step 1: emb conv + merge ---
  k_emb_mfma<<<512, 256, 0, stream>>>(XtH, XtL, WtEH, WtEL, part);
  k_embmerge_nc<<<512, 256, 0, stream>>>(part, emb_b, featnc);
  // --- step 2: q proj -> main Q frags directly (scale folded) ---
  k_gemm_frag_main<<<512, 256, 0, stream>>>(wfq_h, wfq_l, tgtfh, tgtfl, biasq,
                                            aQh, aQl, aVh, aVl, 512, 16, 8);
  // --- step 3+4: fused ln1 -> xbuf + n1 -> frags (slabH) ---
  k_ln1n1<<<2048, 256, 0, stream>>>(featnc, ln1_w, ln1_b, n1_w, n1_b, xbuf, hfh, hfl);
  // --- step 5+6a: mqkv GEMM -> mb Q/K/V frags directly ---
  k_gemm_frag_mb<<<1536, 256, 0, stream>>>(wfmqkv_h, wfmqkv_l, hfh, hfl, biasmb,
                                           mQh, mQl, mKh, mKl, mVh, mVl);
  // --- step 6: mb attention ---
  k_mbattn_mfma<<<1024, 256, 0, stream>>>(mQh, mQl, mKh, mKl, mVh, mVl, ofh, ofl);
  // --- step 7: mbproj + residual ---
  k_gemm_mfma<<<512, 256, 0, stream>>>(wfmp_h, wfmp_l, ofh, ofl, mbp_b, P_cm, 8, 4, 256);
  k_transadd_tm<<<512, 256, 0, stream>>>(P_cm, xbuf);
  // --- step 8: n2 -> h2 frags ---
  k_ln_frag<<<2048, 256, 0, stream>>>(xbuf, n2_w, n2_b, h2fh, h2fl, 1e-6f);
  // --- step 9: fc1 ---
  k_gemm_mfma<<<2048, 256, 0, stream>>>(wff1_h, wff1_l, h2fh, h2fl, fc1_b, m_cm, 8, 16, 1024);
  // --- step 10: dw3 + gelu; mi frags ---
  k_dw3<<<32768, 256, 0, stream>>>(m_cm, dw3_w, dw3_b, mi_cm);
  k_prep_cm2frag<<<4096, 256, 0, stream>>>(mi_cm, 1024, 32, mifh, mifl);
  // --- step 11: fc2 + residual -> offin nc ---
  k_gemm_mfma<<<512, 256, 0, stream>>>(wff2_h, wff2_l, mifh, mifl, fc2_b, ygemm, 32, 4, 256);
  k_transadd_nc<<<512, 256, 0, stream>>>(ygemm, xbuf, offin);
  // --- step 12: dw9 ---
  k_dw9_nc<<<1024, 256, 0, stream>>>(offin, wt9, dw9_b, offdwnc);
  // --- step 13: cotail ---
  k_cotail_nc<<<2048, 256, 0, stream>>>(offdwnc, coln_w, coln_b, coout_w, posb);
  // --- step 14: grid sample + frags ---
  k_gsample_nc<<<128, 256, 0, stream>>>(featnc, posb, samplednc);
  k_prep_s2frag<<<1024, 256, 0, stream>>>(samplednc, sfh, sfl);
  // --- step 15+16a: k+v GEMM -> main K frags + V^T frags directly ---
  k_gemm_frag_main<<<1024, 256, 0, stream>>>(wfkv_h, wfkv_l, sfh, sfl, biaskv,
                                             aKh, aKl, aVh, aVl, 512, 16, 16);
  // --- step 16: main attention ---
  k_mainattn_mfma<<<512, 256, 0, stream>>>(aQh, aQl, aKh, aKl, aVh, aVl, anfh, anfl);
  // --- step 17: out proj -> d_out ---
  k_gemm_mfma<<<512, 256, 0, stream>>>(wfo_h, wfo_l, anfh, anfl, out_b, (float*)d_out, 16, 8, 512);
}

// Round 12
// 563.864 us; speedup vs baseline: 5.4168x; 1.0210x over previous
//
#include <hip/hip_runtime.h>
#include <math.h>

// ---------------------------------------------------------------------------
// DAttention forward. R12: dw3 and grid-sample write consumer MFMA frags
// directly (kills mi_cm and samplednc fp32 round-trips + 2 dispatches).
// Dims: B=4, C=512, H=W=32, G=2, gc=256, BG=8, heads=8, hc=64, mh=8, mhd=32.
// ---------------------------------------------------------------------------

static constexpr int HW = 1024;

typedef __attribute__((ext_vector_type(8))) short bf16x8;
typedef __attribute__((ext_vector_type(4))) float f32x4;

union V16u { int4 i4; ushort u[8]; };

__device__ __forceinline__ float gelu_exact(float v) {
  return 0.5f * v * (1.0f + erff(v * 0.7071067811865475f));
}

__device__ __forceinline__ ushort bf16_rne(float v) {
  unsigned int b = __float_as_uint(v);
  return (ushort)((b + 0x7fffu + ((b >> 16) & 1u)) >> 16);
}

__device__ __forceinline__ void split2(float v, ushort& h, ushort& l) {
  h = bf16_rne(v);
  l = bf16_rne(v - __uint_as_float(((unsigned int)h) << 16));
}

// ---------------- weight frag body (shared); scale folded into weights
__device__ __forceinline__ void wfrag_body(const float* __restrict__ W, int K, int KC,
                                           ushort* __restrict__ dh, ushort* __restrict__ dl,
                                           int gtid, float scale) {
  int l = gtid & 63; int fr = gtid >> 6;
  int kc = fr % KC; int ot = fr / KC;
  int lr = l & 15, lu = l >> 4;
  const float* sp = W + (size_t)(ot * 16 + lr) * K + kc * 32 + lu * 8;
  V16u hi, lo;
#pragma unroll
  for (int j = 0; j < 8; ++j) split2(sp[j] * scale, hi.u[j], lo.u[j]);
  *(int4*)(dh + (size_t)gtid * 8) = hi.i4;
  *(int4*)(dl + (size_t)gtid * 8) = lo.i4;
}

// ---------------- MEGA-PREP: emb w/x prep + all weight frags + wt9 + biases.
__global__ void k_prep_all(
    const float* __restrict__ emb_w, const float* __restrict__ tgt,
    const float* __restrict__ refp,
    const float* q_w, const float* k_w, const float* v_w, const float* o_w,
    const float* mq_w, const float* mkv_w, const float* mp_w,
    const float* f1_w, const float* f2_w, const float* dw9_w,
    const float* q_b, const float* mq_b, const float* mkv_b,
    const float* k_b, const float* v_b,
    ushort* __restrict__ WtEH, ushort* __restrict__ WtEL,
    ushort* __restrict__ XtH, ushort* __restrict__ XtL,
    ushort* qh, ushort* ql, ushort* kvh, ushort* kvl,
    ushort* oh, ushort* ol, ushort* mqkvh, ushort* mqkvl,
    ushort* mph, ushort* mpl, ushort* f1h, ushort* f1l, ushort* f2h, ushort* f2l,
    float* wt9, float* biasmb, float* biaskv, float* biasq) {
  int bid = blockIdx.x, tid = threadIdx.x;
  if (bid < 2048) {                      // emb weights -> [9][512][1024] hi/lo
    int idx = bid * 256 + tid;
    int o = idx >> 10, ci = idx & 1023;
    const float* src = emb_w + (size_t)idx * 9;
#pragma unroll
    for (int t = 0; t < 9; ++t) {
      ushort h, l; split2(src[t], h, l);
      size_t oo = ((size_t)(t * 512 + o)) * 1024 + ci;
      WtEH[oo] = h; WtEL[oo] = l;
    }
  } else if (bid < 4360) {               // inputs -> [4][34][34][1024] hi/lo
    int idx = (bid - 2048) * 256 + tid;
    int xp = idx % 34; int r = idx / 34;
    int g8 = r & 127; r >>= 7;
    int yp = r % 34; int b = r / 34;
    int y = yp - 1, x = xp - 1;
    bool valid = (unsigned)y < 32u && (unsigned)x < 32u;
    V16u hi, lo;
    const float* in = (g8 < 64) ? (tgt + ((size_t)(b * 512 + g8 * 8)) * HW)
                                : (refp + ((size_t)(b * 512 + (g8 - 64) * 8)) * HW);
#pragma unroll
    for (int j = 0; j < 8; ++j) {
      float v = valid ? in[(size_t)j * HW + y * 32 + x] : 0.f;
      split2(v, hi.u[j], lo.u[j]);
    }
    size_t oo = (((size_t)(b * 34 + yp)) * 34 + xp) * 1024 + g8 * 8;
    *(int4*)(XtH + oo) = hi.i4;
    *(int4*)(XtL + oo) = lo.i4;
  }
  // q weights pre-scaled by 0.125 (main-attn softmax scale)
  else if (bid < 4488) wfrag_body(q_w, 512, 16, qh, ql, (bid - 4360) * 256 + tid, 0.125f);
  else if (bid < 4616) wfrag_body(k_w, 512, 16, kvh, kvl, (bid - 4488) * 256 + tid, 1.f);
  // v frags at +262144 (one 512x512 frag set)
  else if (bid < 4744) wfrag_body(v_w, 512, 16, kvh + 262144, kvl + 262144,
                                  (bid - 4616) * 256 + tid, 1.f);
  else if (bid < 4872) wfrag_body(o_w, 512, 16, oh, ol, (bid - 4744) * 256 + tid, 1.f);
  // mq pre-scaled by 32^-0.5
  else if (bid < 4904) wfrag_body(mq_w, 256, 8, mqkvh, mqkvl, (bid - 4872) * 256 + tid,
                                  0.17677669529663689f);
  // mkv frags at +65536 (one 256x256 frag set)
  else if (bid < 4968) wfrag_body(mkv_w, 256, 8, mqkvh + 65536, mqkvl + 65536,
                                  (bid - 4904) * 256 + tid, 1.f);
  else if (bid < 5000) wfrag_body(mp_w, 256, 8, mph, mpl, (bid - 4968) * 256 + tid, 1.f);
  else if (bid < 5128) wfrag_body(f1_w, 256, 8, f1h, f1l, (bid - 5000) * 256 + tid, 1.f);
  else if (bid < 5256) wfrag_body(f2_w, 1024, 32, f2h, f2l, (bid - 5128) * 256 + tid, 1.f);
  else if (bid < 5337) {                 // dw9 weight transpose [81][256]
    int idx = (bid - 5256) * 256 + tid;
    int t = idx >> 8, c = idx & 255;
    wt9[idx] = dw9_w[c * 81 + t];
  } else {                               // biases: 9 blocks x 256 = 2304
    int idx = (bid - 5337) * 256 + tid;
    if (idx < 768)
      biasmb[idx] = idx < 256 ? mq_b[idx] * 0.17677669529663689f : mkv_b[idx - 256];
    else if (idx < 1792) {
      int j = idx - 768;
      biaskv[j] = j < 512 ? k_b[j] : v_b[j - 512];
    } else if (idx < 2304) {
      biasq[idx - 1792] = q_b[idx - 1792] * 0.125f;
    }
  }
}

// cm activations [b][CH][1024] -> B-frags (used for tgt only)
__global__ void k_prep_cm2frag(const float* __restrict__ src, int CH, int KC,
                               ushort* __restrict__ dh, ushort* __restrict__ dl) {
  int gtid = blockIdx.x * 256 + threadIdx.x;
  int l = gtid & 63; int fr = gtid >> 6;
  int kc = fr % KC; int r2 = fr / KC; int nt = r2 & 63; int b = r2 >> 6;
  int lr = l & 15, lu = l >> 4;
  const float* sp = src + ((size_t)(b * CH) + kc * 32 + lu * 8) * 1024 + nt * 16 + lr;
  V16u hi, lo;
#pragma unroll
  for (int j = 0; j < 8; ++j) split2(sp[(size_t)j * 1024], hi.u[j], lo.u[j]);
  *(int4*)(dh + (size_t)gtid * 8) = hi.i4;
  *(int4*)(dl + (size_t)gtid * 8) = lo.i4;
}

// ---------------- emb conv via MFMA, split-bf16, 4-way K-split, 4 rows/wave
__global__ __launch_bounds__(256, 2)
void k_emb_mfma(const ushort* __restrict__ Xt_hi, const ushort* __restrict__ Xt_lo,
                const ushort* __restrict__ Wt_hi, const ushort* __restrict__ Wt_lo,
                float* __restrict__ part) {
  int wgid = (blockIdx.x & 7) * 64 + (blockIdx.x >> 3);
  int yt = wgid & 7;  wgid >>= 3;
  int b  = wgid & 3;  wgid >>= 2;
  int mt = wgid & 3;  wgid >>= 2;
  int ks = wgid;
  int tid = threadIdx.x;
  int w = tid >> 6, l = tid & 63;
  int lr = l & 15, lu = l >> 4;
  int y0 = yt * 4;
  int obase = mt * 128 + w * 32;

  __shared__ int4 LsH[2][816];
  __shared__ int4 LsL[2][816];

  int4 gh[4], gl[4];
  int kc0 = ks * 8;

  auto loadstage = [&](int kcg) {
#pragma unroll
    for (int i = 0; i < 4; ++i) {
      int s = tid + 256 * i;
      if (s < 816) {
        int px = s >> 2;
        int u = (s & 3) ^ ((px >> 1) & 3);
        size_t off = ((size_t)(b * 34 + y0) * 34 + px) * 1024 + kcg * 32 + u * 8;
        gh[i] = *(const int4*)(Xt_hi + off);
        gl[i] = *(const int4*)(Xt_lo + off);
      }
    }
  };
  auto writestage = [&](int buf) {
#pragma unroll
    for (int i = 0; i < 4; ++i) {
      int s = tid + 256 * i;
      if (s < 816) { LsH[buf][s] = gh[i]; LsL[buf][s] = gl[i]; }
    }
  };

  f32x4 zero = {0.f, 0.f, 0.f, 0.f};
  f32x4 acc[2][8];
#pragma unroll
  for (int a = 0; a < 2; ++a)
#pragma unroll
    for (int n = 0; n < 8; ++n) acc[a][n] = zero;

  loadstage(kc0);
  writestage(0);

  for (int kc = 0; kc < 8; ++kc) {
    int buf = kc & 1;
    __syncthreads();
    if (kc < 7) loadstage(kc0 + kc + 1);
    int kcg = kc0 + kc;
    const bf16x8* BH = (const bf16x8*)&LsH[buf][0];
    const bf16x8* BL = (const bf16x8*)&LsL[buf][0];
#pragma unroll
    for (int kx = 0; kx < 3; ++kx) {
      bf16x8 bh[12], bl[12];
#pragma unroll
      for (int f = 0; f < 12; ++f) {
        int px = (f >> 1) * 34 + (f & 1) * 16 + kx + lr;
        int idx = px * 4 + (lu ^ ((px >> 1) & 3));
        bh[f] = BH[idx]; bl[f] = BL[idx];
      }
#pragma unroll
      for (int ky = 0; ky < 3; ++ky) {
        int tap = ky * 3 + kx;
        size_t wo = (((size_t)(tap * 512 + obase + lr)) * 1024) + kcg * 32 + lu * 8;
        bf16x8 ah0 = *(const bf16x8*)(Wt_hi + wo);
        bf16x8 al0 = *(const bf16x8*)(Wt_lo + wo);
        bf16x8 ah1 = *(const bf16x8*)(Wt_hi + wo + 16 * 1024);
        bf16x8 al1 = *(const bf16x8*)(Wt_lo + wo + 16 * 1024);
#pragma unroll
        for (int yr = 0; yr < 4; ++yr)
#pragma unroll
          for (int h = 0; h < 2; ++h) {
            int f = (yr + ky) * 2 + h;
            int nf = yr * 2 + h;
            acc[0][nf] = __builtin_amdgcn_mfma_f32_16x16x32_bf16(ah0, bh[f], acc[0][nf], 0, 0, 0);
            acc[0][nf] = __builtin_amdgcn_mfma_f32_16x16x32_bf16(ah0, bl[f], acc[0][nf], 0, 0, 0);
            acc[0][nf] = __builtin_amdgcn_mfma_f32_16x16x32_bf16(al0, bh[f], acc[0][nf], 0, 0, 0);
            acc[1][nf] = __builtin_amdgcn_mfma_f32_16x16x32_bf16(ah1, bh[f], acc[1][nf], 0, 0, 0);
            acc[1][nf] = __builtin_amdgcn_mfma_f32_16x16x32_bf16(ah1, bl[f], acc[1][nf], 0, 0, 0);
            acc[1][nf] = __builtin_amdgcn_mfma_f32_16x16x32_bf16(al1, bh[f], acc[1][nf], 0, 0, 0);
          }
      }
    }
    if (kc < 7) writestage(buf ^ 1);
  }

  float* pb = part + (size_t)ks * 2097152;
#pragma unroll
  for (int a = 0; a < 2; ++a)
#pragma unroll
    for (int yr = 0; yr < 4; ++yr)
#pragma unroll
      for (int h = 0; h < 2; ++h) {
        f32x4 c = acc[a][yr * 2 + h];
        size_t base = ((size_t)(b * 512 + obase + a * 16 + lu * 4)) * 1024
                      + (y0 + yr) * 32 + h * 16 + lr;
#pragma unroll
        for (int r = 0; r < 4; ++r) pb[base + (size_t)r * 1024] = c[r];
      }
}

// ---------------- emb merge: sum 4 parts + bias, write feat_nc (transposing)
__global__ void k_embmerge_nc(const float* __restrict__ part, const float* __restrict__ bias,
                              float* __restrict__ featnc) {
  __shared__ float T[64][65];
  int bid = blockIdx.x;
  int n0 = (bid & 15) << 6; bid >>= 4;
  int c0 = (bid & 3) << 6; int bg = bid >> 2;
  int cl = threadIdx.x & 63, rw = threadIdx.x >> 6;
#pragma unroll
  for (int i = 0; i < 16; ++i) {
    int crow = i * 4 + rw;
    size_t idx = ((size_t)(bg * 256 + c0 + crow)) * 1024 + n0 + cl;
    float v = part[idx] + part[2097152 + idx] + part[4194304 + idx] + part[6291456 + idx];
    T[crow][cl] = v + bias[(bg & 1) * 256 + c0 + crow];
  }
  __syncthreads();
#pragma unroll
  for (int i = 0; i < 16; ++i) {
    int nrow = i * 4 + rw;
    featnc[((size_t)(bg * 1024 + n0 + nrow)) * 256 + c0 + cl] = T[cl][nrow];
  }
}

// ============ generic MFMA GEMM (cm fp32 output) ============
__global__ __launch_bounds__(256)
void k_gemm_mfma(const ushort* __restrict__ Ah, const ushort* __restrict__ Al,
                 const ushort* __restrict__ Bh, const ushort* __restrict__ Bl,
                 const float* __restrict__ bias, float* __restrict__ Y,
                 int KC, int MT, int Mtot) {
  int bid = blockIdx.x;
  int ntb = bid & 15; bid >>= 4;
  int mt = bid % MT; int b = bid / MT;
  int tid = threadIdx.x, w = tid >> 6, l = tid & 63, lr = l & 15, lu = l >> 4;
  int wo = w >> 1, wn = w & 1;
  int ot0 = mt * 4 + wo * 2;
  int nf0 = ntb * 4 + wn * 2;
  const bf16x8* pAh = (const bf16x8*)Ah;
  const bf16x8* pAl = (const bf16x8*)Al;
  const bf16x8* pBh = (const bf16x8*)Bh;
  const bf16x8* pBl = (const bf16x8*)Bl;
  f32x4 zero = {0.f, 0.f, 0.f, 0.f};
  f32x4 acc[2][2];
#pragma unroll
  for (int a = 0; a < 2; ++a)
#pragma unroll
    for (int n = 0; n < 2; ++n) acc[a][n] = zero;
  for (int kc = 0; kc < KC; ++kc) {
    bf16x8 a_h[2], a_l[2];
#pragma unroll
    for (int a = 0; a < 2; ++a) {
      size_t idx = ((size_t)(ot0 + a) * KC + kc) * 64 + l;
      a_h[a] = pAh[idx]; a_l[a] = pAl[idx];
    }
#pragma unroll
    for (int n = 0; n < 2; ++n) {
      size_t idx = (((size_t)(b * 64 + nf0 + n)) * KC + kc) * 64 + l;
      bf16x8 b_h = pBh[idx], b_l = pBl[idx];
#pragma unroll
      for (int a = 0; a < 2; ++a) {
        acc[a][n] = __builtin_amdgcn_mfma_f32_16x16x32_bf16(a_h[a], b_h, acc[a][n], 0, 0, 0);
        acc[a][n] = __builtin_amdgcn_mfma_f32_16x16x32_bf16(a_h[a], b_l, acc[a][n], 0, 0, 0);
        acc[a][n] = __builtin_amdgcn_mfma_f32_16x16x32_bf16(a_l[a], b_h, acc[a][n], 0, 0, 0);
      }
    }
  }
#pragma unroll
  for (int a = 0; a < 2; ++a) {
    int o = (ot0 + a) * 16 + lu * 4;
#pragma unroll
    for (int n = 0; n < 2; ++n) {
      int col = (nf0 + n) * 16 + lr;
#pragma unroll
      for (int r = 0; r < 4; ++r)
        Y[((size_t)(b * Mtot + o + r)) * 1024 + col] = acc[a][n][r] + bias[o + r];
    }
  }
}

// ============ GEMM with mb-attention frag epilogue (d=32 heads) ============
__global__ __launch_bounds__(256)
void k_gemm_frag_mb(const ushort* __restrict__ Ah, const ushort* __restrict__ Al,
                    const ushort* __restrict__ Bh, const ushort* __restrict__ Bl,
                    const float* __restrict__ bias,
                    ushort* __restrict__ mQh, ushort* __restrict__ mQl,
                    ushort* __restrict__ mKh, ushort* __restrict__ mKl,
                    ushort* __restrict__ mVh, ushort* __restrict__ mVl) {
  int bid = blockIdx.x;
  int ntb = bid & 15; bid >>= 4;
  int mt = bid % 12; int b = bid / 12;
  int tid = threadIdx.x, w = tid >> 6, l = tid & 63, lr = l & 15, lu = l >> 4;
  int wo = w >> 1, wn = w & 1;
  int ot0 = mt * 4 + wo * 2;
  int nf0 = ntb * 4 + wn * 2;
  const bf16x8* pAh = (const bf16x8*)Ah;
  const bf16x8* pAl = (const bf16x8*)Al;
  const bf16x8* pBh = (const bf16x8*)Bh;
  const bf16x8* pBl = (const bf16x8*)Bl;
  f32x4 zero = {0.f, 0.f, 0.f, 0.f};
  f32x4 acc[2][2];
#pragma unroll
  for (int a = 0; a < 2; ++a)
#pragma unroll
    for (int n = 0; n < 2; ++n) acc[a][n] = zero;
  for (int kc = 0; kc < 8; ++kc) {
    bf16x8 a_h[2], a_l[2];
#pragma unroll
    for (int a = 0; a < 2; ++a) {
      size_t idx = ((size_t)(ot0 + a) * 8 + kc) * 64 + l;
      a_h[a] = pAh[idx]; a_l[a] = pAl[idx];
    }
#pragma unroll
    for (int n = 0; n < 2; ++n) {
      size_t idx = (((size_t)(b * 64 + nf0 + n)) * 8 + kc) * 64 + l;
      bf16x8 b_h = pBh[idx], b_l = pBl[idx];
#pragma unroll
      for (int a = 0; a < 2; ++a) {
        acc[a][n] = __builtin_amdgcn_mfma_f32_16x16x32_bf16(a_h[a], b_h, acc[a][n], 0, 0, 0);
        acc[a][n] = __builtin_amdgcn_mfma_f32_16x16x32_bf16(a_h[a], b_l, acc[a][n], 0, 0, 0);
        acc[a][n] = __builtin_amdgcn_mfma_f32_16x16x32_bf16(a_l[a], b_h, acc[a][n], 0, 0, 0);
      }
    }
  }
#pragma unroll
  for (int a = 0; a < 2; ++a) {
    int o0 = (ot0 + a) * 16 + lu * 4;
#pragma unroll
    for (int n = 0; n < 2; ++n) {
      int col = (nf0 + n) * 16 + lr;
      ushort4 h4, l4;
      split2(acc[a][n][0] + bias[o0 + 0], h4.x, l4.x);
      split2(acc[a][n][1] + bias[o0 + 1], h4.y, l4.y);
      split2(acc[a][n][2] + bias[o0 + 2], h4.z, l4.z);
      split2(acc[a][n][3] + bias[o0 + 3], h4.w, l4.w);
      if (o0 < 512) {
        int oo = o0 & 255;
        int hh = oo >> 5, d = oo & 31;
        ushort* dh = o0 < 256 ? mQh : mKh;
        ushort* dl = o0 < 256 ? mQl : mKl;
        size_t base = ((((size_t)(b * 8 + hh) * 64 + (col >> 4)) * 64)
                       + ((d >> 3) << 4) + (col & 15)) * 8 + (d & 7);
        *(ushort4*)(dh + base) = h4;
        *(ushort4*)(dl + base) = l4;
      } else {
        int oo = o0 - 512;
        int hh = oo >> 5, d = oo & 31;
        int et = d >> 4;
        size_t eb = ((((size_t)((b * 8 + hh) * 2 + et)) * 32 + (col >> 5)) * 64
                     + ((col >> 3) & 3) * 16 + (d & 15)) * 8 + (col & 7);
        mVh[eb] = h4.x; mVh[eb + 8] = h4.y; mVh[eb + 16] = h4.z; mVh[eb + 24] = h4.w;
        mVl[eb] = l4.x; mVl[eb + 8] = l4.y; mVl[eb + 16] = l4.z; mVl[eb + 24] = l4.w;
      }
    }
  }
}

// ============ GEMM with main-attention frag epilogue (d=64 heads) ============
__global__ __launch_bounds__(256)
void k_gemm_frag_main(const ushort* __restrict__ Ah, const ushort* __restrict__ Al,
                      const ushort* __restrict__ Bh, const ushort* __restrict__ Bl,
                      const float* __restrict__ bias,
                      ushort* __restrict__ fh, ushort* __restrict__ fl,
                      ushort* __restrict__ vfh, ushort* __restrict__ vfl,
                      int vbase, int KC, int MT) {
  int bid = blockIdx.x;
  int ntb = bid & 15; bid >>= 4;
  int mt = bid % MT; int b = bid / MT;
  int tid = threadIdx.x, w = tid >> 6, l = tid & 63, lr = l & 15, lu = l >> 4;
  int wo = w >> 1, wn = w & 1;
  int ot0 = mt * 4 + wo * 2;
  int nf0 = ntb * 4 + wn * 2;
  const bf16x8* pAh = (const bf16x8*)Ah;
  const bf16x8* pAl = (const bf16x8*)Al;
  const bf16x8* pBh = (const bf16x8*)Bh;
  const bf16x8* pBl = (const bf16x8*)Bl;
  f32x4 zero = {0.f, 0.f, 0.f, 0.f};
  f32x4 acc[2][2];
#pragma unroll
  for (int a = 0; a < 2; ++a)
#pragma unroll
    for (int n = 0; n < 2; ++n) acc[a][n] = zero;
  for (int kc = 0; kc < KC; ++kc) {
    bf16x8 a_h[2], a_l[2];
#pragma unroll
    for (int a = 0; a < 2; ++a) {
      size_t idx = ((size_t)(ot0 + a) * KC + kc) * 64 + l;
      a_h[a] = pAh[idx]; a_l[a] = pAl[idx];
    }
#pragma unroll
    for (int n = 0; n < 2; ++n) {
      size_t idx = (((size_t)(b * 64 + nf0 + n)) * KC + kc) * 64 + l;
      bf16x8 b_h = pBh[idx], b_l = pBl[idx];
#pragma unroll
      for (int a = 0; a < 2; ++a) {
        acc[a][n] = __builtin_amdgcn_mfma_f32_16x16x32_bf16(a_h[a], b_h, acc[a][n], 0, 0, 0);
        acc[a][n] = __builtin_amdgcn_mfma_f32_16x16x32_bf16(a_h[a], b_l, acc[a][n], 0, 0, 0);
        acc[a][n] = __builtin_amdgcn_mfma_f32_16x16x32_bf16(a_l[a], b_h, acc[a][n], 0, 0, 0);
      }
    }
  }
#pragma unroll
  for (int a = 0; a < 2; ++a) {
    int o0 = (ot0 + a) * 16 + lu * 4;
#pragma unroll
    for (int n = 0; n < 2; ++n) {
      int col = (nf0 + n) * 16 + lr;
      ushort4 h4, l4;
      split2(acc[a][n][0] + bias[o0 + 0], h4.x, l4.x);
      split2(acc[a][n][1] + bias[o0 + 1], h4.y, l4.y);
      split2(acc[a][n][2] + bias[o0 + 2], h4.z, l4.z);
      split2(acc[a][n][3] + bias[o0 + 3], h4.w, l4.w);
      if (o0 < vbase) {
        int h = o0 >> 6, d = o0 & 63;
        int dc = d >> 5;
        size_t base = (((((size_t)(b * 8 + h) * 64 + (col >> 4)) * 2 + dc) * 64)
                       + (((d & 31) >> 3) << 4) + (col & 15)) * 8 + (d & 7);
        *(ushort4*)(fh + base) = h4;
        *(ushort4*)(fl + base) = l4;
      } else {
        int oo = o0 - vbase;
        int h = oo >> 6, d = oo & 63;
        int et = d >> 4;
        size_t eb = ((((size_t)((b * 8 + h) * 4 + et)) * 32 + (col >> 5)) * 64
                     + ((col >> 3) & 3) * 16 + (d & 15)) * 8 + (col & 7);
        vfh[eb] = h4.x; vfh[eb + 8] = h4.y; vfh[eb + 16] = h4.z; vfh[eb + 24] = h4.w;
        vfl[eb] = l4.x; vfl[eb + 8] = l4.y; vfl[eb + 16] = l4.z; vfl[eb + 24] = l4.w;
      }
    }
  }
}

// ============ transposes ============
__global__ void k_transadd_tm(const float* __restrict__ Pcm, float* __restrict__ Xtm) {
  __shared__ float T[64][65];
  int bid = blockIdx.x; int n0 = (bid & 15) << 6; bid >>= 4;
  int c0 = (bid & 3) << 6; int bg = bid >> 2;
  int cl = threadIdx.x & 63, rw = threadIdx.x >> 6;
#pragma unroll
  for (int i = 0; i < 16; ++i) {
    int crow = i * 4 + rw;
    T[crow][cl] = Pcm[((size_t)(bg * 256 + c0 + crow)) * 1024 + n0 + cl];
  }
  __syncthreads();
#pragma unroll
  for (int i = 0; i < 16; ++i) {
    int nrow = i * 4 + rw;
    Xtm[((size_t)((bg << 10) + n0 + nrow)) * 256 + c0 + cl] += T[cl][nrow];
  }
}

__global__ void k_transadd_nc(const float* __restrict__ Yg, const float* __restrict__ Xtm,
                              float* __restrict__ out_nc) {
  __shared__ float T[64][65];
  int bid = blockIdx.x; int n0 = (bid & 15) << 6; bid >>= 4;
  int c0 = (bid & 3) << 6; int bg = bid >> 2;
  int cl = threadIdx.x & 63, rw = threadIdx.x >> 6;
#pragma unroll
  for (int i = 0; i < 16; ++i) {
    int crow = i * 4 + rw;
    T[crow][cl] = Yg[((size_t)(bg * 256 + c0 + crow)) * 1024 + n0 + cl];
  }
  __syncthreads();
#pragma unroll
  for (int i = 0; i < 16; ++i) {
    int nrow = i * 4 + rw;
    size_t a = ((size_t)((bg << 10) + n0 + nrow)) * 256 + c0 + cl;
    out_nc[a] = T[cl][nrow] + Xtm[a];
  }
}

// ---------------- FUSED ln1 (->xbuf) + n1 (->B-frags), wave per token
__global__ void k_ln1n1(const float* __restrict__ featnc,
                        const float* __restrict__ g1, const float* __restrict__ b1,
                        const float* __restrict__ gn, const float* __restrict__ bn,
                        float* __restrict__ xbuf,
                        ushort* __restrict__ dh, ushort* __restrict__ dl) {
  int token = (blockIdx.x * 256 + threadIdx.x) >> 6;
  int lane = threadIdx.x & 63;
  float4 v4 = *reinterpret_cast<const float4*>(featnc + (size_t)token * 256 + lane * 4);
  float s  = v4.x + v4.y + v4.z + v4.w;
  float s2 = v4.x * v4.x + v4.y * v4.y + v4.z * v4.z + v4.w * v4.w;
#pragma unroll
  for (int off = 32; off; off >>= 1) { s += __shfl_xor(s, off); s2 += __shfl_xor(s2, off); }
  float mean = s * (1.f / 256.f);
  float rstd = rsqrtf(s2 * (1.f / 256.f) - mean * mean + 1e-5f);
  float4 g4 = *reinterpret_cast<const float4*>(g1 + lane * 4);
  float4 b4 = *reinterpret_cast<const float4*>(b1 + lane * 4);
  float4 x;
  x.x = (v4.x - mean) * rstd * g4.x + b4.x;
  x.y = (v4.y - mean) * rstd * g4.y + b4.y;
  x.z = (v4.z - mean) * rstd * g4.z + b4.z;
  x.w = (v4.w - mean) * rstd * g4.w + b4.w;
  *reinterpret_cast<float4*>(xbuf + (size_t)token * 256 + lane * 4) = x;
  float t  = x.x + x.y + x.z + x.w;
  float t2 = x.x * x.x + x.y * x.y + x.z * x.z + x.w * x.w;
#pragma unroll
  for (int off = 32; off; off >>= 1) { t += __shfl_xor(t, off); t2 += __shfl_xor(t2, off); }
  float mean2 = t * (1.f / 256.f);
  float rstd2 = rsqrtf(t2 * (1.f / 256.f) - mean2 * mean2 + 1e-6f);
  float4 gg = *reinterpret_cast<const float4*>(gn + lane * 4);
  float4 bb = *reinterpret_cast<const float4*>(bn + lane * 4);
  ushort4 h4, l4;
  split2((x.x - mean2) * rstd2 * gg.x + bb.x, h4.x, l4.x);
  split2((x.y - mean2) * rstd2 * gg.y + bb.y, h4.y, l4.y);
  split2((x.z - mean2) * rstd2 * gg.z + bb.z, h4.z, l4.z);
  split2((x.w - mean2) * rstd2 * gg.w + bb.w, h4.w, l4.w);
  int bg = token >> 10, nt = (token >> 4) & 63, lr = token & 15;
  int kc = lane >> 3, lu_f = (lane >> 1) & 3, j0 = (lane & 1) * 4;
  size_t base = ((((size_t)(bg * 64 + nt)) * 8 + kc) * 64 + lu_f * 16 + lr) * 8 + j0;
  *(ushort4*)(dh + base) = h4;
  *(ushort4*)(dl + base) = l4;
}

// ---------------- token-major LN -> B-frags (KC=8), standalone (n2)
__global__ void k_ln_frag(const float* __restrict__ xin, const float* __restrict__ g_,
                          const float* __restrict__ b_, ushort* __restrict__ dh,
                          ushort* __restrict__ dl, float eps) {
  int token = (blockIdx.x * 256 + threadIdx.x) >> 6;
  int lane = threadIdx.x & 63;
  float4 v4 = *reinterpret_cast<const float4*>(xin + (size_t)token * 256 + lane * 4);
  float s  = v4.x + v4.y + v4.z + v4.w;
  float s2 = v4.x * v4.x + v4.y * v4.y + v4.z * v4.z + v4.w * v4.w;
#pragma unroll
  for (int off = 32; off; off >>= 1) { s += __shfl_xor(s, off); s2 += __shfl_xor(s2, off); }
  float mean = s * (1.f / 256.f);
  float rstd = rsqrtf(s2 * (1.f / 256.f) - mean * mean + eps);
  float4 g4 = *reinterpret_cast<const float4*>(g_ + lane * 4);
  float4 b4 = *reinterpret_cast<const float4*>(b_ + lane * 4);
  ushort4 h4, l4;
  split2((v4.x - mean) * rstd * g4.x + b4.x, h4.x, l4.x);
  split2((v4.y - mean) * rstd * g4.y + b4.y, h4.y, l4.y);
  split2((v4.z - mean) * rstd * g4.z + b4.z, h4.z, l4.z);
  split2((v4.w - mean) * rstd * g4.w + b4.w, h4.w, l4.w);
  int bg = token >> 10, nt = (token >> 4) & 63, lr = token & 15;
  int kc = lane >> 3, lu_f = (lane >> 1) & 3, j0 = (lane & 1) * 4;
  size_t base = ((((size_t)(bg * 64 + nt)) * 8 + kc) * 64 + lu_f * 16 + lr) * 8 + j0;
  *(ushort4*)(dh + base) = h4;
  *(ushort4*)(dl + base) = l4;
}

// ============ MitBlock attention (MFMA, d=32), epilogue -> B-frags ============
__global__ __launch_bounds__(256)
void k_mbattn_mfma(const ushort* __restrict__ Qh, const ushort* __restrict__ Ql,
                   const ushort* __restrict__ Kh, const ushort* __restrict__ Kl,
                   const ushort* __restrict__ Vh, const ushort* __restrict__ Vl,
                   ushort* __restrict__ ofh, ushort* __restrict__ ofl) {
  int qb = blockIdx.x & 15, bgh = blockIdx.x >> 4;
  int tid = threadIdx.x, w = tid >> 6, l = tid & 63, lr = l & 15, lu = l >> 4;
  int qt = qb * 4 + w;
  bf16x8 qh = ((const bf16x8*)Qh)[(size_t)(bgh * 64 + qt) * 64 + l];
  bf16x8 ql = ((const bf16x8*)Ql)[(size_t)(bgh * 64 + qt) * 64 + l];
  __shared__ ushort Ph[4][16][72];
  __shared__ ushort Pl[4][16][72];
  f32x4 zero = {0.f, 0.f, 0.f, 0.f};
  f32x4 oacc[2] = {zero, zero};
  float den = 0.f;
  for (int kb = 0; kb < 16; ++kb) {
#pragma unroll
    for (int kt4 = 0; kt4 < 4; ++kt4) {
      int kt = kb * 4 + kt4;
      bf16x8 kh = ((const bf16x8*)Kh)[(size_t)(bgh * 64 + kt) * 64 + l];
      bf16x8 kl = ((const bf16x8*)Kl)[(size_t)(bgh * 64 + kt) * 64 + l];
      f32x4 s = zero;
      s = __builtin_amdgcn_mfma_f32_16x16x32_bf16(kh, qh, s, 0, 0, 0);
      s = __builtin_amdgcn_mfma_f32_16x16x32_bf16(kh, ql, s, 0, 0, 0);
      s = __builtin_amdgcn_mfma_f32_16x16x32_bf16(kl, qh, s, 0, 0, 0);
      uint2 uh, ul;
      {
        float p0 = __expf(s[0]), p1 = __expf(s[1]), p2 = __expf(s[2]), p3 = __expf(s[3]);
        den += (p0 + p1) + (p2 + p3);
        ushort h0, l0, h1, l1, h2, l2, h3, l3;
        split2(p0, h0, l0); split2(p1, h1, l1); split2(p2, h2, l2); split2(p3, h3, l3);
        uh.x = (unsigned)h0 | ((unsigned)h1 << 16); uh.y = (unsigned)h2 | ((unsigned)h3 << 16);
        ul.x = (unsigned)l0 | ((unsigned)l1 << 16); ul.y = (unsigned)l2 | ((unsigned)l3 << 16);
      }
      *(uint2*)&Ph[w][lr][kt4 * 16 + lu * 4] = uh;
      *(uint2*)&Pl[w][lr][kt4 * 16 + lu * 4] = ul;
    }
#pragma unroll
    for (int kc2 = 0; kc2 < 2; ++kc2) {
      int kc = kb * 2 + kc2;
      bf16x8 bph = *(const bf16x8*)&Ph[w][lr][kc2 * 32 + lu * 8];
      bf16x8 bpl = *(const bf16x8*)&Pl[w][lr][kc2 * 32 + lu * 8];
#pragma unroll
      for (int et = 0; et < 2; ++et) {
        bf16x8 vh = ((const bf16x8*)Vh)[(size_t)((bgh * 2 + et) * 32 + kc) * 64 + l];
        bf16x8 vl = ((const bf16x8*)Vl)[(size_t)((bgh * 2 + et) * 32 + kc) * 64 + l];
        oacc[et] = __builtin_amdgcn_mfma_f32_16x16x32_bf16(vh, bph, oacc[et], 0, 0, 0);
        oacc[et] = __builtin_amdgcn_mfma_f32_16x16x32_bf16(vh, bpl, oacc[et], 0, 0, 0);
        oacc[et] = __builtin_amdgcn_mfma_f32_16x16x32_bf16(vl, bph, oacc[et], 0, 0, 0);
      }
    }
  }
  den += __shfl_xor(den, 16);
  den += __shfl_xor(den, 32);
  float inv = 1.f / den;
  int bg = bgh >> 3, hh = bgh & 7;
#pragma unroll
  for (int et = 0; et < 2; ++et) {
    ushort4 h4, l4;
    split2(oacc[et][0] * inv, h4.x, l4.x); split2(oacc[et][1] * inv, h4.y, l4.y);
    split2(oacc[et][2] * inv, h4.z, l4.z); split2(oacc[et][3] * inv, h4.w, l4.w);
    int lu_f = et * 2 + (lu >> 1), j0 = (lu & 1) * 4;
    size_t base = ((((size_t)(bg * 64 + qt)) * 8 + hh) * 64 + lu_f * 16 + lr) * 8 + j0;
    *(ushort4*)(ofh + base) = h4;
    *(ushort4*)(ofl + base) = l4;
  }
}

// ============ main attention (MFMA, d=64), epilogue -> B-frags (KC=16) ========
__global__ __launch_bounds__(256)
void k_mainattn_mfma(const ushort* __restrict__ Qh, const ushort* __restrict__ Ql,
                     const ushort* __restrict__ Kh, const ushort* __restrict__ Kl,
                     const ushort* __restrict__ Vh, const ushort* __restrict__ Vl,
                     ushort* __restrict__ anfh, ushort* __restrict__ anfl) {
  int qb = blockIdx.x & 15, bh = blockIdx.x >> 4;
  int tid = threadIdx.x, w = tid >> 6, l = tid & 63, lr = l & 15, lu = l >> 4;
  int qt = qb * 4 + w;
  bf16x8 qh[2], ql[2];
#pragma unroll
  for (int dc = 0; dc < 2; ++dc) {
    qh[dc] = ((const bf16x8*)Qh)[(size_t)((bh * 64 + qt) * 2 + dc) * 64 + l];
    ql[dc] = ((const bf16x8*)Ql)[(size_t)((bh * 64 + qt) * 2 + dc) * 64 + l];
  }
  __shared__ ushort Ph[4][16][72];
  __shared__ ushort Pl[4][16][72];
  f32x4 zero = {0.f, 0.f, 0.f, 0.f};
  f32x4 oacc[4] = {zero, zero, zero, zero};
  float den = 0.f;
  for (int kb = 0; kb < 16; ++kb) {
#pragma unroll
    for (int kt4 = 0; kt4 < 4; ++kt4) {
      int kt = kb * 4 + kt4;
      f32x4 s = zero;
#pragma unroll
      for (int dc = 0; dc < 2; ++dc) {
        bf16x8 kh = ((const bf16x8*)Kh)[(size_t)((bh * 64 + kt) * 2 + dc) * 64 + l];
        bf16x8 kl = ((const bf16x8*)Kl)[(size_t)((bh * 64 + kt) * 2 + dc) * 64 + l];
        s = __builtin_amdgcn_mfma_f32_16x16x32_bf16(kh, qh[dc], s, 0, 0, 0);
        s = __builtin_amdgcn_mfma_f32_16x16x32_bf16(kh, ql[dc], s, 0, 0, 0);
        s = __builtin_amdgcn_mfma_f32_16x16x32_bf16(kl, qh[dc], s, 0, 0, 0);
      }
      uint2 uh, ul;
      {
        float p0 = __expf(s[0]), p1 = __expf(s[1]), p2 = __expf(s[2]), p3 = __expf(s[3]);
        den += (p0 + p1) + (p2 + p3);
        ushort h0, l0, h1, l1, h2, l2, h3, l3;
        split2(p0, h0, l0); split2(p1, h1, l1); split2(p2, h2, l2); split2(p3, h3, l3);
        uh.x = (unsigned)h0 | ((unsigned)h1 << 16); uh.y = (unsigned)h2 | ((unsigned)h3 << 16);
        ul.x = (unsigned)l0 | ((unsigned)l1 << 16); ul.y = (unsigned)l2 | ((unsigned)l3 << 16);
      }
      *(uint2*)&Ph[w][lr][kt4 * 16 + lu * 4] = uh;
      *(uint2*)&Pl[w][lr][kt4 * 16 + lu * 4] = ul;
    }
#pragma unroll
    for (int kc2 = 0; kc2 < 2; ++kc2) {
      int kc = kb * 2 + kc2;
      bf16x8 bph = *(const bf16x8*)&Ph[w][lr][kc2 * 32 + lu * 8];
      bf16x8 bpl = *(const bf16x8*)&Pl[w][lr][kc2 * 32 + lu * 8];
#pragma unroll
      for (int et = 0; et < 4; ++et) {
        bf16x8 vh = ((const bf16x8*)Vh)[(size_t)((bh * 4 + et) * 32 + kc) * 64 + l];
        bf16x8 vl = ((const bf16x8*)Vl)[(size_t)((bh * 4 + et) * 32 + kc) * 64 + l];
        oacc[et] = __builtin_amdgcn_mfma_f32_16x16x32_bf16(vh, bph, oacc[et], 0, 0, 0);
        oacc[et] = __builtin_amdgcn_mfma_f32_16x16x32_bf16(vh, bpl, oacc[et], 0, 0, 0);
        oacc[et] = __builtin_amdgcn_mfma_f32_16x16x32_bf16(vl, bph, oacc[et], 0, 0, 0);
      }
    }
  }
  den += __shfl_xor(den, 16);
  den += __shfl_xor(den, 32);
  float inv = 1.f / den;
  int b = bh >> 3, h = bh & 7;
#pragma unroll
  for (int et = 0; et < 4; ++et) {
    ushort4 h4, l4;
    split2(oacc[et][0] * inv, h4.x, l4.x); split2(oacc[et][1] * inv, h4.y, l4.y);
    split2(oacc[et][2] * inv, h4.z, l4.z); split2(oacc[et][3] * inv, h4.w, l4.w);
    int kc = h * 2 + (et >> 1);
    int lu_f = (et & 1) * 2 + (lu >> 1), j0 = (lu & 1) * 4;
    size_t base = ((((size_t)(b * 64 + qt)) * 16 + kc) * 64 + lu_f * 16 + lr) * 8 + j0;
    *(ushort4*)(anfh + base) = h4;
    *(ushort4*)(anfl + base) = l4;
  }
}

// ---------------- FUSED dw3 + GELU -> fc2 B-frags directly
// thread = pixel, 8 consecutive channels; frag word = ushort8 contiguous.
__global__ void k_dw3_frag(const float* __restrict__ X, const float* __restrict__ w,
                           const float* __restrict__ bias,
                           ushort* __restrict__ dh, ushort* __restrict__ dl) {
  int bid = blockIdx.x;               // 4096 = bg(8) x chg(128) x pch(4)
  int pch = bid & 3; bid >>= 2;
  int chg = bid & 127; int bg = bid >> 7;
  int tid = threadIdx.x;
  int n = pch * 256 + tid;            // pixel [0,1024)
  int x = n & 31, y = n >> 5;
  int ch0 = chg * 8;
  V16u hi, lo;
#pragma unroll
  for (int jj = 0; jj < 8; ++jj) {
    int ch = ch0 + jj;
    const float* src = X + ((size_t)((bg << 10) + ch)) * HW;
    const float* wr = w + ch * 9;
    float acc = bias[ch];
#pragma unroll
    for (int ky = 0; ky < 3; ++ky) {
      int yy = y + ky - 1;
      if ((unsigned)yy < 32u) {
        const float* row = src + yy * 32;
#pragma unroll
        for (int kx = 0; kx < 3; ++kx) {
          int xx = x + kx - 1;
          if ((unsigned)xx < 32u) acc += row[xx] * wr[ky * 3 + kx];
        }
      }
    }
    split2(gelu_exact(acc), hi.u[jj], lo.u[jj]);
  }
  // fc2 B-frag (K=1024, KC=32): kc=ch0>>5, lu_f=(ch0>>3)&3, j=0..7
  size_t base = ((((size_t)(bg * 64 + (n >> 4)) * 32 + (ch0 >> 5)) * 64)
                 + ((ch0 >> 3) & 3) * 16 + (n & 15)) * 8;
  *(int4*)(dh + base) = hi.i4;
  *(int4*)(dl + base) = lo.i4;
}

// ---------------- depthwise 9x9 pad 4 on nc layout
__global__ void k_dw9_nc(const float* __restrict__ Xnc, const float* __restrict__ wt9,
                         const float* __restrict__ bias, float* __restrict__ Ync) {
  int bid = blockIdx.x;
  int pt = bid & 127; int bg = bid >> 7;
  int tid = threadIdx.x;
  int y = pt >> 2, x0 = (pt & 3) * 8;
  float acc[8];
  float bs = bias[tid];
#pragma unroll
  for (int p = 0; p < 8; ++p) acc[p] = bs;
  const float* src = Xnc + (size_t)(bg << 10) * 256;
  for (int ky = 0; ky < 9; ++ky) {
    int yy = y + ky - 4;
    if ((unsigned)yy >= 32u) continue;
#pragma unroll
    for (int kx = 0; kx < 9; ++kx) {
      float wv = wt9[(ky * 9 + kx) * 256 + tid];
#pragma unroll
      for (int p = 0; p < 8; ++p) {
        int xx = x0 + p + kx - 4;
        if ((unsigned)xx < 32u)
          acc[p] += src[(size_t)(yy * 32 + xx) * 256 + tid] * wv;
      }
    }
  }
#pragma unroll
  for (int p = 0; p < 8; ++p)
    Ync[((size_t)((bg << 10) + y * 32 + x0 + p)) * 256 + tid] = acc[p];
}

// ---------------- co tail on nc layout: wave per token
__global__ void k_cotail_nc(const float* __restrict__ Xnc, const float* __restrict__ lnw,
                            const float* __restrict__ lnb, const float* __restrict__ w2,
                            float* __restrict__ pos) {
  int token = (blockIdx.x * 256 + threadIdx.x) >> 6;
  int lane = threadIdx.x & 63;
  float4 v4 = *(const float4*)(Xnc + (size_t)token * 256 + lane * 4);
  float s = v4.x + v4.y + v4.z + v4.w;
  float s2 = v4.x * v4.x + v4.y * v4.y + v4.z * v4.z + v4.w * v4.w;
#pragma unroll
  for (int off = 32; off; off >>= 1) { s += __shfl_xor(s, off); s2 += __shfl_xor(s2, off); }
  float mean = s * (1.f / 256.f);
  float rstd = rsqrtf(s2 * (1.f / 256.f) - mean * mean + 1e-5f);
  float4 g4 = *(const float4*)(lnw + lane * 4);
  float4 b4 = *(const float4*)(lnb + lane * 4);
  float4 wa = *(const float4*)(w2 + lane * 4);
  float4 wb = *(const float4*)(w2 + 256 + lane * 4);
  float ge0 = gelu_exact((v4.x - mean) * rstd * g4.x + b4.x);
  float ge1 = gelu_exact((v4.y - mean) * rstd * g4.y + b4.y);
  float ge2 = gelu_exact((v4.z - mean) * rstd * g4.z + b4.z);
  float ge3 = gelu_exact((v4.w - mean) * rstd * g4.w + b4.w);
  float o0 = ge0 * wa.x + ge1 * wa.y + ge2 * wa.z + ge3 * wa.w;
  float o1 = ge0 * wb.x + ge1 * wb.y + ge2 * wb.z + ge3 * wb.w;
#pragma unroll
  for (int off = 32; off; off >>= 1) { o0 += __shfl_xor(o0, off); o1 += __shfl_xor(o1, off); }
  if (lane == 0) {
    float offy = tanhf(o0) * (2.f / 32.f);
    float offx = tanhf(o1) * (2.f / 32.f);
    int n = token & 1023;
    int ky = n >> 5, kx = n & 31;
    float refy = ((ky + 0.5f) * (1.f / 32.f)) * 2.f - 1.f;
    float refx = ((kx + 0.5f) * (1.f / 32.f)) * 2.f - 1.f;
    pos[token * 2] = offx + refx;
    pos[token * 2 + 1] = offy + refy;
  }
}

// ---------------- FUSED bilinear grid sample -> kv-GEMM B-frags directly
__global__ void k_gsample_frag(const float* __restrict__ Xnc, const float* __restrict__ pos,
                               ushort* __restrict__ dh, ushort* __restrict__ dl) {
  int bid = blockIdx.x;               // 128 = bg(8) x nch(16)
  int nch = bid & 15; int bg = bid >> 4;
  int tid = threadIdx.x;              // channel c [0,256)
  __shared__ int sI[4][64];
  __shared__ float sW[4][64];
  if (tid < 64) {
    int j = nch * 64 + tid;
    float gx = pos[((bg << 10) + j) * 2];
    float gy = pos[((bg << 10) + j) * 2 + 1];
    float fx = (gx + 1.f) * 0.5f * 31.f;
    float fy = (gy + 1.f) * 0.5f * 31.f;
    float x0f = floorf(fx), y0f = floorf(fy);
    int x0 = (int)x0f, y0 = (int)y0f;
    float wx1 = fx - x0f, wx0 = 1.f - wx1;
    float wy1 = fy - y0f, wy0 = 1.f - wy1;
    bool vx0 = (x0 >= 0) & (x0 <= 31);
    bool vx1 = (x0 + 1 >= 0) & (x0 + 1 <= 31);
    bool vy0 = (y0 >= 0) & (y0 <= 31);
    bool vy1 = (y0 + 1 >= 0) & (y0 + 1 <= 31);
    int cx0 = min(max(x0, 0), 31), cx1 = min(max(x0 + 1, 0), 31);
    int cy0 = min(max(y0, 0), 31), cy1 = min(max(y0 + 1, 0), 31);
    sW[0][tid] = wx0 * wy0 * ((vx0 && vy0) ? 1.f : 0.f);
    sW[1][tid] = wx1 * wy0 * ((vx1 && vy0) ? 1.f : 0.f);
    sW[2][tid] = wx0 * wy1 * ((vx0 && vy1) ? 1.f : 0.f);
    sW[3][tid] = wx1 * wy1 * ((vx1 && vy1) ? 1.f : 0.f);
    sI[0][tid] = cy0 * 32 + cx0; sI[1][tid] = cy0 * 32 + cx1;
    sI[2][tid] = cy1 * 32 + cx0; sI[3][tid] = cy1 * 32 + cx1;
  }
  __syncthreads();
  int b = bg >> 1, g = bg & 1;
  const float* src = Xnc + (size_t)(bg << 10) * 256;
  for (int nn = 0; nn < 64; ++nn) {
    float acc = src[(size_t)sI[0][nn] * 256 + tid] * sW[0][nn]
              + src[(size_t)sI[1][nn] * 256 + tid] * sW[1][nn]
              + src[(size_t)sI[2][nn] * 256 + tid] * sW[2][nn]
              + src[(size_t)sI[3][nn] * 256 + tid] * sW[3][nn];
    ushort h, l; split2(acc, h, l);
    int jglob = nch * 64 + nn;
    // kv B-frag (K=512, KC=16): k = g*256 + c
    size_t addr = ((((size_t)(b * 64 + (jglob >> 4)) * 16) + g * 8 + (tid >> 5)) * 64
                   + ((tid >> 3) & 3) * 16 + (jglob & 15)) * 8 + (tid & 7);
    dh[addr] = h; dl[addr] = l;
  }
}

// ---------------------------------------------------------------------------
extern "C" void kernel_launch(void* const* d_in, const int* in_sizes, int n_in,
                              void* d_out, int out_size, void* d_ws, size_t ws_size,
                              hipStream_t stream) {
  const float* tgt    = (const float*)d_in[0];
  const float* refp   = (const float*)d_in[1];
  const float* emb_w  = (const float*)d_in[2];
  const float* emb_b  = (const float*)d_in[3];
  const float* q_w    = (const float*)d_in[4];
  const float* q_b    = (const float*)d_in[5];
  const float* k_w    = (const float*)d_in[6];
  const float* k_b    = (const float*)d_in[7];
  const float* v_w    = (const float*)d_in[8];
  const float* v_b    = (const float*)d_in[9];
  const float* out_w  = (const float*)d_in[10];
  const float* out_b  = (const float*)d_in[11];
  const float* ln1_w  = (const float*)d_in[12];
  const float* ln1_b  = (const float*)d_in[13];
  const float* n1_w   = (const float*)d_in[14];
  const float* n1_b   = (const float*)d_in[15];
  const float* mbq_w  = (const float*)d_in[16];
  const float* mbq_b  = (const float*)d_in[17];
  const float* mbkv_w = (const float*)d_in[18];
  const float* mbkv_b = (const float*)d_in[19];
  const float* mbp_w  = (const float*)d_in[20];
  const float* mbp_b  = (const float*)d_in[21];
  const float* n2_w   = (const float*)d_in[22];
  const float* n2_b   = (const float*)d_in[23];
  const float* fc1_w  = (const float*)d_in[24];
  const float* fc1_b  = (const float*)d_in[25];
  const float* dw3_w  = (const float*)d_in[26];
  const float* dw3_b  = (const float*)d_in[27];
  const float* fc2_w  = (const float*)d_in[28];
  const float* fc2_b  = (const float*)d_in[29];
  const float* dw9_w  = (const float*)d_in[30];
  const float* dw9_b  = (const float*)d_in[31];
  const float* coln_w = (const float*)d_in[32];
  const float* coln_b = (const float*)d_in[33];
  const float* coout_w= (const float*)d_in[34];

  float* ws = (float*)d_ws;
  float* slabA = ws + 0;
  float* qfrag = ws + 2097152;      // main Q frags (hi+lo), persists to step 16
  float* xbuf  = ws + 4194304;
  float* slabD = ws + 6291456;
  float* slabE = ws + 8388608;
  float* slabF = ws + 10485760;
  float* slabG = ws + 14680064;
  float* slabH = ws + 23068672;
  float* featnc= ws + 31457280;
  float* posb  = ws + 35389440;
  float* wt9   = ws + 35405824;
  float* biasmb= ws + 35426560;
  float* biaskv= ws + 35427328;
  float* biasq = ws + 35428352;

  ushort* XtH = (ushort*)(ws + 4194304);
  ushort* XtL = XtH + 4734976;
  ushort* WtEH = (ushort*)slabG;
  ushort* WtEL = WtEH + 4718592;
  float* part = slabH;
  ushort* tgtfh = (ushort*)slabF;
  ushort* tgtfl = tgtfh + 2097152;

  // weight frags (slab J)
  ushort* J = (ushort*)(ws + 33554432);
  ushort* wfq_h   = J;                ushort* wfq_l   = J + 262144;
  ushort* wfkv_h  = J + 524288;       ushort* wfkv_l  = J + 1048576;
  ushort* wfo_h   = J + 1572864;      ushort* wfo_l   = J + 1835008;
  ushort* wfmqkv_h= J + 2097152;      ushort* wfmqkv_l= J + 2293760;
  ushort* wfmp_h  = J + 2490368;      ushort* wfmp_l  = J + 2555904;
  ushort* wff1_h  = J + 2621440;      ushort* wff1_l  = J + 2883584;
  ushort* wff2_h  = J + 3145728;      ushort* wff2_l  = J + 3407872;

  // phase pointers
  ushort* hfh = (ushort*)slabH;     ushort* hfl = hfh + 2097152;   // n1 frags (part dead)
  ushort* mQh = (ushort*)slabG;     ushort* mQl = mQh + 2097152;
  ushort* mKh = mQh + 4194304;      ushort* mKl = mQh + 6291456;
  ushort* mVh = mQh + 8388608;      ushort* mVl = mQh + 10485760;
  ushort* ofh = (ushort*)slabF;     ushort* ofl = ofh + 2097152;   // mb out frags
  float* P_cm = slabD;
  ushort* h2fh = (ushort*)slabF;    ushort* h2fl = h2fh + 2097152;
  float* m_cm = slabG;
  // R12: dw3_frag reads m_cm (slabG) and writes mi frags -> slabH (disjoint).
  ushort* mifh = (ushort*)slabH;    ushort* mifl = mifh + 8388608;
  float* ygemm = slabD;
  float* offin = slabA;
  float* offdwnc = slabE;
  ushort* sfh = (ushort*)slabF;     ushort* sfl = sfh + 2097152;
  ushort* aQh = (ushort*)qfrag;     ushort* aQl = aQh + 2097152;   // main Q frags
  ushort* aKh = (ushort*)slabG;     ushort* aKl = aKh + 2097152;   // main K/V frags
  ushort* aVh = aKh + 4194304;      ushort* aVl = aKh + 6291456;
  ushort* anfh = (ushort*)slabH;    ushort* anfl = anfh + 2097152;

  // --- step 0: mega-prep + tgt frags ---
  k_prep_all<<<5346, 256, 0, stream>>>(
      emb_w, tgt, refp, q_w, k_w, v_w, out_w, mbq_w, mbkv_w, mbp_w, fc1_w, fc2_w,
      dw9_w, q_b, mbq_b, mbkv_b, k_b, v_b,
      WtEH, WtEL, XtH, XtL,
      wfq_h, wfq_l, wfkv_h, wfkv_l, wfo_h, wfo_l, wfmqkv_h, wfmqkv_l,
      wfmp_h, wfmp_l, wff1_h, wff1_l, wff2_h, wff2_l,
      wt9, biasmb, biaskv, biasq);
  k_prep_cm2frag<<<1024, 256, 0, stream>>>(tgt, 512, 16, tgtfh, tgtfl);
  // --- step 1: emb conv + merge ---
  k_emb_mfma<<<512, 256, 0, stream>>>(XtH, XtL, WtEH, WtEL, part);
  k_embmerge_nc<<<512, 256, 0, stream>>>(part, emb_b, featnc);
  // --- step 2: q proj -> main Q frags directly (scale folded) ---
  k_gemm_frag_main<<<512, 256, 0, stream>>>(wfq_h, wfq_l, tgtfh, tgtfl, biasq,
                                            aQh, aQl, aVh, aVl, 512, 16, 8);
  // --- step 3+4: fused ln1 -> xbuf + n1 -> frags (slabH) ---
  k_ln1n1<<<2048, 256, 0, stream>>>(featnc, ln1_w, ln1_b, n1_w, n1_b, xbuf, hfh, hfl);
  // --- step 5+6a: mqkv GEMM -> mb Q/K/V frags directly ---
  k_gemm_frag_mb<<<1536, 256, 0, stream>>>(wfmqkv_h, wfmqkv_l, hfh, hfl, biasmb,
                                           mQh, mQl, mKh, mKl, mVh, mVl);
  // --- step 6: mb attention ---
  k_mbattn_mfma<<<1024, 256, 0, stream>>>(mQh, mQl, mKh, mKl, mVh, mVl, ofh, ofl);
  // --- step 7: mbproj + residual ---
  k_gemm_mfma<<<512, 256, 0, stream>>>(wfmp_h, wfmp_l, ofh, ofl, mbp_b, P_cm, 8, 4, 256);
  k_transadd_tm<<<512, 256, 0, stream>>>(P_cm, xbuf);
  // --- step 8: n2 -> h2 frags ---
  k_ln_frag<<<2048, 256, 0, stream>>>(xbuf, n2_w, n2_b, h2fh, h2fl, 1e-6f);
  // --- step 9: fc1 -> m_cm (slabG) ---
  k_gemm_mfma<<<2048, 256, 0, stream>>>(wff1_h, wff1_l, h2fh, h2fl, fc1_b, m_cm, 8, 16, 1024);
  // --- step 10: dw3 + gelu -> fc2 B-frags directly (slabH) ---
  k_dw3_frag<<<4096, 256, 0, stream>>>(m_cm, dw3_w, dw3_b, mifh, mifl);
  // --- step 11: fc2 + residual -> offin nc ---
  k_gemm_mfma<<<512, 256, 0, stream>>>(wff2_h, wff2_l, mifh, mifl, fc2_b, ygemm, 32, 4, 256);
  k_transadd_nc<<<512, 256, 0, stream>>>(ygemm, xbuf, offin);
  // --- step 12: dw9 ---
  k_dw9_nc<<<1024, 256, 0, stream>>>(offin, wt9, dw9_b, offdwnc);
  // --- step 13: cotail ---
  k_cotail_nc<<<2048, 256, 0, stream>>>(offdwnc, coln_w, coln_b, coout_w, posb);
  // --- step 14+15a: grid sample -> kv B-frags directly (slabF) ---
  k_gsample_frag<<<128, 256, 0, stream>>>(featnc, posb, sfh, sfl);
  // --- step 15+16a: k+v GEMM -> main K frags + V^T frags directly ---
  k_gemm_frag_main<<<1024, 256, 0, stream>>>(wfkv_h, wfkv_l, sfh, sfl, biaskv,
                                             aKh, aKl, aVh, aVl, 512, 16, 16);
  // --- step 16: main attention ---
  k_mainattn_mfma<<<512, 256, 0, stream>>>(aQh, aQl, aKh, aKl, aVh, aVl, anfh, anfl);
  // --- step 17: out proj -> d_out ---
  k_gemm_mfma<<<512, 256, 0, stream>>>(wfo_h, wfo_l, anfh, anfl, out_b, (float*)d_out, 16, 8, 512);
}